// Round 17
// baseline (1370.257 us; speedup 1.0000x reference)
//
#include <hip/hip_runtime.h>
#include <math.h>

#define BB 64
#define LL 2048
#define CC 128
#define HH 128
#define KK 64
#define PP 336
#define EPSf 1e-5f

typedef __attribute__((ext_vector_type(8))) short short8v;
typedef __attribute__((ext_vector_type(4))) float float4v;

__device__ inline ushort f2bf(float f) {
    union { float f; unsigned u; } v; v.f = f;
    unsigned r = (v.u + 0x7FFFu + ((v.u >> 16) & 1u)) >> 16;
    return (ushort)r;
}
__device__ inline float bf2f(ushort h) {
    union { unsigned u; float f; } v; v.u = ((unsigned)h) << 16;
    return v.f;
}

// exact-GELU via Abramowitz-Stegun 7.1.26 erf (|err| <= 1.5e-7)
__device__ inline float fast_gelu(float v) {
    float x = 0.70710678118654752f * v;
    float ax = fabsf(x);
    float t = 1.f / fmaf(0.3275911f, ax, 1.f);
    float p = t * fmaf(t, fmaf(t, fmaf(t, fmaf(t, 1.061405429f, -1.453152027f),
                                       1.421413741f), -0.284496736f), 0.254829592f);
    float er = fmaf(-p, __expf(-ax * ax), 1.f);
    er = (x < 0.f) ? -er : er;
    return 0.5f * v * (1.f + er);
}

// async 16B global -> LDS (wave-uniform LDS base + lane*16, per-lane global src)
__device__ __forceinline__ void async16(const ushort* g, ushort* l) {
    __builtin_amdgcn_global_load_lds(
        (const __attribute__((address_space(1))) void*)g,
        (__attribute__((address_space(3))) void*)l, 16, 0, 0);
}

// ---------------------------------------------------------------------------
// RevIN column stats, two-stage. part: grid (8, B), block 256.
// ---------------------------------------------------------------------------
__global__ __launch_bounds__(256)
void colstats_part_kernel(const float* __restrict__ x, float* __restrict__ part) {
    int b = blockIdx.y, chunk = blockIdx.x;
    int t = threadIdx.x;
    int c4 = (t & 31) * 4, rg = t >> 5;
    const float* xb = x + ((size_t)b * LL + chunk * 256) * CC;
    float4 s = make_float4(0.f, 0.f, 0.f, 0.f);
    float4 q = make_float4(0.f, 0.f, 0.f, 0.f);
    for (int l = rg; l < 256; l += 8) {
        float4 v = *(const float4*)(xb + (size_t)l * CC + c4);
        s.x += v.x; s.y += v.y; s.z += v.z; s.w += v.w;
        q.x += v.x * v.x; q.y += v.y * v.y; q.z += v.z * v.z; q.w += v.w * v.w;
    }
    __shared__ float ls[8][128];
    __shared__ float lq[8][128];
    *(float4*)&ls[rg][c4] = s;
    *(float4*)&lq[rg][c4] = q;
    __syncthreads();
    if (t < 128) {
        float a = 0.f, d = 0.f;
        #pragma unroll
        for (int i = 0; i < 8; ++i) { a += ls[i][t]; d += lq[i][t]; }
        part[((size_t)b * 8 + chunk) * 256 + t] = a;
        part[((size_t)b * 8 + chunk) * 256 + 128 + t] = d;
    }
}

__global__ void colstats_final_kernel(const float* __restrict__ part, float* __restrict__ mean,
                                      float* __restrict__ rstd, float* __restrict__ stdv) {
    int b = blockIdx.x, c = threadIdx.x;
    float s = 0.f, q = 0.f;
    #pragma unroll
    for (int i = 0; i < 8; ++i) {
        s += part[((size_t)b * 8 + i) * 256 + c];
        q += part[((size_t)b * 8 + i) * 256 + 128 + c];
    }
    float mu = s * (1.f / LL);
    float var = q * (1.f / LL) - mu * mu;
    var = fmaxf(var, 0.f);
    float sd = sqrtf(var + EPSf);
    mean[b * CC + c] = mu;
    stdv[b * CC + c] = sd;
    rstd[b * CC + c] = 1.f / sd;
}

__global__ void colstats2_final_kernel(const float* __restrict__ cpart, float* __restrict__ mean,
                                       float* __restrict__ rstd, float* __restrict__ stdv) {
    int b = blockIdx.x, c = threadIdx.x;
    float s = 0.f, q = 0.f;
    #pragma unroll
    for (int i = 0; i < 16; ++i) {
        s += cpart[((size_t)b * 16 + i) * 256 + c];
        q += cpart[((size_t)b * 16 + i) * 256 + 128 + c];
    }
    float mu = s * (1.f / LL);
    float var = q * (1.f / LL) - mu * mu;
    var = fmaxf(var, 0.f);
    float sd = sqrtf(var + EPSf);
    mean[b * CC + c] = mu;
    stdv[b * CC + c] = sd;
    rstd[b * CC + c] = 1.f / sd;
}

// rn[i] = 1/(sqrt(rowsumsq)+1e-8); grid 512, block 256
__global__ void rn_final_kernel(const float* __restrict__ rsq, float* __restrict__ rn) {
    size_t i = (size_t)blockIdx.x * 256 + threadIdx.x;
    rn[i] = 1.f / (sqrtf(rsq[i]) + 1e-8f);
}

// ---------------------------------------------------------------------------
// plain f32 VALU GEMM (tiny Q-GEMM only)
// ---------------------------------------------------------------------------
__global__ __launch_bounds__(256)
void gemm_kernel(const float* __restrict__ A, const float* __restrict__ W,
                 const float* __restrict__ bias, float* __restrict__ Out,
                 int M, int N, int Kd, int lda, int ldw, int ldo) {
    __shared__ float As[32][128];
    __shared__ float Ws[32][128];
    int tid = threadIdx.x;
    int tx = tid & 15, ty = tid >> 4;
    int n0 = blockIdx.x * 128;
    int m0 = blockIdx.y * 128;
    float acc[8][8] = {};

    for (int kt = 0; kt < Kd; kt += 32) {
        __syncthreads();
        #pragma unroll
        for (int it = 0; it < 4; ++it) {
            int q = tid + it * 256;
            int row = q >> 3;
            int kq = (q & 7) << 2;
            float4 v = make_float4(0.f, 0.f, 0.f, 0.f);
            int m = m0 + row;
            if (m < M) v = *(const float4*)(A + (size_t)m * lda + kt + kq);
            As[kq    ][row] = v.x;
            As[kq + 1][row] = v.y;
            As[kq + 2][row] = v.z;
            As[kq + 3][row] = v.w;
        }
        #pragma unroll
        for (int it = 0; it < 4; ++it) {
            int q = tid + it * 256;
            int kr = q >> 5;
            int nc = (q & 31) << 2;
            int n = n0 + nc;
            float4 v = make_float4(0.f, 0.f, 0.f, 0.f);
            if (n < N) v = *(const float4*)(W + (size_t)(kt + kr) * ldw + n);
            *(float4*)&Ws[kr][nc] = v;
        }
        __syncthreads();
        #pragma unroll
        for (int k = 0; k < 32; ++k) {
            float a[8], w[8];
            *(float4*)&a[0] = *(const float4*)&As[k][ty * 8];
            *(float4*)&a[4] = *(const float4*)&As[k][ty * 8 + 4];
            *(float4*)&w[0] = *(const float4*)&Ws[k][tx * 4];
            *(float4*)&w[4] = *(const float4*)&Ws[k][64 + tx * 4];
            #pragma unroll
            for (int i = 0; i < 8; ++i)
                #pragma unroll
                for (int j = 0; j < 8; ++j)
                    acc[i][j] = fmaf(a[i], w[j], acc[i][j]);
        }
    }

    #pragma unroll
    for (int i = 0; i < 8; ++i) {
        int m = m0 + ty * 8 + i;
        if (m >= M) continue;
        #pragma unroll
        for (int jj = 0; jj < 8; jj += 4) {
            int n = n0 + (jj ? 64 + tx * 4 : tx * 4);
            if (n >= N) continue;
            float o[4];
            #pragma unroll
            for (int j = 0; j < 4; ++j)
                o[j] = acc[i][jj + j] + (bias ? bias[n + j] : 0.f);
            *(float4*)(Out + (size_t)m * ldo + n) = *(float4*)o;
        }
    }
}

// ---------------------------------------------------------------------------
// Split-precision MFMA GEMM for K=128 (A f32 [M][128], W split bf16 [128][128]).
// EP: 0 -> Out[m*128+n]; 2 -> Out[m*64+n] only n<64.
// ---------------------------------------------------------------------------
template <int NORM, int ACT, int EP>
__global__ __launch_bounds__(256)
void mfma_sq_kernel(const float* __restrict__ A, const ushort* __restrict__ Whi,
                    const ushort* __restrict__ Wlo, const float* __restrict__ bias,
                    float* Out,
                    const float* __restrict__ nmu, const float* __restrict__ ns,
                    const float* __restrict__ nt, int normStride,
                    ushort* __restrict__ hbOut) {
    __shared__ ushort Ahi[128][72];
    __shared__ ushort Alo[128][72];
    __shared__ ushort Bhi[128][72];
    __shared__ ushort Blo[128][72];
    int tid = threadIdx.x;
    int m0 = blockIdx.x * 128;
    int noff = (NORM == 1) ? (m0 / LL) * normStride : 0;

    int w = tid >> 6, lane = tid & 63;
    int wm = (w >> 1) * 64, wn = (w & 1) * 64;
    int col = lane & 15, kq = lane >> 4;

    float4v acc[4][4];
    #pragma unroll
    for (int i = 0; i < 4; ++i)
        #pragma unroll
        for (int j = 0; j < 4; ++j) acc[i][j] = (float4v){0.f, 0.f, 0.f, 0.f};

    for (int kt = 0; kt < 2; ++kt) {
        __syncthreads();
        #pragma unroll
        for (int it = 0; it < 4; ++it) {
            int q = tid + it * 256;
            int row = q >> 3, k0 = (q & 7) * 8;
            int kg = kt * 64 + k0;
            const float* ap = A + (size_t)(m0 + row) * 128 + kg;
            float vv[8];
            *(float4*)&vv[0] = *(const float4*)ap;
            *(float4*)&vv[4] = *(const float4*)(ap + 4);
            ushort hi[8], lo[8];
            #pragma unroll
            for (int j = 0; j < 8; ++j) {
                float v = vv[j];
                if (NORM == 1) v = (v - nmu[noff + kg + j]) * ns[noff + kg + j];
                if (NORM == 2) v = (v - nmu[kg + j]) * ns[kg + j] + nt[kg + j];
                ushort h = f2bf(v);
                hi[j] = h;
                lo[j] = f2bf(v - bf2f(h));
            }
            if (hbOut)
                *(short8v*)(hbOut + (size_t)(m0 + row) * 128 + kg) = *(short8v*)hi;
            *(short8v*)&Ahi[row][k0] = *(short8v*)hi;
            *(short8v*)&Alo[row][k0] = *(short8v*)lo;
        }
        #pragma unroll
        for (int it = 0; it < 4; ++it) {
            int q = tid + it * 256;
            int row = q >> 3, k0 = (q & 7) * 8;
            *(short8v*)&Bhi[row][k0] =
                *(const short8v*)(Whi + (size_t)row * 128 + kt * 64 + k0);
            *(short8v*)&Blo[row][k0] =
                *(const short8v*)(Wlo + (size_t)row * 128 + kt * 64 + k0);
        }
        __syncthreads();
        #pragma unroll
        for (int ksub = 0; ksub < 2; ++ksub) {
            short8v ah[4], al[4], bh[4], bl[4];
            #pragma unroll
            for (int mf = 0; mf < 4; ++mf) {
                ah[mf] = *(const short8v*)&Ahi[wm + mf * 16 + col][ksub * 32 + kq * 8];
                al[mf] = *(const short8v*)&Alo[wm + mf * 16 + col][ksub * 32 + kq * 8];
            }
            #pragma unroll
            for (int nf = 0; nf < 4; ++nf) {
                bh[nf] = *(const short8v*)&Bhi[wn + nf * 16 + col][ksub * 32 + kq * 8];
                bl[nf] = *(const short8v*)&Blo[wn + nf * 16 + col][ksub * 32 + kq * 8];
            }
            #pragma unroll
            for (int mf = 0; mf < 4; ++mf)
                #pragma unroll
                for (int nf = 0; nf < 4; ++nf)
                    acc[mf][nf] = __builtin_amdgcn_mfma_f32_16x16x32_bf16(
                        ah[mf], bh[nf], acc[mf][nf], 0, 0, 0);
            #pragma unroll
            for (int mf = 0; mf < 4; ++mf)
                #pragma unroll
                for (int nf = 0; nf < 4; ++nf)
                    acc[mf][nf] = __builtin_amdgcn_mfma_f32_16x16x32_bf16(
                        ah[mf], bl[nf], acc[mf][nf], 0, 0, 0);
            #pragma unroll
            for (int mf = 0; mf < 4; ++mf)
                #pragma unroll
                for (int nf = 0; nf < 4; ++nf)
                    acc[mf][nf] = __builtin_amdgcn_mfma_f32_16x16x32_bf16(
                        al[mf], bh[nf], acc[mf][nf], 0, 0, 0);
        }
    }

    int rbase = kq * 4;
    #pragma unroll
    for (int nf = 0; nf < 4; ++nf) {
        int n = wn + nf * 16 + col;
        if (EP == 2 && n >= 64) continue;
        float bn = bias ? bias[n] : 0.f;
        #pragma unroll
        for (int mf = 0; mf < 4; ++mf) {
            #pragma unroll
            for (int r = 0; r < 4; ++r) {
                int m = m0 + wm + mf * 16 + rbase + r;
                float v = acc[mf][nf][r] + bn;
                if (ACT == 1) v = fmaxf(v, 0.f);
                if (ACT == 2) v = fast_gelu(v);
                if (EP == 0) Out[(size_t)m * 128 + n] = v;
                else if (EP == 1) Out[(size_t)m * 128 + n] += v;
                else Out[(size_t)m * 64 + n] = v;
            }
        }
    }
}

// ---------------------------------------------------------------------------
// FUSED pair of K=128 GEMMs (PREC=1: split-precision, PREC=0: plain bf16):
// EP2: 0 store; 1 residual+= with row sum/sumsq -> rsum/rsq;
//      2 store with per-block column partials -> rsum;
//      3 store with per-row sumsq -> rsq (for rownorm)
// ---------------------------------------------------------------------------
template <int NORM, int ACT1, int ACT2, int EP2, int PREC>
__global__ __launch_bounds__(256)
void mfma_sq2_kernel(const float* __restrict__ A,
                     const ushort* __restrict__ W1h, const ushort* __restrict__ W1l,
                     const float* __restrict__ b1v,
                     const ushort* __restrict__ W2h, const ushort* __restrict__ W2l,
                     const float* __restrict__ b2v, float* Out,
                     const float* __restrict__ nmu, const float* __restrict__ ns,
                     const float* __restrict__ nt, int normStride,
                     float* __restrict__ rsum, float* __restrict__ rsq) {
    __shared__ ushort Xhi[128][72];
    __shared__ ushort Xlo[PREC ? 128 : 1][72];
    __shared__ ushort Bh[128][72];
    __shared__ ushort Bl[PREC ? 128 : 1][72];
    int tid = threadIdx.x;
    int m0 = blockIdx.x * 128;
    int noff = (NORM == 1) ? (m0 / LL) * normStride : 0;
    int w = tid >> 6, lane = tid & 63;
    int wm = (w >> 1) * 64, wn = (w & 1) * 64;
    int col = lane & 15, kq = lane >> 4;

    float4v acc[4][4];
    #pragma unroll
    for (int i = 0; i < 4; ++i)
        #pragma unroll
        for (int j = 0; j < 4; ++j) acc[i][j] = (float4v){0.f, 0.f, 0.f, 0.f};

    // ---- GEMM1 over 2 K-tiles ----
    for (int kt = 0; kt < 2; ++kt) {
        __syncthreads();
        #pragma unroll
        for (int it = 0; it < 4; ++it) {
            int q = tid + it * 256;
            int row = q >> 3, k0 = (q & 7) * 8;
            int kg = kt * 64 + k0;
            const float* ap = A + (size_t)(m0 + row) * 128 + kg;
            float vv[8];
            *(float4*)&vv[0] = *(const float4*)ap;
            *(float4*)&vv[4] = *(const float4*)(ap + 4);
            ushort hi[8], lo[8];
            #pragma unroll
            for (int j = 0; j < 8; ++j) {
                float v = vv[j];
                if (NORM == 1) v = (v - nmu[noff + kg + j]) * ns[noff + kg + j];
                if (NORM == 2) v = (v - nmu[kg + j]) * ns[kg + j] + nt[kg + j];
                ushort h = f2bf(v);
                hi[j] = h;
                if (PREC) lo[j] = f2bf(v - bf2f(h));
            }
            *(short8v*)&Xhi[row][k0] = *(short8v*)hi;
            if (PREC) *(short8v*)&Xlo[row][k0] = *(short8v*)lo;
        }
        #pragma unroll
        for (int it = 0; it < 4; ++it) {
            int q = tid + it * 256;
            int row = q >> 3, k0 = (q & 7) * 8;
            *(short8v*)&Bh[row][k0] =
                *(const short8v*)(W1h + (size_t)row * 128 + kt * 64 + k0);
            if (PREC)
                *(short8v*)&Bl[row][k0] =
                    *(const short8v*)(W1l + (size_t)row * 128 + kt * 64 + k0);
        }
        __syncthreads();
        #pragma unroll
        for (int ksub = 0; ksub < 2; ++ksub) {
            short8v ah[4], al[4], bh[4], bl[4];
            #pragma unroll
            for (int mf = 0; mf < 4; ++mf) {
                ah[mf] = *(const short8v*)&Xhi[wm + mf * 16 + col][ksub * 32 + kq * 8];
                if (PREC) al[mf] = *(const short8v*)&Xlo[wm + mf * 16 + col][ksub * 32 + kq * 8];
            }
            #pragma unroll
            for (int nf = 0; nf < 4; ++nf) {
                bh[nf] = *(const short8v*)&Bh[wn + nf * 16 + col][ksub * 32 + kq * 8];
                if (PREC) bl[nf] = *(const short8v*)&Bl[wn + nf * 16 + col][ksub * 32 + kq * 8];
            }
            #pragma unroll
            for (int mf = 0; mf < 4; ++mf)
                #pragma unroll
                for (int nf = 0; nf < 4; ++nf)
                    acc[mf][nf] = __builtin_amdgcn_mfma_f32_16x16x32_bf16(
                        ah[mf], bh[nf], acc[mf][nf], 0, 0, 0);
            if (PREC) {
                #pragma unroll
                for (int mf = 0; mf < 4; ++mf)
                    #pragma unroll
                    for (int nf = 0; nf < 4; ++nf)
                        acc[mf][nf] = __builtin_amdgcn_mfma_f32_16x16x32_bf16(
                            ah[mf], bl[nf], acc[mf][nf], 0, 0, 0);
                #pragma unroll
                for (int mf = 0; mf < 4; ++mf)
                    #pragma unroll
                    for (int nf = 0; nf < 4; ++nf)
                        acc[mf][nf] = __builtin_amdgcn_mfma_f32_16x16x32_bf16(
                            al[mf], bh[nf], acc[mf][nf], 0, 0, 0);
            }
        }
    }

    // ---- GEMM2 ----
    float4v acc2[4][4];
    #pragma unroll
    for (int i = 0; i < 4; ++i)
        #pragma unroll
        for (int j = 0; j < 4; ++j) acc2[i][j] = (float4v){0.f, 0.f, 0.f, 0.f};

    for (int kt2 = 0; kt2 < 2; ++kt2) {
        __syncthreads();
        if ((wn >> 6) == kt2) {   // wave-uniform
            #pragma unroll
            for (int nf = 0; nf < 4; ++nf) {
                float bn = b1v[wn + nf * 16 + col];
                #pragma unroll
                for (int mf = 0; mf < 4; ++mf) {
                    #pragma unroll
                    for (int r = 0; r < 4; ++r) {
                        float v = acc[mf][nf][r] + bn;
                        if (ACT1 == 1) v = fmaxf(v, 0.f);
                        if (ACT1 == 2) v = fast_gelu(v);
                        int row = wm + mf * 16 + kq * 4 + r;
                        int c2 = nf * 16 + col;
                        ushort h = f2bf(v);
                        Xhi[row][c2] = h;
                        if (PREC) Xlo[row][c2] = f2bf(v - bf2f(h));
                    }
                }
            }
        }
        #pragma unroll
        for (int it = 0; it < 4; ++it) {
            int q = tid + it * 256;
            int row = q >> 3, k0 = (q & 7) * 8;
            *(short8v*)&Bh[row][k0] =
                *(const short8v*)(W2h + (size_t)row * 128 + kt2 * 64 + k0);
            if (PREC)
                *(short8v*)&Bl[row][k0] =
                    *(const short8v*)(W2l + (size_t)row * 128 + kt2 * 64 + k0);
        }
        __syncthreads();
        #pragma unroll
        for (int ksub = 0; ksub < 2; ++ksub) {
            short8v ah[4], al[4], bh[4], bl[4];
            #pragma unroll
            for (int mf = 0; mf < 4; ++mf) {
                ah[mf] = *(const short8v*)&Xhi[wm + mf * 16 + col][ksub * 32 + kq * 8];
                if (PREC) al[mf] = *(const short8v*)&Xlo[wm + mf * 16 + col][ksub * 32 + kq * 8];
            }
            #pragma unroll
            for (int nf = 0; nf < 4; ++nf) {
                bh[nf] = *(const short8v*)&Bh[wn + nf * 16 + col][ksub * 32 + kq * 8];
                if (PREC) bl[nf] = *(const short8v*)&Bl[wn + nf * 16 + col][ksub * 32 + kq * 8];
            }
            #pragma unroll
            for (int mf = 0; mf < 4; ++mf)
                #pragma unroll
                for (int nf = 0; nf < 4; ++nf)
                    acc2[mf][nf] = __builtin_amdgcn_mfma_f32_16x16x32_bf16(
                        ah[mf], bh[nf], acc2[mf][nf], 0, 0, 0);
            if (PREC) {
                #pragma unroll
                for (int mf = 0; mf < 4; ++mf)
                    #pragma unroll
                    for (int nf = 0; nf < 4; ++nf)
                        acc2[mf][nf] = __builtin_amdgcn_mfma_f32_16x16x32_bf16(
                            ah[mf], bl[nf], acc2[mf][nf], 0, 0, 0);
                #pragma unroll
                for (int mf = 0; mf < 4; ++mf)
                    #pragma unroll
                    for (int nf = 0; nf < 4; ++nf)
                        acc2[mf][nf] = __builtin_amdgcn_mfma_f32_16x16x32_bf16(
                            al[mf], bh[nf], acc2[mf][nf], 0, 0, 0);
            }
        }
    }

    int rbase = kq * 4;
    float rs_[4][4];
    float rq_[4][4];
    float cs_[4], cq_[4];
    if (EP2 == 1 || EP2 == 3) {
        #pragma unroll
        for (int a = 0; a < 4; ++a)
            #pragma unroll
            for (int b = 0; b < 4; ++b) { rs_[a][b] = 0.f; rq_[a][b] = 0.f; }
    }
    if (EP2 == 2) {
        #pragma unroll
        for (int a = 0; a < 4; ++a) { cs_[a] = 0.f; cq_[a] = 0.f; }
    }
    #pragma unroll
    for (int nf = 0; nf < 4; ++nf) {
        int n = wn + nf * 16 + col;
        float bn = b2v[n];
        #pragma unroll
        for (int mf = 0; mf < 4; ++mf) {
            #pragma unroll
            for (int r = 0; r < 4; ++r) {
                int m = m0 + wm + mf * 16 + rbase + r;
                float v = acc2[mf][nf][r] + bn;
                if (ACT2 == 1) v = fmaxf(v, 0.f);
                if (ACT2 == 2) v = fast_gelu(v);
                if (EP2 == 1) {
                    float fin = Out[(size_t)m * 128 + n] + v;
                    Out[(size_t)m * 128 + n] = fin;
                    rs_[mf][r] += fin;
                    rq_[mf][r] += fin * fin;
                } else {
                    Out[(size_t)m * 128 + n] = v;
                    if (EP2 == 2) { cs_[nf] += v; cq_[nf] += v * v; }
                    if (EP2 == 3) rq_[mf][r] += v * v;
                }
            }
        }
    }
    if (EP2 == 1) {
        #pragma unroll
        for (int mf = 0; mf < 4; ++mf)
            #pragma unroll
            for (int r = 0; r < 4; ++r) {
                float s = rs_[mf][r], q = rq_[mf][r];
                #pragma unroll
                for (int o = 1; o <= 8; o <<= 1) {
                    s += __shfl_xor(s, o);
                    q += __shfl_xor(q, o);
                }
                rs_[mf][r] = s; rq_[mf][r] = q;
            }
        __syncthreads();
        float* sred = (float*)&Xhi[0][0];   // [128][2]
        float* qred = sred + 256;
        if (col == 0) {
            #pragma unroll
            for (int mf = 0; mf < 4; ++mf)
                #pragma unroll
                for (int r = 0; r < 4; ++r) {
                    int row = wm + mf * 16 + kq * 4 + r;
                    sred[row * 2 + (wn >> 6)] = rs_[mf][r];
                    qred[row * 2 + (wn >> 6)] = rq_[mf][r];
                }
        }
        __syncthreads();
        if (tid < 128) {
            rsum[(size_t)m0 + tid] = sred[tid * 2] + sred[tid * 2 + 1];
            rsq[(size_t)m0 + tid]  = qred[tid * 2] + qred[tid * 2 + 1];
        }
    }
    if (EP2 == 3) {
        #pragma unroll
        for (int mf = 0; mf < 4; ++mf)
            #pragma unroll
            for (int r = 0; r < 4; ++r) {
                float q = rq_[mf][r];
                #pragma unroll
                for (int o = 1; o <= 8; o <<= 1) q += __shfl_xor(q, o);
                rq_[mf][r] = q;
            }
        __syncthreads();
        float* qred = (float*)&Xhi[0][0];   // [128][2]
        if (col == 0) {
            #pragma unroll
            for (int mf = 0; mf < 4; ++mf)
                #pragma unroll
                for (int r = 0; r < 4; ++r) {
                    int row = wm + mf * 16 + kq * 4 + r;
                    qred[row * 2 + (wn >> 6)] = rq_[mf][r];
                }
        }
        __syncthreads();
        if (tid < 128)
            rsq[(size_t)m0 + tid] = qred[tid * 2] + qred[tid * 2 + 1];
    }
    if (EP2 == 2) {
        #pragma unroll
        for (int nf = 0; nf < 4; ++nf) {
            #pragma unroll
            for (int o = 16; o <= 32; o <<= 1) {
                cs_[nf] += __shfl_xor(cs_[nf], o);
                cq_[nf] += __shfl_xor(cq_[nf], o);
            }
        }
        __syncthreads();
        float* colS = (float*)&Xhi[0][0];   // [2][128]
        float* colQ = colS + 256;
        if (kq == 0) {
            #pragma unroll
            for (int nf = 0; nf < 4; ++nf) {
                int n = wn + nf * 16 + col;
                colS[(wm >> 6) * 128 + n] = cs_[nf];
                colQ[(wm >> 6) * 128 + n] = cq_[nf];
            }
        }
        __syncthreads();
        if (tid < 128) {
            rsum[(size_t)blockIdx.x * 256 + tid] = colS[tid] + colS[128 + tid];
            rsum[(size_t)blockIdx.x * 256 + 128 + tid] = colQ[tid] + colQ[128 + tid];
        }
    }
}

// W [128][128] f32 -> Whi/Wlo [n][k] bf16 split (transposed). grid (4,4), block (32,8)
__global__ void wsplit_kernel(const float* __restrict__ W, ushort* __restrict__ Whi,
                              ushort* __restrict__ Wlo) {
    __shared__ float t[32][33];
    int k0 = blockIdx.x * 32, n0 = blockIdx.y * 32;
    int tx = threadIdx.x, ty = threadIdx.y;
    for (int i = ty; i < 32; i += 8)
        t[i][tx] = W[(size_t)(k0 + i) * 128 + n0 + tx];
    __syncthreads();
    for (int i = ty; i < 32; i += 8) {
        float v = t[tx][i];
        ushort h = f2bf(v);
        Whi[(size_t)(n0 + i) * 128 + k0 + tx] = h;
        Wlo[(size_t)(n0 + i) * 128 + k0 + tx] = f2bf(v - bf2f(h));
    }
}

// ---------------------------------------------------------------------------
// Timestep MFMA GEMM v3: 256x256 tile, counted-vmcnt 4-slot K-half pipeline
// (T3+T4). A [8192][2048] bf16, W [2048][2048] bf16, 512 threads (2m x 4n).
// 64 phases: phase P computes K cols [P*32, P*32+32) from slot P&3; issues
// unit P+3 (A+B 32KB) into slot (P+3)&3; waits vmcnt(8) (2 units in flight,
// never drained to 0 until the tail). Epilogue identical to v2 (verified).
// ---------------------------------------------------------------------------
__global__ __launch_bounds__(512, 1)
void mfma_ts3_kernel(const ushort* __restrict__ A, const ushort* __restrict__ W,
                     const float* __restrict__ bias, float* Z,
                     float* __restrict__ bnfP) {
    extern __shared__ __align__(16) ushort smem2[];
    float (*Ol)[260] = (float(*)[260])smem2;

    int bid = blockIdx.x;
    int swz = (bid & 7) * 32 + (bid >> 3);   // nwg=256, cpx=32 (bijective)
    int n0 = (swz & 7) * 256;                // nx = 8
    int m0 = (swz >> 3) * 256;

    int tid = threadIdx.x;
    int w = tid >> 6, lane = tid & 63;
    int wm = (w >> 2) * 128, wn = (w & 3) * 64;
    int col = lane & 15, kq = lane >> 4;

    // stage-side lane constants: LDS dest is linear (base + lane*16B);
    // global src pre-swizzled so read-side XOR lands on the right bytes.
    int l3 = lane >> 3;
    int u0 = (lane & 7) ^ l3;                // R0 is always a multiple of 8
    int urow = l3 * 2 + (u0 >> 2);
    int ucol = (u0 & 3) * 8;

    // read-side fragment address: line r2 = row>>1 (128B lines),
    // 16B-unit u = (((row&1)<<2)|kq) ^ (r2&7); r2&7 == col>>1 for all frags.
    int uoff = ((((col & 1) << 2) | kq) ^ (col >> 1)) * 8;   // ushort offset
    int rA2b = (wm >> 1) + (col >> 1);
    int rB2b = (wn >> 1) + (col >> 1);

    float4v acc[8][4];
    #pragma unroll
    for (int i = 0; i < 8; ++i)
        #pragma unroll
        for (int j = 0; j < 4; ++j) acc[i][j] = (float4v){0.f, 0.f, 0.f, 0.f};

    auto stage = [&](int q) {   // unit q: tile q>>1, K-half q&1, slot q&3
        int kb = (q >> 1) * 64 + (q & 1) * 32;
        ushort* base = smem2 + (q & 3) * 16384;
        #pragma unroll
        for (int it = 0; it < 2; ++it) {
            int R0 = w * 16 + it * 8;        // line block (8 lines = 16 rows)
            async16(A + (size_t)(m0 + R0 * 2 + urow) * LL + kb + ucol,
                    base + R0 * 64);
            async16(W + (size_t)(n0 + R0 * 2 + urow) * LL + kb + ucol,
                    base + 8192 + R0 * 64);
        }
    };

    // prologue: units 0,1,2 in flight (12 loads/thread)
    stage(0); stage(1); stage(2);

    for (int P = 0; P < 64; ++P) {
        // wait for unit P; units P+1, P+2 (8 loads) may stay in flight
        if (P < 62)       asm volatile("s_waitcnt vmcnt(8)" ::: "memory");
        else if (P == 62) asm volatile("s_waitcnt vmcnt(4)" ::: "memory");
        else              asm volatile("s_waitcnt vmcnt(0)" ::: "memory");
        __builtin_amdgcn_s_barrier();
        __builtin_amdgcn_sched_barrier(0);
        if (P < 61) stage(P + 3);            // slot (P+3)&3 == (P-1)&3: safe
        const ushort* base = smem2 + (size_t)(P & 3) * 16384;
        short8v af[8], bf4[4];
        #pragma unroll
        for (int mf = 0; mf < 8; ++mf)
            af[mf] = *(const short8v*)(base + (rA2b + mf * 8) * 64 + uoff);
        #pragma unroll
        for (int nf = 0; nf < 4; ++nf)
            bf4[nf] = *(const short8v*)(base + 8192 + (rB2b + nf * 8) * 64 + uoff);
        __builtin_amdgcn_s_setprio(1);
        #pragma unroll
        for (int mf = 0; mf < 8; ++mf)
            #pragma unroll
            for (int nf = 0; nf < 4; ++nf)
                acc[mf][nf] = __builtin_amdgcn_mfma_f32_16x16x32_bf16(
                    af[mf], bf4[nf], acc[mf][nf], 0, 0, 0);
        __builtin_amdgcn_s_setprio(0);
    }

    // Epilogue: 8 rounds of 32-n strips through Ol (verbatim from v2)
    int b0 = m0 >> 7;
    float cs[16], cq[16];
    #pragma unroll
    for (int j = 0; j < 16; ++j) { cs[j] = 0.f; cq[j] = 0.f; }
    int nloc = tid >> 4, c0 = (tid & 15) * 16;
    int bb = b0 + (c0 >> 7);
    int ccc = c0 & 127;
    #pragma unroll
    for (int q = 0; q < 8; ++q) {
        __syncthreads();
        #pragma unroll
        for (int nf = 0; nf < 4; ++nf) {
            int gnl = wn + nf * 16;
            if ((gnl >> 5) != q) continue;
            int gn = n0 + gnl + col;
            float bn = bias[gn];
            int nl = gnl - q * 32 + col;
            #pragma unroll
            for (int mf = 0; mf < 8; ++mf)
                #pragma unroll
                for (int r = 0; r < 4; ++r) {
                    float v = acc[mf][nf][r] + bn;
                    v = fast_gelu(v);
                    Ol[nl][wm + mf * 16 + kq * 4 + r] = v;
                }
        }
        __syncthreads();
        int gn = n0 + q * 32 + nloc;
        float* zr = Z + ((size_t)bb * LL + gn) * CC + ccc;
        #pragma unroll
        for (int i = 0; i < 4; ++i) {
            float4 v = *(float4*)&Ol[nloc][c0 + i * 4];
            float4 o = *(float4*)(zr + i * 4);
            v.x += o.x; v.y += o.y; v.z += o.z; v.w += o.w;
            *(float4*)(zr + i * 4) = v;
            cs[i * 4 + 0] += v.x; cs[i * 4 + 1] += v.y;
            cs[i * 4 + 2] += v.z; cs[i * 4 + 3] += v.w;
            cq[i * 4 + 0] += v.x * v.x; cq[i * 4 + 1] += v.y * v.y;
            cq[i * 4 + 2] += v.z * v.z; cq[i * 4 + 3] += v.w * v.w;
        }
    }
    // per-block feature-BN partials (sum over this block's 2 b x 256 n rows)
    __syncthreads();
    float* sred = (float*)smem2;          // [32][256]
    float* qred = sred + 8192;            // [32][256]
    #pragma unroll
    for (int j = 0; j < 16; ++j) {
        sred[nloc * 256 + c0 + j] = cs[j];
        qred[nloc * 256 + c0 + j] = cq[j];
    }
    __syncthreads();
    if (tid < 128) {
        float a = 0.f;
        for (int r = 0; r < 32; ++r)
            a += sred[r * 256 + tid] + sred[r * 256 + 128 + tid];
        bnfP[(size_t)bid * 256 + tid] = a;
    } else if (tid < 256) {
        int c = tid - 128;
        float a = 0.f;
        for (int r = 0; r < 32; ++r)
            a += qred[r * 256 + c] + qred[r * 256 + 128 + c];
        bnfP[(size_t)bid * 256 + 128 + c] = a;
    }
}

// ---------------------------------------------------------------------------
// bf16 MFMA GEMM (big-K), 2-phase double-buffered prefetch (head/scores/fallback).
// ---------------------------------------------------------------------------
template <int EPM>
__global__ __launch_bounds__(256)
void mfma_gemm_kernel(const ushort* __restrict__ A, const ushort* __restrict__ W,
                      const float* __restrict__ bias, float* Z,
                      int N, int Kd, int LDO, int nx, int nwg,
                      const float* __restrict__ epS, const float* __restrict__ epM,
                      float* __restrict__ bnfP) {
    __shared__ __align__(16) ushort smem[32768];   // 64 KB = 2 x (A 16KB + B 16KB)
    float (*Ol)[132] = (float(*)[132])smem;        // epilogue overlay

    int bid = blockIdx.x;
    int cpx = nwg >> 3;
    int swz = (bid & 7) * cpx + (bid >> 3);
    int n0 = (swz % nx) * 128;
    int m0 = (swz / nx) * 128;

    int tid = threadIdx.x;
    int w = tid >> 6, lane = tid & 63;
    int wm = (w >> 1) * 64, wn = (w & 1) * 64;
    int col = lane & 15, kq = lane >> 4;

    int srow = lane >> 3;                    // 0..7
    int scol = ((lane & 7) ^ srow) << 3;     // pre-swizzled src ushort offset
    int xr = (col & 7) << 4;                 // read-side XOR (bytes)

    float4v acc[4][4];
    #pragma unroll
    for (int i = 0; i < 4; ++i)
        #pragma unroll
        for (int j = 0; j < 4; ++j) acc[i][j] = (float4v){0.f, 0.f, 0.f, 0.f};

    int kTiles = Kd >> 6;

    // prologue: stage K-tile 0 into buffer 0
    #pragma unroll
    for (int it = 0; it < 4; ++it) {
        int rb = (w << 5) + (it << 3);
        async16(A + (size_t)(m0 + rb + srow) * Kd + scol, smem + (rb << 6));
    }
    #pragma unroll
    for (int it = 0; it < 4; ++it) {
        int rb = (w << 5) + (it << 3);
        async16(W + (size_t)(n0 + rb + srow) * Kd + scol, smem + 8192 + (rb << 6));
    }
    __syncthreads();

    for (int kt = 0; kt < kTiles; ++kt) {
        int cur = kt & 1;
        ushort* Ac = smem + (cur << 14);
        ushort* Bc = Ac + 8192;
        if (kt + 1 < kTiles) {
            ushort* An = smem + ((cur ^ 1) << 14);
            ushort* Bn = An + 8192;
            int kb = (kt + 1) << 6;
            #pragma unroll
            for (int it = 0; it < 4; ++it) {
                int rb = (w << 5) + (it << 3);
                async16(A + (size_t)(m0 + rb + srow) * Kd + kb + scol, An + (rb << 6));
            }
            #pragma unroll
            for (int it = 0; it < 4; ++it) {
                int rb = (w << 5) + (it << 3);
                async16(W + (size_t)(n0 + rb + srow) * Kd + kb + scol, Bn + (rb << 6));
            }
        }
        __builtin_amdgcn_s_setprio(1);
        #pragma unroll
        for (int ksub = 0; ksub < 2; ++ksub) {
            int cswz = (((ksub << 6) + (kq << 4)) ^ xr) >> 1;
            short8v af[4], bf[4];
            #pragma unroll
            for (int mf = 0; mf < 4; ++mf)
                af[mf] = *(const short8v*)(Ac + (wm + mf * 16 + col) * 64 + cswz);
            #pragma unroll
            for (int nf = 0; nf < 4; ++nf)
                bf[nf] = *(const short8v*)(Bc + (wn + nf * 16 + col) * 64 + cswz);
            #pragma unroll
            for (int mf = 0; mf < 4; ++mf)
                #pragma unroll
                for (int nf = 0; nf < 4; ++nf)
                    acc[mf][nf] = __builtin_amdgcn_mfma_f32_16x16x32_bf16(
                        af[mf], bf[nf], acc[mf][nf], 0, 0, 0);
        }
        __builtin_amdgcn_s_setprio(0);
        __syncthreads();
    }

    // Epilogue: 4 rounds of 32-n strips through Ol
    int b = m0 >> 7;
    float cs[16], cq[16];
    if (EPM == 1) {
        #pragma unroll
        for (int k2 = 0; k2 < 16; ++k2) { cs[k2] = 0.f; cq[k2] = 0.f; }
    }
    #pragma unroll
    for (int q = 0; q < 4; ++q) {
        __syncthreads();
        #pragma unroll
        for (int nf = 0; nf < 4; ++nf) {
            int gnl = wn + nf * 16;
            if ((gnl >> 5) != q) continue;
            int gn = n0 + gnl + col;
            float bn = (EPM == 2 && gn >= N) ? 0.f : bias[gn];
            int nl = gnl - q * 32 + col;
            #pragma unroll
            for (int mf = 0; mf < 4; ++mf) {
                #pragma unroll
                for (int r = 0; r < 4; ++r) {
                    float v = acc[mf][nf][r] + bn;
                    if (EPM == 1) v = fast_gelu(v);
                    Ol[nl][wm + mf * 16 + kq * 4 + r] = v;
                }
            }
        }
        __syncthreads();
        int nloc = tid >> 3, c0 = (tid & 7) * 16;
        int gn = n0 + q * 32 + nloc;
        if ((EPM == 2 || EPM == 3) && gn >= N) continue;
        float* zr;
        if (EPM == 3)
            zr = Z + (((size_t)(m0 >> 11) * 64 + gn) * 2048) + (m0 & 2047) + c0;
        else
            zr = Z + ((size_t)b * LDO + gn) * CC + c0;
        #pragma unroll
        for (int i = 0; i < 4; ++i) {
            float4 v = *(float4*)&Ol[nloc][c0 + i * 4];
            if (EPM == 1) {
                float4 o = *(float4*)(zr + i * 4);
                v.x += o.x; v.y += o.y; v.z += o.z; v.w += o.w;
                *(float4*)(zr + i * 4) = v;
                cs[i * 4 + 0] += v.x; cs[i * 4 + 1] += v.y;
                cs[i * 4 + 2] += v.z; cs[i * 4 + 3] += v.w;
                cq[i * 4 + 0] += v.x * v.x; cq[i * 4 + 1] += v.y * v.y;
                cq[i * 4 + 2] += v.z * v.z; cq[i * 4 + 3] += v.w * v.w;
            } else if (EPM == 2) {
                int mb = m0 + c0 + i * 4;
                float4 s4 = *(const float4*)(epS + mb);
                float4 m4 = *(const float4*)(epM + mb);
                v.x = v.x * s4.x + m4.x; v.y = v.y * s4.y + m4.y;
                v.z = v.z * s4.z + m4.z; v.w = v.w * s4.w + m4.w;
                *(float4*)(zr + i * 4) = v;
            } else {
                *(float4*)(zr + i * 4) = v;
            }
        }
    }
    if (EPM == 1) {
        __syncthreads();
        float* sred = (float*)smem;         // [32][128]
        float* qred = sred + 4096;          // [32][128]
        int rrow = tid >> 3, cb = (tid & 7) * 16;
        #pragma unroll
        for (int k2 = 0; k2 < 16; ++k2) {
            sred[rrow * 128 + cb + k2] = cs[k2];
            qred[rrow * 128 + cb + k2] = cq[k2];
        }
        __syncthreads();
        if (tid < 128) {
            float a = 0.f;
            for (int r = 0; r < 32; ++r) a += sred[r * 128 + tid];
            bnfP[(size_t)bid * 256 + tid] = a;
        } else {
            int c = tid - 128;
            float a = 0.f;
            for (int r = 0; r < 32; ++r) a += qred[r * 128 + c];
            bnfP[(size_t)bid * 256 + 128 + c] = a;
        }
    }
}

// W [K][N] f32 -> WT [Npad][K] bf16 (zero-filled for n >= N).
__global__ void wtrans_kernel(const float* __restrict__ W, ushort* __restrict__ WT,
                              int Kd, int N) {
    __shared__ float t[32][33];
    int k0 = blockIdx.x * 32, n0 = blockIdx.y * 32;
    int tx = threadIdx.x, ty = threadIdx.y;
    for (int i = ty; i < 32; i += 8) {
        int n = n0 + tx;
        t[i][tx] = (n < N) ? W[(size_t)(k0 + i) * N + n] : 0.f;
    }
    __syncthreads();
    for (int i = ty; i < 32; i += 8)
        WT[(size_t)(n0 + i) * Kd + k0 + tx] = f2bf(t[tx][i]);
}

// ---------------------------------------------------------------------------
__global__ void cn_split_kernel(const float* __restrict__ ce, ushort* __restrict__ ch,
                                ushort* __restrict__ cl) {
    int k = blockIdx.x, h = threadIdx.x;
    if (k >= KK) {
        ch[(size_t)k * 128 + h] = 0;
        cl[(size_t)k * 128 + h] = 0;
        return;
    }
    __shared__ float sh[128];
    float v = ce[(size_t)k * HH + h];
    sh[h] = v * v;
    __syncthreads();
    for (int o = 64; o >= 1; o >>= 1) {
        if (h < o) sh[h] += sh[h + o];
        __syncthreads();
    }
    float nv = v / (sqrtf(sh[0]) + 1e-8f);
    ushort hh = f2bf(nv);
    ch[(size_t)k * 128 + h] = hh;
    cl[(size_t)k * 128 + h] = f2bf(nv - bf2f(hh));
}

// Qp bf16 [128][128] (rows >= 64 zero), qb f32 [128]
__global__ void qprime_kernel(const float* __restrict__ Q, const float* __restrict__ wk_w,
                              const float* __restrict__ wk_b, ushort* __restrict__ qpb,
                              float* __restrict__ qbp) {
    int k = blockIdx.x;
    int hp = threadIdx.x;
    if (k >= KK) {
        qpb[(size_t)k * HH + hp] = 0;
        if (hp == 0) qbp[k] = 0.f;
        return;
    }
    __shared__ float qrow[128];
    __shared__ float red[128];
    qrow[hp] = Q[(size_t)k * HH + hp];
    __syncthreads();
    float s = 0.f;
    for (int h = 0; h < HH; ++h) s = fmaf(qrow[h], wk_w[(size_t)hp * HH + h], s);
    const float rs = 0.088388347648318447f;
    qpb[(size_t)k * HH + hp] = f2bf(s * rs);
    red[hp] = qrow[hp] * wk_b[hp];
    __syncthreads();
    for (int o = 64; o >= 1; o >>= 1) {
        if (hp < o) red[hp] += red[hp + o];
        __syncthreads();
    }
    if (hp == 0) qbp[k] = red[0] * rs;
}

// ---------------------------------------------------------------------------
__global__ __launch_bounds__(256)
void pmask_kernel(const float* __restrict__ sp, const float* __restrict__ rn,
                  const float* __restrict__ bern, unsigned char* __restrict__ Mt,
                  float* __restrict__ ppart) {
    int b = blockIdx.y;
    int l0 = blockIdx.x * 32;
    int tid = threadIdx.x;
    int wv = tid >> 6, lane = tid & 63;
    __shared__ float Msh[64][33];
    __shared__ float psum[4][64];
    float pa = 0.f;
    for (int tt = 0; tt < 8; ++tt) {
        int l = l0 + wv * 8 + tt;
        size_t tok = (size_t)b * LL + l;
        float s = sp[tok * 64 + lane] * rn[tok];
        float mx = s;
        #pragma unroll
        for (int o = 32; o >= 1; o >>= 1) mx = fmaxf(mx, __shfl_xor(mx, o));
        float ev = expf(s - mx);
        float sm = ev;
        #pragma unroll
        for (int o = 32; o >= 1; o >>= 1) sm += __shfl_xor(sm, o);
        float p = ev / sm;
        pa += p;
        Msh[lane][wv * 8 + tt] = (bern[tok * KK + lane] < p) ? 1.f : 0.f;
    }
    psum[wv][lane] = pa;
    __syncthreads();
    for (int q = tid; q < 64 * 32; q += 256) {
        int k = q >> 5, j = q & 31;
        Mt[((size_t)b * KK + k) * LL + l0 + j] = (unsigned char)Msh[k][j];
    }
    if (tid < 64)
        ppart[((size_t)b * (LL / 32) + blockIdx.x) * KK + tid] =
            psum[0][tid] + psum[1][tid] + psum[2][tid] + psum[3][tid];
}

__global__ void pmean_final_kernel(const float* __restrict__ part, float* __restrict__ pm) {
    int b = blockIdx.x, k = threadIdx.x;
    float s = 0.f;
    for (int i = 0; i < LL / 32; ++i) s += part[((size_t)b * (LL / 32) + i) * KK + k];
    pm[b * KK + k] = s * (1.f / LL);
}

// ---------------------------------------------------------------------------
__global__ __launch_bounds__(256)
void aw_kernel(float* __restrict__ S, const unsigned char* __restrict__ Mt) {
    size_t base = (size_t)blockIdx.x * LL;
    int tid = threadIdx.x;
    float t[8];
    float mx = -1e30f;
    #pragma unroll
    for (int i = 0; i < 8; ++i) {
        int l = tid + i * 256;
        float v = expf(S[base + l]) * (float)Mt[base + l];
        t[i] = v;
        mx = fmaxf(mx, v);
    }
    __shared__ float shA[4];
    __shared__ float shB[4];
    #pragma unroll
    for (int o = 32; o >= 1; o >>= 1) mx = fmaxf(mx, __shfl_xor(mx, o));
    if ((tid & 63) == 0) shA[tid >> 6] = mx;
    __syncthreads();
    mx = fmaxf(fmaxf(shA[0], shA[1]), fmaxf(shA[2], shA[3]));
    float e[8];
    float sum = 0.f;
    #pragma unroll
    for (int i = 0; i < 8; ++i) { e[i] = expf(t[i] - mx); sum += e[i]; }
    #pragma unroll
    for (int o = 32; o >= 1; o >>= 1) sum += __shfl_xor(sum, o);
    if ((tid & 63) == 0) shB[tid >> 6] = sum;
    __syncthreads();
    sum = (shB[0] + shB[1]) + (shB[2] + shB[3]);
    float inv = 1.f / sum;
    #pragma unroll
    for (int i = 0; i < 8; ++i) S[base + tid + i * 256] = e[i] * inv;
}

// ---------------------------------------------------------------------------
__global__ __launch_bounds__(256)
void awh_part_kernel(const float* __restrict__ AWs, const float* __restrict__ hmat,
                     float* __restrict__ part) {
    __shared__ float AT[32][64];
    __shared__ float VT[32][128];
    int b = blockIdx.y, sp = blockIdx.x;
    int tid = threadIdx.x;
    int tx = tid & 15, ty = tid >> 4;
    float acc[4][8] = {};
    const float* Ab = AWs + (size_t)b * KK * LL + sp * 512;
    const float* Vb = hmat + ((size_t)b * LL + sp * 512) * HH;
    for (int lt = 0; lt < 512; lt += 32) {
        __syncthreads();
        #pragma unroll
        for (int it = 0; it < 2; ++it) {
            int q = tid + it * 256;
            int row = q >> 3;
            int lq = (q & 7) << 2;
            float4 v = *(const float4*)(Ab + (size_t)row * LL + lt + lq);
            AT[lq][row] = v.x; AT[lq + 1][row] = v.y;
            AT[lq + 2][row] = v.z; AT[lq + 3][row] = v.w;
        }
        #pragma unroll
        for (int it = 0; it < 4; ++it) {
            int q = tid + it * 256;
            int lr = q >> 5;
            int hc = (q & 31) << 2;
            *(float4*)&VT[lr][hc] = *(const float4*)(Vb + (size_t)(lt + lr) * HH + hc);
        }
        __syncthreads();
        #pragma unroll
        for (int l = 0; l < 32; ++l) {
            float av[4], vv[8];
            *(float4*)&av[0] = *(const float4*)&AT[l][ty * 4];
            *(float4*)&vv[0] = *(const float4*)&VT[l][tx * 4];
            *(float4*)&vv[4] = *(const float4*)&VT[l][64 + tx * 4];
            #pragma unroll
            for (int i = 0; i < 4; ++i)
                #pragma unroll
                for (int j = 0; j < 8; ++j)
                    acc[i][j] = fmaf(av[i], vv[j], acc[i][j]);
        }
    }
    #pragma unroll
    for (int i = 0; i < 4; ++i) {
        int k = ty * 4 + i;
        #pragma unroll
        for (int jj = 0; jj < 8; jj += 4) {
            int h = (jj ? 64 + tx * 4 : tx * 4);
            float o[4];
            #pragma unroll
            for (int j = 0; j < 4; ++j) o[j] = acc[i][jj + j];
            *(float4*)(part + (((size_t)b * 4 + sp) * KK + k) * HH + h) = *(float4*)o;
        }
    }
}

__global__ void awh_reduce_kernel(const float* __restrict__ part, float* __restrict__ awh) {
    int bk = blockIdx.x, h = threadIdx.x;
    int b = bk >> 6, k = bk & 63;
    float s = 0.f;
    #pragma unroll
    for (int sp = 0; sp < 4; ++sp)
        s += part[(((size_t)b * 4 + sp) * KK + k) * HH + h];
    awh[(size_t)bk * HH + h] = s;
}

__global__ void newce_kernel(const float* __restrict__ ao, const float* __restrict__ pm,
                             float* __restrict__ outTail) {
    int k = blockIdx.x, h = threadIdx.x;
    float s = 0.f;
    for (int b = 0; b < BB; ++b)
        s += ao[((size_t)b * KK + k) * HH + h] * pm[b * KK + k];
    outTail[(size_t)k * HH + h] = s * (1.f / BB);
}

// z_out = (in - mean2)*rstd2; also emits per-row sum/sumsq. grid (32, B), block 256
__global__ void revin_apply_kernel(const float* __restrict__ in, float* __restrict__ out,
                                   const float* __restrict__ mu, const float* __restrict__ rs,
                                   float* __restrict__ rsum, float* __restrict__ rsq) {
    int b = blockIdx.y;
    size_t base = (size_t)b * LL * CC + (size_t)blockIdx.x * 8192;
    int c0 = (threadIdx.x * 4) & 127;
    int lane = threadIdx.x & 63;
    float4 m4 = *(const float4*)(mu + b * CC + c0);
    float4 r4 = *(const float4*)(rs + b * CC + c0);
    #pragma unroll
    for (int j = 0; j < 8; ++j) {
        float4 v = *(const float4*)(in + base + threadIdx.x * 4 + j * 1024);
        v.x = (v.x - m4.x) * r4.x; v.y = (v.y - m4.y) * r4.y;
        v.z = (v.z - m4.z) * r4.z; v.w = (v.w - m4.w) * r4.w;
        *(float4*)(out + base + threadIdx.x * 4 + j * 1024) = v;
        float s = v.x + v.y + v.z + v.w;
        float q = v.x * v.x + v.y * v.y + v.z * v.z + v.w * v.w;
        #pragma unroll
        for (int o = 1; o <= 16; o <<= 1) {
            s += __shfl_xor(s, o);
            q += __shfl_xor(q, o);
        }
        if ((lane & 31) == 0) {
            size_t row = (base + (size_t)threadIdx.x * 4 + (size_t)j * 1024) >> 7;
            rsum[row] = s;
            rsq[row] = q;
        }
    }
}

// timestep-BN final: per l over 64 b's of row stats. grid 8, block 256
__global__ void bnt_final_kernel(const float* __restrict__ rsum, const float* __restrict__ rsq,
                                 float* __restrict__ mu, float* __restrict__ rv) {
    int l = blockIdx.x * 256 + threadIdx.x;
    float s = 0.f, q = 0.f;
    for (int b = 0; b < BB; ++b) {
        s += rsum[(size_t)b * LL + l];
        q += rsq[(size_t)b * LL + l];
    }
    float m = s * (1.f / (BB * CC));
    float var = q * (1.f / (BB * CC)) - m * m;
    var = fmaxf(var, 0.f);
    mu[l] = m;
    rv[l] = 1.f / sqrtf(var + EPSf);
}

// ---------------------------------------------------------------------------
// [B,L,C] f32 -> [B,C,L] bf16, optional timestep-BN. v2: 64(l)x32(c) tiles,
// uint4 (8 bf16) coalesced writes. grid (L/64, C/32, B), block 256.
// ---------------------------------------------------------------------------
template <bool DO_BN>
__global__ __launch_bounds__(256)
void transpose_bn_kernel(const float* __restrict__ in, ushort* __restrict__ out,
                         const float* __restrict__ mu, const float* __restrict__ rv,
                         const float* __restrict__ g, const float* __restrict__ be) {
    __shared__ ushort tile[32][72];   // [c][l] bf16, padded
    int l0 = blockIdx.x * 64, c0 = blockIdx.y * 32, b = blockIdx.z;
    int t = threadIdx.x;
    const float* ib = in + ((size_t)b * LL + l0) * CC + c0;
    #pragma unroll
    for (int it = 0; it < 2; ++it) {
        int idx = t + it * 256;
        int row = idx >> 3;           // 0..63 (l offset)
        int c = (idx & 7) * 4;        // 0..28
        float4 v = *(const float4*)(ib + (size_t)row * CC + c);
        if (DO_BN) {
            int l = l0 + row;
            float sc = rv[l] * g[l];
            float m = mu[l], bb = be[l];
            v.x = (v.x - m) * sc + bb; v.y = (v.y - m) * sc + bb;
            v.z = (v.z - m) * sc + bb; v.w = (v.w - m) * sc + bb;
        }
        tile[c    ][row] = f2bf(v.x);
        tile[c + 1][row] = f2bf(v.y);
        tile[c + 2][row] = f2bf(v.z);
        tile[c + 3][row] = f2bf(v.w);
    }
    __syncthreads();
    int cc = t >> 3, l8 = (t & 7) * 8;
    ushort* ob = out + (size_t)b * CC * LL + (size_t)(c0 + cc) * LL + l0 + l8;
    *(uint4*)ob = *(const uint4*)&tile[cc][l8];
}

// feature-BN two-stage reduce: mid over cnt blocks each; final over 64 mids
__global__ void bnf_mid_kernel(const float* __restrict__ part, float* __restrict__ mid,
                               int cnt) {
    int gblk = blockIdx.x, t = threadIdx.x;   // grid 64, block 256
    float s = 0.f;
    for (int i = 0; i < cnt; ++i)
        s += part[(size_t)(gblk * cnt + i) * 256 + t];
    mid[(size_t)gblk * 256 + t] = s;
}

__global__ void bnf_final_kernel(const float* __restrict__ mid, const float* __restrict__ g,
                                 const float* __restrict__ be, float* __restrict__ mu,
                                 float* __restrict__ sA, float* __restrict__ tA) {
    int c = threadIdx.x;   // block 128
    float s = 0.f, s2 = 0.f;
    #pragma unroll
    for (int i = 0; i < 64; ++i) {
        s += mid[(size_t)i * 256 + c];
        s2 += mid[(size_t)i * 256 + 128 + c];
    }
    float m = s / (float)(BB * LL);
    float var = s2 / (float)(BB * LL) - m * m;
    var = fmaxf(var, 0.f);
    float rvv = 1.f / sqrtf(var + EPSf);
    mu[c] = m;
    sA[c] = rvv * g[c];
    tA[c] = be[c];
}

// ---------------------------------------------------------------------------
extern "C" void kernel_launch(void* const* d_in, const int* in_sizes, int n_in,
                              void* d_out, int out_size, void* d_ws, size_t ws_size,
                              hipStream_t stream) {
    const float* x     = (const float*)d_in[0];
    const float* bern  = (const float*)d_in[1];
    const float* ce    = (const float*)d_in[2];
    const float* wq_w  = (const float*)d_in[3];
    const float* wq_b  = (const float*)d_in[4];
    const float* wk_w  = (const float*)d_in[5];
    const float* wk_b  = (const float*)d_in[6];
    const float* wv_w  = (const float*)d_in[7];
    const float* wv_b  = (const float*)d_in[8];
    const float* cm_w1 = (const float*)d_in[9];
    const float* cm_b1 = (const float*)d_in[10];
    const float* cm_w2 = (const float*)d_in[11];
    const float* cm_b2 = (const float*)d_in[12];
    const float* tm_w1 = (const float*)d_in[13];
    const float* tm_b1 = (const float*)d_in[14];
    const float* tm_w2 = (const float*)d_in[15];
    const float* tm_b2 = (const float*)d_in[16];
    const float* bn_t_g = (const float*)d_in[17];
    const float* bn_t_b = (const float*)d_in[18];
    const float* lin_t_w = (const float*)d_in[19];
    const float* lin_t_b = (const float*)d_in[20];
    const float* bn_f_g = (const float*)d_in[21];
    const float* bn_f_b = (const float*)d_in[22];
    const float* f1_w  = (const float*)d_in[23];
    const float* f1_b  = (const float*)d_in[24];
    const float* f2_w  = (const float*)d_in[25];
    const float* f2_b  = (const float*)d_in[26];
    const float* out_w = (const float*)d_in[27];
    const float* out_b = (const float*)d_in[28];
    (void)in_sizes; (void)n_in; (void)out_size;

    float* y = (float*)d_out;                         // [B,P,C]
    float* ceOut = y + (size_t)BB * PP * CC;          // [K,H]

    float* ws = (float*)d_ws;
    size_t off = 0;
    auto alloc = [&](size_t n) { float* p = ws + off; off += n; return p; };
    float* mean1  = alloc(BB * CC);
    float* rstd1  = alloc(BB * CC);
    float* std1   = alloc(BB * CC);
    float* mean2  = alloc(BB * CC);
    float* rstd2  = alloc(BB * CC);
    float* std2   = alloc(BB * CC);
    float* bnmu   = alloc(LL);
    float* bnrv   = alloc(LL);
    float* bfpart = alloc(1024 * 256);
    float* bfmid  = alloc(64 * 256);
    float* bfmu   = alloc(CC);
    float* bfs    = alloc(CC);
    float* bft    = alloc(CC);
    float* cxpart = alloc(BB * 8 * 256);                      // colstats-1 partials
    float* cpart2 = alloc(1024 * 256);                        // colstats-2 partials (tm pair)
    float* qbuf   = alloc(KK * HH);
    ushort* qpb   = (ushort*)alloc(128 * 128 / 2);            // Qp bf16 padded
    float* qbp    = alloc(128);
    ushort* cnbh  = (ushort*)alloc(8192);                     // codebook hi bf16 [128][128]
    ushort* cnbl  = (ushort*)alloc(8192);                     // codebook lo
    float* rn     = alloc((size_t)BB * LL);
    float* rsum   = alloc((size_t)BB * LL);                   // per-row z sums
    float* rsq    = alloc((size_t)BB * LL);
    float* ppart  = alloc((size_t)BB * (LL / 32) * KK);
    float* pmean  = alloc(BB * KK);
    float* awhprt = alloc((size_t)BB * 4 * KK * HH);
    float* awh    = alloc((size_t)BB * KK * HH);
    float* aobuf  = alloc((size_t)BB * KK * HH);
    ushort* wsp   = (ushort*)alloc(7 * 2 * 16384 / 2);        // 7 split 128x128 weights
    ushort* wtT   = (ushort*)alloc((size_t)LL * LL / 2);      // lin_t_w^T bf16 [2048][2048]
    ushort* owT   = (ushort*)alloc((size_t)384 * LL / 2);     // out_w^T bf16 [384][2048]
    float* S      = alloc((size_t)BB * KK * LL);
    float* buf0   = alloc((size_t)BB * LL * CC);
    float* buf2   = alloc((size_t)BB * LL * CC);
    unsigned char* Mt = (unsigned char*)(ws + off);           // [B,K,L] u8
    ushort* abf = (ushort*)S;       // bf16 [B,C,L] overlay on S (mixer phase)
    ushort* hb  = (ushort*)buf0;    // bf16 h [B,L,H] overlay on buf0 (attn phase)
    (void)ws_size;

    auto whi = [&](int i) { return wsp + (size_t)i * 2 * 16384; };
    auto wlo = [&](int i) { return wsp + (size_t)i * 2 * 16384 + 16384; };

    const int ML = BB * LL;      // 131072
    dim3 tb(32, 8);
    dim3 tgrid(LL / 64, CC / 32, BB);
    dim3 wsg(4, 4);

    // enable 128 KB dynamic LDS for the 256^2 timestep kernel; fallback if rejected
    bool useTs3 =
        (hipFuncSetAttribute((const void*)mfma_ts3_kernel,
                             hipFuncAttributeMaxDynamicSharedMemorySize,
                             131072) == hipSuccess);

    // 0) weight prep
    wtrans_kernel<<<dim3(LL / 32, LL / 32), tb, 0, stream>>>(lin_t_w, wtT, LL, LL);
    wtrans_kernel<<<dim3(LL / 32, 12), tb, 0, stream>>>(out_w, owT, LL, PP);
    wsplit_kernel<<<wsg, tb, 0, stream>>>(cm_w1, whi(0), wlo(0));
    wsplit_kernel<<<wsg, tb, 0, stream>>>(cm_w2, whi(1), wlo(1));
    wsplit_kernel<<<wsg, tb, 0, stream>>>(tm_w1, whi(2), wlo(2));
    wsplit_kernel<<<wsg, tb, 0, stream>>>(tm_w2, whi(3), wlo(3));
    wsplit_kernel<<<wsg, tb, 0, stream>>>(f1_w, whi(4), wlo(4));
    wsplit_kernel<<<wsg, tb, 0, stream>>>(f2_w, whi(5), wlo(5));
    wsplit_kernel<<<wsg, tb, 0, stream>>>(wv_w, whi(6), wlo(6));

    // 1) RevIN-1 stats (two-stage)
    colstats_part_kernel<<<dim3(8, BB), 256, 0, stream>>>(x, cxpart);
    colstats_final_kernel<<<dim3(BB), dim3(128), 0, stream>>>(cxpart, mean1, rstd1, std1);
    // 2) h = buf2 (fused split pair) + per-row sumsq -> rsq (for rownorm)
    mfma_sq2_kernel<1, 1, 0, 3, 1><<<dim3(ML / 128), 256, 0, stream>>>(
        x, whi(0), wlo(0), cm_b1, whi(1), wlo(1), cm_b2, buf2, mean1, rstd1, nullptr, CC,
        nullptr, rsq);
    rn_final_kernel<<<dim3(ML / 256), 256, 0, stream>>>(rsq, rn);
    // 3) Q, Qp(bf16), qb ; split codebook
    gemm_kernel<<<dim3(1, 1), 256, 0, stream>>>(ce, wq_w, wq_b, qbuf,
        KK, HH, HH, HH, HH, HH);
    qprime_kernel<<<dim3(128), dim3(128), 0, stream>>>(qbuf, wk_w, wk_b, qpb, qbp);
    cn_split_kernel<<<dim3(128), dim3(128), 0, stream>>>(ce, cnbh, cnbl);
    // 4) routing scores via split-precision MFMA (also emits hb = bf16 h)
    mfma_sq_kernel<0, 0, 2><<<dim3(ML / 128), 256, 0, stream>>>(
        buf2, cnbh, cnbl, nullptr, S, nullptr, nullptr, nullptr, 0, hb);
    // 5) softmax/mask/p-mean
    pmask_kernel<<<dim3(LL / 32, BB), 256, 0, stream>>>(S, rn, bern, Mt, ppart);
    pmean_final_kernel<<<dim3(BB), dim3(64), 0, stream>>>(ppart, pmean);
    // 6) attn scores via MFMA: S[b][k][l] = Qp.h + qb   (overwrites S, k-major)
    mfma_gemm_kernel<3><<<dim3(1024), 256, 0, stream>>>(
        hb, qpb, qbp, S, KK, 128, 0, 1, 1024, nullptr, nullptr, nullptr);
    // 7) masked double-exp softmax
    aw_kernel<<<dim3(BB * KK), 256, 0, stream>>>(S, Mt);
    // 8) awh -> ao -> cluster update
    awh_part_kernel<<<dim3(4, BB), 256, 0, stream>>>(S, buf2, awhprt);
    awh_reduce_kernel<<<dim3(BB * KK), dim3(128), 0, stream>>>(awhprt, awh);
    mfma_sq_kernel<0, 0, 0><<<dim3((BB * KK) / 128), 256, 0, stream>>>(
        awh, whi(6), wlo(6), wv_b, aobuf, nullptr, nullptr, nullptr, 0, nullptr);
    newce_kernel<<<dim3(KK), dim3(128), 0, stream>>>(aobuf, pmean, ceOut);
    // 9) temporal module (fused split pair): h2 = buf0, emits column-stat partials
    mfma_sq2_kernel<0, 1, 0, 2, 1><<<dim3(ML / 128), 256, 0, stream>>>(
        buf2, whi(2), wlo(2), tm_b1, whi(3), wlo(3), tm_b2, buf0,
        nullptr, nullptr, nullptr, 0, cpart2, nullptr);
    // 10) RevIN-2 stats (from fused partials) + apply: z = buf2
    colstats2_final_kernel<<<dim3(BB), dim3(128), 0, stream>>>(cpart2, mean2, rstd2, std2);
    revin_apply_kernel<<<dim3(32, BB), 256, 0, stream>>>(buf0, buf2, mean2, rstd2, rsum, rsq);
    // 11) 4 mixer blocks
    for (int blkI = 0; blkI < 4; ++blkI) {
        bnt_final_kernel<<<dim3(8), 256, 0, stream>>>(rsum, rsq, bnmu, bnrv);
        transpose_bn_kernel<true><<<tgrid, 256, 0, stream>>>(buf2, abf, bnmu, bnrv, bn_t_g, bn_t_b);
        if (useTs3) {
            mfma_ts3_kernel<<<dim3(256), 512, 131072, stream>>>(
                abf, wtT, lin_t_b, buf2, bfpart);
            bnf_mid_kernel<<<dim3(64), 256, 0, stream>>>(bfpart, bfmid, 4);
        } else {
            mfma_gemm_kernel<1><<<dim3(1024), 256, 0, stream>>>(
                abf, wtT, lin_t_b, buf2, LL, LL, LL, 16, 1024, nullptr, nullptr, bfpart);
            bnf_mid_kernel<<<dim3(64), 256, 0, stream>>>(bfpart, bfmid, 16);
        }
        bnf_final_kernel<<<dim3(1), dim3(128), 0, stream>>>(bfmid, bn_f_g, bn_f_b, bfmu, bfs, bft);
        mfma_sq2_kernel<2, 2, 0, 1, 0><<<dim3(ML / 128), 256, 0, stream>>>(
            buf2, whi(4), wlo(4), f1_b, whi(5), wlo(5), f2_b, buf2, bfmu, bfs, bft, 0,
            rsum, rsq);
    }
    // 12) head via MFMA: y[b,p,c] = (z^T @ out_w + out_b) * std2 + mean2
    transpose_bn_kernel<false><<<tgrid, 256, 0, stream>>>(buf2, abf,
        nullptr, nullptr, nullptr, nullptr);
    mfma_gemm_kernel<2><<<dim3(192), 256, 0, stream>>>(
        abf, owT, out_b, y, PP, LL, PP, 3, 192, std2, mean2, nullptr);
}

// Round 18
// 1278.651 us; speedup vs baseline: 1.0716x; 1.0716x over previous
//
#include <hip/hip_runtime.h>
#include <math.h>

#define BB 64
#define LL 2048
#define CC 128
#define HH 128
#define KK 64
#define PP 336
#define EPSf 1e-5f

typedef __attribute__((ext_vector_type(8))) short short8v;
typedef __attribute__((ext_vector_type(4))) float float4v;

__device__ inline ushort f2bf(float f) {
    union { float f; unsigned u; } v; v.f = f;
    unsigned r = (v.u + 0x7FFFu + ((v.u >> 16) & 1u)) >> 16;
    return (ushort)r;
}
__device__ inline float bf2f(ushort h) {
    union { unsigned u; float f; } v; v.u = ((unsigned)h) << 16;
    return v.f;
}

// exact-GELU via Abramowitz-Stegun 7.1.26 erf (|err| <= 1.5e-7)
__device__ inline float fast_gelu(float v) {
    float x = 0.70710678118654752f * v;
    float ax = fabsf(x);
    float t = 1.f / fmaf(0.3275911f, ax, 1.f);
    float p = t * fmaf(t, fmaf(t, fmaf(t, fmaf(t, 1.061405429f, -1.453152027f),
                                       1.421413741f), -0.284496736f), 0.254829592f);
    float er = fmaf(-p, __expf(-ax * ax), 1.f);
    er = (x < 0.f) ? -er : er;
    return 0.5f * v * (1.f + er);
}

// async 16B global -> LDS (wave-uniform LDS base + lane*16, per-lane global src)
__device__ __forceinline__ void async16(const ushort* g, ushort* l) {
    __builtin_amdgcn_global_load_lds(
        (const __attribute__((address_space(1))) void*)g,
        (__attribute__((address_space(3))) void*)l, 16, 0, 0);
}

// ---------------------------------------------------------------------------
// RevIN column stats, two-stage. part: grid (8, B), block 256.
// ---------------------------------------------------------------------------
__global__ __launch_bounds__(256)
void colstats_part_kernel(const float* __restrict__ x, float* __restrict__ part) {
    int b = blockIdx.y, chunk = blockIdx.x;
    int t = threadIdx.x;
    int c4 = (t & 31) * 4, rg = t >> 5;
    const float* xb = x + ((size_t)b * LL + chunk * 256) * CC;
    float4 s = make_float4(0.f, 0.f, 0.f, 0.f);
    float4 q = make_float4(0.f, 0.f, 0.f, 0.f);
    for (int l = rg; l < 256; l += 8) {
        float4 v = *(const float4*)(xb + (size_t)l * CC + c4);
        s.x += v.x; s.y += v.y; s.z += v.z; s.w += v.w;
        q.x += v.x * v.x; q.y += v.y * v.y; q.z += v.z * v.z; q.w += v.w * v.w;
    }
    __shared__ float ls[8][128];
    __shared__ float lq[8][128];
    *(float4*)&ls[rg][c4] = s;
    *(float4*)&lq[rg][c4] = q;
    __syncthreads();
    if (t < 128) {
        float a = 0.f, d = 0.f;
        #pragma unroll
        for (int i = 0; i < 8; ++i) { a += ls[i][t]; d += lq[i][t]; }
        part[((size_t)b * 8 + chunk) * 256 + t] = a;
        part[((size_t)b * 8 + chunk) * 256 + 128 + t] = d;
    }
}

__global__ void colstats_final_kernel(const float* __restrict__ part, float* __restrict__ mean,
                                      float* __restrict__ rstd, float* __restrict__ stdv) {
    int b = blockIdx.x, c = threadIdx.x;
    float s = 0.f, q = 0.f;
    #pragma unroll
    for (int i = 0; i < 8; ++i) {
        s += part[((size_t)b * 8 + i) * 256 + c];
        q += part[((size_t)b * 8 + i) * 256 + 128 + c];
    }
    float mu = s * (1.f / LL);
    float var = q * (1.f / LL) - mu * mu;
    var = fmaxf(var, 0.f);
    float sd = sqrtf(var + EPSf);
    mean[b * CC + c] = mu;
    stdv[b * CC + c] = sd;
    rstd[b * CC + c] = 1.f / sd;
}

__global__ void colstats2_final_kernel(const float* __restrict__ cpart, float* __restrict__ mean,
                                       float* __restrict__ rstd, float* __restrict__ stdv) {
    int b = blockIdx.x, c = threadIdx.x;
    float s = 0.f, q = 0.f;
    #pragma unroll
    for (int i = 0; i < 16; ++i) {
        s += cpart[((size_t)b * 16 + i) * 256 + c];
        q += cpart[((size_t)b * 16 + i) * 256 + 128 + c];
    }
    float mu = s * (1.f / LL);
    float var = q * (1.f / LL) - mu * mu;
    var = fmaxf(var, 0.f);
    float sd = sqrtf(var + EPSf);
    mean[b * CC + c] = mu;
    stdv[b * CC + c] = sd;
    rstd[b * CC + c] = 1.f / sd;
}

// rn[i] = 1/(sqrt(rowsumsq)+1e-8); grid 512, block 256
__global__ void rn_final_kernel(const float* __restrict__ rsq, float* __restrict__ rn) {
    size_t i = (size_t)blockIdx.x * 256 + threadIdx.x;
    rn[i] = 1.f / (sqrtf(rsq[i]) + 1e-8f);
}

// ---------------------------------------------------------------------------
// plain f32 VALU GEMM (tiny Q-GEMM only)
// ---------------------------------------------------------------------------
__global__ __launch_bounds__(256)
void gemm_kernel(const float* __restrict__ A, const float* __restrict__ W,
                 const float* __restrict__ bias, float* __restrict__ Out,
                 int M, int N, int Kd, int lda, int ldw, int ldo) {
    __shared__ float As[32][128];
    __shared__ float Ws[32][128];
    int tid = threadIdx.x;
    int tx = tid & 15, ty = tid >> 4;
    int n0 = blockIdx.x * 128;
    int m0 = blockIdx.y * 128;
    float acc[8][8] = {};

    for (int kt = 0; kt < Kd; kt += 32) {
        __syncthreads();
        #pragma unroll
        for (int it = 0; it < 4; ++it) {
            int q = tid + it * 256;
            int row = q >> 3;
            int kq = (q & 7) << 2;
            float4 v = make_float4(0.f, 0.f, 0.f, 0.f);
            int m = m0 + row;
            if (m < M) v = *(const float4*)(A + (size_t)m * lda + kt + kq);
            As[kq    ][row] = v.x;
            As[kq + 1][row] = v.y;
            As[kq + 2][row] = v.z;
            As[kq + 3][row] = v.w;
        }
        #pragma unroll
        for (int it = 0; it < 4; ++it) {
            int q = tid + it * 256;
            int kr = q >> 5;
            int nc = (q & 31) << 2;
            int n = n0 + nc;
            float4 v = make_float4(0.f, 0.f, 0.f, 0.f);
            if (n < N) v = *(const float4*)(W + (size_t)(kt + kr) * ldw + n);
            *(float4*)&Ws[kr][nc] = v;
        }
        __syncthreads();
        #pragma unroll
        for (int k = 0; k < 32; ++k) {
            float a[8], w[8];
            *(float4*)&a[0] = *(const float4*)&As[k][ty * 8];
            *(float4*)&a[4] = *(const float4*)&As[k][ty * 8 + 4];
            *(float4*)&w[0] = *(const float4*)&Ws[k][tx * 4];
            *(float4*)&w[4] = *(const float4*)&Ws[k][64 + tx * 4];
            #pragma unroll
            for (int i = 0; i < 8; ++i)
                #pragma unroll
                for (int j = 0; j < 8; ++j)
                    acc[i][j] = fmaf(a[i], w[j], acc[i][j]);
        }
    }

    #pragma unroll
    for (int i = 0; i < 8; ++i) {
        int m = m0 + ty * 8 + i;
        if (m >= M) continue;
        #pragma unroll
        for (int jj = 0; jj < 8; jj += 4) {
            int n = n0 + (jj ? 64 + tx * 4 : tx * 4);
            if (n >= N) continue;
            float o[4];
            #pragma unroll
            for (int j = 0; j < 4; ++j)
                o[j] = acc[i][jj + j] + (bias ? bias[n + j] : 0.f);
            *(float4*)(Out + (size_t)m * ldo + n) = *(float4*)o;
        }
    }
}

// ---------------------------------------------------------------------------
// Split-precision MFMA GEMM for K=128 (A f32 [M][128], W split bf16 [128][128]).
// EP: 0 -> Out[m*128+n]; 2 -> Out[m*64+n] only n<64.
// ---------------------------------------------------------------------------
template <int NORM, int ACT, int EP>
__global__ __launch_bounds__(256)
void mfma_sq_kernel(const float* __restrict__ A, const ushort* __restrict__ Whi,
                    const ushort* __restrict__ Wlo, const float* __restrict__ bias,
                    float* Out,
                    const float* __restrict__ nmu, const float* __restrict__ ns,
                    const float* __restrict__ nt, int normStride,
                    ushort* __restrict__ hbOut) {
    __shared__ ushort Ahi[128][72];
    __shared__ ushort Alo[128][72];
    __shared__ ushort Bhi[128][72];
    __shared__ ushort Blo[128][72];
    int tid = threadIdx.x;
    int m0 = blockIdx.x * 128;
    int noff = (NORM == 1) ? (m0 / LL) * normStride : 0;

    int w = tid >> 6, lane = tid & 63;
    int wm = (w >> 1) * 64, wn = (w & 1) * 64;
    int col = lane & 15, kq = lane >> 4;

    float4v acc[4][4];
    #pragma unroll
    for (int i = 0; i < 4; ++i)
        #pragma unroll
        for (int j = 0; j < 4; ++j) acc[i][j] = (float4v){0.f, 0.f, 0.f, 0.f};

    for (int kt = 0; kt < 2; ++kt) {
        __syncthreads();
        #pragma unroll
        for (int it = 0; it < 4; ++it) {
            int q = tid + it * 256;
            int row = q >> 3, k0 = (q & 7) * 8;
            int kg = kt * 64 + k0;
            const float* ap = A + (size_t)(m0 + row) * 128 + kg;
            float vv[8];
            *(float4*)&vv[0] = *(const float4*)ap;
            *(float4*)&vv[4] = *(const float4*)(ap + 4);
            ushort hi[8], lo[8];
            #pragma unroll
            for (int j = 0; j < 8; ++j) {
                float v = vv[j];
                if (NORM == 1) v = (v - nmu[noff + kg + j]) * ns[noff + kg + j];
                if (NORM == 2) v = (v - nmu[kg + j]) * ns[kg + j] + nt[kg + j];
                ushort h = f2bf(v);
                hi[j] = h;
                lo[j] = f2bf(v - bf2f(h));
            }
            if (hbOut)
                *(short8v*)(hbOut + (size_t)(m0 + row) * 128 + kg) = *(short8v*)hi;
            *(short8v*)&Ahi[row][k0] = *(short8v*)hi;
            *(short8v*)&Alo[row][k0] = *(short8v*)lo;
        }
        #pragma unroll
        for (int it = 0; it < 4; ++it) {
            int q = tid + it * 256;
            int row = q >> 3, k0 = (q & 7) * 8;
            *(short8v*)&Bhi[row][k0] =
                *(const short8v*)(Whi + (size_t)row * 128 + kt * 64 + k0);
            *(short8v*)&Blo[row][k0] =
                *(const short8v*)(Wlo + (size_t)row * 128 + kt * 64 + k0);
        }
        __syncthreads();
        #pragma unroll
        for (int ksub = 0; ksub < 2; ++ksub) {
            short8v ah[4], al[4], bh[4], bl[4];
            #pragma unroll
            for (int mf = 0; mf < 4; ++mf) {
                ah[mf] = *(const short8v*)&Ahi[wm + mf * 16 + col][ksub * 32 + kq * 8];
                al[mf] = *(const short8v*)&Alo[wm + mf * 16 + col][ksub * 32 + kq * 8];
            }
            #pragma unroll
            for (int nf = 0; nf < 4; ++nf) {
                bh[nf] = *(const short8v*)&Bhi[wn + nf * 16 + col][ksub * 32 + kq * 8];
                bl[nf] = *(const short8v*)&Blo[wn + nf * 16 + col][ksub * 32 + kq * 8];
            }
            #pragma unroll
            for (int mf = 0; mf < 4; ++mf)
                #pragma unroll
                for (int nf = 0; nf < 4; ++nf)
                    acc[mf][nf] = __builtin_amdgcn_mfma_f32_16x16x32_bf16(
                        ah[mf], bh[nf], acc[mf][nf], 0, 0, 0);
            #pragma unroll
            for (int mf = 0; mf < 4; ++mf)
                #pragma unroll
                for (int nf = 0; nf < 4; ++nf)
                    acc[mf][nf] = __builtin_amdgcn_mfma_f32_16x16x32_bf16(
                        ah[mf], bl[nf], acc[mf][nf], 0, 0, 0);
            #pragma unroll
            for (int mf = 0; mf < 4; ++mf)
                #pragma unroll
                for (int nf = 0; nf < 4; ++nf)
                    acc[mf][nf] = __builtin_amdgcn_mfma_f32_16x16x32_bf16(
                        al[mf], bh[nf], acc[mf][nf], 0, 0, 0);
        }
    }

    int rbase = kq * 4;
    #pragma unroll
    for (int nf = 0; nf < 4; ++nf) {
        int n = wn + nf * 16 + col;
        if (EP == 2 && n >= 64) continue;
        float bn = bias ? bias[n] : 0.f;
        #pragma unroll
        for (int mf = 0; mf < 4; ++mf) {
            #pragma unroll
            for (int r = 0; r < 4; ++r) {
                int m = m0 + wm + mf * 16 + rbase + r;
                float v = acc[mf][nf][r] + bn;
                if (ACT == 1) v = fmaxf(v, 0.f);
                if (ACT == 2) v = fast_gelu(v);
                if (EP == 0) Out[(size_t)m * 128 + n] = v;
                else if (EP == 1) Out[(size_t)m * 128 + n] += v;
                else Out[(size_t)m * 64 + n] = v;
            }
        }
    }
}

// ---------------------------------------------------------------------------
// FUSED pair of K=128 GEMMs (PREC=1: split-precision, PREC=0: plain bf16):
// EP2: 0 store; 1 residual+= with row sum/sumsq -> rsum/rsq;
//      2 store with per-block column partials -> rsum;
//      3 store with per-row sumsq -> rsq (for rownorm)
// ---------------------------------------------------------------------------
template <int NORM, int ACT1, int ACT2, int EP2, int PREC>
__global__ __launch_bounds__(256)
void mfma_sq2_kernel(const float* __restrict__ A,
                     const ushort* __restrict__ W1h, const ushort* __restrict__ W1l,
                     const float* __restrict__ b1v,
                     const ushort* __restrict__ W2h, const ushort* __restrict__ W2l,
                     const float* __restrict__ b2v, float* Out,
                     const float* __restrict__ nmu, const float* __restrict__ ns,
                     const float* __restrict__ nt, int normStride,
                     float* __restrict__ rsum, float* __restrict__ rsq) {
    __shared__ ushort Xhi[128][72];
    __shared__ ushort Xlo[PREC ? 128 : 1][72];
    __shared__ ushort Bh[128][72];
    __shared__ ushort Bl[PREC ? 128 : 1][72];
    int tid = threadIdx.x;
    int m0 = blockIdx.x * 128;
    int noff = (NORM == 1) ? (m0 / LL) * normStride : 0;
    int w = tid >> 6, lane = tid & 63;
    int wm = (w >> 1) * 64, wn = (w & 1) * 64;
    int col = lane & 15, kq = lane >> 4;

    float4v acc[4][4];
    #pragma unroll
    for (int i = 0; i < 4; ++i)
        #pragma unroll
        for (int j = 0; j < 4; ++j) acc[i][j] = (float4v){0.f, 0.f, 0.f, 0.f};

    // ---- GEMM1 over 2 K-tiles ----
    for (int kt = 0; kt < 2; ++kt) {
        __syncthreads();
        #pragma unroll
        for (int it = 0; it < 4; ++it) {
            int q = tid + it * 256;
            int row = q >> 3, k0 = (q & 7) * 8;
            int kg = kt * 64 + k0;
            const float* ap = A + (size_t)(m0 + row) * 128 + kg;
            float vv[8];
            *(float4*)&vv[0] = *(const float4*)ap;
            *(float4*)&vv[4] = *(const float4*)(ap + 4);
            ushort hi[8], lo[8];
            #pragma unroll
            for (int j = 0; j < 8; ++j) {
                float v = vv[j];
                if (NORM == 1) v = (v - nmu[noff + kg + j]) * ns[noff + kg + j];
                if (NORM == 2) v = (v - nmu[kg + j]) * ns[kg + j] + nt[kg + j];
                ushort h = f2bf(v);
                hi[j] = h;
                if (PREC) lo[j] = f2bf(v - bf2f(h));
            }
            *(short8v*)&Xhi[row][k0] = *(short8v*)hi;
            if (PREC) *(short8v*)&Xlo[row][k0] = *(short8v*)lo;
        }
        #pragma unroll
        for (int it = 0; it < 4; ++it) {
            int q = tid + it * 256;
            int row = q >> 3, k0 = (q & 7) * 8;
            *(short8v*)&Bh[row][k0] =
                *(const short8v*)(W1h + (size_t)row * 128 + kt * 64 + k0);
            if (PREC)
                *(short8v*)&Bl[row][k0] =
                    *(const short8v*)(W1l + (size_t)row * 128 + kt * 64 + k0);
        }
        __syncthreads();
        #pragma unroll
        for (int ksub = 0; ksub < 2; ++ksub) {
            short8v ah[4], al[4], bh[4], bl[4];
            #pragma unroll
            for (int mf = 0; mf < 4; ++mf) {
                ah[mf] = *(const short8v*)&Xhi[wm + mf * 16 + col][ksub * 32 + kq * 8];
                if (PREC) al[mf] = *(const short8v*)&Xlo[wm + mf * 16 + col][ksub * 32 + kq * 8];
            }
            #pragma unroll
            for (int nf = 0; nf < 4; ++nf) {
                bh[nf] = *(const short8v*)&Bh[wn + nf * 16 + col][ksub * 32 + kq * 8];
                if (PREC) bl[nf] = *(const short8v*)&Bl[wn + nf * 16 + col][ksub * 32 + kq * 8];
            }
            #pragma unroll
            for (int mf = 0; mf < 4; ++mf)
                #pragma unroll
                for (int nf = 0; nf < 4; ++nf)
                    acc[mf][nf] = __builtin_amdgcn_mfma_f32_16x16x32_bf16(
                        ah[mf], bh[nf], acc[mf][nf], 0, 0, 0);
            if (PREC) {
                #pragma unroll
                for (int mf = 0; mf < 4; ++mf)
                    #pragma unroll
                    for (int nf = 0; nf < 4; ++nf)
                        acc[mf][nf] = __builtin_amdgcn_mfma_f32_16x16x32_bf16(
                            ah[mf], bl[nf], acc[mf][nf], 0, 0, 0);
                #pragma unroll
                for (int mf = 0; mf < 4; ++mf)
                    #pragma unroll
                    for (int nf = 0; nf < 4; ++nf)
                        acc[mf][nf] = __builtin_amdgcn_mfma_f32_16x16x32_bf16(
                            al[mf], bh[nf], acc[mf][nf], 0, 0, 0);
            }
        }
    }

    // ---- GEMM2 ----
    float4v acc2[4][4];
    #pragma unroll
    for (int i = 0; i < 4; ++i)
        #pragma unroll
        for (int j = 0; j < 4; ++j) acc2[i][j] = (float4v){0.f, 0.f, 0.f, 0.f};

    for (int kt2 = 0; kt2 < 2; ++kt2) {
        __syncthreads();
        if ((wn >> 6) == kt2) {   // wave-uniform
            #pragma unroll
            for (int nf = 0; nf < 4; ++nf) {
                float bn = b1v[wn + nf * 16 + col];
                #pragma unroll
                for (int mf = 0; mf < 4; ++mf) {
                    #pragma unroll
                    for (int r = 0; r < 4; ++r) {
                        float v = acc[mf][nf][r] + bn;
                        if (ACT1 == 1) v = fmaxf(v, 0.f);
                        if (ACT1 == 2) v = fast_gelu(v);
                        int row = wm + mf * 16 + kq * 4 + r;
                        int c2 = nf * 16 + col;
                        ushort h = f2bf(v);
                        Xhi[row][c2] = h;
                        if (PREC) Xlo[row][c2] = f2bf(v - bf2f(h));
                    }
                }
            }
        }
        #pragma unroll
        for (int it = 0; it < 4; ++it) {
            int q = tid + it * 256;
            int row = q >> 3, k0 = (q & 7) * 8;
            *(short8v*)&Bh[row][k0] =
                *(const short8v*)(W2h + (size_t)row * 128 + kt2 * 64 + k0);
            if (PREC)
                *(short8v*)&Bl[row][k0] =
                    *(const short8v*)(W2l + (size_t)row * 128 + kt2 * 64 + k0);
        }
        __syncthreads();
        #pragma unroll
        for (int ksub = 0; ksub < 2; ++ksub) {
            short8v ah[4], al[4], bh[4], bl[4];
            #pragma unroll
            for (int mf = 0; mf < 4; ++mf) {
                ah[mf] = *(const short8v*)&Xhi[wm + mf * 16 + col][ksub * 32 + kq * 8];
                if (PREC) al[mf] = *(const short8v*)&Xlo[wm + mf * 16 + col][ksub * 32 + kq * 8];
            }
            #pragma unroll
            for (int nf = 0; nf < 4; ++nf) {
                bh[nf] = *(const short8v*)&Bh[wn + nf * 16 + col][ksub * 32 + kq * 8];
                if (PREC) bl[nf] = *(const short8v*)&Bl[wn + nf * 16 + col][ksub * 32 + kq * 8];
            }
            #pragma unroll
            for (int mf = 0; mf < 4; ++mf)
                #pragma unroll
                for (int nf = 0; nf < 4; ++nf)
                    acc2[mf][nf] = __builtin_amdgcn_mfma_f32_16x16x32_bf16(
                        ah[mf], bh[nf], acc2[mf][nf], 0, 0, 0);
            if (PREC) {
                #pragma unroll
                for (int mf = 0; mf < 4; ++mf)
                    #pragma unroll
                    for (int nf = 0; nf < 4; ++nf)
                        acc2[mf][nf] = __builtin_amdgcn_mfma_f32_16x16x32_bf16(
                            ah[mf], bl[nf], acc2[mf][nf], 0, 0, 0);
                #pragma unroll
                for (int mf = 0; mf < 4; ++mf)
                    #pragma unroll
                    for (int nf = 0; nf < 4; ++nf)
                        acc2[mf][nf] = __builtin_amdgcn_mfma_f32_16x16x32_bf16(
                            al[mf], bh[nf], acc2[mf][nf], 0, 0, 0);
            }
        }
    }

    int rbase = kq * 4;
    float rs_[4][4];
    float rq_[4][4];
    float cs_[4], cq_[4];
    if (EP2 == 1 || EP2 == 3) {
        #pragma unroll
        for (int a = 0; a < 4; ++a)
            #pragma unroll
            for (int b = 0; b < 4; ++b) { rs_[a][b] = 0.f; rq_[a][b] = 0.f; }
    }
    if (EP2 == 2) {
        #pragma unroll
        for (int a = 0; a < 4; ++a) { cs_[a] = 0.f; cq_[a] = 0.f; }
    }
    #pragma unroll
    for (int nf = 0; nf < 4; ++nf) {
        int n = wn + nf * 16 + col;
        float bn = b2v[n];
        #pragma unroll
        for (int mf = 0; mf < 4; ++mf) {
            #pragma unroll
            for (int r = 0; r < 4; ++r) {
                int m = m0 + wm + mf * 16 + rbase + r;
                float v = acc2[mf][nf][r] + bn;
                if (ACT2 == 1) v = fmaxf(v, 0.f);
                if (ACT2 == 2) v = fast_gelu(v);
                if (EP2 == 1) {
                    float fin = Out[(size_t)m * 128 + n] + v;
                    Out[(size_t)m * 128 + n] = fin;
                    rs_[mf][r] += fin;
                    rq_[mf][r] += fin * fin;
                } else {
                    Out[(size_t)m * 128 + n] = v;
                    if (EP2 == 2) { cs_[nf] += v; cq_[nf] += v * v; }
                    if (EP2 == 3) rq_[mf][r] += v * v;
                }
            }
        }
    }
    if (EP2 == 1) {
        #pragma unroll
        for (int mf = 0; mf < 4; ++mf)
            #pragma unroll
            for (int r = 0; r < 4; ++r) {
                float s = rs_[mf][r], q = rq_[mf][r];
                #pragma unroll
                for (int o = 1; o <= 8; o <<= 1) {
                    s += __shfl_xor(s, o);
                    q += __shfl_xor(q, o);
                }
                rs_[mf][r] = s; rq_[mf][r] = q;
            }
        __syncthreads();
        float* sred = (float*)&Xhi[0][0];   // [128][2]
        float* qred = sred + 256;
        if (col == 0) {
            #pragma unroll
            for (int mf = 0; mf < 4; ++mf)
                #pragma unroll
                for (int r = 0; r < 4; ++r) {
                    int row = wm + mf * 16 + kq * 4 + r;
                    sred[row * 2 + (wn >> 6)] = rs_[mf][r];
                    qred[row * 2 + (wn >> 6)] = rq_[mf][r];
                }
        }
        __syncthreads();
        if (tid < 128) {
            rsum[(size_t)m0 + tid] = sred[tid * 2] + sred[tid * 2 + 1];
            rsq[(size_t)m0 + tid]  = qred[tid * 2] + qred[tid * 2 + 1];
        }
    }
    if (EP2 == 3) {
        #pragma unroll
        for (int mf = 0; mf < 4; ++mf)
            #pragma unroll
            for (int r = 0; r < 4; ++r) {
                float q = rq_[mf][r];
                #pragma unroll
                for (int o = 1; o <= 8; o <<= 1) q += __shfl_xor(q, o);
                rq_[mf][r] = q;
            }
        __syncthreads();
        float* qred = (float*)&Xhi[0][0];   // [128][2]
        if (col == 0) {
            #pragma unroll
            for (int mf = 0; mf < 4; ++mf)
                #pragma unroll
                for (int r = 0; r < 4; ++r) {
                    int row = wm + mf * 16 + kq * 4 + r;
                    qred[row * 2 + (wn >> 6)] = rq_[mf][r];
                }
        }
        __syncthreads();
        if (tid < 128)
            rsq[(size_t)m0 + tid] = qred[tid * 2] + qred[tid * 2 + 1];
    }
    if (EP2 == 2) {
        #pragma unroll
        for (int nf = 0; nf < 4; ++nf) {
            #pragma unroll
            for (int o = 16; o <= 32; o <<= 1) {
                cs_[nf] += __shfl_xor(cs_[nf], o);
                cq_[nf] += __shfl_xor(cq_[nf], o);
            }
        }
        __syncthreads();
        float* colS = (float*)&Xhi[0][0];   // [2][128]
        float* colQ = colS + 256;
        if (kq == 0) {
            #pragma unroll
            for (int nf = 0; nf < 4; ++nf) {
                int n = wn + nf * 16 + col;
                colS[(wm >> 6) * 128 + n] = cs_[nf];
                colQ[(wm >> 6) * 128 + n] = cq_[nf];
            }
        }
        __syncthreads();
        if (tid < 128) {
            rsum[(size_t)blockIdx.x * 256 + tid] = colS[tid] + colS[128 + tid];
            rsum[(size_t)blockIdx.x * 256 + 128 + tid] = colQ[tid] + colQ[128 + tid];
        }
    }
}

// W [128][128] f32 -> Whi/Wlo [n][k] bf16 split (transposed). grid (4,4), block (32,8)
__global__ void wsplit_kernel(const float* __restrict__ W, ushort* __restrict__ Whi,
                              ushort* __restrict__ Wlo) {
    __shared__ float t[32][33];
    int k0 = blockIdx.x * 32, n0 = blockIdx.y * 32;
    int tx = threadIdx.x, ty = threadIdx.y;
    for (int i = ty; i < 32; i += 8)
        t[i][tx] = W[(size_t)(k0 + i) * 128 + n0 + tx];
    __syncthreads();
    for (int i = ty; i < 32; i += 8) {
        float v = t[tx][i];
        ushort h = f2bf(v);
        Whi[(size_t)(n0 + i) * 128 + k0 + tx] = h;
        Wlo[(size_t)(n0 + i) * 128 + k0 + tx] = f2bf(v - bf2f(h));
    }
}

// ---------------------------------------------------------------------------
// Timestep MFMA GEMM v4: 128x128 tile, BK=32, 32 KB LDS -> 4 blocks/CU.
// Same proven 2-phase __syncthreads template as mfma_gemm_kernel, smaller BK.
// A [M][2048] bf16, W [2048][2048] bf16. Epilogue = EPM=1 (gelu+residual+bnf).
// Swizzle (64B rows, 4x16B units): store su=(sj^((srow>>1)&3))*8 pre-swizzled
// global src; read uo=(kq^((col>>1)&3))*8. Conflict-free per 8-lane beat.
// ---------------------------------------------------------------------------
__global__ __launch_bounds__(256)
void mfma_ts4_kernel(const ushort* __restrict__ A, const ushort* __restrict__ W,
                     const float* __restrict__ bias, float* Z,
                     int nx, int nwg, float* __restrict__ bnfP) {
    __shared__ __align__(16) ushort smem[16384];   // 32 KB = 2 x (A 8KB + B 8KB)
    float (*Ol)[132] = (float(*)[132])smem;        // epilogue overlay (16.9 KB)

    int bid = blockIdx.x;
    int cpx = nwg >> 3;
    int swz = (bid & 7) * cpx + (bid >> 3);
    int n0 = (swz % nx) * 128;
    int m0 = (swz / nx) * 128;

    int tid = threadIdx.x;
    int w = tid >> 6, lane = tid & 63;
    int wm = (w >> 1) * 64, wn = (w & 1) * 64;
    int col = lane & 15, kq = lane >> 4;

    int srow = lane >> 2;                    // 0..15 row within 16-row group
    int sj = lane & 3;                       // 16B unit slot within 64B row
    int su = (sj ^ ((srow >> 1) & 3)) * 8;   // pre-swizzled global ushort offset
    int uo = (kq ^ ((col >> 1) & 3)) * 8;    // read-side swizzled unit offset

    float4v acc[4][4];
    #pragma unroll
    for (int i = 0; i < 4; ++i)
        #pragma unroll
        for (int j = 0; j < 4; ++j) acc[i][j] = (float4v){0.f, 0.f, 0.f, 0.f};

    const int Kd = LL;          // 2048
    const int kTiles = 64;      // BK=32

    // prologue: stage K-tile 0 into buffer 0
    #pragma unroll
    for (int it = 0; it < 2; ++it) {
        int R = w * 32 + it * 16;
        async16(A + (size_t)(m0 + R + srow) * Kd + su, smem + R * 32);
        async16(W + (size_t)(n0 + R + srow) * Kd + su, smem + 4096 + R * 32);
    }
    __syncthreads();

    for (int kt = 0; kt < kTiles; ++kt) {
        int cur = kt & 1;
        const ushort* Ac = smem + (cur << 13);
        const ushort* Bc = Ac + 4096;
        if (kt + 1 < kTiles) {
            ushort* An = smem + ((cur ^ 1) << 13);
            ushort* Bn = An + 4096;
            int kb = (kt + 1) << 5;
            #pragma unroll
            for (int it = 0; it < 2; ++it) {
                int R = w * 32 + it * 16;
                async16(A + (size_t)(m0 + R + srow) * Kd + kb + su, An + R * 32);
                async16(W + (size_t)(n0 + R + srow) * Kd + kb + su, Bn + R * 32);
            }
        }
        __builtin_amdgcn_s_setprio(1);
        short8v af[4], bf[4];
        #pragma unroll
        for (int mf = 0; mf < 4; ++mf)
            af[mf] = *(const short8v*)(Ac + (wm + mf * 16 + col) * 32 + uo);
        #pragma unroll
        for (int nf = 0; nf < 4; ++nf)
            bf[nf] = *(const short8v*)(Bc + (wn + nf * 16 + col) * 32 + uo);
        #pragma unroll
        for (int mf = 0; mf < 4; ++mf)
            #pragma unroll
            for (int nf = 0; nf < 4; ++nf)
                acc[mf][nf] = __builtin_amdgcn_mfma_f32_16x16x32_bf16(
                    af[mf], bf[nf], acc[mf][nf], 0, 0, 0);
        __builtin_amdgcn_s_setprio(0);
        __syncthreads();
    }

    // Epilogue (verbatim EPM=1): 4 rounds of 32-n strips through Ol
    int b = m0 >> 7;
    float cs[16], cq[16];
    #pragma unroll
    for (int k2 = 0; k2 < 16; ++k2) { cs[k2] = 0.f; cq[k2] = 0.f; }
    #pragma unroll
    for (int q = 0; q < 4; ++q) {
        __syncthreads();
        #pragma unroll
        for (int nf = 0; nf < 4; ++nf) {
            int gnl = wn + nf * 16;
            if ((gnl >> 5) != q) continue;
            int gn = n0 + gnl + col;
            float bn = bias[gn];
            int nl = gnl - q * 32 + col;
            #pragma unroll
            for (int mf = 0; mf < 4; ++mf) {
                #pragma unroll
                for (int r = 0; r < 4; ++r) {
                    float v = acc[mf][nf][r] + bn;
                    v = fast_gelu(v);
                    Ol[nl][wm + mf * 16 + kq * 4 + r] = v;
                }
            }
        }
        __syncthreads();
        int nloc = tid >> 3, c0 = (tid & 7) * 16;
        int gn = n0 + q * 32 + nloc;
        float* zr = Z + ((size_t)b * LL + gn) * CC + c0;
        #pragma unroll
        for (int i = 0; i < 4; ++i) {
            float4 v = *(float4*)&Ol[nloc][c0 + i * 4];
            float4 o = *(float4*)(zr + i * 4);
            v.x += o.x; v.y += o.y; v.z += o.z; v.w += o.w;
            *(float4*)(zr + i * 4) = v;
            cs[i * 4 + 0] += v.x; cs[i * 4 + 1] += v.y;
            cs[i * 4 + 2] += v.z; cs[i * 4 + 3] += v.w;
            cq[i * 4 + 0] += v.x * v.x; cq[i * 4 + 1] += v.y * v.y;
            cq[i * 4 + 2] += v.z * v.z; cq[i * 4 + 3] += v.w * v.w;
        }
    }
    // per-block feature-BN partials
    __syncthreads();
    float* sred = (float*)smem;         // [32][128]
    float* qred = sred + 4096;          // [32][128]
    int rrow = tid >> 3, cb = (tid & 7) * 16;
    #pragma unroll
    for (int k2 = 0; k2 < 16; ++k2) {
        sred[rrow * 128 + cb + k2] = cs[k2];
        qred[rrow * 128 + cb + k2] = cq[k2];
    }
    __syncthreads();
    if (tid < 128) {
        float a = 0.f;
        for (int r = 0; r < 32; ++r) a += sred[r * 128 + tid];
        bnfP[(size_t)bid * 256 + tid] = a;
    } else {
        int c = tid - 128;
        float a = 0.f;
        for (int r = 0; r < 32; ++r) a += qred[r * 128 + c];
        bnfP[(size_t)bid * 256 + 128 + c] = a;
    }
}

// ---------------------------------------------------------------------------
// bf16 MFMA GEMM (big-K), 2-phase double-buffered prefetch.
// ---------------------------------------------------------------------------
template <int EPM>
__global__ __launch_bounds__(256)
void mfma_gemm_kernel(const ushort* __restrict__ A, const ushort* __restrict__ W,
                      const float* __restrict__ bias, float* Z,
                      int N, int Kd, int LDO, int nx, int nwg,
                      const float* __restrict__ epS, const float* __restrict__ epM,
                      float* __restrict__ bnfP) {
    __shared__ __align__(16) ushort smem[32768];   // 64 KB = 2 x (A 16KB + B 16KB)
    float (*Ol)[132] = (float(*)[132])smem;        // epilogue overlay

    int bid = blockIdx.x;
    int cpx = nwg >> 3;
    int swz = (bid & 7) * cpx + (bid >> 3);
    int n0 = (swz % nx) * 128;
    int m0 = (swz / nx) * 128;

    int tid = threadIdx.x;
    int w = tid >> 6, lane = tid & 63;
    int wm = (w >> 1) * 64, wn = (w & 1) * 64;
    int col = lane & 15, kq = lane >> 4;

    int srow = lane >> 3;                    // 0..7
    int scol = ((lane & 7) ^ srow) << 3;     // pre-swizzled src ushort offset
    int xr = (col & 7) << 4;                 // read-side XOR (bytes)

    float4v acc[4][4];
    #pragma unroll
    for (int i = 0; i < 4; ++i)
        #pragma unroll
        for (int j = 0; j < 4; ++j) acc[i][j] = (float4v){0.f, 0.f, 0.f, 0.f};

    int kTiles = Kd >> 6;

    // prologue: stage K-tile 0 into buffer 0
    #pragma unroll
    for (int it = 0; it < 4; ++it) {
        int rb = (w << 5) + (it << 3);
        async16(A + (size_t)(m0 + rb + srow) * Kd + scol, smem + (rb << 6));
    }
    #pragma unroll
    for (int it = 0; it < 4; ++it) {
        int rb = (w << 5) + (it << 3);
        async16(W + (size_t)(n0 + rb + srow) * Kd + scol, smem + 8192 + (rb << 6));
    }
    __syncthreads();

    for (int kt = 0; kt < kTiles; ++kt) {
        int cur = kt & 1;
        ushort* Ac = smem + (cur << 14);
        ushort* Bc = Ac + 8192;
        if (kt + 1 < kTiles) {
            ushort* An = smem + ((cur ^ 1) << 14);
            ushort* Bn = An + 8192;
            int kb = (kt + 1) << 6;
            #pragma unroll
            for (int it = 0; it < 4; ++it) {
                int rb = (w << 5) + (it << 3);
                async16(A + (size_t)(m0 + rb + srow) * Kd + kb + scol, An + (rb << 6));
            }
            #pragma unroll
            for (int it = 0; it < 4; ++it) {
                int rb = (w << 5) + (it << 3);
                async16(W + (size_t)(n0 + rb + srow) * Kd + kb + scol, Bn + (rb << 6));
            }
        }
        __builtin_amdgcn_s_setprio(1);
        #pragma unroll
        for (int ksub = 0; ksub < 2; ++ksub) {
            int cswz = (((ksub << 6) + (kq << 4)) ^ xr) >> 1;
            short8v af[4], bf[4];
            #pragma unroll
            for (int mf = 0; mf < 4; ++mf)
                af[mf] = *(const short8v*)(Ac + (wm + mf * 16 + col) * 64 + cswz);
            #pragma unroll
            for (int nf = 0; nf < 4; ++nf)
                bf[nf] = *(const short8v*)(Bc + (wn + nf * 16 + col) * 64 + cswz);
            #pragma unroll
            for (int mf = 0; mf < 4; ++mf)
                #pragma unroll
                for (int nf = 0; nf < 4; ++nf)
                    acc[mf][nf] = __builtin_amdgcn_mfma_f32_16x16x32_bf16(
                        af[mf], bf[nf], acc[mf][nf], 0, 0, 0);
        }
        __builtin_amdgcn_s_setprio(0);
        __syncthreads();
    }

    // Epilogue: 4 rounds of 32-n strips through Ol
    int b = m0 >> 7;
    float cs[16], cq[16];
    if (EPM == 1) {
        #pragma unroll
        for (int k2 = 0; k2 < 16; ++k2) { cs[k2] = 0.f; cq[k2] = 0.f; }
    }
    #pragma unroll
    for (int q = 0; q < 4; ++q) {
        __syncthreads();
        #pragma unroll
        for (int nf = 0; nf < 4; ++nf) {
            int gnl = wn + nf * 16;
            if ((gnl >> 5) != q) continue;
            int gn = n0 + gnl + col;
            float bn = (EPM == 2 && gn >= N) ? 0.f : bias[gn];
            int nl = gnl - q * 32 + col;
            #pragma unroll
            for (int mf = 0; mf < 4; ++mf) {
                #pragma unroll
                for (int r = 0; r < 4; ++r) {
                    float v = acc[mf][nf][r] + bn;
                    if (EPM == 1) v = fast_gelu(v);
                    Ol[nl][wm + mf * 16 + kq * 4 + r] = v;
                }
            }
        }
        __syncthreads();
        int nloc = tid >> 3, c0 = (tid & 7) * 16;
        int gn = n0 + q * 32 + nloc;
        if ((EPM == 2 || EPM == 3) && gn >= N) continue;
        float* zr;
        if (EPM == 3)
            zr = Z + (((size_t)(m0 >> 11) * 64 + gn) * 2048) + (m0 & 2047) + c0;
        else
            zr = Z + ((size_t)b * LDO + gn) * CC + c0;
        #pragma unroll
        for (int i = 0; i < 4; ++i) {
            float4 v = *(float4*)&Ol[nloc][c0 + i * 4];
            if (EPM == 1) {
                float4 o = *(float4*)(zr + i * 4);
                v.x += o.x; v.y += o.y; v.z += o.z; v.w += o.w;
                *(float4*)(zr + i * 4) = v;
                cs[i * 4 + 0] += v.x; cs[i * 4 + 1] += v.y;
                cs[i * 4 + 2] += v.z; cs[i * 4 + 3] += v.w;
                cq[i * 4 + 0] += v.x * v.x; cq[i * 4 + 1] += v.y * v.y;
                cq[i * 4 + 2] += v.z * v.z; cq[i * 4 + 3] += v.w * v.w;
            } else if (EPM == 2) {
                int mb = m0 + c0 + i * 4;
                float4 s4 = *(const float4*)(epS + mb);
                float4 m4 = *(const float4*)(epM + mb);
                v.x = v.x * s4.x + m4.x; v.y = v.y * s4.y + m4.y;
                v.z = v.z * s4.z + m4.z; v.w = v.w * s4.w + m4.w;
                *(float4*)(zr + i * 4) = v;
            } else {
                *(float4*)(zr + i * 4) = v;
            }
        }
    }
    if (EPM == 1) {
        __syncthreads();
        float* sred = (float*)smem;         // [32][128]
        float* qred = sred + 4096;          // [32][128]
        int rrow = tid >> 3, cb = (tid & 7) * 16;
        #pragma unroll
        for (int k2 = 0; k2 < 16; ++k2) {
            sred[rrow * 128 + cb + k2] = cs[k2];
            qred[rrow * 128 + cb + k2] = cq[k2];
        }
        __syncthreads();
        if (tid < 128) {
            float a = 0.f;
            for (int r = 0; r < 32; ++r) a += sred[r * 128 + tid];
            bnfP[(size_t)bid * 256 + tid] = a;
        } else {
            int c = tid - 128;
            float a = 0.f;
            for (int r = 0; r < 32; ++r) a += qred[r * 128 + c];
            bnfP[(size_t)bid * 256 + 128 + c] = a;
        }
    }
}

// W [K][N] f32 -> WT [Npad][K] bf16 (zero-filled for n >= N).
__global__ void wtrans_kernel(const float* __restrict__ W, ushort* __restrict__ WT,
                              int Kd, int N) {
    __shared__ float t[32][33];
    int k0 = blockIdx.x * 32, n0 = blockIdx.y * 32;
    int tx = threadIdx.x, ty = threadIdx.y;
    for (int i = ty; i < 32; i += 8) {
        int n = n0 + tx;
        t[i][tx] = (n < N) ? W[(size_t)(k0 + i) * N + n] : 0.f;
    }
    __syncthreads();
    for (int i = ty; i < 32; i += 8)
        WT[(size_t)(n0 + i) * Kd + k0 + tx] = f2bf(t[tx][i]);
}

// ---------------------------------------------------------------------------
__global__ void cn_split_kernel(const float* __restrict__ ce, ushort* __restrict__ ch,
                                ushort* __restrict__ cl) {
    int k = blockIdx.x, h = threadIdx.x;
    if (k >= KK) {
        ch[(size_t)k * 128 + h] = 0;
        cl[(size_t)k * 128 + h] = 0;
        return;
    }
    __shared__ float sh[128];
    float v = ce[(size_t)k * HH + h];
    sh[h] = v * v;
    __syncthreads();
    for (int o = 64; o >= 1; o >>= 1) {
        if (h < o) sh[h] += sh[h + o];
        __syncthreads();
    }
    float nv = v / (sqrtf(sh[0]) + 1e-8f);
    ushort hh = f2bf(nv);
    ch[(size_t)k * 128 + h] = hh;
    cl[(size_t)k * 128 + h] = f2bf(nv - bf2f(hh));
}

// Qp bf16 [128][128] (rows >= 64 zero), qb f32 [128]
__global__ void qprime_kernel(const float* __restrict__ Q, const float* __restrict__ wk_w,
                              const float* __restrict__ wk_b, ushort* __restrict__ qpb,
                              float* __restrict__ qbp) {
    int k = blockIdx.x;
    int hp = threadIdx.x;
    if (k >= KK) {
        qpb[(size_t)k * HH + hp] = 0;
        if (hp == 0) qbp[k] = 0.f;
        return;
    }
    __shared__ float qrow[128];
    __shared__ float red[128];
    qrow[hp] = Q[(size_t)k * HH + hp];
    __syncthreads();
    float s = 0.f;
    for (int h = 0; h < HH; ++h) s = fmaf(qrow[h], wk_w[(size_t)hp * HH + h], s);
    const float rs = 0.088388347648318447f;
    qpb[(size_t)k * HH + hp] = f2bf(s * rs);
    red[hp] = qrow[hp] * wk_b[hp];
    __syncthreads();
    for (int o = 64; o >= 1; o >>= 1) {
        if (hp < o) red[hp] += red[hp + o];
        __syncthreads();
    }
    if (hp == 0) qbp[k] = red[0] * rs;
}

// ---------------------------------------------------------------------------
__global__ __launch_bounds__(256)
void pmask_kernel(const float* __restrict__ sp, const float* __restrict__ rn,
                  const float* __restrict__ bern, unsigned char* __restrict__ Mt,
                  float* __restrict__ ppart) {
    int b = blockIdx.y;
    int l0 = blockIdx.x * 32;
    int tid = threadIdx.x;
    int wv = tid >> 6, lane = tid & 63;
    __shared__ float Msh[64][33];
    __shared__ float psum[4][64];
    float pa = 0.f;
    for (int tt = 0; tt < 8; ++tt) {
        int l = l0 + wv * 8 + tt;
        size_t tok = (size_t)b * LL + l;
        float s = sp[tok * 64 + lane] * rn[tok];
        float mx = s;
        #pragma unroll
        for (int o = 32; o >= 1; o >>= 1) mx = fmaxf(mx, __shfl_xor(mx, o));
        float ev = expf(s - mx);
        float sm = ev;
        #pragma unroll
        for (int o = 32; o >= 1; o >>= 1) sm += __shfl_xor(sm, o);
        float p = ev / sm;
        pa += p;
        Msh[lane][wv * 8 + tt] = (bern[tok * KK + lane] < p) ? 1.f : 0.f;
    }
    psum[wv][lane] = pa;
    __syncthreads();
    for (int q = tid; q < 64 * 32; q += 256) {
        int k = q >> 5, j = q & 31;
        Mt[((size_t)b * KK + k) * LL + l0 + j] = (unsigned char)Msh[k][j];
    }
    if (tid < 64)
        ppart[((size_t)b * (LL / 32) + blockIdx.x) * KK + tid] =
            psum[0][tid] + psum[1][tid] + psum[2][tid] + psum[3][tid];
}

__global__ void pmean_final_kernel(const float* __restrict__ part, float* __restrict__ pm) {
    int b = blockIdx.x, k = threadIdx.x;
    float s = 0.f;
    for (int i = 0; i < LL / 32; ++i) s += part[((size_t)b * (LL / 32) + i) * KK + k];
    pm[b * KK + k] = s * (1.f / LL);
}

// ---------------------------------------------------------------------------
__global__ __launch_bounds__(256)
void aw_kernel(float* __restrict__ S, const unsigned char* __restrict__ Mt) {
    size_t base = (size_t)blockIdx.x * LL;
    int tid = threadIdx.x;
    float t[8];
    float mx = -1e30f;
    #pragma unroll
    for (int i = 0; i < 8; ++i) {
        int l = tid + i * 256;
        float v = expf(S[base + l]) * (float)Mt[base + l];
        t[i] = v;
        mx = fmaxf(mx, v);
    }
    __shared__ float shA[4];
    __shared__ float shB[4];
    #pragma unroll
    for (int o = 32; o >= 1; o >>= 1) mx = fmaxf(mx, __shfl_xor(mx, o));
    if ((tid & 63) == 0) shA[tid >> 6] = mx;
    __syncthreads();
    mx = fmaxf(fmaxf(shA[0], shA[1]), fmaxf(shA[2], shA[3]));
    float e[8];
    float sum = 0.f;
    #pragma unroll
    for (int i = 0; i < 8; ++i) { e[i] = expf(t[i] - mx); sum += e[i]; }
    #pragma unroll
    for (int o = 32; o >= 1; o >>= 1) sum += __shfl_xor(sum, o);
    if ((tid & 63) == 0) shB[tid >> 6] = sum;
    __syncthreads();
    sum = (shB[0] + shB[1]) + (shB[2] + shB[3]);
    float inv = 1.f / sum;
    #pragma unroll
    for (int i = 0; i < 8; ++i) S[base + tid + i * 256] = e[i] * inv;
}

// ---------------------------------------------------------------------------
__global__ __launch_bounds__(256)
void awh_part_kernel(const float* __restrict__ AWs, const float* __restrict__ hmat,
                     float* __restrict__ part) {
    __shared__ float AT[32][64];
    __shared__ float VT[32][128];
    int b = blockIdx.y, sp = blockIdx.x;
    int tid = threadIdx.x;
    int tx = tid & 15, ty = tid >> 4;
    float acc[4][8] = {};
    const float* Ab = AWs + (size_t)b * KK * LL + sp * 512;
    const float* Vb = hmat + ((size_t)b * LL + sp * 512) * HH;
    for (int lt = 0; lt < 512; lt += 32) {
        __syncthreads();
        #pragma unroll
        for (int it = 0; it < 2; ++it) {
            int q = tid + it * 256;
            int row = q >> 3;
            int lq = (q & 7) << 2;
            float4 v = *(const float4*)(Ab + (size_t)row * LL + lt + lq);
            AT[lq][row] = v.x; AT[lq + 1][row] = v.y;
            AT[lq + 2][row] = v.z; AT[lq + 3][row] = v.w;
        }
        #pragma unroll
        for (int it = 0; it < 4; ++it) {
            int q = tid + it * 256;
            int lr = q >> 5;
            int hc = (q & 31) << 2;
            *(float4*)&VT[lr][hc] = *(const float4*)(Vb + (size_t)(lt + lr) * HH + hc);
        }
        __syncthreads();
        #pragma unroll
        for (int l = 0; l < 32; ++l) {
            float av[4], vv[8];
            *(float4*)&av[0] = *(const float4*)&AT[l][ty * 4];
            *(float4*)&vv[0] = *(const float4*)&VT[l][tx * 4];
            *(float4*)&vv[4] = *(const float4*)&VT[l][64 + tx * 4];
            #pragma unroll
            for (int i = 0; i < 4; ++i)
                #pragma unroll
                for (int j = 0; j < 8; ++j)
                    acc[i][j] = fmaf(av[i], vv[j], acc[i][j]);
        }
    }
    #pragma unroll
    for (int i = 0; i < 4; ++i) {
        int k = ty * 4 + i;
        #pragma unroll
        for (int jj = 0; jj < 8; jj += 4) {
            int h = (jj ? 64 + tx * 4 : tx * 4);
            float o[4];
            #pragma unroll
            for (int j = 0; j < 4; ++j) o[j] = acc[i][jj + j];
            *(float4*)(part + (((size_t)b * 4 + sp) * KK + k) * HH + h) = *(float4*)o;
        }
    }
}

__global__ void awh_reduce_kernel(const float* __restrict__ part, float* __restrict__ awh) {
    int bk = blockIdx.x, h = threadIdx.x;
    int b = bk >> 6, k = bk & 63;
    float s = 0.f;
    #pragma unroll
    for (int sp = 0; sp < 4; ++sp)
        s += part[(((size_t)b * 4 + sp) * KK + k) * HH + h];
    awh[(size_t)bk * HH + h] = s;
}

__global__ void newce_kernel(const float* __restrict__ ao, const float* __restrict__ pm,
                             float* __restrict__ outTail) {
    int k = blockIdx.x, h = threadIdx.x;
    float s = 0.f;
    for (int b = 0; b < BB; ++b)
        s += ao[((size_t)b * KK + k) * HH + h] * pm[b * KK + k];
    outTail[(size_t)k * HH + h] = s * (1.f / BB);
}

// z_out = (in - mean2)*rstd2; also emits per-row sum/sumsq. grid (32, B), block 256
__global__ void revin_apply_kernel(const float* __restrict__ in, float* __restrict__ out,
                                   const float* __restrict__ mu, const float* __restrict__ rs,
                                   float* __restrict__ rsum, float* __restrict__ rsq) {
    int b = blockIdx.y;
    size_t base = (size_t)b * LL * CC + (size_t)blockIdx.x * 8192;
    int c0 = (threadIdx.x * 4) & 127;
    int lane = threadIdx.x & 63;
    float4 m4 = *(const float4*)(mu + b * CC + c0);
    float4 r4 = *(const float4*)(rs + b * CC + c0);
    #pragma unroll
    for (int j = 0; j < 8; ++j) {
        float4 v = *(const float4*)(in + base + threadIdx.x * 4 + j * 1024);
        v.x = (v.x - m4.x) * r4.x; v.y = (v.y - m4.y) * r4.y;
        v.z = (v.z - m4.z) * r4.z; v.w = (v.w - m4.w) * r4.w;
        *(float4*)(out + base + threadIdx.x * 4 + j * 1024) = v;
        float s = v.x + v.y + v.z + v.w;
        float q = v.x * v.x + v.y * v.y + v.z * v.z + v.w * v.w;
        #pragma unroll
        for (int o = 1; o <= 16; o <<= 1) {
            s += __shfl_xor(s, o);
            q += __shfl_xor(q, o);
        }
        if ((lane & 31) == 0) {
            size_t row = (base + (size_t)threadIdx.x * 4 + (size_t)j * 1024) >> 7;
            rsum[row] = s;
            rsq[row] = q;
        }
    }
}

// timestep-BN final: per l over 64 b's of row stats. grid 8, block 256
__global__ void bnt_final_kernel(const float* __restrict__ rsum, const float* __restrict__ rsq,
                                 float* __restrict__ mu, float* __restrict__ rv) {
    int l = blockIdx.x * 256 + threadIdx.x;
    float s = 0.f, q = 0.f;
    for (int b = 0; b < BB; ++b) {
        s += rsum[(size_t)b * LL + l];
        q += rsq[(size_t)b * LL + l];
    }
    float m = s * (1.f / (BB * CC));
    float var = q * (1.f / (BB * CC)) - m * m;
    var = fmaxf(var, 0.f);
    mu[l] = m;
    rv[l] = 1.f / sqrtf(var + EPSf);
}

// ---------------------------------------------------------------------------
// [B,L,C] f32 -> [B,C,L] bf16, optional timestep-BN. v2: 64(l)x32(c) tiles,
// uint4 (8 bf16) coalesced writes. grid (L/64, C/32, B), block 256.
// ---------------------------------------------------------------------------
template <bool DO_BN>
__global__ __launch_bounds__(256)
void transpose_bn_kernel(const float* __restrict__ in, ushort* __restrict__ out,
                         const float* __restrict__ mu, const float* __restrict__ rv,
                         const float* __restrict__ g, const float* __restrict__ be) {
    __shared__ ushort tile[32][72];   // [c][l] bf16, padded
    int l0 = blockIdx.x * 64, c0 = blockIdx.y * 32, b = blockIdx.z;
    int t = threadIdx.x;
    const float* ib = in + ((size_t)b * LL + l0) * CC + c0;
    #pragma unroll
    for (int it = 0; it < 2; ++it) {
        int idx = t + it * 256;
        int row = idx >> 3;           // 0..63 (l offset)
        int c = (idx & 7) * 4;        // 0..28
        float4 v = *(const float4*)(ib + (size_t)row * CC + c);
        if (DO_BN) {
            int l = l0 + row;
            float sc = rv[l] * g[l];
            float m = mu[l], bb = be[l];
            v.x = (v.x - m) * sc + bb; v.y = (v.y - m) * sc + bb;
            v.z = (v.z - m) * sc + bb; v.w = (v.w - m) * sc + bb;
        }
        tile[c    ][row] = f2bf(v.x);
        tile[c + 1][row] = f2bf(v.y);
        tile[c + 2][row] = f2bf(v.z);
        tile[c + 3][row] = f2bf(v.w);
    }
    __syncthreads();
    int cc = t >> 3, l8 = (t & 7) * 8;
    ushort* ob = out + (size_t)b * CC * LL + (size_t)(c0 + cc) * LL + l0 + l8;
    *(uint4*)ob = *(const uint4*)&tile[cc][l8];
}

// feature-BN two-stage reduce: mid over 16 blocks each; final over 64 mids
__global__ void bnf_mid_kernel(const float* __restrict__ part, float* __restrict__ mid) {
    int gblk = blockIdx.x, t = threadIdx.x;   // grid 64, block 256
    float s = 0.f;
    #pragma unroll
    for (int i = 0; i < 16; ++i)
        s += part[(size_t)(gblk * 16 + i) * 256 + t];
    mid[(size_t)gblk * 256 + t] = s;
}

__global__ void bnf_final_kernel(const float* __restrict__ mid, const float* __restrict__ g,
                                 const float* __restrict__ be, float* __restrict__ mu,
                                 float* __restrict__ sA, float* __restrict__ tA) {
    int c = threadIdx.x;   // block 128
    float s = 0.f, s2 = 0.f;
    #pragma unroll
    for (int i = 0; i < 64; ++i) {
        s += mid[(size_t)i * 256 + c];
        s2 += mid[(size_t)i * 256 + 128 + c];
    }
    float m = s / (float)(BB * LL);
    float var = s2 / (float)(BB * LL) - m * m;
    var = fmaxf(var, 0.f);
    float rvv = 1.f / sqrtf(var + EPSf);
    mu[c] = m;
    sA[c] = rvv * g[c];
    tA[c] = be[c];
}

// ---------------------------------------------------------------------------
extern "C" void kernel_launch(void* const* d_in, const int* in_sizes, int n_in,
                              void* d_out, int out_size, void* d_ws, size_t ws_size,
                              hipStream_t stream) {
    const float* x     = (const float*)d_in[0];
    const float* bern  = (const float*)d_in[1];
    const float* ce    = (const float*)d_in[2];
    const float* wq_w  = (const float*)d_in[3];
    const float* wq_b  = (const float*)d_in[4];
    const float* wk_w  = (const float*)d_in[5];
    const float* wk_b  = (const float*)d_in[6];
    const float* wv_w  = (const float*)d_in[7];
    const float* wv_b  = (const float*)d_in[8];
    const float* cm_w1 = (const float*)d_in[9];
    const float* cm_b1 = (const float*)d_in[10];
    const float* cm_w2 = (const float*)d_in[11];
    const float* cm_b2 = (const float*)d_in[12];
    const float* tm_w1 = (const float*)d_in[13];
    const float* tm_b1 = (const float*)d_in[14];
    const float* tm_w2 = (const float*)d_in[15];
    const float* tm_b2 = (const float*)d_in[16];
    const float* bn_t_g = (const float*)d_in[17];
    const float* bn_t_b = (const float*)d_in[18];
    const float* lin_t_w = (const float*)d_in[19];
    const float* lin_t_b = (const float*)d_in[20];
    const float* bn_f_g = (const float*)d_in[21];
    const float* bn_f_b = (const float*)d_in[22];
    const float* f1_w  = (const float*)d_in[23];
    const float* f1_b  = (const float*)d_in[24];
    const float* f2_w  = (const float*)d_in[25];
    const float* f2_b  = (const float*)d_in[26];
    const float* out_w = (const float*)d_in[27];
    const float* out_b = (const float*)d_in[28];
    (void)in_sizes; (void)n_in; (void)out_size;

    float* y = (float*)d_out;                         // [B,P,C]
    float* ceOut = y + (size_t)BB * PP * CC;          // [K,H]

    float* ws = (float*)d_ws;
    size_t off = 0;
    auto alloc = [&](size_t n) { float* p = ws + off; off += n; return p; };
    float* mean1  = alloc(BB * CC);
    float* rstd1  = alloc(BB * CC);
    float* std1   = alloc(BB * CC);
    float* mean2  = alloc(BB * CC);
    float* rstd2  = alloc(BB * CC);
    float* std2   = alloc(BB * CC);
    float* bnmu   = alloc(LL);
    float* bnrv   = alloc(LL);
    float* bfpart = alloc(1024 * 256);
    float* bfmid  = alloc(64 * 256);
    float* bfmu   = alloc(CC);
    float* bfs    = alloc(CC);
    float* bft    = alloc(CC);
    float* cxpart = alloc(BB * 8 * 256);                      // colstats-1 partials
    float* cpart2 = alloc(1024 * 256);                        // colstats-2 partials (tm pair)
    float* qbuf   = alloc(KK * HH);
    ushort* qpb   = (ushort*)alloc(128 * 128 / 2);            // Qp bf16 padded
    float* qbp    = alloc(128);
    ushort* cnbh  = (ushort*)alloc(8192);                     // codebook hi bf16 [128][128]
    ushort* cnbl  = (ushort*)alloc(8192);                     // codebook lo
    float* rn     = alloc((size_t)BB * LL);
    float* rsum   = alloc((size_t)BB * LL);                   // per-row z sums
    float* rsq    = alloc((size_t)BB * LL);
    float* ppart  = alloc((size_t)BB * (LL / 32) * KK);
    float* pmean  = alloc(BB * KK);
    float* awhprt = alloc((size_t)BB * 4 * KK * HH);
    float* awh    = alloc((size_t)BB * KK * HH);
    float* aobuf  = alloc((size_t)BB * KK * HH);
    ushort* wsp   = (ushort*)alloc(7 * 2 * 16384 / 2);        // 7 split 128x128 weights
    ushort* wtT   = (ushort*)alloc((size_t)LL * LL / 2);      // lin_t_w^T bf16 [2048][2048]
    ushort* owT   = (ushort*)alloc((size_t)384 * LL / 2);     // out_w^T bf16 [384][2048]
    float* S      = alloc((size_t)BB * KK * LL);
    float* buf0   = alloc((size_t)BB * LL * CC);
    float* buf2   = alloc((size_t)BB * LL * CC);
    unsigned char* Mt = (unsigned char*)(ws + off);           // [B,K,L] u8
    ushort* abf = (ushort*)S;       // bf16 [B,C,L] overlay on S (mixer phase)
    ushort* hb  = (ushort*)buf0;    // bf16 h [B,L,H] overlay on buf0 (attn phase)
    (void)ws_size;

    auto whi = [&](int i) { return wsp + (size_t)i * 2 * 16384; };
    auto wlo = [&](int i) { return wsp + (size_t)i * 2 * 16384 + 16384; };

    const int ML = BB * LL;      // 131072
    dim3 tb(32, 8);
    dim3 tgrid(LL / 64, CC / 32, BB);
    dim3 wsg(4, 4);

    // 0) weight prep
    wtrans_kernel<<<dim3(LL / 32, LL / 32), tb, 0, stream>>>(lin_t_w, wtT, LL, LL);
    wtrans_kernel<<<dim3(LL / 32, 12), tb, 0, stream>>>(out_w, owT, LL, PP);
    wsplit_kernel<<<wsg, tb, 0, stream>>>(cm_w1, whi(0), wlo(0));
    wsplit_kernel<<<wsg, tb, 0, stream>>>(cm_w2, whi(1), wlo(1));
    wsplit_kernel<<<wsg, tb, 0, stream>>>(tm_w1, whi(2), wlo(2));
    wsplit_kernel<<<wsg, tb, 0, stream>>>(tm_w2, whi(3), wlo(3));
    wsplit_kernel<<<wsg, tb, 0, stream>>>(f1_w, whi(4), wlo(4));
    wsplit_kernel<<<wsg, tb, 0, stream>>>(f2_w, whi(5), wlo(5));
    wsplit_kernel<<<wsg, tb, 0, stream>>>(wv_w, whi(6), wlo(6));

    // 1) RevIN-1 stats (two-stage)
    colstats_part_kernel<<<dim3(8, BB), 256, 0, stream>>>(x, cxpart);
    colstats_final_kernel<<<dim3(BB), dim3(128), 0, stream>>>(cxpart, mean1, rstd1, std1);
    // 2) h = buf2 (fused split pair) + per-row sumsq -> rsq (for rownorm)
    mfma_sq2_kernel<1, 1, 0, 3, 1><<<dim3(ML / 128), 256, 0, stream>>>(
        x, whi(0), wlo(0), cm_b1, whi(1), wlo(1), cm_b2, buf2, mean1, rstd1, nullptr, CC,
        nullptr, rsq);
    rn_final_kernel<<<dim3(ML / 256), 256, 0, stream>>>(rsq, rn);
    // 3) Q, Qp(bf16), qb ; split codebook
    gemm_kernel<<<dim3(1, 1), 256, 0, stream>>>(ce, wq_w, wq_b, qbuf,
        KK, HH, HH, HH, HH, HH);
    qprime_kernel<<<dim3(128), dim3(128), 0, stream>>>(qbuf, wk_w, wk_b, qpb, qbp);
    cn_split_kernel<<<dim3(128), dim3(128), 0, stream>>>(ce, cnbh, cnbl);
    // 4) routing scores via split-precision MFMA (also emits hb = bf16 h)
    mfma_sq_kernel<0, 0, 2><<<dim3(ML / 128), 256, 0, stream>>>(
        buf2, cnbh, cnbl, nullptr, S, nullptr, nullptr, nullptr, 0, hb);
    // 5) softmax/mask/p-mean
    pmask_kernel<<<dim3(LL / 32, BB), 256, 0, stream>>>(S, rn, bern, Mt, ppart);
    pmean_final_kernel<<<dim3(BB), dim3(64), 0, stream>>>(ppart, pmean);
    // 6) attn scores via MFMA: S[b][k][l] = Qp.h + qb   (overwrites S, k-major)
    mfma_gemm_kernel<3><<<dim3(1024), 256, 0, stream>>>(
        hb, qpb, qbp, S, KK, 128, 0, 1, 1024, nullptr, nullptr, nullptr);
    // 7) masked double-exp softmax
    aw_kernel<<<dim3(BB * KK), 256, 0, stream>>>(S, Mt);
    // 8) awh -> ao -> cluster update
    awh_part_kernel<<<dim3(4, BB), 256, 0, stream>>>(S, buf2, awhprt);
    awh_reduce_kernel<<<dim3(BB * KK), dim3(128), 0, stream>>>(awhprt, awh);
    mfma_sq_kernel<0, 0, 0><<<dim3((BB * KK) / 128), 256, 0, stream>>>(
        awh, whi(6), wlo(6), wv_b, aobuf, nullptr, nullptr, nullptr, 0, nullptr);
    newce_kernel<<<dim3(KK), dim3(128), 0, stream>>>(aobuf, pmean, ceOut);
    // 9) temporal module (fused split pair): h2 = buf0, emits column-stat partials
    mfma_sq2_kernel<0, 1, 0, 2, 1><<<dim3(ML / 128), 256, 0, stream>>>(
        buf2, whi(2), wlo(2), tm_b1, whi(3), wlo(3), tm_b2, buf0,
        nullptr, nullptr, nullptr, 0, cpart2, nullptr);
    // 10) RevIN-2 stats (from fused partials) + apply: z = buf2
    colstats2_final_kernel<<<dim3(BB), dim3(128), 0, stream>>>(cpart2, mean2, rstd2, std2);
    revin_apply_kernel<<<dim3(32, BB), 256, 0, stream>>>(buf0, buf2, mean2, rstd2, rsum, rsq);
    // 11) 4 mixer blocks
    for (int blkI = 0; blkI < 4; ++blkI) {
        bnt_final_kernel<<<dim3(8), 256, 0, stream>>>(rsum, rsq, bnmu, bnrv);
        transpose_bn_kernel<true><<<tgrid, 256, 0, stream>>>(buf2, abf, bnmu, bnrv, bn_t_g, bn_t_b);
        mfma_ts4_kernel<<<dim3(1024), 256, 0, stream>>>(
            abf, wtT, lin_t_b, buf2, 16, 1024, bfpart);
        bnf_mid_kernel<<<dim3(64), 256, 0, stream>>>(bfpart, bfmid);
        bnf_final_kernel<<<dim3(1), dim3(128), 0, stream>>>(bfmid, bn_f_g, bn_f_b, bfmu, bfs, bft);
        mfma_sq2_kernel<2, 2, 0, 1, 0><<<dim3(ML / 128), 256, 0, stream>>>(
            buf2, whi(4), wlo(4), f1_b, whi(5), wlo(5), f2_b, buf2, bfmu, bfs, bft, 0,
            rsum, rsq);
    }
    // 12) head via MFMA: y[b,p,c] = (z^T @ out_w + out_b) * std2 + mean2
    transpose_bn_kernel<false><<<tgrid, 256, 0, stream>>>(buf2, abf,
        nullptr, nullptr, nullptr, nullptr);
    mfma_gemm_kernel<2><<<dim3(192), 256, 0, stream>>>(
        abf, owT, out_b, y, PP, LL, PP, 3, 192, std2, mean2, nullptr);
}

// Round 19
// 1249.121 us; speedup vs baseline: 1.0970x; 1.0236x over previous
//
#include <hip/hip_runtime.h>
#include <math.h>

#define BB 64
#define LL 2048
#define CC 128
#define HH 128
#define KK 64
#define PP 336
#define EPSf 1e-5f

typedef __attribute__((ext_vector_type(8))) short short8v;
typedef __attribute__((ext_vector_type(4))) float float4v;

__device__ inline ushort f2bf(float f) {
    union { float f; unsigned u; } v; v.f = f;
    unsigned r = (v.u + 0x7FFFu + ((v.u >> 16) & 1u)) >> 16;
    return (ushort)r;
}
__device__ inline float bf2f(ushort h) {
    union { unsigned u; float f; } v; v.u = ((unsigned)h) << 16;
    return v.f;
}

// exact-GELU via Abramowitz-Stegun 7.1.26 erf (|err| <= 1.5e-7)
__device__ inline float fast_gelu(float v) {
    float x = 0.70710678118654752f * v;
    float ax = fabsf(x);
    float t = 1.f / fmaf(0.3275911f, ax, 1.f);
    float p = t * fmaf(t, fmaf(t, fmaf(t, fmaf(t, 1.061405429f, -1.453152027f),
                                       1.421413741f), -0.284496736f), 0.254829592f);
    float er = fmaf(-p, __expf(-ax * ax), 1.f);
    er = (x < 0.f) ? -er : er;
    return 0.5f * v * (1.f + er);
}

// async 16B global -> LDS (wave-uniform LDS base + lane*16, per-lane global src)
__device__ __forceinline__ void async16(const ushort* g, ushort* l) {
    __builtin_amdgcn_global_load_lds(
        (const __attribute__((address_space(1))) void*)g,
        (__attribute__((address_space(3))) void*)l, 16, 0, 0);
}

// ---------------------------------------------------------------------------
// RevIN column stats, two-stage. part: grid (8, B), block 256.
// ---------------------------------------------------------------------------
__global__ __launch_bounds__(256)
void colstats_part_kernel(const float* __restrict__ x, float* __restrict__ part) {
    int b = blockIdx.y, chunk = blockIdx.x;
    int t = threadIdx.x;
    int c4 = (t & 31) * 4, rg = t >> 5;
    const float* xb = x + ((size_t)b * LL + chunk * 256) * CC;
    float4 s = make_float4(0.f, 0.f, 0.f, 0.f);
    float4 q = make_float4(0.f, 0.f, 0.f, 0.f);
    for (int l = rg; l < 256; l += 8) {
        float4 v = *(const float4*)(xb + (size_t)l * CC + c4);
        s.x += v.x; s.y += v.y; s.z += v.z; s.w += v.w;
        q.x += v.x * v.x; q.y += v.y * v.y; q.z += v.z * v.z; q.w += v.w * v.w;
    }
    __shared__ float ls[8][128];
    __shared__ float lq[8][128];
    *(float4*)&ls[rg][c4] = s;
    *(float4*)&lq[rg][c4] = q;
    __syncthreads();
    if (t < 128) {
        float a = 0.f, d = 0.f;
        #pragma unroll
        for (int i = 0; i < 8; ++i) { a += ls[i][t]; d += lq[i][t]; }
        part[((size_t)b * 8 + chunk) * 256 + t] = a;
        part[((size_t)b * 8 + chunk) * 256 + 128 + t] = d;
    }
}

__global__ void colstats_final_kernel(const float* __restrict__ part, float* __restrict__ mean,
                                      float* __restrict__ rstd, float* __restrict__ stdv) {
    int b = blockIdx.x, c = threadIdx.x;
    float s = 0.f, q = 0.f;
    #pragma unroll
    for (int i = 0; i < 8; ++i) {
        s += part[((size_t)b * 8 + i) * 256 + c];
        q += part[((size_t)b * 8 + i) * 256 + 128 + c];
    }
    float mu = s * (1.f / LL);
    float var = q * (1.f / LL) - mu * mu;
    var = fmaxf(var, 0.f);
    float sd = sqrtf(var + EPSf);
    mean[b * CC + c] = mu;
    stdv[b * CC + c] = sd;
    rstd[b * CC + c] = 1.f / sd;
}

__global__ void colstats2_final_kernel(const float* __restrict__ cpart, float* __restrict__ mean,
                                       float* __restrict__ rstd, float* __restrict__ stdv) {
    int b = blockIdx.x, c = threadIdx.x;
    float s = 0.f, q = 0.f;
    #pragma unroll
    for (int i = 0; i < 16; ++i) {
        s += cpart[((size_t)b * 16 + i) * 256 + c];
        q += cpart[((size_t)b * 16 + i) * 256 + 128 + c];
    }
    float mu = s * (1.f / LL);
    float var = q * (1.f / LL) - mu * mu;
    var = fmaxf(var, 0.f);
    float sd = sqrtf(var + EPSf);
    mean[b * CC + c] = mu;
    stdv[b * CC + c] = sd;
    rstd[b * CC + c] = 1.f / sd;
}

// rn[i] = 1/(sqrt(rowsumsq)+1e-8); grid 512, block 256
__global__ void rn_final_kernel(const float* __restrict__ rsq, float* __restrict__ rn) {
    size_t i = (size_t)blockIdx.x * 256 + threadIdx.x;
    rn[i] = 1.f / (sqrtf(rsq[i]) + 1e-8f);
}

// ---------------------------------------------------------------------------
// plain f32 VALU GEMM (tiny Q-GEMM only)
// ---------------------------------------------------------------------------
__global__ __launch_bounds__(256)
void gemm_kernel(const float* __restrict__ A, const float* __restrict__ W,
                 const float* __restrict__ bias, float* __restrict__ Out,
                 int M, int N, int Kd, int lda, int ldw, int ldo) {
    __shared__ float As[32][128];
    __shared__ float Ws[32][128];
    int tid = threadIdx.x;
    int tx = tid & 15, ty = tid >> 4;
    int n0 = blockIdx.x * 128;
    int m0 = blockIdx.y * 128;
    float acc[8][8] = {};

    for (int kt = 0; kt < Kd; kt += 32) {
        __syncthreads();
        #pragma unroll
        for (int it = 0; it < 4; ++it) {
            int q = tid + it * 256;
            int row = q >> 3;
            int kq = (q & 7) << 2;
            float4 v = make_float4(0.f, 0.f, 0.f, 0.f);
            int m = m0 + row;
            if (m < M) v = *(const float4*)(A + (size_t)m * lda + kt + kq);
            As[kq    ][row] = v.x;
            As[kq + 1][row] = v.y;
            As[kq + 2][row] = v.z;
            As[kq + 3][row] = v.w;
        }
        #pragma unroll
        for (int it = 0; it < 4; ++it) {
            int q = tid + it * 256;
            int kr = q >> 5;
            int nc = (q & 31) << 2;
            int n = n0 + nc;
            float4 v = make_float4(0.f, 0.f, 0.f, 0.f);
            if (n < N) v = *(const float4*)(W + (size_t)(kt + kr) * ldw + n);
            *(float4*)&Ws[kr][nc] = v;
        }
        __syncthreads();
        #pragma unroll
        for (int k = 0; k < 32; ++k) {
            float a[8], w[8];
            *(float4*)&a[0] = *(const float4*)&As[k][ty * 8];
            *(float4*)&a[4] = *(const float4*)&As[k][ty * 8 + 4];
            *(float4*)&w[0] = *(const float4*)&Ws[k][tx * 4];
            *(float4*)&w[4] = *(const float4*)&Ws[k][64 + tx * 4];
            #pragma unroll
            for (int i = 0; i < 8; ++i)
                #pragma unroll
                for (int j = 0; j < 8; ++j)
                    acc[i][j] = fmaf(a[i], w[j], acc[i][j]);
        }
    }

    #pragma unroll
    for (int i = 0; i < 8; ++i) {
        int m = m0 + ty * 8 + i;
        if (m >= M) continue;
        #pragma unroll
        for (int jj = 0; jj < 8; jj += 4) {
            int n = n0 + (jj ? 64 + tx * 4 : tx * 4);
            if (n >= N) continue;
            float o[4];
            #pragma unroll
            for (int j = 0; j < 4; ++j)
                o[j] = acc[i][jj + j] + (bias ? bias[n + j] : 0.f);
            *(float4*)(Out + (size_t)m * ldo + n) = *(float4*)o;
        }
    }
}

// ---------------------------------------------------------------------------
// Split-precision MFMA GEMM for K=128 (A f32 [M][128], W split bf16 [128][128]).
// EP: 0 -> Out[m*128+n]; 2 -> Out[m*64+n] only n<64.
// ---------------------------------------------------------------------------
template <int NORM, int ACT, int EP>
__global__ __launch_bounds__(256)
void mfma_sq_kernel(const float* __restrict__ A, const ushort* __restrict__ Whi,
                    const ushort* __restrict__ Wlo, const float* __restrict__ bias,
                    float* Out,
                    const float* __restrict__ nmu, const float* __restrict__ ns,
                    const float* __restrict__ nt, int normStride,
                    ushort* __restrict__ hbOut) {
    __shared__ ushort Ahi[128][72];
    __shared__ ushort Alo[128][72];
    __shared__ ushort Bhi[128][72];
    __shared__ ushort Blo[128][72];
    int tid = threadIdx.x;
    int m0 = blockIdx.x * 128;
    int noff = (NORM == 1) ? (m0 / LL) * normStride : 0;

    int w = tid >> 6, lane = tid & 63;
    int wm = (w >> 1) * 64, wn = (w & 1) * 64;
    int col = lane & 15, kq = lane >> 4;

    float4v acc[4][4];
    #pragma unroll
    for (int i = 0; i < 4; ++i)
        #pragma unroll
        for (int j = 0; j < 4; ++j) acc[i][j] = (float4v){0.f, 0.f, 0.f, 0.f};

    for (int kt = 0; kt < 2; ++kt) {
        __syncthreads();
        #pragma unroll
        for (int it = 0; it < 4; ++it) {
            int q = tid + it * 256;
            int row = q >> 3, k0 = (q & 7) * 8;
            int kg = kt * 64 + k0;
            const float* ap = A + (size_t)(m0 + row) * 128 + kg;
            float vv[8];
            *(float4*)&vv[0] = *(const float4*)ap;
            *(float4*)&vv[4] = *(const float4*)(ap + 4);
            ushort hi[8], lo[8];
            #pragma unroll
            for (int j = 0; j < 8; ++j) {
                float v = vv[j];
                if (NORM == 1) v = (v - nmu[noff + kg + j]) * ns[noff + kg + j];
                if (NORM == 2) v = (v - nmu[kg + j]) * ns[kg + j] + nt[kg + j];
                ushort h = f2bf(v);
                hi[j] = h;
                lo[j] = f2bf(v - bf2f(h));
            }
            if (hbOut)
                *(short8v*)(hbOut + (size_t)(m0 + row) * 128 + kg) = *(short8v*)hi;
            *(short8v*)&Ahi[row][k0] = *(short8v*)hi;
            *(short8v*)&Alo[row][k0] = *(short8v*)lo;
        }
        #pragma unroll
        for (int it = 0; it < 4; ++it) {
            int q = tid + it * 256;
            int row = q >> 3, k0 = (q & 7) * 8;
            *(short8v*)&Bhi[row][k0] =
                *(const short8v*)(Whi + (size_t)row * 128 + kt * 64 + k0);
            *(short8v*)&Blo[row][k0] =
                *(const short8v*)(Wlo + (size_t)row * 128 + kt * 64 + k0);
        }
        __syncthreads();
        #pragma unroll
        for (int ksub = 0; ksub < 2; ++ksub) {
            short8v ah[4], al[4], bh[4], bl[4];
            #pragma unroll
            for (int mf = 0; mf < 4; ++mf) {
                ah[mf] = *(const short8v*)&Ahi[wm + mf * 16 + col][ksub * 32 + kq * 8];
                al[mf] = *(const short8v*)&Alo[wm + mf * 16 + col][ksub * 32 + kq * 8];
            }
            #pragma unroll
            for (int nf = 0; nf < 4; ++nf) {
                bh[nf] = *(const short8v*)&Bhi[wn + nf * 16 + col][ksub * 32 + kq * 8];
                bl[nf] = *(const short8v*)&Blo[wn + nf * 16 + col][ksub * 32 + kq * 8];
            }
            #pragma unroll
            for (int mf = 0; mf < 4; ++mf)
                #pragma unroll
                for (int nf = 0; nf < 4; ++nf)
                    acc[mf][nf] = __builtin_amdgcn_mfma_f32_16x16x32_bf16(
                        ah[mf], bh[nf], acc[mf][nf], 0, 0, 0);
            #pragma unroll
            for (int mf = 0; mf < 4; ++mf)
                #pragma unroll
                for (int nf = 0; nf < 4; ++nf)
                    acc[mf][nf] = __builtin_amdgcn_mfma_f32_16x16x32_bf16(
                        ah[mf], bl[nf], acc[mf][nf], 0, 0, 0);
            #pragma unroll
            for (int mf = 0; mf < 4; ++mf)
                #pragma unroll
                for (int nf = 0; nf < 4; ++nf)
                    acc[mf][nf] = __builtin_amdgcn_mfma_f32_16x16x32_bf16(
                        al[mf], bh[nf], acc[mf][nf], 0, 0, 0);
        }
    }

    int rbase = kq * 4;
    #pragma unroll
    for (int nf = 0; nf < 4; ++nf) {
        int n = wn + nf * 16 + col;
        if (EP == 2 && n >= 64) continue;
        float bn = bias ? bias[n] : 0.f;
        #pragma unroll
        for (int mf = 0; mf < 4; ++mf) {
            #pragma unroll
            for (int r = 0; r < 4; ++r) {
                int m = m0 + wm + mf * 16 + rbase + r;
                float v = acc[mf][nf][r] + bn;
                if (ACT == 1) v = fmaxf(v, 0.f);
                if (ACT == 2) v = fast_gelu(v);
                if (EP == 0) Out[(size_t)m * 128 + n] = v;
                else if (EP == 1) Out[(size_t)m * 128 + n] += v;
                else Out[(size_t)m * 64 + n] = v;
            }
        }
    }
}

// ---------------------------------------------------------------------------
// FUSED pair of K=128 GEMMs (PREC=1: split-precision, PREC=0: plain bf16):
// EP2: 0 store; 1 residual+= with row sum/sumsq -> rsum/rsq;
//      2 store with per-block column partials -> rsum;
//      3 store with per-row sumsq -> rsq (for rownorm)
// ---------------------------------------------------------------------------
template <int NORM, int ACT1, int ACT2, int EP2, int PREC>
__global__ __launch_bounds__(256)
void mfma_sq2_kernel(const float* __restrict__ A,
                     const ushort* __restrict__ W1h, const ushort* __restrict__ W1l,
                     const float* __restrict__ b1v,
                     const ushort* __restrict__ W2h, const ushort* __restrict__ W2l,
                     const float* __restrict__ b2v, float* Out,
                     const float* __restrict__ nmu, const float* __restrict__ ns,
                     const float* __restrict__ nt, int normStride,
                     float* __restrict__ rsum, float* __restrict__ rsq) {
    __shared__ ushort Xhi[128][72];
    __shared__ ushort Xlo[PREC ? 128 : 1][72];
    __shared__ ushort Bh[128][72];
    __shared__ ushort Bl[PREC ? 128 : 1][72];
    int tid = threadIdx.x;
    int m0 = blockIdx.x * 128;
    int noff = (NORM == 1) ? (m0 / LL) * normStride : 0;
    int w = tid >> 6, lane = tid & 63;
    int wm = (w >> 1) * 64, wn = (w & 1) * 64;
    int col = lane & 15, kq = lane >> 4;

    float4v acc[4][4];
    #pragma unroll
    for (int i = 0; i < 4; ++i)
        #pragma unroll
        for (int j = 0; j < 4; ++j) acc[i][j] = (float4v){0.f, 0.f, 0.f, 0.f};

    // ---- GEMM1 over 2 K-tiles ----
    for (int kt = 0; kt < 2; ++kt) {
        __syncthreads();
        #pragma unroll
        for (int it = 0; it < 4; ++it) {
            int q = tid + it * 256;
            int row = q >> 3, k0 = (q & 7) * 8;
            int kg = kt * 64 + k0;
            const float* ap = A + (size_t)(m0 + row) * 128 + kg;
            float vv[8];
            *(float4*)&vv[0] = *(const float4*)ap;
            *(float4*)&vv[4] = *(const float4*)(ap + 4);
            ushort hi[8], lo[8];
            #pragma unroll
            for (int j = 0; j < 8; ++j) {
                float v = vv[j];
                if (NORM == 1) v = (v - nmu[noff + kg + j]) * ns[noff + kg + j];
                if (NORM == 2) v = (v - nmu[kg + j]) * ns[kg + j] + nt[kg + j];
                ushort h = f2bf(v);
                hi[j] = h;
                if (PREC) lo[j] = f2bf(v - bf2f(h));
            }
            *(short8v*)&Xhi[row][k0] = *(short8v*)hi;
            if (PREC) *(short8v*)&Xlo[row][k0] = *(short8v*)lo;
        }
        #pragma unroll
        for (int it = 0; it < 4; ++it) {
            int q = tid + it * 256;
            int row = q >> 3, k0 = (q & 7) * 8;
            *(short8v*)&Bh[row][k0] =
                *(const short8v*)(W1h + (size_t)row * 128 + kt * 64 + k0);
            if (PREC)
                *(short8v*)&Bl[row][k0] =
                    *(const short8v*)(W1l + (size_t)row * 128 + kt * 64 + k0);
        }
        __syncthreads();
        #pragma unroll
        for (int ksub = 0; ksub < 2; ++ksub) {
            short8v ah[4], al[4], bh[4], bl[4];
            #pragma unroll
            for (int mf = 0; mf < 4; ++mf) {
                ah[mf] = *(const short8v*)&Xhi[wm + mf * 16 + col][ksub * 32 + kq * 8];
                if (PREC) al[mf] = *(const short8v*)&Xlo[wm + mf * 16 + col][ksub * 32 + kq * 8];
            }
            #pragma unroll
            for (int nf = 0; nf < 4; ++nf) {
                bh[nf] = *(const short8v*)&Bh[wn + nf * 16 + col][ksub * 32 + kq * 8];
                if (PREC) bl[nf] = *(const short8v*)&Bl[wn + nf * 16 + col][ksub * 32 + kq * 8];
            }
            #pragma unroll
            for (int mf = 0; mf < 4; ++mf)
                #pragma unroll
                for (int nf = 0; nf < 4; ++nf)
                    acc[mf][nf] = __builtin_amdgcn_mfma_f32_16x16x32_bf16(
                        ah[mf], bh[nf], acc[mf][nf], 0, 0, 0);
            if (PREC) {
                #pragma unroll
                for (int mf = 0; mf < 4; ++mf)
                    #pragma unroll
                    for (int nf = 0; nf < 4; ++nf)
                        acc[mf][nf] = __builtin_amdgcn_mfma_f32_16x16x32_bf16(
                            ah[mf], bl[nf], acc[mf][nf], 0, 0, 0);
                #pragma unroll
                for (int mf = 0; mf < 4; ++mf)
                    #pragma unroll
                    for (int nf = 0; nf < 4; ++nf)
                        acc[mf][nf] = __builtin_amdgcn_mfma_f32_16x16x32_bf16(
                            al[mf], bh[nf], acc[mf][nf], 0, 0, 0);
            }
        }
    }

    // ---- GEMM2 ----
    float4v acc2[4][4];
    #pragma unroll
    for (int i = 0; i < 4; ++i)
        #pragma unroll
        for (int j = 0; j < 4; ++j) acc2[i][j] = (float4v){0.f, 0.f, 0.f, 0.f};

    for (int kt2 = 0; kt2 < 2; ++kt2) {
        __syncthreads();
        if ((wn >> 6) == kt2) {   // wave-uniform
            #pragma unroll
            for (int nf = 0; nf < 4; ++nf) {
                float bn = b1v[wn + nf * 16 + col];
                #pragma unroll
                for (int mf = 0; mf < 4; ++mf) {
                    #pragma unroll
                    for (int r = 0; r < 4; ++r) {
                        float v = acc[mf][nf][r] + bn;
                        if (ACT1 == 1) v = fmaxf(v, 0.f);
                        if (ACT1 == 2) v = fast_gelu(v);
                        int row = wm + mf * 16 + kq * 4 + r;
                        int c2 = nf * 16 + col;
                        ushort h = f2bf(v);
                        Xhi[row][c2] = h;
                        if (PREC) Xlo[row][c2] = f2bf(v - bf2f(h));
                    }
                }
            }
        }
        #pragma unroll
        for (int it = 0; it < 4; ++it) {
            int q = tid + it * 256;
            int row = q >> 3, k0 = (q & 7) * 8;
            *(short8v*)&Bh[row][k0] =
                *(const short8v*)(W2h + (size_t)row * 128 + kt2 * 64 + k0);
            if (PREC)
                *(short8v*)&Bl[row][k0] =
                    *(const short8v*)(W2l + (size_t)row * 128 + kt2 * 64 + k0);
        }
        __syncthreads();
        #pragma unroll
        for (int ksub = 0; ksub < 2; ++ksub) {
            short8v ah[4], al[4], bh[4], bl[4];
            #pragma unroll
            for (int mf = 0; mf < 4; ++mf) {
                ah[mf] = *(const short8v*)&Xhi[wm + mf * 16 + col][ksub * 32 + kq * 8];
                if (PREC) al[mf] = *(const short8v*)&Xlo[wm + mf * 16 + col][ksub * 32 + kq * 8];
            }
            #pragma unroll
            for (int nf = 0; nf < 4; ++nf) {
                bh[nf] = *(const short8v*)&Bh[wn + nf * 16 + col][ksub * 32 + kq * 8];
                if (PREC) bl[nf] = *(const short8v*)&Bl[wn + nf * 16 + col][ksub * 32 + kq * 8];
            }
            #pragma unroll
            for (int mf = 0; mf < 4; ++mf)
                #pragma unroll
                for (int nf = 0; nf < 4; ++nf)
                    acc2[mf][nf] = __builtin_amdgcn_mfma_f32_16x16x32_bf16(
                        ah[mf], bh[nf], acc2[mf][nf], 0, 0, 0);
            if (PREC) {
                #pragma unroll
                for (int mf = 0; mf < 4; ++mf)
                    #pragma unroll
                    for (int nf = 0; nf < 4; ++nf)
                        acc2[mf][nf] = __builtin_amdgcn_mfma_f32_16x16x32_bf16(
                            ah[mf], bl[nf], acc2[mf][nf], 0, 0, 0);
                #pragma unroll
                for (int mf = 0; mf < 4; ++mf)
                    #pragma unroll
                    for (int nf = 0; nf < 4; ++nf)
                        acc2[mf][nf] = __builtin_amdgcn_mfma_f32_16x16x32_bf16(
                            al[mf], bh[nf], acc2[mf][nf], 0, 0, 0);
            }
        }
    }

    int rbase = kq * 4;
    float rs_[4][4];
    float rq_[4][4];
    float cs_[4], cq_[4];
    if (EP2 == 1 || EP2 == 3) {
        #pragma unroll
        for (int a = 0; a < 4; ++a)
            #pragma unroll
            for (int b = 0; b < 4; ++b) { rs_[a][b] = 0.f; rq_[a][b] = 0.f; }
    }
    if (EP2 == 2) {
        #pragma unroll
        for (int a = 0; a < 4; ++a) { cs_[a] = 0.f; cq_[a] = 0.f; }
    }
    #pragma unroll
    for (int nf = 0; nf < 4; ++nf) {
        int n = wn + nf * 16 + col;
        float bn = b2v[n];
        #pragma unroll
        for (int mf = 0; mf < 4; ++mf) {
            #pragma unroll
            for (int r = 0; r < 4; ++r) {
                int m = m0 + wm + mf * 16 + rbase + r;
                float v = acc2[mf][nf][r] + bn;
                if (ACT2 == 1) v = fmaxf(v, 0.f);
                if (ACT2 == 2) v = fast_gelu(v);
                if (EP2 == 1) {
                    float fin = Out[(size_t)m * 128 + n] + v;
                    Out[(size_t)m * 128 + n] = fin;
                    rs_[mf][r] += fin;
                    rq_[mf][r] += fin * fin;
                } else {
                    Out[(size_t)m * 128 + n] = v;
                    if (EP2 == 2) { cs_[nf] += v; cq_[nf] += v * v; }
                    if (EP2 == 3) rq_[mf][r] += v * v;
                }
            }
        }
    }
    if (EP2 == 1) {
        #pragma unroll
        for (int mf = 0; mf < 4; ++mf)
            #pragma unroll
            for (int r = 0; r < 4; ++r) {
                float s = rs_[mf][r], q = rq_[mf][r];
                #pragma unroll
                for (int o = 1; o <= 8; o <<= 1) {
                    s += __shfl_xor(s, o);
                    q += __shfl_xor(q, o);
                }
                rs_[mf][r] = s; rq_[mf][r] = q;
            }
        __syncthreads();
        float* sred = (float*)&Xhi[0][0];   // [128][2]
        float* qred = sred + 256;
        if (col == 0) {
            #pragma unroll
            for (int mf = 0; mf < 4; ++mf)
                #pragma unroll
                for (int r = 0; r < 4; ++r) {
                    int row = wm + mf * 16 + kq * 4 + r;
                    sred[row * 2 + (wn >> 6)] = rs_[mf][r];
                    qred[row * 2 + (wn >> 6)] = rq_[mf][r];
                }
        }
        __syncthreads();
        if (tid < 128) {
            rsum[(size_t)m0 + tid] = sred[tid * 2] + sred[tid * 2 + 1];
            rsq[(size_t)m0 + tid]  = qred[tid * 2] + qred[tid * 2 + 1];
        }
    }
    if (EP2 == 3) {
        #pragma unroll
        for (int mf = 0; mf < 4; ++mf)
            #pragma unroll
            for (int r = 0; r < 4; ++r) {
                float q = rq_[mf][r];
                #pragma unroll
                for (int o = 1; o <= 8; o <<= 1) q += __shfl_xor(q, o);
                rq_[mf][r] = q;
            }
        __syncthreads();
        float* qred = (float*)&Xhi[0][0];   // [128][2]
        if (col == 0) {
            #pragma unroll
            for (int mf = 0; mf < 4; ++mf)
                #pragma unroll
                for (int r = 0; r < 4; ++r) {
                    int row = wm + mf * 16 + kq * 4 + r;
                    qred[row * 2 + (wn >> 6)] = rq_[mf][r];
                }
        }
        __syncthreads();
        if (tid < 128)
            rsq[(size_t)m0 + tid] = qred[tid * 2] + qred[tid * 2 + 1];
    }
    if (EP2 == 2) {
        #pragma unroll
        for (int nf = 0; nf < 4; ++nf) {
            #pragma unroll
            for (int o = 16; o <= 32; o <<= 1) {
                cs_[nf] += __shfl_xor(cs_[nf], o);
                cq_[nf] += __shfl_xor(cq_[nf], o);
            }
        }
        __syncthreads();
        float* colS = (float*)&Xhi[0][0];   // [2][128]
        float* colQ = colS + 256;
        if (kq == 0) {
            #pragma unroll
            for (int nf = 0; nf < 4; ++nf) {
                int n = wn + nf * 16 + col;
                colS[(wm >> 6) * 128 + n] = cs_[nf];
                colQ[(wm >> 6) * 128 + n] = cq_[nf];
            }
        }
        __syncthreads();
        if (tid < 128) {
            rsum[(size_t)blockIdx.x * 256 + tid] = colS[tid] + colS[128 + tid];
            rsum[(size_t)blockIdx.x * 256 + 128 + tid] = colQ[tid] + colQ[128 + tid];
        }
    }
}

// W [128][128] f32 -> Whi/Wlo [n][k] bf16 split (transposed). grid (4,4), block (32,8)
__global__ void wsplit_kernel(const float* __restrict__ W, ushort* __restrict__ Whi,
                              ushort* __restrict__ Wlo) {
    __shared__ float t[32][33];
    int k0 = blockIdx.x * 32, n0 = blockIdx.y * 32;
    int tx = threadIdx.x, ty = threadIdx.y;
    for (int i = ty; i < 32; i += 8)
        t[i][tx] = W[(size_t)(k0 + i) * 128 + n0 + tx];
    __syncthreads();
    for (int i = ty; i < 32; i += 8) {
        float v = t[tx][i];
        ushort h = f2bf(v);
        Whi[(size_t)(n0 + i) * 128 + k0 + tx] = h;
        Wlo[(size_t)(n0 + i) * 128 + k0 + tx] = f2bf(v - bf2f(h));
    }
}

// ---------------------------------------------------------------------------
// Timestep MFMA GEMM v5: identical 2-phase BK=64 128x128 64KB template, but
// 512 threads / 8 waves (4m x 2n, acc 2x4) -> 16 waves/CU at 2 blocks/CU.
// Epilogue: v=gelu(acc+bias[n]); Z[(b*2048+n)*128+c] += v; emits bnf partials.
// ---------------------------------------------------------------------------
__global__ __launch_bounds__(512)
void mfma_ts5_kernel(const ushort* __restrict__ A, const ushort* __restrict__ W,
                     const float* __restrict__ bias, float* Z,
                     int nx, int nwg, float* __restrict__ bnfP) {
    __shared__ __align__(16) ushort smem[32768];   // 64 KB = 2 x (A 16KB + B 16KB)
    float (*Ol)[132] = (float(*)[132])smem;        // epilogue overlay

    int bid = blockIdx.x;
    int cpx = nwg >> 3;
    int swz = (bid & 7) * cpx + (bid >> 3);
    int n0 = (swz % nx) * 128;
    int m0 = (swz / nx) * 128;

    int tid = threadIdx.x;
    int w = tid >> 6, lane = tid & 63;
    int wm = (w >> 1) * 32, wn = (w & 1) * 64;   // 4m x 2n wave grid
    int col = lane & 15, kq = lane >> 4;

    int srow = lane >> 3;                    // 0..7
    int scol = ((lane & 7) ^ srow) << 3;     // pre-swizzled src ushort offset
    int xr = (col & 7) << 4;                 // read-side XOR (bytes)

    float4v acc[2][4];
    #pragma unroll
    for (int i = 0; i < 2; ++i)
        #pragma unroll
        for (int j = 0; j < 4; ++j) acc[i][j] = (float4v){0.f, 0.f, 0.f, 0.f};

    const int Kd = LL;
    const int kTiles = 32;

    // prologue: stage K-tile 0 into buffer 0 (each wave: 16 rows of A and B)
    #pragma unroll
    for (int it = 0; it < 2; ++it) {
        int rb = (w << 4) + (it << 3);
        async16(A + (size_t)(m0 + rb + srow) * Kd + scol, smem + (rb << 6));
        async16(W + (size_t)(n0 + rb + srow) * Kd + scol, smem + 8192 + (rb << 6));
    }
    __syncthreads();

    for (int kt = 0; kt < kTiles; ++kt) {
        int cur = kt & 1;
        const ushort* Ac = smem + (cur << 14);
        const ushort* Bc = Ac + 8192;
        if (kt + 1 < kTiles) {
            ushort* An = smem + ((cur ^ 1) << 14);
            ushort* Bn = An + 8192;
            int kb = (kt + 1) << 6;
            #pragma unroll
            for (int it = 0; it < 2; ++it) {
                int rb = (w << 4) + (it << 3);
                async16(A + (size_t)(m0 + rb + srow) * Kd + kb + scol, An + (rb << 6));
                async16(W + (size_t)(n0 + rb + srow) * Kd + kb + scol, Bn + (rb << 6));
            }
        }
        __builtin_amdgcn_s_setprio(1);
        #pragma unroll
        for (int ksub = 0; ksub < 2; ++ksub) {
            int cswz = (((ksub << 6) + (kq << 4)) ^ xr) >> 1;
            short8v af[2], bf[4];
            #pragma unroll
            for (int mf = 0; mf < 2; ++mf)
                af[mf] = *(const short8v*)(Ac + (wm + mf * 16 + col) * 64 + cswz);
            #pragma unroll
            for (int nf = 0; nf < 4; ++nf)
                bf[nf] = *(const short8v*)(Bc + (wn + nf * 16 + col) * 64 + cswz);
            #pragma unroll
            for (int mf = 0; mf < 2; ++mf)
                #pragma unroll
                for (int nf = 0; nf < 4; ++nf)
                    acc[mf][nf] = __builtin_amdgcn_mfma_f32_16x16x32_bf16(
                        af[mf], bf[nf], acc[mf][nf], 0, 0, 0);
        }
        __builtin_amdgcn_s_setprio(0);
        __syncthreads();
    }

    // Epilogue: 4 rounds of 32-n strips through Ol (512-thread variant)
    int b = m0 >> 7;
    float cs[8], cq[8];
    #pragma unroll
    for (int j = 0; j < 8; ++j) { cs[j] = 0.f; cq[j] = 0.f; }
    int nloc = tid >> 4, c0 = (tid & 15) * 8;
    #pragma unroll
    for (int q = 0; q < 4; ++q) {
        __syncthreads();
        #pragma unroll
        for (int nf = 0; nf < 4; ++nf) {
            int gnl = wn + nf * 16;
            if ((gnl >> 5) != q) continue;
            int gn = n0 + gnl + col;
            float bn = bias[gn];
            int nl = gnl - q * 32 + col;
            #pragma unroll
            for (int mf = 0; mf < 2; ++mf)
                #pragma unroll
                for (int r = 0; r < 4; ++r) {
                    float v = acc[mf][nf][r] + bn;
                    v = fast_gelu(v);
                    Ol[nl][wm + mf * 16 + kq * 4 + r] = v;
                }
        }
        __syncthreads();
        int gn = n0 + q * 32 + nloc;
        float* zr = Z + ((size_t)b * LL + gn) * CC + c0;
        #pragma unroll
        for (int i = 0; i < 2; ++i) {
            float4 v = *(float4*)&Ol[nloc][c0 + i * 4];
            float4 o = *(float4*)(zr + i * 4);
            v.x += o.x; v.y += o.y; v.z += o.z; v.w += o.w;
            *(float4*)(zr + i * 4) = v;
            cs[i * 4 + 0] += v.x; cs[i * 4 + 1] += v.y;
            cs[i * 4 + 2] += v.z; cs[i * 4 + 3] += v.w;
            cq[i * 4 + 0] += v.x * v.x; cq[i * 4 + 1] += v.y * v.y;
            cq[i * 4 + 2] += v.z * v.z; cq[i * 4 + 3] += v.w * v.w;
        }
    }
    // per-block feature-BN partials
    __syncthreads();
    float* sred = (float*)smem;         // [32][128]
    float* qred = sred + 4096;          // [32][128]
    #pragma unroll
    for (int j = 0; j < 8; ++j) {
        sred[nloc * 128 + c0 + j] = cs[j];
        qred[nloc * 128 + c0 + j] = cq[j];
    }
    __syncthreads();
    if (tid < 128) {
        float a = 0.f;
        for (int r = 0; r < 32; ++r) a += sred[r * 128 + tid];
        bnfP[(size_t)bid * 256 + tid] = a;
    } else if (tid < 256) {
        int c = tid - 128;
        float a = 0.f;
        for (int r = 0; r < 32; ++r) a += qred[r * 128 + c];
        bnfP[(size_t)bid * 256 + 128 + c] = a;
    }
}

// ---------------------------------------------------------------------------
// bf16 MFMA GEMM (big-K), 2-phase double-buffered prefetch (scores + head).
// ---------------------------------------------------------------------------
template <int EPM>
__global__ __launch_bounds__(256)
void mfma_gemm_kernel(const ushort* __restrict__ A, const ushort* __restrict__ W,
                      const float* __restrict__ bias, float* Z,
                      int N, int Kd, int LDO, int nx, int nwg,
                      const float* __restrict__ epS, const float* __restrict__ epM,
                      float* __restrict__ bnfP) {
    __shared__ __align__(16) ushort smem[32768];   // 64 KB = 2 x (A 16KB + B 16KB)
    float (*Ol)[132] = (float(*)[132])smem;        // epilogue overlay

    int bid = blockIdx.x;
    int cpx = nwg >> 3;
    int swz = (bid & 7) * cpx + (bid >> 3);
    int n0 = (swz % nx) * 128;
    int m0 = (swz / nx) * 128;

    int tid = threadIdx.x;
    int w = tid >> 6, lane = tid & 63;
    int wm = (w >> 1) * 64, wn = (w & 1) * 64;
    int col = lane & 15, kq = lane >> 4;

    int srow = lane >> 3;                    // 0..7
    int scol = ((lane & 7) ^ srow) << 3;     // pre-swizzled src ushort offset
    int xr = (col & 7) << 4;                 // read-side XOR (bytes)

    float4v acc[4][4];
    #pragma unroll
    for (int i = 0; i < 4; ++i)
        #pragma unroll
        for (int j = 0; j < 4; ++j) acc[i][j] = (float4v){0.f, 0.f, 0.f, 0.f};

    int kTiles = Kd >> 6;

    // prologue: stage K-tile 0 into buffer 0
    #pragma unroll
    for (int it = 0; it < 4; ++it) {
        int rb = (w << 5) + (it << 3);
        async16(A + (size_t)(m0 + rb + srow) * Kd + scol, smem + (rb << 6));
    }
    #pragma unroll
    for (int it = 0; it < 4; ++it) {
        int rb = (w << 5) + (it << 3);
        async16(W + (size_t)(n0 + rb + srow) * Kd + scol, smem + 8192 + (rb << 6));
    }
    __syncthreads();

    for (int kt = 0; kt < kTiles; ++kt) {
        int cur = kt & 1;
        ushort* Ac = smem + (cur << 14);
        ushort* Bc = Ac + 8192;
        if (kt + 1 < kTiles) {
            ushort* An = smem + ((cur ^ 1) << 14);
            ushort* Bn = An + 8192;
            int kb = (kt + 1) << 6;
            #pragma unroll
            for (int it = 0; it < 4; ++it) {
                int rb = (w << 5) + (it << 3);
                async16(A + (size_t)(m0 + rb + srow) * Kd + kb + scol, An + (rb << 6));
            }
            #pragma unroll
            for (int it = 0; it < 4; ++it) {
                int rb = (w << 5) + (it << 3);
                async16(W + (size_t)(n0 + rb + srow) * Kd + kb + scol, Bn + (rb << 6));
            }
        }
        __builtin_amdgcn_s_setprio(1);
        #pragma unroll
        for (int ksub = 0; ksub < 2; ++ksub) {
            int cswz = (((ksub << 6) + (kq << 4)) ^ xr) >> 1;
            short8v af[4], bf[4];
            #pragma unroll
            for (int mf = 0; mf < 4; ++mf)
                af[mf] = *(const short8v*)(Ac + (wm + mf * 16 + col) * 64 + cswz);
            #pragma unroll
            for (int nf = 0; nf < 4; ++nf)
                bf[nf] = *(const short8v*)(Bc + (wn + nf * 16 + col) * 64 + cswz);
            #pragma unroll
            for (int mf = 0; mf < 4; ++mf)
                #pragma unroll
                for (int nf = 0; nf < 4; ++nf)
                    acc[mf][nf] = __builtin_amdgcn_mfma_f32_16x16x32_bf16(
                        af[mf], bf[nf], acc[mf][nf], 0, 0, 0);
        }
        __builtin_amdgcn_s_setprio(0);
        __syncthreads();
    }

    // Epilogue: 4 rounds of 32-n strips through Ol
    int b = m0 >> 7;
    float cs[16], cq[16];
    if (EPM == 1) {
        #pragma unroll
        for (int k2 = 0; k2 < 16; ++k2) { cs[k2] = 0.f; cq[k2] = 0.f; }
    }
    #pragma unroll
    for (int q = 0; q < 4; ++q) {
        __syncthreads();
        #pragma unroll
        for (int nf = 0; nf < 4; ++nf) {
            int gnl = wn + nf * 16;
            if ((gnl >> 5) != q) continue;
            int gn = n0 + gnl + col;
            float bn = (EPM == 2 && gn >= N) ? 0.f : bias[gn];
            int nl = gnl - q * 32 + col;
            #pragma unroll
            for (int mf = 0; mf < 4; ++mf) {
                #pragma unroll
                for (int r = 0; r < 4; ++r) {
                    float v = acc[mf][nf][r] + bn;
                    if (EPM == 1) v = fast_gelu(v);
                    Ol[nl][wm + mf * 16 + kq * 4 + r] = v;
                }
            }
        }
        __syncthreads();
        int nloc = tid >> 3, c0 = (tid & 7) * 16;
        int gn = n0 + q * 32 + nloc;
        if ((EPM == 2 || EPM == 3) && gn >= N) continue;
        float* zr;
        if (EPM == 3)
            zr = Z + (((size_t)(m0 >> 11) * 64 + gn) * 2048) + (m0 & 2047) + c0;
        else
            zr = Z + ((size_t)b * LDO + gn) * CC + c0;
        #pragma unroll
        for (int i = 0; i < 4; ++i) {
            float4 v = *(float4*)&Ol[nloc][c0 + i * 4];
            if (EPM == 1) {
                float4 o = *(float4*)(zr + i * 4);
                v.x += o.x; v.y += o.y; v.z += o.z; v.w += o.w;
                *(float4*)(zr + i * 4) = v;
                cs[i * 4 + 0] += v.x; cs[i * 4 + 1] += v.y;
                cs[i * 4 + 2] += v.z; cs[i * 4 + 3] += v.w;
                cq[i * 4 + 0] += v.x * v.x; cq[i * 4 + 1] += v.y * v.y;
                cq[i * 4 + 2] += v.z * v.z; cq[i * 4 + 3] += v.w * v.w;
            } else if (EPM == 2) {
                int mb = m0 + c0 + i * 4;
                float4 s4 = *(const float4*)(epS + mb);
                float4 m4 = *(const float4*)(epM + mb);
                v.x = v.x * s4.x + m4.x; v.y = v.y * s4.y + m4.y;
                v.z = v.z * s4.z + m4.z; v.w = v.w * s4.w + m4.w;
                *(float4*)(zr + i * 4) = v;
            } else {
                *(float4*)(zr + i * 4) = v;
            }
        }
    }
    if (EPM == 1) {
        __syncthreads();
        float* sred = (float*)smem;         // [32][128]
        float* qred = sred + 4096;          // [32][128]
        int rrow = tid >> 3, cb = (tid & 7) * 16;
        #pragma unroll
        for (int k2 = 0; k2 < 16; ++k2) {
            sred[rrow * 128 + cb + k2] = cs[k2];
            qred[rrow * 128 + cb + k2] = cq[k2];
        }
        __syncthreads();
        if (tid < 128) {
            float a = 0.f;
            for (int r = 0; r < 32; ++r) a += sred[r * 128 + tid];
            bnfP[(size_t)bid * 256 + tid] = a;
        } else {
            int c = tid - 128;
            float a = 0.f;
            for (int r = 0; r < 32; ++r) a += qred[r * 128 + c];
            bnfP[(size_t)bid * 256 + 128 + c] = a;
        }
    }
}

// W [K][N] f32 -> WT [Npad][K] bf16 (zero-filled for n >= N).
__global__ void wtrans_kernel(const float* __restrict__ W, ushort* __restrict__ WT,
                              int Kd, int N) {
    __shared__ float t[32][33];
    int k0 = blockIdx.x * 32, n0 = blockIdx.y * 32;
    int tx = threadIdx.x, ty = threadIdx.y;
    for (int i = ty; i < 32; i += 8) {
        int n = n0 + tx;
        t[i][tx] = (n < N) ? W[(size_t)(k0 + i) * N + n] : 0.f;
    }
    __syncthreads();
    for (int i = ty; i < 32; i += 8)
        WT[(size_t)(n0 + i) * Kd + k0 + tx] = f2bf(t[tx][i]);
}

// ---------------------------------------------------------------------------
__global__ void cn_split_kernel(const float* __restrict__ ce, ushort* __restrict__ ch,
                                ushort* __restrict__ cl) {
    int k = blockIdx.x, h = threadIdx.x;
    if (k >= KK) {
        ch[(size_t)k * 128 + h] = 0;
        cl[(size_t)k * 128 + h] = 0;
        return;
    }
    __shared__ float sh[128];
    float v = ce[(size_t)k * HH + h];
    sh[h] = v * v;
    __syncthreads();
    for (int o = 64; o >= 1; o >>= 1) {
        if (h < o) sh[h] += sh[h + o];
        __syncthreads();
    }
    float nv = v / (sqrtf(sh[0]) + 1e-8f);
    ushort hh = f2bf(nv);
    ch[(size_t)k * 128 + h] = hh;
    cl[(size_t)k * 128 + h] = f2bf(nv - bf2f(hh));
}

// Qp bf16 [128][128] (rows >= 64 zero), qb f32 [128]
__global__ void qprime_kernel(const float* __restrict__ Q, const float* __restrict__ wk_w,
                              const float* __restrict__ wk_b, ushort* __restrict__ qpb,
                              float* __restrict__ qbp) {
    int k = blockIdx.x;
    int hp = threadIdx.x;
    if (k >= KK) {
        qpb[(size_t)k * HH + hp] = 0;
        if (hp == 0) qbp[k] = 0.f;
        return;
    }
    __shared__ float qrow[128];
    __shared__ float red[128];
    qrow[hp] = Q[(size_t)k * HH + hp];
    __syncthreads();
    float s = 0.f;
    for (int h = 0; h < HH; ++h) s = fmaf(qrow[h], wk_w[(size_t)hp * HH + h], s);
    const float rs = 0.088388347648318447f;
    qpb[(size_t)k * HH + hp] = f2bf(s * rs);
    red[hp] = qrow[hp] * wk_b[hp];
    __syncthreads();
    for (int o = 64; o >= 1; o >>= 1) {
        if (hp < o) red[hp] += red[hp + o];
        __syncthreads();
    }
    if (hp == 0) qbp[k] = red[0] * rs;
}

// ---------------------------------------------------------------------------
__global__ __launch_bounds__(256)
void pmask_kernel(const float* __restrict__ sp, const float* __restrict__ rn,
                  const float* __restrict__ bern, unsigned char* __restrict__ Mt,
                  float* __restrict__ ppart) {
    int b = blockIdx.y;
    int l0 = blockIdx.x * 32;
    int tid = threadIdx.x;
    int wv = tid >> 6, lane = tid & 63;
    __shared__ float Msh[64][33];
    __shared__ float psum[4][64];
    float pa = 0.f;
    for (int tt = 0; tt < 8; ++tt) {
        int l = l0 + wv * 8 + tt;
        size_t tok = (size_t)b * LL + l;
        float s = sp[tok * 64 + lane] * rn[tok];
        float mx = s;
        #pragma unroll
        for (int o = 32; o >= 1; o >>= 1) mx = fmaxf(mx, __shfl_xor(mx, o));
        float ev = expf(s - mx);
        float sm = ev;
        #pragma unroll
        for (int o = 32; o >= 1; o >>= 1) sm += __shfl_xor(sm, o);
        float p = ev / sm;
        pa += p;
        Msh[lane][wv * 8 + tt] = (bern[tok * KK + lane] < p) ? 1.f : 0.f;
    }
    psum[wv][lane] = pa;
    __syncthreads();
    for (int q = tid; q < 64 * 32; q += 256) {
        int k = q >> 5, j = q & 31;
        Mt[((size_t)b * KK + k) * LL + l0 + j] = (unsigned char)Msh[k][j];
    }
    if (tid < 64)
        ppart[((size_t)b * (LL / 32) + blockIdx.x) * KK + tid] =
            psum[0][tid] + psum[1][tid] + psum[2][tid] + psum[3][tid];
}

__global__ void pmean_final_kernel(const float* __restrict__ part, float* __restrict__ pm) {
    int b = blockIdx.x, k = threadIdx.x;
    float s = 0.f;
    for (int i = 0; i < LL / 32; ++i) s += part[((size_t)b * (LL / 32) + i) * KK + k];
    pm[b * KK + k] = s * (1.f / LL);
}

// ---------------------------------------------------------------------------
__global__ __launch_bounds__(256)
void aw_kernel(float* __restrict__ S, const unsigned char* __restrict__ Mt) {
    size_t base = (size_t)blockIdx.x * LL;
    int tid = threadIdx.x;
    float t[8];
    float mx = -1e30f;
    #pragma unroll
    for (int i = 0; i < 8; ++i) {
        int l = tid + i * 256;
        float v = expf(S[base + l]) * (float)Mt[base + l];
        t[i] = v;
        mx = fmaxf(mx, v);
    }
    __shared__ float shA[4];
    __shared__ float shB[4];
    #pragma unroll
    for (int o = 32; o >= 1; o >>= 1) mx = fmaxf(mx, __shfl_xor(mx, o));
    if ((tid & 63) == 0) shA[tid >> 6] = mx;
    __syncthreads();
    mx = fmaxf(fmaxf(shA[0], shA[1]), fmaxf(shA[2], shA[3]));
    float e[8];
    float sum = 0.f;
    #pragma unroll
    for (int i = 0; i < 8; ++i) { e[i] = expf(t[i] - mx); sum += e[i]; }
    #pragma unroll
    for (int o = 32; o >= 1; o >>= 1) sum += __shfl_xor(sum, o);
    if ((tid & 63) == 0) shB[tid >> 6] = sum;
    __syncthreads();
    sum = (shB[0] + shB[1]) + (shB[2] + shB[3]);
    float inv = 1.f / sum;
    #pragma unroll
    for (int i = 0; i < 8; ++i) S[base + tid + i * 256] = e[i] * inv;
}

// ---------------------------------------------------------------------------
__global__ __launch_bounds__(256)
void awh_part_kernel(const float* __restrict__ AWs, const float* __restrict__ hmat,
                     float* __restrict__ part) {
    __shared__ float AT[32][64];
    __shared__ float VT[32][128];
    int b = blockIdx.y, sp = blockIdx.x;
    int tid = threadIdx.x;
    int tx = tid & 15, ty = tid >> 4;
    float acc[4][8] = {};
    const float* Ab = AWs + (size_t)b * KK * LL + sp * 512;
    const float* Vb = hmat + ((size_t)b * LL + sp * 512) * HH;
    for (int lt = 0; lt < 512; lt += 32) {
        __syncthreads();
        #pragma unroll
        for (int it = 0; it < 2; ++it) {
            int q = tid + it * 256;
            int row = q >> 3;
            int lq = (q & 7) << 2;
            float4 v = *(const float4*)(Ab + (size_t)row * LL + lt + lq);
            AT[lq][row] = v.x; AT[lq + 1][row] = v.y;
            AT[lq + 2][row] = v.z; AT[lq + 3][row] = v.w;
        }
        #pragma unroll
        for (int it = 0; it < 4; ++it) {
            int q = tid + it * 256;
            int lr = q >> 5;
            int hc = (q & 31) << 2;
            *(float4*)&VT[lr][hc] = *(const float4*)(Vb + (size_t)(lt + lr) * HH + hc);
        }
        __syncthreads();
        #pragma unroll
        for (int l = 0; l < 32; ++l) {
            float av[4], vv[8];
            *(float4*)&av[0] = *(const float4*)&AT[l][ty * 4];
            *(float4*)&vv[0] = *(const float4*)&VT[l][tx * 4];
            *(float4*)&vv[4] = *(const float4*)&VT[l][64 + tx * 4];
            #pragma unroll
            for (int i = 0; i < 4; ++i)
                #pragma unroll
                for (int j = 0; j < 8; ++j)
                    acc[i][j] = fmaf(av[i], vv[j], acc[i][j]);
        }
    }
    #pragma unroll
    for (int i = 0; i < 4; ++i) {
        int k = ty * 4 + i;
        #pragma unroll
        for (int jj = 0; jj < 8; jj += 4) {
            int h = (jj ? 64 + tx * 4 : tx * 4);
            float o[4];
            #pragma unroll
            for (int j = 0; j < 4; ++j) o[j] = acc[i][jj + j];
            *(float4*)(part + (((size_t)b * 4 + sp) * KK + k) * HH + h) = *(float4*)o;
        }
    }
}

__global__ void awh_reduce_kernel(const float* __restrict__ part, float* __restrict__ awh) {
    int bk = blockIdx.x, h = threadIdx.x;
    int b = bk >> 6, k = bk & 63;
    float s = 0.f;
    #pragma unroll
    for (int sp = 0; sp < 4; ++sp)
        s += part[(((size_t)b * 4 + sp) * KK + k) * HH + h];
    awh[(size_t)bk * HH + h] = s;
}

__global__ void newce_kernel(const float* __restrict__ ao, const float* __restrict__ pm,
                             float* __restrict__ outTail) {
    int k = blockIdx.x, h = threadIdx.x;
    float s = 0.f;
    for (int b = 0; b < BB; ++b)
        s += ao[((size_t)b * KK + k) * HH + h] * pm[b * KK + k];
    outTail[(size_t)k * HH + h] = s * (1.f / BB);
}

// z_out = (in - mean2)*rstd2; also emits per-row sum/sumsq. grid (32, B), block 256
__global__ void revin_apply_kernel(const float* __restrict__ in, float* __restrict__ out,
                                   const float* __restrict__ mu, const float* __restrict__ rs,
                                   float* __restrict__ rsum, float* __restrict__ rsq) {
    int b = blockIdx.y;
    size_t base = (size_t)b * LL * CC + (size_t)blockIdx.x * 8192;
    int c0 = (threadIdx.x * 4) & 127;
    int lane = threadIdx.x & 63;
    float4 m4 = *(const float4*)(mu + b * CC + c0);
    float4 r4 = *(const float4*)(rs + b * CC + c0);
    #pragma unroll
    for (int j = 0; j < 8; ++j) {
        float4 v = *(const float4*)(in + base + threadIdx.x * 4 + j * 1024);
        v.x = (v.x - m4.x) * r4.x; v.y = (v.y - m4.y) * r4.y;
        v.z = (v.z - m4.z) * r4.z; v.w = (v.w - m4.w) * r4.w;
        *(float4*)(out + base + threadIdx.x * 4 + j * 1024) = v;
        float s = v.x + v.y + v.z + v.w;
        float q = v.x * v.x + v.y * v.y + v.z * v.z + v.w * v.w;
        #pragma unroll
        for (int o = 1; o <= 16; o <<= 1) {
            s += __shfl_xor(s, o);
            q += __shfl_xor(q, o);
        }
        if ((lane & 31) == 0) {
            size_t row = (base + (size_t)threadIdx.x * 4 + (size_t)j * 1024) >> 7;
            rsum[row] = s;
            rsq[row] = q;
        }
    }
}

// timestep-BN final: per l over 64 b's of row stats. grid 8, block 256
__global__ void bnt_final_kernel(const float* __restrict__ rsum, const float* __restrict__ rsq,
                                 float* __restrict__ mu, float* __restrict__ rv) {
    int l = blockIdx.x * 256 + threadIdx.x;
    float s = 0.f, q = 0.f;
    for (int b = 0; b < BB; ++b) {
        s += rsum[(size_t)b * LL + l];
        q += rsq[(size_t)b * LL + l];
    }
    float m = s * (1.f / (BB * CC));
    float var = q * (1.f / (BB * CC)) - m * m;
    var = fmaxf(var, 0.f);
    mu[l] = m;
    rv[l] = 1.f / sqrtf(var + EPSf);
}

// ---------------------------------------------------------------------------
// [B,L,C] f32 -> [B,C,L] bf16, optional timestep-BN. v2: 64(l)x32(c) tiles,
// uint4 (8 bf16) coalesced writes. grid (L/64, C/32, B), block 256.
// ---------------------------------------------------------------------------
template <bool DO_BN>
__global__ __launch_bounds__(256)
void transpose_bn_kernel(const float* __restrict__ in, ushort* __restrict__ out,
                         const float* __restrict__ mu, const float* __restrict__ rv,
                         const float* __restrict__ g, const float* __restrict__ be) {
    __shared__ ushort tile[32][72];   // [c][l] bf16, padded
    int l0 = blockIdx.x * 64, c0 = blockIdx.y * 32, b = blockIdx.z;
    int t = threadIdx.x;
    const float* ib = in + ((size_t)b * LL + l0) * CC + c0;
    #pragma unroll
    for (int it = 0; it < 2; ++it) {
        int idx = t + it * 256;
        int row = idx >> 3;           // 0..63 (l offset)
        int c = (idx & 7) * 4;        // 0..28
        float4 v = *(const float4*)(ib + (size_t)row * CC + c);
        if (DO_BN) {
            int l = l0 + row;
            float sc = rv[l] * g[l];
            float m = mu[l], bb = be[l];
            v.x = (v.x - m) * sc + bb; v.y = (v.y - m) * sc + bb;
            v.z = (v.z - m) * sc + bb; v.w = (v.w - m) * sc + bb;
        }
        tile[c    ][row] = f2bf(v.x);
        tile[c + 1][row] = f2bf(v.y);
        tile[c + 2][row] = f2bf(v.z);
        tile[c + 3][row] = f2bf(v.w);
    }
    __syncthreads();
    int cc = t >> 3, l8 = (t & 7) * 8;
    ushort* ob = out + (size_t)b * CC * LL + (size_t)(c0 + cc) * LL + l0 + l8;
    *(uint4*)ob = *(const uint4*)&tile[cc][l8];
}

// feature-BN two-stage reduce: mid over 16 blocks each; final over 64 mids
__global__ void bnf_mid_kernel(const float* __restrict__ part, float* __restrict__ mid) {
    int gblk = blockIdx.x, t = threadIdx.x;   // grid 64, block 256
    float s = 0.f;
    #pragma unroll
    for (int i = 0; i < 16; ++i)
        s += part[(size_t)(gblk * 16 + i) * 256 + t];
    mid[(size_t)gblk * 256 + t] = s;
}

__global__ void bnf_final_kernel(const float* __restrict__ mid, const float* __restrict__ g,
                                 const float* __restrict__ be, float* __restrict__ mu,
                                 float* __restrict__ sA, float* __restrict__ tA) {
    int c = threadIdx.x;   // block 128
    float s = 0.f, s2 = 0.f;
    #pragma unroll
    for (int i = 0; i < 64; ++i) {
        s += mid[(size_t)i * 256 + c];
        s2 += mid[(size_t)i * 256 + 128 + c];
    }
    float m = s / (float)(BB * LL);
    float var = s2 / (float)(BB * LL) - m * m;
    var = fmaxf(var, 0.f);
    float rvv = 1.f / sqrtf(var + EPSf);
    mu[c] = m;
    sA[c] = rvv * g[c];
    tA[c] = be[c];
}

// ---------------------------------------------------------------------------
extern "C" void kernel_launch(void* const* d_in, const int* in_sizes, int n_in,
                              void* d_out, int out_size, void* d_ws, size_t ws_size,
                              hipStream_t stream) {
    const float* x     = (const float*)d_in[0];
    const float* bern  = (const float*)d_in[1];
    const float* ce    = (const float*)d_in[2];
    const float* wq_w  = (const float*)d_in[3];
    const float* wq_b  = (const float*)d_in[4];
    const float* wk_w  = (const float*)d_in[5];
    const float* wk_b  = (const float*)d_in[6];
    const float* wv_w  = (const float*)d_in[7];
    const float* wv_b  = (const float*)d_in[8];
    const float* cm_w1 = (const float*)d_in[9];
    const float* cm_b1 = (const float*)d_in[10];
    const float* cm_w2 = (const float*)d_in[11];
    const float* cm_b2 = (const float*)d_in[12];
    const float* tm_w1 = (const float*)d_in[13];
    const float* tm_b1 = (const float*)d_in[14];
    const float* tm_w2 = (const float*)d_in[15];
    const float* tm_b2 = (const float*)d_in[16];
    const float* bn_t_g = (const float*)d_in[17];
    const float* bn_t_b = (const float*)d_in[18];
    const float* lin_t_w = (const float*)d_in[19];
    const float* lin_t_b = (const float*)d_in[20];
    const float* bn_f_g = (const float*)d_in[21];
    const float* bn_f_b = (const float*)d_in[22];
    const float* f1_w  = (const float*)d_in[23];
    const float* f1_b  = (const float*)d_in[24];
    const float* f2_w  = (const float*)d_in[25];
    const float* f2_b  = (const float*)d_in[26];
    const float* out_w = (const float*)d_in[27];
    const float* out_b = (const float*)d_in[28];
    (void)in_sizes; (void)n_in; (void)out_size;

    float* y = (float*)d_out;                         // [B,P,C]
    float* ceOut = y + (size_t)BB * PP * CC;          // [K,H]

    float* ws = (float*)d_ws;
    size_t off = 0;
    auto alloc = [&](size_t n) { float* p = ws + off; off += n; return p; };
    float* mean1  = alloc(BB * CC);
    float* rstd1  = alloc(BB * CC);
    float* std1   = alloc(BB * CC);
    float* mean2  = alloc(BB * CC);
    float* rstd2  = alloc(BB * CC);
    float* std2   = alloc(BB * CC);
    float* bnmu   = alloc(LL);
    float* bnrv   = alloc(LL);
    float* bfpart = alloc(1024 * 256);
    float* bfmid  = alloc(64 * 256);
    float* bfmu   = alloc(CC);
    float* bfs    = alloc(CC);
    float* bft    = alloc(CC);
    float* cxpart = alloc(BB * 8 * 256);                      // colstats-1 partials
    float* cpart2 = alloc(1024 * 256);                        // colstats-2 partials (tm pair)
    float* qbuf   = alloc(KK * HH);
    ushort* qpb   = (ushort*)alloc(128 * 128 / 2);            // Qp bf16 padded
    float* qbp    = alloc(128);
    ushort* cnbh  = (ushort*)alloc(8192);                     // codebook hi bf16 [128][128]
    ushort* cnbl  = (ushort*)alloc(8192);                     // codebook lo
    float* rn     = alloc((size_t)BB * LL);
    float* rsum   = alloc((size_t)BB * LL);                   // per-row z sums
    float* rsq    = alloc((size_t)BB * LL);
    float* ppart  = alloc((size_t)BB * (LL / 32) * KK);
    float* pmean  = alloc(BB * KK);
    float* awhprt = alloc((size_t)BB * 4 * KK * HH);
    float* awh    = alloc((size_t)BB * KK * HH);
    float* aobuf  = alloc((size_t)BB * KK * HH);
    ushort* wsp   = (ushort*)alloc(7 * 2 * 16384 / 2);        // 7 split 128x128 weights
    ushort* wtT   = (ushort*)alloc((size_t)LL * LL / 2);      // lin_t_w^T bf16 [2048][2048]
    ushort* owT   = (ushort*)alloc((size_t)384 * LL / 2);     // out_w^T bf16 [384][2048]
    float* S      = alloc((size_t)BB * KK * LL);
    float* buf0   = alloc((size_t)BB * LL * CC);
    float* buf2   = alloc((size_t)BB * LL * CC);
    unsigned char* Mt = (unsigned char*)(ws + off);           // [B,K,L] u8
    ushort* abf = (ushort*)S;       // bf16 [B,C,L] overlay on S (mixer phase)
    ushort* hb  = (ushort*)buf0;    // bf16 h [B,L,H] overlay on buf0 (attn phase)
    (void)ws_size;

    auto whi = [&](int i) { return wsp + (size_t)i * 2 * 16384; };
    auto wlo = [&](int i) { return wsp + (size_t)i * 2 * 16384 + 16384; };

    const int ML = BB * LL;      // 131072
    dim3 tb(32, 8);
    dim3 tgrid(LL / 64, CC / 32, BB);
    dim3 wsg(4, 4);

    // 0) weight prep
    wtrans_kernel<<<dim3(LL / 32, LL / 32), tb, 0, stream>>>(lin_t_w, wtT, LL, LL);
    wtrans_kernel<<<dim3(LL / 32, 12), tb, 0, stream>>>(out_w, owT, LL, PP);
    wsplit_kernel<<<wsg, tb, 0, stream>>>(cm_w1, whi(0), wlo(0));
    wsplit_kernel<<<wsg, tb, 0, stream>>>(cm_w2, whi(1), wlo(1));
    wsplit_kernel<<<wsg, tb, 0, stream>>>(tm_w1, whi(2), wlo(2));
    wsplit_kernel<<<wsg, tb, 0, stream>>>(tm_w2, whi(3), wlo(3));
    wsplit_kernel<<<wsg, tb, 0, stream>>>(f1_w, whi(4), wlo(4));
    wsplit_kernel<<<wsg, tb, 0, stream>>>(f2_w, whi(5), wlo(5));
    wsplit_kernel<<<wsg, tb, 0, stream>>>(wv_w, whi(6), wlo(6));

    // 1) RevIN-1 stats (two-stage)
    colstats_part_kernel<<<dim3(8, BB), 256, 0, stream>>>(x, cxpart);
    colstats_final_kernel<<<dim3(BB), dim3(128), 0, stream>>>(cxpart, mean1, rstd1, std1);
    // 2) h = buf2 (fused split pair) + per-row sumsq -> rsq (for rownorm)
    mfma_sq2_kernel<1, 1, 0, 3, 1><<<dim3(ML / 128), 256, 0, stream>>>(
        x, whi(0), wlo(0), cm_b1, whi(1), wlo(1), cm_b2, buf2, mean1, rstd1, nullptr, CC,
        nullptr, rsq);
    rn_final_kernel<<<dim3(ML / 256), 256, 0, stream>>>(rsq, rn);
    // 3) Q, Qp(bf16), qb ; split codebook
    gemm_kernel<<<dim3(1, 1), 256, 0, stream>>>(ce, wq_w, wq_b, qbuf,
        KK, HH, HH, HH, HH, HH);
    qprime_kernel<<<dim3(128), dim3(128), 0, stream>>>(qbuf, wk_w, wk_b, qpb, qbp);
    cn_split_kernel<<<dim3(128), dim3(128), 0, stream>>>(ce, cnbh, cnbl);
    // 4) routing scores via split-precision MFMA (also emits hb = bf16 h)
    mfma_sq_kernel<0, 0, 2><<<dim3(ML / 128), 256, 0, stream>>>(
        buf2, cnbh, cnbl, nullptr, S, nullptr, nullptr, nullptr, 0, hb);
    // 5) softmax/mask/p-mean
    pmask_kernel<<<dim3(LL / 32, BB), 256, 0, stream>>>(S, rn, bern, Mt, ppart);
    pmean_final_kernel<<<dim3(BB), dim3(64), 0, stream>>>(ppart, pmean);
    // 6) attn scores via MFMA: S[b][k][l] = Qp.h + qb   (overwrites S, k-major)
    mfma_gemm_kernel<3><<<dim3(1024), 256, 0, stream>>>(
        hb, qpb, qbp, S, KK, 128, 0, 1, 1024, nullptr, nullptr, nullptr);
    // 7) masked double-exp softmax
    aw_kernel<<<dim3(BB * KK), 256, 0, stream>>>(S, Mt);
    // 8) awh -> ao -> cluster update
    awh_part_kernel<<<dim3(4, BB), 256, 0, stream>>>(S, buf2, awhprt);
    awh_reduce_kernel<<<dim3(BB * KK), dim3(128), 0, stream>>>(awhprt, awh);
    mfma_sq_kernel<0, 0, 0><<<dim3((BB * KK) / 128), 256, 0, stream>>>(
        awh, whi(6), wlo(6), wv_b, aobuf, nullptr, nullptr, nullptr, 0, nullptr);
    newce_kernel<<<dim3(KK), dim3(128), 0, stream>>>(aobuf, pmean, ceOut);
    // 9) temporal module (fused split pair): h2 = buf0, emits column-stat partials
    mfma_sq2_kernel<0, 1, 0, 2, 1><<<dim3(ML / 128), 256, 0, stream>>>(
        buf2, whi(2), wlo(2), tm_b1, whi(3), wlo(3), tm_b2, buf0,
        nullptr, nullptr, nullptr, 0, cpart2, nullptr);
    // 10) RevIN-2 stats (from fused partials) + apply: z = buf2
    colstats2_final_kernel<<<dim3(BB), dim3(128), 0, stream>>>(cpart2, mean2, rstd2, std2);
    revin_apply_kernel<<<dim3(32, BB), 256, 0, stream>>>(buf0, buf2, mean2, rstd2, rsum, rsq);
    // 11) 4 mixer blocks
    for (int blkI = 0; blkI < 4; ++blkI) {
        bnt_final_kernel<<<dim3(8), 256, 0, stream>>>(rsum, rsq, bnmu, bnrv);
        transpose_bn_kernel<true><<<tgrid, 256, 0, stream>>>(buf2, abf, bnmu, bnrv, bn_t_g, bn_t_b);
        mfma_ts5_kernel<<<dim3(1024), 512, 0, stream>>>(
            abf, wtT, lin_t_b, buf2, 16, 1024, bfpart);
        bnf_mid_kernel<<<dim3(64), 256, 0, stream>>>(bfpart, bfmid);
        bnf_final_kernel<<<dim3(1), dim3(128), 0, stream>>>(bfmid, bn_f_g, bn_f_b, bfmu, bfs, bft);
        mfma_sq2_kernel<2, 2, 0, 1, 0><<<dim3(ML / 128), 256, 0, stream>>>(
            buf2, whi(4), wlo(4), f1_b, whi(5), wlo(5), f2_b, buf2, bfmu, bfs, bft, 0,
            rsum, rsq);
    }
    // 12) head via MFMA: y[b,p,c] = (z^T @ out_w + out_b) * std2 + mean2
    transpose_bn_kernel<false><<<tgrid, 256, 0, stream>>>(buf2, abf,
        nullptr, nullptr, nullptr, nullptr);
    mfma_gemm_kernel<2><<<dim3(192), 256, 0, stream>>>(
        abf, owT, out_b, y, PP, LL, PP, 3, 192, std2, mean2, nullptr);
}

// Round 20
// 1242.697 us; speedup vs baseline: 1.1026x; 1.0052x over previous
//
#include <hip/hip_runtime.h>
#include <math.h>

#define BB 64
#define LL 2048
#define CC 128
#define HH 128
#define KK 64
#define PP 336
#define EPSf 1e-5f

typedef __attribute__((ext_vector_type(8))) short short8v;
typedef __attribute__((ext_vector_type(4))) float float4v;

__device__ inline ushort f2bf(float f) {
    union { float f; unsigned u; } v; v.f = f;
    unsigned r = (v.u + 0x7FFFu + ((v.u >> 16) & 1u)) >> 16;
    return (ushort)r;
}
__device__ inline float bf2f(ushort h) {
    union { unsigned u; float f; } v; v.u = ((unsigned)h) << 16;
    return v.f;
}

// exact-GELU via Abramowitz-Stegun 7.1.26 erf (|err| <= 1.5e-7)
__device__ inline float fast_gelu(float v) {
    float x = 0.70710678118654752f * v;
    float ax = fabsf(x);
    float t = 1.f / fmaf(0.3275911f, ax, 1.f);
    float p = t * fmaf(t, fmaf(t, fmaf(t, fmaf(t, 1.061405429f, -1.453152027f),
                                       1.421413741f), -0.284496736f), 0.254829592f);
    float er = fmaf(-p, __expf(-ax * ax), 1.f);
    er = (x < 0.f) ? -er : er;
    return 0.5f * v * (1.f + er);
}

// async 16B global -> LDS (wave-uniform LDS base + lane*16, per-lane global src)
__device__ __forceinline__ void async16(const ushort* g, ushort* l) {
    __builtin_amdgcn_global_load_lds(
        (const __attribute__((address_space(1))) void*)g,
        (__attribute__((address_space(3))) void*)l, 16, 0, 0);
}

// ---------------------------------------------------------------------------
// RevIN column stats, two-stage. part: grid (8, B), block 256.
// ---------------------------------------------------------------------------
__global__ __launch_bounds__(256)
void colstats_part_kernel(const float* __restrict__ x, float* __restrict__ part) {
    int b = blockIdx.y, chunk = blockIdx.x;
    int t = threadIdx.x;
    int c4 = (t & 31) * 4, rg = t >> 5;
    const float* xb = x + ((size_t)b * LL + chunk * 256) * CC;
    float4 s = make_float4(0.f, 0.f, 0.f, 0.f);
    float4 q = make_float4(0.f, 0.f, 0.f, 0.f);
    for (int l = rg; l < 256; l += 8) {
        float4 v = *(const float4*)(xb + (size_t)l * CC + c4);
        s.x += v.x; s.y += v.y; s.z += v.z; s.w += v.w;
        q.x += v.x * v.x; q.y += v.y * v.y; q.z += v.z * v.z; q.w += v.w * v.w;
    }
    __shared__ float ls[8][128];
    __shared__ float lq[8][128];
    *(float4*)&ls[rg][c4] = s;
    *(float4*)&lq[rg][c4] = q;
    __syncthreads();
    if (t < 128) {
        float a = 0.f, d = 0.f;
        #pragma unroll
        for (int i = 0; i < 8; ++i) { a += ls[i][t]; d += lq[i][t]; }
        part[((size_t)b * 8 + chunk) * 256 + t] = a;
        part[((size_t)b * 8 + chunk) * 256 + 128 + t] = d;
    }
}

__global__ void colstats_final_kernel(const float* __restrict__ part, float* __restrict__ mean,
                                      float* __restrict__ rstd, float* __restrict__ stdv) {
    int b = blockIdx.x, c = threadIdx.x;
    float s = 0.f, q = 0.f;
    #pragma unroll
    for (int i = 0; i < 8; ++i) {
        s += part[((size_t)b * 8 + i) * 256 + c];
        q += part[((size_t)b * 8 + i) * 256 + 128 + c];
    }
    float mu = s * (1.f / LL);
    float var = q * (1.f / LL) - mu * mu;
    var = fmaxf(var, 0.f);
    float sd = sqrtf(var + EPSf);
    mean[b * CC + c] = mu;
    stdv[b * CC + c] = sd;
    rstd[b * CC + c] = 1.f / sd;
}

__global__ void colstats2_final_kernel(const float* __restrict__ cpart, float* __restrict__ mean,
                                       float* __restrict__ rstd, float* __restrict__ stdv) {
    int b = blockIdx.x, c = threadIdx.x;
    float s = 0.f, q = 0.f;
    #pragma unroll
    for (int i = 0; i < 16; ++i) {
        s += cpart[((size_t)b * 16 + i) * 256 + c];
        q += cpart[((size_t)b * 16 + i) * 256 + 128 + c];
    }
    float mu = s * (1.f / LL);
    float var = q * (1.f / LL) - mu * mu;
    var = fmaxf(var, 0.f);
    float sd = sqrtf(var + EPSf);
    mean[b * CC + c] = mu;
    stdv[b * CC + c] = sd;
    rstd[b * CC + c] = 1.f / sd;
}

// rn[i] = 1/(sqrt(rowsumsq)+1e-8); grid 512, block 256
__global__ void rn_final_kernel(const float* __restrict__ rsq, float* __restrict__ rn) {
    size_t i = (size_t)blockIdx.x * 256 + threadIdx.x;
    rn[i] = 1.f / (sqrtf(rsq[i]) + 1e-8f);
}

// ---------------------------------------------------------------------------
// plain f32 VALU GEMM (tiny Q-GEMM only)
// ---------------------------------------------------------------------------
__global__ __launch_bounds__(256)
void gemm_kernel(const float* __restrict__ A, const float* __restrict__ W,
                 const float* __restrict__ bias, float* __restrict__ Out,
                 int M, int N, int Kd, int lda, int ldw, int ldo) {
    __shared__ float As[32][128];
    __shared__ float Ws[32][128];
    int tid = threadIdx.x;
    int tx = tid & 15, ty = tid >> 4;
    int n0 = blockIdx.x * 128;
    int m0 = blockIdx.y * 128;
    float acc[8][8] = {};

    for (int kt = 0; kt < Kd; kt += 32) {
        __syncthreads();
        #pragma unroll
        for (int it = 0; it < 4; ++it) {
            int q = tid + it * 256;
            int row = q >> 3;
            int kq = (q & 7) << 2;
            float4 v = make_float4(0.f, 0.f, 0.f, 0.f);
            int m = m0 + row;
            if (m < M) v = *(const float4*)(A + (size_t)m * lda + kt + kq);
            As[kq    ][row] = v.x;
            As[kq + 1][row] = v.y;
            As[kq + 2][row] = v.z;
            As[kq + 3][row] = v.w;
        }
        #pragma unroll
        for (int it = 0; it < 4; ++it) {
            int q = tid + it * 256;
            int kr = q >> 5;
            int nc = (q & 31) << 2;
            int n = n0 + nc;
            float4 v = make_float4(0.f, 0.f, 0.f, 0.f);
            if (n < N) v = *(const float4*)(W + (size_t)(kt + kr) * ldw + n);
            *(float4*)&Ws[kr][nc] = v;
        }
        __syncthreads();
        #pragma unroll
        for (int k = 0; k < 32; ++k) {
            float a[8], w[8];
            *(float4*)&a[0] = *(const float4*)&As[k][ty * 8];
            *(float4*)&a[4] = *(const float4*)&As[k][ty * 8 + 4];
            *(float4*)&w[0] = *(const float4*)&Ws[k][tx * 4];
            *(float4*)&w[4] = *(const float4*)&Ws[k][64 + tx * 4];
            #pragma unroll
            for (int i = 0; i < 8; ++i)
                #pragma unroll
                for (int j = 0; j < 8; ++j)
                    acc[i][j] = fmaf(a[i], w[j], acc[i][j]);
        }
    }

    #pragma unroll
    for (int i = 0; i < 8; ++i) {
        int m = m0 + ty * 8 + i;
        if (m >= M) continue;
        #pragma unroll
        for (int jj = 0; jj < 8; jj += 4) {
            int n = n0 + (jj ? 64 + tx * 4 : tx * 4);
            if (n >= N) continue;
            float o[4];
            #pragma unroll
            for (int j = 0; j < 4; ++j)
                o[j] = acc[i][jj + j] + (bias ? bias[n + j] : 0.f);
            *(float4*)(Out + (size_t)m * ldo + n) = *(float4*)o;
        }
    }
}

// ---------------------------------------------------------------------------
// Split-precision MFMA GEMM for K=128 (A f32 [M][128], W split bf16 [128][128]).
// EP: 0 -> Out[m*128+n]; 2 -> Out[m*64+n] only n<64.
// ---------------------------------------------------------------------------
template <int NORM, int ACT, int EP>
__global__ __launch_bounds__(256)
void mfma_sq_kernel(const float* __restrict__ A, const ushort* __restrict__ Whi,
                    const ushort* __restrict__ Wlo, const float* __restrict__ bias,
                    float* Out,
                    const float* __restrict__ nmu, const float* __restrict__ ns,
                    const float* __restrict__ nt, int normStride,
                    ushort* __restrict__ hbOut) {
    __shared__ ushort Ahi[128][72];
    __shared__ ushort Alo[128][72];
    __shared__ ushort Bhi[128][72];
    __shared__ ushort Blo[128][72];
    int tid = threadIdx.x;
    int m0 = blockIdx.x * 128;
    int noff = (NORM == 1) ? (m0 / LL) * normStride : 0;

    int w = tid >> 6, lane = tid & 63;
    int wm = (w >> 1) * 64, wn = (w & 1) * 64;
    int col = lane & 15, kq = lane >> 4;

    float4v acc[4][4];
    #pragma unroll
    for (int i = 0; i < 4; ++i)
        #pragma unroll
        for (int j = 0; j < 4; ++j) acc[i][j] = (float4v){0.f, 0.f, 0.f, 0.f};

    for (int kt = 0; kt < 2; ++kt) {
        __syncthreads();
        #pragma unroll
        for (int it = 0; it < 4; ++it) {
            int q = tid + it * 256;
            int row = q >> 3, k0 = (q & 7) * 8;
            int kg = kt * 64 + k0;
            const float* ap = A + (size_t)(m0 + row) * 128 + kg;
            float vv[8];
            *(float4*)&vv[0] = *(const float4*)ap;
            *(float4*)&vv[4] = *(const float4*)(ap + 4);
            ushort hi[8], lo[8];
            #pragma unroll
            for (int j = 0; j < 8; ++j) {
                float v = vv[j];
                if (NORM == 1) v = (v - nmu[noff + kg + j]) * ns[noff + kg + j];
                if (NORM == 2) v = (v - nmu[kg + j]) * ns[kg + j] + nt[kg + j];
                ushort h = f2bf(v);
                hi[j] = h;
                lo[j] = f2bf(v - bf2f(h));
            }
            if (hbOut)
                *(short8v*)(hbOut + (size_t)(m0 + row) * 128 + kg) = *(short8v*)hi;
            *(short8v*)&Ahi[row][k0] = *(short8v*)hi;
            *(short8v*)&Alo[row][k0] = *(short8v*)lo;
        }
        #pragma unroll
        for (int it = 0; it < 4; ++it) {
            int q = tid + it * 256;
            int row = q >> 3, k0 = (q & 7) * 8;
            *(short8v*)&Bhi[row][k0] =
                *(const short8v*)(Whi + (size_t)row * 128 + kt * 64 + k0);
            *(short8v*)&Blo[row][k0] =
                *(const short8v*)(Wlo + (size_t)row * 128 + kt * 64 + k0);
        }
        __syncthreads();
        #pragma unroll
        for (int ksub = 0; ksub < 2; ++ksub) {
            short8v ah[4], al[4], bh[4], bl[4];
            #pragma unroll
            for (int mf = 0; mf < 4; ++mf) {
                ah[mf] = *(const short8v*)&Ahi[wm + mf * 16 + col][ksub * 32 + kq * 8];
                al[mf] = *(const short8v*)&Alo[wm + mf * 16 + col][ksub * 32 + kq * 8];
            }
            #pragma unroll
            for (int nf = 0; nf < 4; ++nf) {
                bh[nf] = *(const short8v*)&Bhi[wn + nf * 16 + col][ksub * 32 + kq * 8];
                bl[nf] = *(const short8v*)&Blo[wn + nf * 16 + col][ksub * 32 + kq * 8];
            }
            #pragma unroll
            for (int mf = 0; mf < 4; ++mf)
                #pragma unroll
                for (int nf = 0; nf < 4; ++nf)
                    acc[mf][nf] = __builtin_amdgcn_mfma_f32_16x16x32_bf16(
                        ah[mf], bh[nf], acc[mf][nf], 0, 0, 0);
            #pragma unroll
            for (int mf = 0; mf < 4; ++mf)
                #pragma unroll
                for (int nf = 0; nf < 4; ++nf)
                    acc[mf][nf] = __builtin_amdgcn_mfma_f32_16x16x32_bf16(
                        ah[mf], bl[nf], acc[mf][nf], 0, 0, 0);
            #pragma unroll
            for (int mf = 0; mf < 4; ++mf)
                #pragma unroll
                for (int nf = 0; nf < 4; ++nf)
                    acc[mf][nf] = __builtin_amdgcn_mfma_f32_16x16x32_bf16(
                        al[mf], bh[nf], acc[mf][nf], 0, 0, 0);
        }
    }

    int rbase = kq * 4;
    #pragma unroll
    for (int nf = 0; nf < 4; ++nf) {
        int n = wn + nf * 16 + col;
        if (EP == 2 && n >= 64) continue;
        float bn = bias ? bias[n] : 0.f;
        #pragma unroll
        for (int mf = 0; mf < 4; ++mf) {
            #pragma unroll
            for (int r = 0; r < 4; ++r) {
                int m = m0 + wm + mf * 16 + rbase + r;
                float v = acc[mf][nf][r] + bn;
                if (ACT == 1) v = fmaxf(v, 0.f);
                if (ACT == 2) v = fast_gelu(v);
                if (EP == 0) Out[(size_t)m * 128 + n] = v;
                else if (EP == 1) Out[(size_t)m * 128 + n] += v;
                else Out[(size_t)m * 64 + n] = v;
            }
        }
    }
}

// ---------------------------------------------------------------------------
// FUSED pair of K=128 GEMMs (PREC=1: split-precision, PREC=0: plain bf16):
// EP2: 0 store; 1 residual+= with row sum/sumsq -> rsum/rsq;
//      2 store with per-block column partials -> rsum;
//      3 store with per-row sumsq -> rsq (for rownorm)
// ---------------------------------------------------------------------------
template <int NORM, int ACT1, int ACT2, int EP2, int PREC>
__global__ __launch_bounds__(256)
void mfma_sq2_kernel(const float* __restrict__ A,
                     const ushort* __restrict__ W1h, const ushort* __restrict__ W1l,
                     const float* __restrict__ b1v,
                     const ushort* __restrict__ W2h, const ushort* __restrict__ W2l,
                     const float* __restrict__ b2v, float* Out,
                     const float* __restrict__ nmu, const float* __restrict__ ns,
                     const float* __restrict__ nt, int normStride,
                     float* __restrict__ rsum, float* __restrict__ rsq) {
    __shared__ ushort Xhi[128][72];
    __shared__ ushort Xlo[PREC ? 128 : 1][72];
    __shared__ ushort Bh[128][72];
    __shared__ ushort Bl[PREC ? 128 : 1][72];
    int tid = threadIdx.x;
    int m0 = blockIdx.x * 128;
    int noff = (NORM == 1) ? (m0 / LL) * normStride : 0;
    int w = tid >> 6, lane = tid & 63;
    int wm = (w >> 1) * 64, wn = (w & 1) * 64;
    int col = lane & 15, kq = lane >> 4;

    float4v acc[4][4];
    #pragma unroll
    for (int i = 0; i < 4; ++i)
        #pragma unroll
        for (int j = 0; j < 4; ++j) acc[i][j] = (float4v){0.f, 0.f, 0.f, 0.f};

    // ---- GEMM1 over 2 K-tiles ----
    for (int kt = 0; kt < 2; ++kt) {
        __syncthreads();
        #pragma unroll
        for (int it = 0; it < 4; ++it) {
            int q = tid + it * 256;
            int row = q >> 3, k0 = (q & 7) * 8;
            int kg = kt * 64 + k0;
            const float* ap = A + (size_t)(m0 + row) * 128 + kg;
            float vv[8];
            *(float4*)&vv[0] = *(const float4*)ap;
            *(float4*)&vv[4] = *(const float4*)(ap + 4);
            ushort hi[8], lo[8];
            #pragma unroll
            for (int j = 0; j < 8; ++j) {
                float v = vv[j];
                if (NORM == 1) v = (v - nmu[noff + kg + j]) * ns[noff + kg + j];
                if (NORM == 2) v = (v - nmu[kg + j]) * ns[kg + j] + nt[kg + j];
                ushort h = f2bf(v);
                hi[j] = h;
                if (PREC) lo[j] = f2bf(v - bf2f(h));
            }
            *(short8v*)&Xhi[row][k0] = *(short8v*)hi;
            if (PREC) *(short8v*)&Xlo[row][k0] = *(short8v*)lo;
        }
        #pragma unroll
        for (int it = 0; it < 4; ++it) {
            int q = tid + it * 256;
            int row = q >> 3, k0 = (q & 7) * 8;
            *(short8v*)&Bh[row][k0] =
                *(const short8v*)(W1h + (size_t)row * 128 + kt * 64 + k0);
            if (PREC)
                *(short8v*)&Bl[row][k0] =
                    *(const short8v*)(W1l + (size_t)row * 128 + kt * 64 + k0);
        }
        __syncthreads();
        #pragma unroll
        for (int ksub = 0; ksub < 2; ++ksub) {
            short8v ah[4], al[4], bh[4], bl[4];
            #pragma unroll
            for (int mf = 0; mf < 4; ++mf) {
                ah[mf] = *(const short8v*)&Xhi[wm + mf * 16 + col][ksub * 32 + kq * 8];
                if (PREC) al[mf] = *(const short8v*)&Xlo[wm + mf * 16 + col][ksub * 32 + kq * 8];
            }
            #pragma unroll
            for (int nf = 0; nf < 4; ++nf) {
                bh[nf] = *(const short8v*)&Bh[wn + nf * 16 + col][ksub * 32 + kq * 8];
                if (PREC) bl[nf] = *(const short8v*)&Bl[wn + nf * 16 + col][ksub * 32 + kq * 8];
            }
            #pragma unroll
            for (int mf = 0; mf < 4; ++mf)
                #pragma unroll
                for (int nf = 0; nf < 4; ++nf)
                    acc[mf][nf] = __builtin_amdgcn_mfma_f32_16x16x32_bf16(
                        ah[mf], bh[nf], acc[mf][nf], 0, 0, 0);
            if (PREC) {
                #pragma unroll
                for (int mf = 0; mf < 4; ++mf)
                    #pragma unroll
                    for (int nf = 0; nf < 4; ++nf)
                        acc[mf][nf] = __builtin_amdgcn_mfma_f32_16x16x32_bf16(
                            ah[mf], bl[nf], acc[mf][nf], 0, 0, 0);
                #pragma unroll
                for (int mf = 0; mf < 4; ++mf)
                    #pragma unroll
                    for (int nf = 0; nf < 4; ++nf)
                        acc[mf][nf] = __builtin_amdgcn_mfma_f32_16x16x32_bf16(
                            al[mf], bh[nf], acc[mf][nf], 0, 0, 0);
            }
        }
    }

    // ---- GEMM2 ----
    float4v acc2[4][4];
    #pragma unroll
    for (int i = 0; i < 4; ++i)
        #pragma unroll
        for (int j = 0; j < 4; ++j) acc2[i][j] = (float4v){0.f, 0.f, 0.f, 0.f};

    for (int kt2 = 0; kt2 < 2; ++kt2) {
        __syncthreads();
        if ((wn >> 6) == kt2) {   // wave-uniform
            #pragma unroll
            for (int nf = 0; nf < 4; ++nf) {
                float bn = b1v[wn + nf * 16 + col];
                #pragma unroll
                for (int mf = 0; mf < 4; ++mf) {
                    #pragma unroll
                    for (int r = 0; r < 4; ++r) {
                        float v = acc[mf][nf][r] + bn;
                        if (ACT1 == 1) v = fmaxf(v, 0.f);
                        if (ACT1 == 2) v = fast_gelu(v);
                        int row = wm + mf * 16 + kq * 4 + r;
                        int c2 = nf * 16 + col;
                        ushort h = f2bf(v);
                        Xhi[row][c2] = h;
                        if (PREC) Xlo[row][c2] = f2bf(v - bf2f(h));
                    }
                }
            }
        }
        #pragma unroll
        for (int it = 0; it < 4; ++it) {
            int q = tid + it * 256;
            int row = q >> 3, k0 = (q & 7) * 8;
            *(short8v*)&Bh[row][k0] =
                *(const short8v*)(W2h + (size_t)row * 128 + kt2 * 64 + k0);
            if (PREC)
                *(short8v*)&Bl[row][k0] =
                    *(const short8v*)(W2l + (size_t)row * 128 + kt2 * 64 + k0);
        }
        __syncthreads();
        #pragma unroll
        for (int ksub = 0; ksub < 2; ++ksub) {
            short8v ah[4], al[4], bh[4], bl[4];
            #pragma unroll
            for (int mf = 0; mf < 4; ++mf) {
                ah[mf] = *(const short8v*)&Xhi[wm + mf * 16 + col][ksub * 32 + kq * 8];
                if (PREC) al[mf] = *(const short8v*)&Xlo[wm + mf * 16 + col][ksub * 32 + kq * 8];
            }
            #pragma unroll
            for (int nf = 0; nf < 4; ++nf) {
                bh[nf] = *(const short8v*)&Bh[wn + nf * 16 + col][ksub * 32 + kq * 8];
                if (PREC) bl[nf] = *(const short8v*)&Bl[wn + nf * 16 + col][ksub * 32 + kq * 8];
            }
            #pragma unroll
            for (int mf = 0; mf < 4; ++mf)
                #pragma unroll
                for (int nf = 0; nf < 4; ++nf)
                    acc2[mf][nf] = __builtin_amdgcn_mfma_f32_16x16x32_bf16(
                        ah[mf], bh[nf], acc2[mf][nf], 0, 0, 0);
            if (PREC) {
                #pragma unroll
                for (int mf = 0; mf < 4; ++mf)
                    #pragma unroll
                    for (int nf = 0; nf < 4; ++nf)
                        acc2[mf][nf] = __builtin_amdgcn_mfma_f32_16x16x32_bf16(
                            ah[mf], bl[nf], acc2[mf][nf], 0, 0, 0);
                #pragma unroll
                for (int mf = 0; mf < 4; ++mf)
                    #pragma unroll
                    for (int nf = 0; nf < 4; ++nf)
                        acc2[mf][nf] = __builtin_amdgcn_mfma_f32_16x16x32_bf16(
                            al[mf], bh[nf], acc2[mf][nf], 0, 0, 0);
            }
        }
    }

    int rbase = kq * 4;
    float rs_[4][4];
    float rq_[4][4];
    float cs_[4], cq_[4];
    if (EP2 == 1 || EP2 == 3) {
        #pragma unroll
        for (int a = 0; a < 4; ++a)
            #pragma unroll
            for (int b = 0; b < 4; ++b) { rs_[a][b] = 0.f; rq_[a][b] = 0.f; }
    }
    if (EP2 == 2) {
        #pragma unroll
        for (int a = 0; a < 4; ++a) { cs_[a] = 0.f; cq_[a] = 0.f; }
    }
    #pragma unroll
    for (int nf = 0; nf < 4; ++nf) {
        int n = wn + nf * 16 + col;
        float bn = b2v[n];
        #pragma unroll
        for (int mf = 0; mf < 4; ++mf) {
            #pragma unroll
            for (int r = 0; r < 4; ++r) {
                int m = m0 + wm + mf * 16 + rbase + r;
                float v = acc2[mf][nf][r] + bn;
                if (ACT2 == 1) v = fmaxf(v, 0.f);
                if (ACT2 == 2) v = fast_gelu(v);
                if (EP2 == 1) {
                    float fin = Out[(size_t)m * 128 + n] + v;
                    Out[(size_t)m * 128 + n] = fin;
                    rs_[mf][r] += fin;
                    rq_[mf][r] += fin * fin;
                } else {
                    Out[(size_t)m * 128 + n] = v;
                    if (EP2 == 2) { cs_[nf] += v; cq_[nf] += v * v; }
                    if (EP2 == 3) rq_[mf][r] += v * v;
                }
            }
        }
    }
    if (EP2 == 1) {
        #pragma unroll
        for (int mf = 0; mf < 4; ++mf)
            #pragma unroll
            for (int r = 0; r < 4; ++r) {
                float s = rs_[mf][r], q = rq_[mf][r];
                #pragma unroll
                for (int o = 1; o <= 8; o <<= 1) {
                    s += __shfl_xor(s, o);
                    q += __shfl_xor(q, o);
                }
                rs_[mf][r] = s; rq_[mf][r] = q;
            }
        __syncthreads();
        float* sred = (float*)&Xhi[0][0];   // [128][2]
        float* qred = sred + 256;
        if (col == 0) {
            #pragma unroll
            for (int mf = 0; mf < 4; ++mf)
                #pragma unroll
                for (int r = 0; r < 4; ++r) {
                    int row = wm + mf * 16 + kq * 4 + r;
                    sred[row * 2 + (wn >> 6)] = rs_[mf][r];
                    qred[row * 2 + (wn >> 6)] = rq_[mf][r];
                }
        }
        __syncthreads();
        if (tid < 128) {
            rsum[(size_t)m0 + tid] = sred[tid * 2] + sred[tid * 2 + 1];
            rsq[(size_t)m0 + tid]  = qred[tid * 2] + qred[tid * 2 + 1];
        }
    }
    if (EP2 == 3) {
        #pragma unroll
        for (int mf = 0; mf < 4; ++mf)
            #pragma unroll
            for (int r = 0; r < 4; ++r) {
                float q = rq_[mf][r];
                #pragma unroll
                for (int o = 1; o <= 8; o <<= 1) q += __shfl_xor(q, o);
                rq_[mf][r] = q;
            }
        __syncthreads();
        float* qred = (float*)&Xhi[0][0];   // [128][2]
        if (col == 0) {
            #pragma unroll
            for (int mf = 0; mf < 4; ++mf)
                #pragma unroll
                for (int r = 0; r < 4; ++r) {
                    int row = wm + mf * 16 + kq * 4 + r;
                    qred[row * 2 + (wn >> 6)] = rq_[mf][r];
                }
        }
        __syncthreads();
        if (tid < 128)
            rsq[(size_t)m0 + tid] = qred[tid * 2] + qred[tid * 2 + 1];
    }
    if (EP2 == 2) {
        #pragma unroll
        for (int nf = 0; nf < 4; ++nf) {
            #pragma unroll
            for (int o = 16; o <= 32; o <<= 1) {
                cs_[nf] += __shfl_xor(cs_[nf], o);
                cq_[nf] += __shfl_xor(cq_[nf], o);
            }
        }
        __syncthreads();
        float* colS = (float*)&Xhi[0][0];   // [2][128]
        float* colQ = colS + 256;
        if (kq == 0) {
            #pragma unroll
            for (int nf = 0; nf < 4; ++nf) {
                int n = wn + nf * 16 + col;
                colS[(wm >> 6) * 128 + n] = cs_[nf];
                colQ[(wm >> 6) * 128 + n] = cq_[nf];
            }
        }
        __syncthreads();
        if (tid < 128) {
            rsum[(size_t)blockIdx.x * 256 + tid] = colS[tid] + colS[128 + tid];
            rsum[(size_t)blockIdx.x * 256 + 128 + tid] = colQ[tid] + colQ[128 + tid];
        }
    }
}

// W [128][128] f32 -> Whi/Wlo [n][k] bf16 split (transposed). grid (4,4), block (32,8)
__global__ void wsplit_kernel(const float* __restrict__ W, ushort* __restrict__ Whi,
                              ushort* __restrict__ Wlo) {
    __shared__ float t[32][33];
    int k0 = blockIdx.x * 32, n0 = blockIdx.y * 32;
    int tx = threadIdx.x, ty = threadIdx.y;
    for (int i = ty; i < 32; i += 8)
        t[i][tx] = W[(size_t)(k0 + i) * 128 + n0 + tx];
    __syncthreads();
    for (int i = ty; i < 32; i += 8) {
        float v = t[tx][i];
        ushort h = f2bf(v);
        Whi[(size_t)(n0 + i) * 128 + k0 + tx] = h;
        Wlo[(size_t)(n0 + i) * 128 + k0 + tx] = f2bf(v - bf2f(h));
    }
}

// ---------------------------------------------------------------------------
// Timestep MFMA GEMM v5: 2-phase BK=64 128x128 64KB, 512 threads / 8 waves.
// Epilogue: v=gelu(acc+bias[n]); Z[(b*2048+n)*128+c] += v; emits bnf partials.
// ---------------------------------------------------------------------------
__global__ __launch_bounds__(512)
void mfma_ts5_kernel(const ushort* __restrict__ A, const ushort* __restrict__ W,
                     const float* __restrict__ bias, float* Z,
                     int nx, int nwg, float* __restrict__ bnfP) {
    __shared__ __align__(16) ushort smem[32768];   // 64 KB = 2 x (A 16KB + B 16KB)
    float (*Ol)[132] = (float(*)[132])smem;        // epilogue overlay

    int bid = blockIdx.x;
    int cpx = nwg >> 3;
    int swz = (bid & 7) * cpx + (bid >> 3);
    int n0 = (swz % nx) * 128;
    int m0 = (swz / nx) * 128;

    int tid = threadIdx.x;
    int w = tid >> 6, lane = tid & 63;
    int wm = (w >> 1) * 32, wn = (w & 1) * 64;   // 4m x 2n wave grid
    int col = lane & 15, kq = lane >> 4;

    int srow = lane >> 3;                    // 0..7
    int scol = ((lane & 7) ^ srow) << 3;     // pre-swizzled src ushort offset
    int xr = (col & 7) << 4;                 // read-side XOR (bytes)

    float4v acc[2][4];
    #pragma unroll
    for (int i = 0; i < 2; ++i)
        #pragma unroll
        for (int j = 0; j < 4; ++j) acc[i][j] = (float4v){0.f, 0.f, 0.f, 0.f};

    const int Kd = LL;
    const int kTiles = 32;

    #pragma unroll
    for (int it = 0; it < 2; ++it) {
        int rb = (w << 4) + (it << 3);
        async16(A + (size_t)(m0 + rb + srow) * Kd + scol, smem + (rb << 6));
        async16(W + (size_t)(n0 + rb + srow) * Kd + scol, smem + 8192 + (rb << 6));
    }
    __syncthreads();

    for (int kt = 0; kt < kTiles; ++kt) {
        int cur = kt & 1;
        const ushort* Ac = smem + (cur << 14);
        const ushort* Bc = Ac + 8192;
        if (kt + 1 < kTiles) {
            ushort* An = smem + ((cur ^ 1) << 14);
            ushort* Bn = An + 8192;
            int kb = (kt + 1) << 6;
            #pragma unroll
            for (int it = 0; it < 2; ++it) {
                int rb = (w << 4) + (it << 3);
                async16(A + (size_t)(m0 + rb + srow) * Kd + kb + scol, An + (rb << 6));
                async16(W + (size_t)(n0 + rb + srow) * Kd + kb + scol, Bn + (rb << 6));
            }
        }
        __builtin_amdgcn_s_setprio(1);
        #pragma unroll
        for (int ksub = 0; ksub < 2; ++ksub) {
            int cswz = (((ksub << 6) + (kq << 4)) ^ xr) >> 1;
            short8v af[2], bf[4];
            #pragma unroll
            for (int mf = 0; mf < 2; ++mf)
                af[mf] = *(const short8v*)(Ac + (wm + mf * 16 + col) * 64 + cswz);
            #pragma unroll
            for (int nf = 0; nf < 4; ++nf)
                bf[nf] = *(const short8v*)(Bc + (wn + nf * 16 + col) * 64 + cswz);
            #pragma unroll
            for (int mf = 0; mf < 2; ++mf)
                #pragma unroll
                for (int nf = 0; nf < 4; ++nf)
                    acc[mf][nf] = __builtin_amdgcn_mfma_f32_16x16x32_bf16(
                        af[mf], bf[nf], acc[mf][nf], 0, 0, 0);
        }
        __builtin_amdgcn_s_setprio(0);
        __syncthreads();
    }

    // Epilogue: 4 rounds of 32-n strips through Ol (512-thread variant)
    int b = m0 >> 7;
    float cs[8], cq[8];
    #pragma unroll
    for (int j = 0; j < 8; ++j) { cs[j] = 0.f; cq[j] = 0.f; }
    int nloc = tid >> 4, c0 = (tid & 15) * 8;
    #pragma unroll
    for (int q = 0; q < 4; ++q) {
        __syncthreads();
        #pragma unroll
        for (int nf = 0; nf < 4; ++nf) {
            int gnl = wn + nf * 16;
            if ((gnl >> 5) != q) continue;
            int gn = n0 + gnl + col;
            float bn = bias[gn];
            int nl = gnl - q * 32 + col;
            #pragma unroll
            for (int mf = 0; mf < 2; ++mf)
                #pragma unroll
                for (int r = 0; r < 4; ++r) {
                    float v = acc[mf][nf][r] + bn;
                    v = fast_gelu(v);
                    Ol[nl][wm + mf * 16 + kq * 4 + r] = v;
                }
        }
        __syncthreads();
        int gn = n0 + q * 32 + nloc;
        float* zr = Z + ((size_t)b * LL + gn) * CC + c0;
        #pragma unroll
        for (int i = 0; i < 2; ++i) {
            float4 v = *(float4*)&Ol[nloc][c0 + i * 4];
            float4 o = *(float4*)(zr + i * 4);
            v.x += o.x; v.y += o.y; v.z += o.z; v.w += o.w;
            *(float4*)(zr + i * 4) = v;
            cs[i * 4 + 0] += v.x; cs[i * 4 + 1] += v.y;
            cs[i * 4 + 2] += v.z; cs[i * 4 + 3] += v.w;
            cq[i * 4 + 0] += v.x * v.x; cq[i * 4 + 1] += v.y * v.y;
            cq[i * 4 + 2] += v.z * v.z; cq[i * 4 + 3] += v.w * v.w;
        }
    }
    // per-block feature-BN partials
    __syncthreads();
    float* sred = (float*)smem;         // [32][128]
    float* qred = sred + 4096;          // [32][128]
    #pragma unroll
    for (int j = 0; j < 8; ++j) {
        sred[nloc * 128 + c0 + j] = cs[j];
        qred[nloc * 128 + c0 + j] = cq[j];
    }
    __syncthreads();
    if (tid < 128) {
        float a = 0.f;
        for (int r = 0; r < 32; ++r) a += sred[r * 128 + tid];
        bnfP[(size_t)bid * 256 + tid] = a;
    } else if (tid < 256) {
        int c = tid - 128;
        float a = 0.f;
        for (int r = 0; r < 32; ++r) a += qred[r * 128 + c];
        bnfP[(size_t)bid * 256 + 128 + c] = a;
    }
}

// ---------------------------------------------------------------------------
// 8-wave bf16 MFMA GEMM (generic K) for scores (EPM=3) and head (EPM=2).
// Same 2-phase 512-thread template as ts5; epilogue address math from the
// proven 256-thread kernel, re-indexed for 512 threads.
// EPM=2: v=acc+bias[n] (n<N guard); Z[(b*LDO+n)*128+c] = v*epS[m]+epM[m]
// EPM=3: scores: Z[((m0>>11)*64+gn)*2048 + (m0&2047) + c] = v  (gn < N)
// ---------------------------------------------------------------------------
template <int EPM>
__global__ __launch_bounds__(512)
void mfma_g8_kernel(const ushort* __restrict__ A, const ushort* __restrict__ W,
                    const float* __restrict__ bias, float* Z,
                    int N, int Kd, int LDO, int nx, int nwg,
                    const float* __restrict__ epS, const float* __restrict__ epM) {
    __shared__ __align__(16) ushort smem[32768];
    float (*Ol)[132] = (float(*)[132])smem;

    int bid = blockIdx.x;
    int cpx = nwg >> 3;
    int swz = (bid & 7) * cpx + (bid >> 3);
    int n0 = (swz % nx) * 128;
    int m0 = (swz / nx) * 128;

    int tid = threadIdx.x;
    int w = tid >> 6, lane = tid & 63;
    int wm = (w >> 1) * 32, wn = (w & 1) * 64;
    int col = lane & 15, kq = lane >> 4;

    int srow = lane >> 3;
    int scol = ((lane & 7) ^ srow) << 3;
    int xr = (col & 7) << 4;

    float4v acc[2][4];
    #pragma unroll
    for (int i = 0; i < 2; ++i)
        #pragma unroll
        for (int j = 0; j < 4; ++j) acc[i][j] = (float4v){0.f, 0.f, 0.f, 0.f};

    int kTiles = Kd >> 6;

    #pragma unroll
    for (int it = 0; it < 2; ++it) {
        int rb = (w << 4) + (it << 3);
        async16(A + (size_t)(m0 + rb + srow) * Kd + scol, smem + (rb << 6));
        async16(W + (size_t)(n0 + rb + srow) * Kd + scol, smem + 8192 + (rb << 6));
    }
    __syncthreads();

    for (int kt = 0; kt < kTiles; ++kt) {
        int cur = kt & 1;
        const ushort* Ac = smem + (cur << 14);
        const ushort* Bc = Ac + 8192;
        if (kt + 1 < kTiles) {
            ushort* An = smem + ((cur ^ 1) << 14);
            ushort* Bn = An + 8192;
            int kb = (kt + 1) << 6;
            #pragma unroll
            for (int it = 0; it < 2; ++it) {
                int rb = (w << 4) + (it << 3);
                async16(A + (size_t)(m0 + rb + srow) * Kd + kb + scol, An + (rb << 6));
                async16(W + (size_t)(n0 + rb + srow) * Kd + kb + scol, Bn + (rb << 6));
            }
        }
        __builtin_amdgcn_s_setprio(1);
        #pragma unroll
        for (int ksub = 0; ksub < 2; ++ksub) {
            int cswz = (((ksub << 6) + (kq << 4)) ^ xr) >> 1;
            short8v af[2], bf[4];
            #pragma unroll
            for (int mf = 0; mf < 2; ++mf)
                af[mf] = *(const short8v*)(Ac + (wm + mf * 16 + col) * 64 + cswz);
            #pragma unroll
            for (int nf = 0; nf < 4; ++nf)
                bf[nf] = *(const short8v*)(Bc + (wn + nf * 16 + col) * 64 + cswz);
            #pragma unroll
            for (int mf = 0; mf < 2; ++mf)
                #pragma unroll
                for (int nf = 0; nf < 4; ++nf)
                    acc[mf][nf] = __builtin_amdgcn_mfma_f32_16x16x32_bf16(
                        af[mf], bf[nf], acc[mf][nf], 0, 0, 0);
        }
        __builtin_amdgcn_s_setprio(0);
        __syncthreads();
    }

    // Epilogue: 4 rounds of 32-n strips through Ol (512-thread indexing)
    int b = m0 >> 7;
    int nloc = tid >> 4, c0 = (tid & 15) * 8;
    #pragma unroll
    for (int q = 0; q < 4; ++q) {
        __syncthreads();
        #pragma unroll
        for (int nf = 0; nf < 4; ++nf) {
            int gnl = wn + nf * 16;
            if ((gnl >> 5) != q) continue;
            int gn = n0 + gnl + col;
            float bn = (EPM == 2 && gn >= N) ? 0.f : bias[gn];
            int nl = gnl - q * 32 + col;
            #pragma unroll
            for (int mf = 0; mf < 2; ++mf)
                #pragma unroll
                for (int r = 0; r < 4; ++r)
                    Ol[nl][wm + mf * 16 + kq * 4 + r] = acc[mf][nf][r] + bn;
        }
        __syncthreads();
        int gn = n0 + q * 32 + nloc;
        if (gn >= N) continue;
        float* zr;
        if (EPM == 3)
            zr = Z + (((size_t)(m0 >> 11) * 64 + gn) * 2048) + (m0 & 2047) + c0;
        else
            zr = Z + ((size_t)b * LDO + gn) * CC + c0;
        #pragma unroll
        for (int i = 0; i < 2; ++i) {
            float4 v = *(float4*)&Ol[nloc][c0 + i * 4];
            if (EPM == 2) {
                int mb = m0 + c0 + i * 4;
                float4 s4 = *(const float4*)(epS + mb);
                float4 m4 = *(const float4*)(epM + mb);
                v.x = v.x * s4.x + m4.x; v.y = v.y * s4.y + m4.y;
                v.z = v.z * s4.z + m4.z; v.w = v.w * s4.w + m4.w;
            }
            *(float4*)(zr + i * 4) = v;
        }
    }
}

// W [K][N] f32 -> WT [Npad][K] bf16 (zero-filled for n >= N).
__global__ void wtrans_kernel(const float* __restrict__ W, ushort* __restrict__ WT,
                              int Kd, int N) {
    __shared__ float t[32][33];
    int k0 = blockIdx.x * 32, n0 = blockIdx.y * 32;
    int tx = threadIdx.x, ty = threadIdx.y;
    for (int i = ty; i < 32; i += 8) {
        int n = n0 + tx;
        t[i][tx] = (n < N) ? W[(size_t)(k0 + i) * N + n] : 0.f;
    }
    __syncthreads();
    for (int i = ty; i < 32; i += 8)
        WT[(size_t)(n0 + i) * Kd + k0 + tx] = f2bf(t[tx][i]);
}

// ---------------------------------------------------------------------------
__global__ void cn_split_kernel(const float* __restrict__ ce, ushort* __restrict__ ch,
                                ushort* __restrict__ cl) {
    int k = blockIdx.x, h = threadIdx.x;
    if (k >= KK) {
        ch[(size_t)k * 128 + h] = 0;
        cl[(size_t)k * 128 + h] = 0;
        return;
    }
    __shared__ float sh[128];
    float v = ce[(size_t)k * HH + h];
    sh[h] = v * v;
    __syncthreads();
    for (int o = 64; o >= 1; o >>= 1) {
        if (h < o) sh[h] += sh[h + o];
        __syncthreads();
    }
    float nv = v / (sqrtf(sh[0]) + 1e-8f);
    ushort hh = f2bf(nv);
    ch[(size_t)k * 128 + h] = hh;
    cl[(size_t)k * 128 + h] = f2bf(nv - bf2f(hh));
}

// Qp bf16 [128][128] (rows >= 64 zero), qb f32 [128]
__global__ void qprime_kernel(const float* __restrict__ Q, const float* __restrict__ wk_w,
                              const float* __restrict__ wk_b, ushort* __restrict__ qpb,
                              float* __restrict__ qbp) {
    int k = blockIdx.x;
    int hp = threadIdx.x;
    if (k >= KK) {
        qpb[(size_t)k * HH + hp] = 0;
        if (hp == 0) qbp[k] = 0.f;
        return;
    }
    __shared__ float qrow[128];
    __shared__ float red[128];
    qrow[hp] = Q[(size_t)k * HH + hp];
    __syncthreads();
    float s = 0.f;
    for (int h = 0; h < HH; ++h) s = fmaf(qrow[h], wk_w[(size_t)hp * HH + h], s);
    const float rs = 0.088388347648318447f;
    qpb[(size_t)k * HH + hp] = f2bf(s * rs);
    red[hp] = qrow[hp] * wk_b[hp];
    __syncthreads();
    for (int o = 64; o >= 1; o >>= 1) {
        if (hp < o) red[hp] += red[hp + o];
        __syncthreads();
    }
    if (hp == 0) qbp[k] = red[0] * rs;
}

// ---------------------------------------------------------------------------
__global__ __launch_bounds__(256)
void pmask_kernel(const float* __restrict__ sp, const float* __restrict__ rn,
                  const float* __restrict__ bern, unsigned char* __restrict__ Mt,
                  float* __restrict__ ppart) {
    int b = blockIdx.y;
    int l0 = blockIdx.x * 32;
    int tid = threadIdx.x;
    int wv = tid >> 6, lane = tid & 63;
    __shared__ float Msh[64][33];
    __shared__ float psum[4][64];
    float pa = 0.f;
    for (int tt = 0; tt < 8; ++tt) {
        int l = l0 + wv * 8 + tt;
        size_t tok = (size_t)b * LL + l;
        float s = sp[tok * 64 + lane] * rn[tok];
        float mx = s;
        #pragma unroll
        for (int o = 32; o >= 1; o >>= 1) mx = fmaxf(mx, __shfl_xor(mx, o));
        float ev = expf(s - mx);
        float sm = ev;
        #pragma unroll
        for (int o = 32; o >= 1; o >>= 1) sm += __shfl_xor(sm, o);
        float p = ev / sm;
        pa += p;
        Msh[lane][wv * 8 + tt] = (bern[tok * KK + lane] < p) ? 1.f : 0.f;
    }
    psum[wv][lane] = pa;
    __syncthreads();
    for (int q = tid; q < 64 * 32; q += 256) {
        int k = q >> 5, j = q & 31;
        Mt[((size_t)b * KK + k) * LL + l0 + j] = (unsigned char)Msh[k][j];
    }
    if (tid < 64)
        ppart[((size_t)b * (LL / 32) + blockIdx.x) * KK + tid] =
            psum[0][tid] + psum[1][tid] + psum[2][tid] + psum[3][tid];
}

__global__ void pmean_final_kernel(const float* __restrict__ part, float* __restrict__ pm) {
    int b = blockIdx.x, k = threadIdx.x;
    float s = 0.f;
    for (int i = 0; i < LL / 32; ++i) s += part[((size_t)b * (LL / 32) + i) * KK + k];
    pm[b * KK + k] = s * (1.f / LL);
}

// ---------------------------------------------------------------------------
__global__ __launch_bounds__(256)
void aw_kernel(float* __restrict__ S, const unsigned char* __restrict__ Mt) {
    size_t base = (size_t)blockIdx.x * LL;
    int tid = threadIdx.x;
    float t[8];
    float mx = -1e30f;
    #pragma unroll
    for (int i = 0; i < 8; ++i) {
        int l = tid + i * 256;
        float v = expf(S[base + l]) * (float)Mt[base + l];
        t[i] = v;
        mx = fmaxf(mx, v);
    }
    __shared__ float shA[4];
    __shared__ float shB[4];
    #pragma unroll
    for (int o = 32; o >= 1; o >>= 1) mx = fmaxf(mx, __shfl_xor(mx, o));
    if ((tid & 63) == 0) shA[tid >> 6] = mx;
    __syncthreads();
    mx = fmaxf(fmaxf(shA[0], shA[1]), fmaxf(shA[2], shA[3]));
    float e[8];
    float sum = 0.f;
    #pragma unroll
    for (int i = 0; i < 8; ++i) { e[i] = expf(t[i] - mx); sum += e[i]; }
    #pragma unroll
    for (int o = 32; o >= 1; o >>= 1) sum += __shfl_xor(sum, o);
    if ((tid & 63) == 0) shB[tid >> 6] = sum;
    __syncthreads();
    sum = (shB[0] + shB[1]) + (shB[2] + shB[3]);
    float inv = 1.f / sum;
    #pragma unroll
    for (int i = 0; i < 8; ++i) S[base + tid + i * 256] = e[i] * inv;
}

// ---------------------------------------------------------------------------
__global__ __launch_bounds__(256)
void awh_part_kernel(const float* __restrict__ AWs, const float* __restrict__ hmat,
                     float* __restrict__ part) {
    __shared__ float AT[32][64];
    __shared__ float VT[32][128];
    int b = blockIdx.y, sp = blockIdx.x;
    int tid = threadIdx.x;
    int tx = tid & 15, ty = tid >> 4;
    float acc[4][8] = {};
    const float* Ab = AWs + (size_t)b * KK * LL + sp * 512;
    const float* Vb = hmat + ((size_t)b * LL + sp * 512) * HH;
    for (int lt = 0; lt < 512; lt += 32) {
        __syncthreads();
        #pragma unroll
        for (int it = 0; it < 2; ++it) {
            int q = tid + it * 256;
            int row = q >> 3;
            int lq = (q & 7) << 2;
            float4 v = *(const float4*)(Ab + (size_t)row * LL + lt + lq);
            AT[lq][row] = v.x; AT[lq + 1][row] = v.y;
            AT[lq + 2][row] = v.z; AT[lq + 3][row] = v.w;
        }
        #pragma unroll
        for (int it = 0; it < 4; ++it) {
            int q = tid + it * 256;
            int lr = q >> 5;
            int hc = (q & 31) << 2;
            *(float4*)&VT[lr][hc] = *(const float4*)(Vb + (size_t)(lt + lr) * HH + hc);
        }
        __syncthreads();
        #pragma unroll
        for (int l = 0; l < 32; ++l) {
            float av[4], vv[8];
            *(float4*)&av[0] = *(const float4*)&AT[l][ty * 4];
            *(float4*)&vv[0] = *(const float4*)&VT[l][tx * 4];
            *(float4*)&vv[4] = *(const float4*)&VT[l][64 + tx * 4];
            #pragma unroll
            for (int i = 0; i < 4; ++i)
                #pragma unroll
                for (int j = 0; j < 8; ++j)
                    acc[i][j] = fmaf(av[i], vv[j], acc[i][j]);
        }
    }
    #pragma unroll
    for (int i = 0; i < 4; ++i) {
        int k = ty * 4 + i;
        #pragma unroll
        for (int jj = 0; jj < 8; jj += 4) {
            int h = (jj ? 64 + tx * 4 : tx * 4);
            float o[4];
            #pragma unroll
            for (int j = 0; j < 4; ++j) o[j] = acc[i][jj + j];
            *(float4*)(part + (((size_t)b * 4 + sp) * KK + k) * HH + h) = *(float4*)o;
        }
    }
}

__global__ void awh_reduce_kernel(const float* __restrict__ part, float* __restrict__ awh) {
    int bk = blockIdx.x, h = threadIdx.x;
    int b = bk >> 6, k = bk & 63;
    float s = 0.f;
    #pragma unroll
    for (int sp = 0; sp < 4; ++sp)
        s += part[(((size_t)b * 4 + sp) * KK + k) * HH + h];
    awh[(size_t)bk * HH + h] = s;
}

__global__ void newce_kernel(const float* __restrict__ ao, const float* __restrict__ pm,
                             float* __restrict__ outTail) {
    int k = blockIdx.x, h = threadIdx.x;
    float s = 0.f;
    for (int b = 0; b < BB; ++b)
        s += ao[((size_t)b * KK + k) * HH + h] * pm[b * KK + k];
    outTail[(size_t)k * HH + h] = s * (1.f / BB);
}

// z_out = (in - mean2)*rstd2; also emits per-row sum/sumsq. grid (32, B), block 256
__global__ void revin_apply_kernel(const float* __restrict__ in, float* __restrict__ out,
                                   const float* __restrict__ mu, const float* __restrict__ rs,
                                   float* __restrict__ rsum, float* __restrict__ rsq) {
    int b = blockIdx.y;
    size_t base = (size_t)b * LL * CC + (size_t)blockIdx.x * 8192;
    int c0 = (threadIdx.x * 4) & 127;
    int lane = threadIdx.x & 63;
    float4 m4 = *(const float4*)(mu + b * CC + c0);
    float4 r4 = *(const float4*)(rs + b * CC + c0);
    #pragma unroll
    for (int j = 0; j < 8; ++j) {
        float4 v = *(const float4*)(in + base + threadIdx.x * 4 + j * 1024);
        v.x = (v.x - m4.x) * r4.x; v.y = (v.y - m4.y) * r4.y;
        v.z = (v.z - m4.z) * r4.z; v.w = (v.w - m4.w) * r4.w;
        *(float4*)(out + base + threadIdx.x * 4 + j * 1024) = v;
        float s = v.x + v.y + v.z + v.w;
        float q = v.x * v.x + v.y * v.y + v.z * v.z + v.w * v.w;
        #pragma unroll
        for (int o = 1; o <= 16; o <<= 1) {
            s += __shfl_xor(s, o);
            q += __shfl_xor(q, o);
        }
        if ((lane & 31) == 0) {
            size_t row = (base + (size_t)threadIdx.x * 4 + (size_t)j * 1024) >> 7;
            rsum[row] = s;
            rsq[row] = q;
        }
    }
}

// timestep-BN final: per l over 64 b's of row stats. grid 8, block 256
__global__ void bnt_final_kernel(const float* __restrict__ rsum, const float* __restrict__ rsq,
                                 float* __restrict__ mu, float* __restrict__ rv) {
    int l = blockIdx.x * 256 + threadIdx.x;
    float s = 0.f, q = 0.f;
    for (int b = 0; b < BB; ++b) {
        s += rsum[(size_t)b * LL + l];
        q += rsq[(size_t)b * LL + l];
    }
    float m = s * (1.f / (BB * CC));
    float var = q * (1.f / (BB * CC)) - m * m;
    var = fmaxf(var, 0.f);
    mu[l] = m;
    rv[l] = 1.f / sqrtf(var + EPSf);
}

// ---------------------------------------------------------------------------
// [B,L,C] f32 -> [B,C,L] bf16, optional timestep-BN. v2: 64(l)x32(c) tiles,
// uint4 (8 bf16) coalesced writes. grid (L/64, C/32, B), block 256.
// ---------------------------------------------------------------------------
template <bool DO_BN>
__global__ __launch_bounds__(256)
void transpose_bn_kernel(const float* __restrict__ in, ushort* __restrict__ out,
                         const float* __restrict__ mu, const float* __restrict__ rv,
                         const float* __restrict__ g, const float* __restrict__ be) {
    __shared__ ushort tile[32][72];   // [c][l] bf16, padded
    int l0 = blockIdx.x * 64, c0 = blockIdx.y * 32, b = blockIdx.z;
    int t = threadIdx.x;
    const float* ib = in + ((size_t)b * LL + l0) * CC + c0;
    #pragma unroll
    for (int it = 0; it < 2; ++it) {
        int idx = t + it * 256;
        int row = idx >> 3;           // 0..63 (l offset)
        int c = (idx & 7) * 4;        // 0..28
        float4 v = *(const float4*)(ib + (size_t)row * CC + c);
        if (DO_BN) {
            int l = l0 + row;
            float sc = rv[l] * g[l];
            float m = mu[l], bb = be[l];
            v.x = (v.x - m) * sc + bb; v.y = (v.y - m) * sc + bb;
            v.z = (v.z - m) * sc + bb; v.w = (v.w - m) * sc + bb;
        }
        tile[c    ][row] = f2bf(v.x);
        tile[c + 1][row] = f2bf(v.y);
        tile[c + 2][row] = f2bf(v.z);
        tile[c + 3][row] = f2bf(v.w);
    }
    __syncthreads();
    int cc = t >> 3, l8 = (t & 7) * 8;
    ushort* ob = out + (size_t)b * CC * LL + (size_t)(c0 + cc) * LL + l0 + l8;
    *(uint4*)ob = *(const uint4*)&tile[cc][l8];
}

// feature-BN two-stage reduce: mid over 16 blocks each; final over 64 mids
__global__ void bnf_mid_kernel(const float* __restrict__ part, float* __restrict__ mid) {
    int gblk = blockIdx.x, t = threadIdx.x;   // grid 64, block 256
    float s = 0.f;
    #pragma unroll
    for (int i = 0; i < 16; ++i)
        s += part[(size_t)(gblk * 16 + i) * 256 + t];
    mid[(size_t)gblk * 256 + t] = s;
}

__global__ void bnf_final_kernel(const float* __restrict__ mid, const float* __restrict__ g,
                                 const float* __restrict__ be, float* __restrict__ mu,
                                 float* __restrict__ sA, float* __restrict__ tA) {
    int c = threadIdx.x;   // block 128
    float s = 0.f, s2 = 0.f;
    #pragma unroll
    for (int i = 0; i < 64; ++i) {
        s += mid[(size_t)i * 256 + c];
        s2 += mid[(size_t)i * 256 + 128 + c];
    }
    float m = s / (float)(BB * LL);
    float var = s2 / (float)(BB * LL) - m * m;
    var = fmaxf(var, 0.f);
    float rvv = 1.f / sqrtf(var + EPSf);
    mu[c] = m;
    sA[c] = rvv * g[c];
    tA[c] = be[c];
}

// ---------------------------------------------------------------------------
extern "C" void kernel_launch(void* const* d_in, const int* in_sizes, int n_in,
                              void* d_out, int out_size, void* d_ws, size_t ws_size,
                              hipStream_t stream) {
    const float* x     = (const float*)d_in[0];
    const float* bern  = (const float*)d_in[1];
    const float* ce    = (const float*)d_in[2];
    const float* wq_w  = (const float*)d_in[3];
    const float* wq_b  = (const float*)d_in[4];
    const float* wk_w  = (const float*)d_in[5];
    const float* wk_b  = (const float*)d_in[6];
    const float* wv_w  = (const float*)d_in[7];
    const float* wv_b  = (const float*)d_in[8];
    const float* cm_w1 = (const float*)d_in[9];
    const float* cm_b1 = (const float*)d_in[10];
    const float* cm_w2 = (const float*)d_in[11];
    const float* cm_b2 = (const float*)d_in[12];
    const float* tm_w1 = (const float*)d_in[13];
    const float* tm_b1 = (const float*)d_in[14];
    const float* tm_w2 = (const float*)d_in[15];
    const float* tm_b2 = (const float*)d_in[16];
    const float* bn_t_g = (const float*)d_in[17];
    const float* bn_t_b = (const float*)d_in[18];
    const float* lin_t_w = (const float*)d_in[19];
    const float* lin_t_b = (const float*)d_in[20];
    const float* bn_f_g = (const float*)d_in[21];
    const float* bn_f_b = (const float*)d_in[22];
    const float* f1_w  = (const float*)d_in[23];
    const float* f1_b  = (const float*)d_in[24];
    const float* f2_w  = (const float*)d_in[25];
    const float* f2_b  = (const float*)d_in[26];
    const float* out_w = (const float*)d_in[27];
    const float* out_b = (const float*)d_in[28];
    (void)in_sizes; (void)n_in; (void)out_size;

    float* y = (float*)d_out;                         // [B,P,C]
    float* ceOut = y + (size_t)BB * PP * CC;          // [K,H]

    float* ws = (float*)d_ws;
    size_t off = 0;
    auto alloc = [&](size_t n) { float* p = ws + off; off += n; return p; };
    float* mean1  = alloc(BB * CC);
    float* rstd1  = alloc(BB * CC);
    float* std1   = alloc(BB * CC);
    float* mean2  = alloc(BB * CC);
    float* rstd2  = alloc(BB * CC);
    float* std2   = alloc(BB * CC);
    float* bnmu   = alloc(LL);
    float* bnrv   = alloc(LL);
    float* bfpart = alloc(1024 * 256);
    float* bfmid  = alloc(64 * 256);
    float* bfmu   = alloc(CC);
    float* bfs    = alloc(CC);
    float* bft    = alloc(CC);
    float* cxpart = alloc(BB * 8 * 256);                      // colstats-1 partials
    float* cpart2 = alloc(1024 * 256);                        // colstats-2 partials (tm pair)
    float* qbuf   = alloc(KK * HH);
    ushort* qpb   = (ushort*)alloc(128 * 128 / 2);            // Qp bf16 padded
    float* qbp    = alloc(128);
    ushort* cnbh  = (ushort*)alloc(8192);                     // codebook hi bf16 [128][128]
    ushort* cnbl  = (ushort*)alloc(8192);                     // codebook lo
    float* rn     = alloc((size_t)BB * LL);
    float* rsum   = alloc((size_t)BB * LL);                   // per-row z sums
    float* rsq    = alloc((size_t)BB * LL);
    float* ppart  = alloc((size_t)BB * (LL / 32) * KK);
    float* pmean  = alloc(BB * KK);
    float* awhprt = alloc((size_t)BB * 4 * KK * HH);
    float* awh    = alloc((size_t)BB * KK * HH);
    float* aobuf  = alloc((size_t)BB * KK * HH);
    ushort* wsp   = (ushort*)alloc(7 * 2 * 16384 / 2);        // 7 split 128x128 weights
    ushort* wtT   = (ushort*)alloc((size_t)LL * LL / 2);      // lin_t_w^T bf16 [2048][2048]
    ushort* owT   = (ushort*)alloc((size_t)384 * LL / 2);     // out_w^T bf16 [384][2048]
    float* S      = alloc((size_t)BB * KK * LL);
    float* buf0   = alloc((size_t)BB * LL * CC);
    float* buf2   = alloc((size_t)BB * LL * CC);
    unsigned char* Mt = (unsigned char*)(ws + off);           // [B,K,L] u8
    ushort* abf = (ushort*)S;       // bf16 [B,C,L] overlay on S (mixer phase)
    ushort* hb  = (ushort*)buf0;    // bf16 h [B,L,H] overlay on buf0 (attn phase)
    (void)ws_size;

    auto whi = [&](int i) { return wsp + (size_t)i * 2 * 16384; };
    auto wlo = [&](int i) { return wsp + (size_t)i * 2 * 16384 + 16384; };

    const int ML = BB * LL;      // 131072
    dim3 tb(32, 8);
    dim3 tgrid(LL / 64, CC / 32, BB);
    dim3 wsg(4, 4);

    // 0) weight prep
    wtrans_kernel<<<dim3(LL / 32, LL / 32), tb, 0, stream>>>(lin_t_w, wtT, LL, LL);
    wtrans_kernel<<<dim3(LL / 32, 12), tb, 0, stream>>>(out_w, owT, LL, PP);
    wsplit_kernel<<<wsg, tb, 0, stream>>>(cm_w1, whi(0), wlo(0));
    wsplit_kernel<<<wsg, tb, 0, stream>>>(cm_w2, whi(1), wlo(1));
    wsplit_kernel<<<wsg, tb, 0, stream>>>(tm_w1, whi(2), wlo(2));
    wsplit_kernel<<<wsg, tb, 0, stream>>>(tm_w2, whi(3), wlo(3));
    wsplit_kernel<<<wsg, tb, 0, stream>>>(f1_w, whi(4), wlo(4));
    wsplit_kernel<<<wsg, tb, 0, stream>>>(f2_w, whi(5), wlo(5));
    wsplit_kernel<<<wsg, tb, 0, stream>>>(wv_w, whi(6), wlo(6));

    // 1) RevIN-1 stats (two-stage)
    colstats_part_kernel<<<dim3(8, BB), 256, 0, stream>>>(x, cxpart);
    colstats_final_kernel<<<dim3(BB), dim3(128), 0, stream>>>(cxpart, mean1, rstd1, std1);
    // 2) h = buf2 (fused split pair) + per-row sumsq -> rsq (for rownorm)
    mfma_sq2_kernel<1, 1, 0, 3, 1><<<dim3(ML / 128), 256, 0, stream>>>(
        x, whi(0), wlo(0), cm_b1, whi(1), wlo(1), cm_b2, buf2, mean1, rstd1, nullptr, CC,
        nullptr, rsq);
    rn_final_kernel<<<dim3(ML / 256), 256, 0, stream>>>(rsq, rn);
    // 3) Q, Qp(bf16), qb ; split codebook
    gemm_kernel<<<dim3(1, 1), 256, 0, stream>>>(ce, wq_w, wq_b, qbuf,
        KK, HH, HH, HH, HH, HH);
    qprime_kernel<<<dim3(128), dim3(128), 0, stream>>>(qbuf, wk_w, wk_b, qpb, qbp);
    cn_split_kernel<<<dim3(128), dim3(128), 0, stream>>>(ce, cnbh, cnbl);
    // 4) routing scores via split-precision MFMA (also emits hb = bf16 h)
    mfma_sq_kernel<0, 0, 2><<<dim3(ML / 128), 256, 0, stream>>>(
        buf2, cnbh, cnbl, nullptr, S, nullptr, nullptr, nullptr, 0, hb);
    // 5) softmax/mask/p-mean
    pmask_kernel<<<dim3(LL / 32, BB), 256, 0, stream>>>(S, rn, bern, Mt, ppart);
    pmean_final_kernel<<<dim3(BB), dim3(64), 0, stream>>>(ppart, pmean);
    // 6) attn scores via 8-wave MFMA: S[b][k][l] = Qp.h + qb   (overwrites S, k-major)
    mfma_g8_kernel<3><<<dim3(1024), 512, 0, stream>>>(
        hb, qpb, qbp, S, KK, 128, 0, 1, 1024, nullptr, nullptr);
    // 7) masked double-exp softmax
    aw_kernel<<<dim3(BB * KK), 256, 0, stream>>>(S, Mt);
    // 8) awh -> ao -> cluster update
    awh_part_kernel<<<dim3(4, BB), 256, 0, stream>>>(S, buf2, awhprt);
    awh_reduce_kernel<<<dim3(BB * KK), dim3(128), 0, stream>>>(awhprt, awh);
    mfma_sq_kernel<0, 0, 0><<<dim3((BB * KK) / 128), 256, 0, stream>>>(
        awh, whi(6), wlo(6), wv_b, aobuf, nullptr, nullptr, nullptr, 0, nullptr);
    newce_kernel<<<dim3(KK), dim3(128), 0, stream>>>(aobuf, pmean, ceOut);
    // 9) temporal module (fused split pair): h2 = buf0, emits column-stat partials
    mfma_sq2_kernel<0, 1, 0, 2, 1><<<dim3(ML / 128), 256, 0, stream>>>(
        buf2, whi(2), wlo(2), tm_b1, whi(3), wlo(3), tm_b2, buf0,
        nullptr, nullptr, nullptr, 0, cpart2, nullptr);
    // 10) RevIN-2 stats (from fused partials) + apply: z = buf2
    colstats2_final_kernel<<<dim3(BB), dim3(128), 0, stream>>>(cpart2, mean2, rstd2, std2);
    revin_apply_kernel<<<dim3(32, BB), 256, 0, stream>>>(buf0, buf2, mean2, rstd2, rsum, rsq);
    // 11) 4 mixer blocks
    for (int blkI = 0; blkI < 4; ++blkI) {
        bnt_final_kernel<<<dim3(8), 256, 0, stream>>>(rsum, rsq, bnmu, bnrv);
        transpose_bn_kernel<true><<<tgrid, 256, 0, stream>>>(buf2, abf, bnmu, bnrv, bn_t_g, bn_t_b);
        mfma_ts5_kernel<<<dim3(1024), 512, 0, stream>>>(
            abf, wtT, lin_t_b, buf2, 16, 1024, bfpart);
        bnf_mid_kernel<<<dim3(64), 256, 0, stream>>>(bfpart, bfmid);
        bnf_final_kernel<<<dim3(1), dim3(128), 0, stream>>>(bfmid, bn_f_g, bn_f_b, bfmu, bfs, bft);
        mfma_sq2_kernel<2, 2, 0, 1, 0><<<dim3(ML / 128), 256, 0, stream>>>(
            buf2, whi(4), wlo(4), f1_b, whi(5), wlo(5), f2_b, buf2, bfmu, bfs, bft, 0,
            rsum, rsq);
    }
    // 12) head via 8-wave MFMA: y[b,p,c] = (z^T @ out_w + out_b) * std2 + mean2
    transpose_bn_kernel<false><<<tgrid, 256, 0, stream>>>(buf2, abf,
        nullptr, nullptr, nullptr, nullptr);
    mfma_g8_kernel<2><<<dim3(192), 512, 0, stream>>>(
        abf, owT, out_b, y, PP, LL, PP, 3, 192, std2, mean2);
}

// Round 21
// 1161.254 us; speedup vs baseline: 1.1800x; 1.0701x over previous
//
#include <hip/hip_runtime.h>
#include <math.h>

#define BB 64
#define LL 2048
#define CC 128
#define HH 128
#define KK 64
#define PP 336
#define EPSf 1e-5f

typedef __attribute__((ext_vector_type(8))) short short8v;
typedef __attribute__((ext_vector_type(4))) float float4v;

__device__ inline ushort f2bf(float f) {
    union { float f; unsigned u; } v; v.f = f;
    unsigned r = (v.u + 0x7FFFu + ((v.u >> 16) & 1u)) >> 16;
    return (ushort)r;
}
__device__ inline float bf2f(ushort h) {
    union { unsigned u; float f; } v; v.u = ((unsigned)h) << 16;
    return v.f;
}

// exact-GELU via Abramowitz-Stegun 7.1.26 erf (|err| <= 1.5e-7)
__device__ inline float fast_gelu(float v) {
    float x = 0.70710678118654752f * v;
    float ax = fabsf(x);
    float t = 1.f / fmaf(0.3275911f, ax, 1.f);
    float p = t * fmaf(t, fmaf(t, fmaf(t, fmaf(t, 1.061405429f, -1.453152027f),
                                       1.421413741f), -0.284496736f), 0.254829592f);
    float er = fmaf(-p, __expf(-ax * ax), 1.f);
    er = (x < 0.f) ? -er : er;
    return 0.5f * v * (1.f + er);
}

// async 16B global -> LDS (wave-uniform LDS base + lane*16, per-lane global src)
__device__ __forceinline__ void async16(const ushort* g, ushort* l) {
    __builtin_amdgcn_global_load_lds(
        (const __attribute__((address_space(1))) void*)g,
        (__attribute__((address_space(3))) void*)l, 16, 0, 0);
}

// ---------------------------------------------------------------------------
// RevIN column stats, two-stage. part: grid (8, B), block 256.
// ---------------------------------------------------------------------------
__global__ __launch_bounds__(256)
void colstats_part_kernel(const float* __restrict__ x, float* __restrict__ part) {
    int b = blockIdx.y, chunk = blockIdx.x;
    int t = threadIdx.x;
    int c4 = (t & 31) * 4, rg = t >> 5;
    const float* xb = x + ((size_t)b * LL + chunk * 256) * CC;
    float4 s = make_float4(0.f, 0.f, 0.f, 0.f);
    float4 q = make_float4(0.f, 0.f, 0.f, 0.f);
    for (int l = rg; l < 256; l += 8) {
        float4 v = *(const float4*)(xb + (size_t)l * CC + c4);
        s.x += v.x; s.y += v.y; s.z += v.z; s.w += v.w;
        q.x += v.x * v.x; q.y += v.y * v.y; q.z += v.z * v.z; q.w += v.w * v.w;
    }
    __shared__ float ls[8][128];
    __shared__ float lq[8][128];
    *(float4*)&ls[rg][c4] = s;
    *(float4*)&lq[rg][c4] = q;
    __syncthreads();
    if (t < 128) {
        float a = 0.f, d = 0.f;
        #pragma unroll
        for (int i = 0; i < 8; ++i) { a += ls[i][t]; d += lq[i][t]; }
        part[((size_t)b * 8 + chunk) * 256 + t] = a;
        part[((size_t)b * 8 + chunk) * 256 + 128 + t] = d;
    }
}

__global__ void colstats_final_kernel(const float* __restrict__ part, float* __restrict__ mean,
                                      float* __restrict__ rstd, float* __restrict__ stdv) {
    int b = blockIdx.x, c = threadIdx.x;
    float s = 0.f, q = 0.f;
    #pragma unroll
    for (int i = 0; i < 8; ++i) {
        s += part[((size_t)b * 8 + i) * 256 + c];
        q += part[((size_t)b * 8 + i) * 256 + 128 + c];
    }
    float mu = s * (1.f / LL);
    float var = q * (1.f / LL) - mu * mu;
    var = fmaxf(var, 0.f);
    float sd = sqrtf(var + EPSf);
    mean[b * CC + c] = mu;
    stdv[b * CC + c] = sd;
    rstd[b * CC + c] = 1.f / sd;
}

__global__ void colstats2_final_kernel(const float* __restrict__ cpart, float* __restrict__ mean,
                                       float* __restrict__ rstd, float* __restrict__ stdv) {
    int b = blockIdx.x, c = threadIdx.x;
    float s = 0.f, q = 0.f;
    #pragma unroll
    for (int i = 0; i < 16; ++i) {
        s += cpart[((size_t)b * 16 + i) * 256 + c];
        q += cpart[((size_t)b * 16 + i) * 256 + 128 + c];
    }
    float mu = s * (1.f / LL);
    float var = q * (1.f / LL) - mu * mu;
    var = fmaxf(var, 0.f);
    float sd = sqrtf(var + EPSf);
    mean[b * CC + c] = mu;
    stdv[b * CC + c] = sd;
    rstd[b * CC + c] = 1.f / sd;
}

// rn[i] = 1/(sqrt(rowsumsq)+1e-8); grid 512, block 256
__global__ void rn_final_kernel(const float* __restrict__ rsq, float* __restrict__ rn) {
    size_t i = (size_t)blockIdx.x * 256 + threadIdx.x;
    rn[i] = 1.f / (sqrtf(rsq[i]) + 1e-8f);
}

// ---------------------------------------------------------------------------
// plain f32 VALU GEMM (tiny Q-GEMM only)
// ---------------------------------------------------------------------------
__global__ __launch_bounds__(256)
void gemm_kernel(const float* __restrict__ A, const float* __restrict__ W,
                 const float* __restrict__ bias, float* __restrict__ Out,
                 int M, int N, int Kd, int lda, int ldw, int ldo) {
    __shared__ float As[32][128];
    __shared__ float Ws[32][128];
    int tid = threadIdx.x;
    int tx = tid & 15, ty = tid >> 4;
    int n0 = blockIdx.x * 128;
    int m0 = blockIdx.y * 128;
    float acc[8][8] = {};

    for (int kt = 0; kt < Kd; kt += 32) {
        __syncthreads();
        #pragma unroll
        for (int it = 0; it < 4; ++it) {
            int q = tid + it * 256;
            int row = q >> 3;
            int kq = (q & 7) << 2;
            float4 v = make_float4(0.f, 0.f, 0.f, 0.f);
            int m = m0 + row;
            if (m < M) v = *(const float4*)(A + (size_t)m * lda + kt + kq);
            As[kq    ][row] = v.x;
            As[kq + 1][row] = v.y;
            As[kq + 2][row] = v.z;
            As[kq + 3][row] = v.w;
        }
        #pragma unroll
        for (int it = 0; it < 4; ++it) {
            int q = tid + it * 256;
            int kr = q >> 5;
            int nc = (q & 31) << 2;
            int n = n0 + nc;
            float4 v = make_float4(0.f, 0.f, 0.f, 0.f);
            if (n < N) v = *(const float4*)(W + (size_t)(kt + kr) * ldw + n);
            *(float4*)&Ws[kr][nc] = v;
        }
        __syncthreads();
        #pragma unroll
        for (int k = 0; k < 32; ++k) {
            float a[8], w[8];
            *(float4*)&a[0] = *(const float4*)&As[k][ty * 8];
            *(float4*)&a[4] = *(const float4*)&As[k][ty * 8 + 4];
            *(float4*)&w[0] = *(const float4*)&Ws[k][tx * 4];
            *(float4*)&w[4] = *(const float4*)&Ws[k][64 + tx * 4];
            #pragma unroll
            for (int i = 0; i < 8; ++i)
                #pragma unroll
                for (int j = 0; j < 8; ++j)
                    acc[i][j] = fmaf(a[i], w[j], acc[i][j]);
        }
    }

    #pragma unroll
    for (int i = 0; i < 8; ++i) {
        int m = m0 + ty * 8 + i;
        if (m >= M) continue;
        #pragma unroll
        for (int jj = 0; jj < 8; jj += 4) {
            int n = n0 + (jj ? 64 + tx * 4 : tx * 4);
            if (n >= N) continue;
            float o[4];
            #pragma unroll
            for (int j = 0; j < 4; ++j)
                o[j] = acc[i][jj + j] + (bias ? bias[n + j] : 0.f);
            *(float4*)(Out + (size_t)m * ldo + n) = *(float4*)o;
        }
    }
}

// ---------------------------------------------------------------------------
// Split-precision MFMA GEMM for K=128, 8-wave (512 thr, 4m x 2n, acc 2x4).
// EP: 0 -> Out[m*128+n]; 2 -> Out[m*64+n] only n<64.
// ---------------------------------------------------------------------------
template <int NORM, int ACT, int EP>
__global__ __launch_bounds__(512)
void mfma_sq_kernel(const float* __restrict__ A, const ushort* __restrict__ Whi,
                    const ushort* __restrict__ Wlo, const float* __restrict__ bias,
                    float* Out,
                    const float* __restrict__ nmu, const float* __restrict__ ns,
                    const float* __restrict__ nt, int normStride,
                    ushort* __restrict__ hbOut) {
    __shared__ ushort Ahi[128][72];
    __shared__ ushort Alo[128][72];
    __shared__ ushort Bhi[128][72];
    __shared__ ushort Blo[128][72];
    int tid = threadIdx.x;
    int m0 = blockIdx.x * 128;
    int noff = (NORM == 1) ? (m0 / LL) * normStride : 0;

    int w = tid >> 6, lane = tid & 63;
    int wm = (w >> 1) * 32, wn = (w & 1) * 64;
    int col = lane & 15, kq = lane >> 4;

    float4v acc[2][4];
    #pragma unroll
    for (int i = 0; i < 2; ++i)
        #pragma unroll
        for (int j = 0; j < 4; ++j) acc[i][j] = (float4v){0.f, 0.f, 0.f, 0.f};

    for (int kt = 0; kt < 2; ++kt) {
        __syncthreads();
        #pragma unroll
        for (int it = 0; it < 2; ++it) {
            int q = tid + it * 512;
            int row = q >> 3, k0 = (q & 7) * 8;
            int kg = kt * 64 + k0;
            const float* ap = A + (size_t)(m0 + row) * 128 + kg;
            float vv[8];
            *(float4*)&vv[0] = *(const float4*)ap;
            *(float4*)&vv[4] = *(const float4*)(ap + 4);
            ushort hi[8], lo[8];
            #pragma unroll
            for (int j = 0; j < 8; ++j) {
                float v = vv[j];
                if (NORM == 1) v = (v - nmu[noff + kg + j]) * ns[noff + kg + j];
                if (NORM == 2) v = (v - nmu[kg + j]) * ns[kg + j] + nt[kg + j];
                ushort h = f2bf(v);
                hi[j] = h;
                lo[j] = f2bf(v - bf2f(h));
            }
            if (hbOut)
                *(short8v*)(hbOut + (size_t)(m0 + row) * 128 + kg) = *(short8v*)hi;
            *(short8v*)&Ahi[row][k0] = *(short8v*)hi;
            *(short8v*)&Alo[row][k0] = *(short8v*)lo;
        }
        #pragma unroll
        for (int it = 0; it < 2; ++it) {
            int q = tid + it * 512;
            int row = q >> 3, k0 = (q & 7) * 8;
            *(short8v*)&Bhi[row][k0] =
                *(const short8v*)(Whi + (size_t)row * 128 + kt * 64 + k0);
            *(short8v*)&Blo[row][k0] =
                *(const short8v*)(Wlo + (size_t)row * 128 + kt * 64 + k0);
        }
        __syncthreads();
        #pragma unroll
        for (int ksub = 0; ksub < 2; ++ksub) {
            short8v ah[2], al[2], bh[4], bl[4];
            #pragma unroll
            for (int mf = 0; mf < 2; ++mf) {
                ah[mf] = *(const short8v*)&Ahi[wm + mf * 16 + col][ksub * 32 + kq * 8];
                al[mf] = *(const short8v*)&Alo[wm + mf * 16 + col][ksub * 32 + kq * 8];
            }
            #pragma unroll
            for (int nf = 0; nf < 4; ++nf) {
                bh[nf] = *(const short8v*)&Bhi[wn + nf * 16 + col][ksub * 32 + kq * 8];
                bl[nf] = *(const short8v*)&Blo[wn + nf * 16 + col][ksub * 32 + kq * 8];
            }
            #pragma unroll
            for (int mf = 0; mf < 2; ++mf)
                #pragma unroll
                for (int nf = 0; nf < 4; ++nf)
                    acc[mf][nf] = __builtin_amdgcn_mfma_f32_16x16x32_bf16(
                        ah[mf], bh[nf], acc[mf][nf], 0, 0, 0);
            #pragma unroll
            for (int mf = 0; mf < 2; ++mf)
                #pragma unroll
                for (int nf = 0; nf < 4; ++nf)
                    acc[mf][nf] = __builtin_amdgcn_mfma_f32_16x16x32_bf16(
                        ah[mf], bl[nf], acc[mf][nf], 0, 0, 0);
            #pragma unroll
            for (int mf = 0; mf < 2; ++mf)
                #pragma unroll
                for (int nf = 0; nf < 4; ++nf)
                    acc[mf][nf] = __builtin_amdgcn_mfma_f32_16x16x32_bf16(
                        al[mf], bh[nf], acc[mf][nf], 0, 0, 0);
        }
    }

    int rbase = kq * 4;
    #pragma unroll
    for (int nf = 0; nf < 4; ++nf) {
        int n = wn + nf * 16 + col;
        if (EP == 2 && n >= 64) continue;
        float bn = bias ? bias[n] : 0.f;
        #pragma unroll
        for (int mf = 0; mf < 2; ++mf) {
            #pragma unroll
            for (int r = 0; r < 4; ++r) {
                int m = m0 + wm + mf * 16 + rbase + r;
                float v = acc[mf][nf][r] + bn;
                if (ACT == 1) v = fmaxf(v, 0.f);
                if (ACT == 2) v = fast_gelu(v);
                if (EP == 0) Out[(size_t)m * 128 + n] = v;
                else if (EP == 1) Out[(size_t)m * 128 + n] += v;
                else Out[(size_t)m * 64 + n] = v;
            }
        }
    }
}

// ---------------------------------------------------------------------------
// FUSED pair of K=128 GEMMs, 8-wave (512 thr, 4m x 2n, acc 2x4).
// EP2: 0 store; 1 residual+= with row sum/sumsq -> rsum/rsq;
//      2 store with per-block column partials -> rsum;
//      3 store with per-row sumsq -> rsq (for rownorm)
// ---------------------------------------------------------------------------
template <int NORM, int ACT1, int ACT2, int EP2, int PREC>
__global__ __launch_bounds__(512)
void mfma_sq2_kernel(const float* __restrict__ A,
                     const ushort* __restrict__ W1h, const ushort* __restrict__ W1l,
                     const float* __restrict__ b1v,
                     const ushort* __restrict__ W2h, const ushort* __restrict__ W2l,
                     const float* __restrict__ b2v, float* Out,
                     const float* __restrict__ nmu, const float* __restrict__ ns,
                     const float* __restrict__ nt, int normStride,
                     float* __restrict__ rsum, float* __restrict__ rsq) {
    __shared__ ushort Xhi[128][72];
    __shared__ ushort Xlo[PREC ? 128 : 1][72];
    __shared__ ushort Bh[128][72];
    __shared__ ushort Bl[PREC ? 128 : 1][72];
    int tid = threadIdx.x;
    int m0 = blockIdx.x * 128;
    int noff = (NORM == 1) ? (m0 / LL) * normStride : 0;
    int w = tid >> 6, lane = tid & 63;
    int wm = (w >> 1) * 32, wn = (w & 1) * 64;
    int col = lane & 15, kq = lane >> 4;

    float4v acc[2][4];
    #pragma unroll
    for (int i = 0; i < 2; ++i)
        #pragma unroll
        for (int j = 0; j < 4; ++j) acc[i][j] = (float4v){0.f, 0.f, 0.f, 0.f};

    // ---- GEMM1 over 2 K-tiles ----
    for (int kt = 0; kt < 2; ++kt) {
        __syncthreads();
        #pragma unroll
        for (int it = 0; it < 2; ++it) {
            int q = tid + it * 512;
            int row = q >> 3, k0 = (q & 7) * 8;
            int kg = kt * 64 + k0;
            const float* ap = A + (size_t)(m0 + row) * 128 + kg;
            float vv[8];
            *(float4*)&vv[0] = *(const float4*)ap;
            *(float4*)&vv[4] = *(const float4*)(ap + 4);
            ushort hi[8], lo[8];
            #pragma unroll
            for (int j = 0; j < 8; ++j) {
                float v = vv[j];
                if (NORM == 1) v = (v - nmu[noff + kg + j]) * ns[noff + kg + j];
                if (NORM == 2) v = (v - nmu[kg + j]) * ns[kg + j] + nt[kg + j];
                ushort h = f2bf(v);
                hi[j] = h;
                if (PREC) lo[j] = f2bf(v - bf2f(h));
            }
            *(short8v*)&Xhi[row][k0] = *(short8v*)hi;
            if (PREC) *(short8v*)&Xlo[row][k0] = *(short8v*)lo;
        }
        #pragma unroll
        for (int it = 0; it < 2; ++it) {
            int q = tid + it * 512;
            int row = q >> 3, k0 = (q & 7) * 8;
            *(short8v*)&Bh[row][k0] =
                *(const short8v*)(W1h + (size_t)row * 128 + kt * 64 + k0);
            if (PREC)
                *(short8v*)&Bl[row][k0] =
                    *(const short8v*)(W1l + (size_t)row * 128 + kt * 64 + k0);
        }
        __syncthreads();
        #pragma unroll
        for (int ksub = 0; ksub < 2; ++ksub) {
            short8v ah[2], al[2], bh[4], bl[4];
            #pragma unroll
            for (int mf = 0; mf < 2; ++mf) {
                ah[mf] = *(const short8v*)&Xhi[wm + mf * 16 + col][ksub * 32 + kq * 8];
                if (PREC) al[mf] = *(const short8v*)&Xlo[wm + mf * 16 + col][ksub * 32 + kq * 8];
            }
            #pragma unroll
            for (int nf = 0; nf < 4; ++nf) {
                bh[nf] = *(const short8v*)&Bh[wn + nf * 16 + col][ksub * 32 + kq * 8];
                if (PREC) bl[nf] = *(const short8v*)&Bl[wn + nf * 16 + col][ksub * 32 + kq * 8];
            }
            #pragma unroll
            for (int mf = 0; mf < 2; ++mf)
                #pragma unroll
                for (int nf = 0; nf < 4; ++nf)
                    acc[mf][nf] = __builtin_amdgcn_mfma_f32_16x16x32_bf16(
                        ah[mf], bh[nf], acc[mf][nf], 0, 0, 0);
            if (PREC) {
                #pragma unroll
                for (int mf = 0; mf < 2; ++mf)
                    #pragma unroll
                    for (int nf = 0; nf < 4; ++nf)
                        acc[mf][nf] = __builtin_amdgcn_mfma_f32_16x16x32_bf16(
                            ah[mf], bl[nf], acc[mf][nf], 0, 0, 0);
                #pragma unroll
                for (int mf = 0; mf < 2; ++mf)
                    #pragma unroll
                    for (int nf = 0; nf < 4; ++nf)
                        acc[mf][nf] = __builtin_amdgcn_mfma_f32_16x16x32_bf16(
                            al[mf], bh[nf], acc[mf][nf], 0, 0, 0);
            }
        }
    }

    // ---- GEMM2 ----
    float4v acc2[2][4];
    #pragma unroll
    for (int i = 0; i < 2; ++i)
        #pragma unroll
        for (int j = 0; j < 4; ++j) acc2[i][j] = (float4v){0.f, 0.f, 0.f, 0.f};

    for (int kt2 = 0; kt2 < 2; ++kt2) {
        __syncthreads();
        if ((wn >> 6) == kt2) {   // wave-uniform
            #pragma unroll
            for (int nf = 0; nf < 4; ++nf) {
                float bn = b1v[wn + nf * 16 + col];
                #pragma unroll
                for (int mf = 0; mf < 2; ++mf) {
                    #pragma unroll
                    for (int r = 0; r < 4; ++r) {
                        float v = acc[mf][nf][r] + bn;
                        if (ACT1 == 1) v = fmaxf(v, 0.f);
                        if (ACT1 == 2) v = fast_gelu(v);
                        int row = wm + mf * 16 + kq * 4 + r;
                        int c2 = nf * 16 + col;
                        ushort h = f2bf(v);
                        Xhi[row][c2] = h;
                        if (PREC) Xlo[row][c2] = f2bf(v - bf2f(h));
                    }
                }
            }
        }
        #pragma unroll
        for (int it = 0; it < 2; ++it) {
            int q = tid + it * 512;
            int row = q >> 3, k0 = (q & 7) * 8;
            *(short8v*)&Bh[row][k0] =
                *(const short8v*)(W2h + (size_t)row * 128 + kt2 * 64 + k0);
            if (PREC)
                *(short8v*)&Bl[row][k0] =
                    *(const short8v*)(W2l + (size_t)row * 128 + kt2 * 64 + k0);
        }
        __syncthreads();
        #pragma unroll
        for (int ksub = 0; ksub < 2; ++ksub) {
            short8v ah[2], al[2], bh[4], bl[4];
            #pragma unroll
            for (int mf = 0; mf < 2; ++mf) {
                ah[mf] = *(const short8v*)&Xhi[wm + mf * 16 + col][ksub * 32 + kq * 8];
                if (PREC) al[mf] = *(const short8v*)&Xlo[wm + mf * 16 + col][ksub * 32 + kq * 8];
            }
            #pragma unroll
            for (int nf = 0; nf < 4; ++nf) {
                bh[nf] = *(const short8v*)&Bh[wn + nf * 16 + col][ksub * 32 + kq * 8];
                if (PREC) bl[nf] = *(const short8v*)&Bl[wn + nf * 16 + col][ksub * 32 + kq * 8];
            }
            #pragma unroll
            for (int mf = 0; mf < 2; ++mf)
                #pragma unroll
                for (int nf = 0; nf < 4; ++nf)
                    acc2[mf][nf] = __builtin_amdgcn_mfma_f32_16x16x32_bf16(
                        ah[mf], bh[nf], acc2[mf][nf], 0, 0, 0);
            if (PREC) {
                #pragma unroll
                for (int mf = 0; mf < 2; ++mf)
                    #pragma unroll
                    for (int nf = 0; nf < 4; ++nf)
                        acc2[mf][nf] = __builtin_amdgcn_mfma_f32_16x16x32_bf16(
                            ah[mf], bl[nf], acc2[mf][nf], 0, 0, 0);
                #pragma unroll
                for (int mf = 0; mf < 2; ++mf)
                    #pragma unroll
                    for (int nf = 0; nf < 4; ++nf)
                        acc2[mf][nf] = __builtin_amdgcn_mfma_f32_16x16x32_bf16(
                            al[mf], bh[nf], acc2[mf][nf], 0, 0, 0);
            }
        }
    }

    int rbase = kq * 4;
    float rs_[2][4];
    float rq_[2][4];
    float cs_[4], cq_[4];
    if (EP2 == 1 || EP2 == 3) {
        #pragma unroll
        for (int a = 0; a < 2; ++a)
            #pragma unroll
            for (int b = 0; b < 4; ++b) { rs_[a][b] = 0.f; rq_[a][b] = 0.f; }
    }
    if (EP2 == 2) {
        #pragma unroll
        for (int a = 0; a < 4; ++a) { cs_[a] = 0.f; cq_[a] = 0.f; }
    }
    #pragma unroll
    for (int nf = 0; nf < 4; ++nf) {
        int n = wn + nf * 16 + col;
        float bn = b2v[n];
        #pragma unroll
        for (int mf = 0; mf < 2; ++mf) {
            #pragma unroll
            for (int r = 0; r < 4; ++r) {
                int m = m0 + wm + mf * 16 + rbase + r;
                float v = acc2[mf][nf][r] + bn;
                if (ACT2 == 1) v = fmaxf(v, 0.f);
                if (ACT2 == 2) v = fast_gelu(v);
                if (EP2 == 1) {
                    float fin = Out[(size_t)m * 128 + n] + v;
                    Out[(size_t)m * 128 + n] = fin;
                    rs_[mf][r] += fin;
                    rq_[mf][r] += fin * fin;
                } else {
                    Out[(size_t)m * 128 + n] = v;
                    if (EP2 == 2) { cs_[nf] += v; cq_[nf] += v * v; }
                    if (EP2 == 3) rq_[mf][r] += v * v;
                }
            }
        }
    }
    if (EP2 == 1) {
        #pragma unroll
        for (int mf = 0; mf < 2; ++mf)
            #pragma unroll
            for (int r = 0; r < 4; ++r) {
                float s = rs_[mf][r], q = rq_[mf][r];
                #pragma unroll
                for (int o = 1; o <= 8; o <<= 1) {
                    s += __shfl_xor(s, o);
                    q += __shfl_xor(q, o);
                }
                rs_[mf][r] = s; rq_[mf][r] = q;
            }
        __syncthreads();
        float* sred = (float*)&Xhi[0][0];   // [128][2]
        float* qred = sred + 256;
        if (col == 0) {
            #pragma unroll
            for (int mf = 0; mf < 2; ++mf)
                #pragma unroll
                for (int r = 0; r < 4; ++r) {
                    int row = wm + mf * 16 + kq * 4 + r;
                    sred[row * 2 + (wn >> 6)] = rs_[mf][r];
                    qred[row * 2 + (wn >> 6)] = rq_[mf][r];
                }
        }
        __syncthreads();
        if (tid < 128) {
            rsum[(size_t)m0 + tid] = sred[tid * 2] + sred[tid * 2 + 1];
            rsq[(size_t)m0 + tid]  = qred[tid * 2] + qred[tid * 2 + 1];
        }
    }
    if (EP2 == 3) {
        #pragma unroll
        for (int mf = 0; mf < 2; ++mf)
            #pragma unroll
            for (int r = 0; r < 4; ++r) {
                float q = rq_[mf][r];
                #pragma unroll
                for (int o = 1; o <= 8; o <<= 1) q += __shfl_xor(q, o);
                rq_[mf][r] = q;
            }
        __syncthreads();
        float* qred = (float*)&Xhi[0][0];   // [128][2]
        if (col == 0) {
            #pragma unroll
            for (int mf = 0; mf < 2; ++mf)
                #pragma unroll
                for (int r = 0; r < 4; ++r) {
                    int row = wm + mf * 16 + kq * 4 + r;
                    qred[row * 2 + (wn >> 6)] = rq_[mf][r];
                }
        }
        __syncthreads();
        if (tid < 128)
            rsq[(size_t)m0 + tid] = qred[tid * 2] + qred[tid * 2 + 1];
    }
    if (EP2 == 2) {
        #pragma unroll
        for (int nf = 0; nf < 4; ++nf) {
            #pragma unroll
            for (int o = 16; o <= 32; o <<= 1) {
                cs_[nf] += __shfl_xor(cs_[nf], o);
                cq_[nf] += __shfl_xor(cq_[nf], o);
            }
        }
        __syncthreads();
        float* colS = (float*)&Xhi[0][0];   // [4][128]
        float* colQ = colS + 512;
        if (kq == 0) {
            #pragma unroll
            for (int nf = 0; nf < 4; ++nf) {
                int n = wn + nf * 16 + col;
                colS[(wm >> 5) * 128 + n] = cs_[nf];
                colQ[(wm >> 5) * 128 + n] = cq_[nf];
            }
        }
        __syncthreads();
        if (tid < 128) {
            rsum[(size_t)blockIdx.x * 256 + tid] =
                (colS[tid] + colS[128 + tid]) + (colS[256 + tid] + colS[384 + tid]);
            rsum[(size_t)blockIdx.x * 256 + 128 + tid] =
                (colQ[tid] + colQ[128 + tid]) + (colQ[256 + tid] + colQ[384 + tid]);
        }
    }
}

// W [128][128] f32 -> Whi/Wlo [n][k] bf16 split (transposed). grid (4,4), block (32,8)
__global__ void wsplit_kernel(const float* __restrict__ W, ushort* __restrict__ Whi,
                              ushort* __restrict__ Wlo) {
    __shared__ float t[32][33];
    int k0 = blockIdx.x * 32, n0 = blockIdx.y * 32;
    int tx = threadIdx.x, ty = threadIdx.y;
    for (int i = ty; i < 32; i += 8)
        t[i][tx] = W[(size_t)(k0 + i) * 128 + n0 + tx];
    __syncthreads();
    for (int i = ty; i < 32; i += 8) {
        float v = t[tx][i];
        ushort h = f2bf(v);
        Whi[(size_t)(n0 + i) * 128 + k0 + tx] = h;
        Wlo[(size_t)(n0 + i) * 128 + k0 + tx] = f2bf(v - bf2f(h));
    }
}

// ---------------------------------------------------------------------------
// Timestep MFMA GEMM v5: 2-phase BK=64 128x128 64KB, 512 threads / 8 waves.
// Epilogue: v=gelu(acc+bias[n]); Z[(b*2048+n)*128+c] += v; emits bnf partials.
// ---------------------------------------------------------------------------
__global__ __launch_bounds__(512)
void mfma_ts5_kernel(const ushort* __restrict__ A, const ushort* __restrict__ W,
                     const float* __restrict__ bias, float* Z,
                     int nx, int nwg, float* __restrict__ bnfP) {
    __shared__ __align__(16) ushort smem[32768];   // 64 KB = 2 x (A 16KB + B 16KB)
    float (*Ol)[132] = (float(*)[132])smem;        // epilogue overlay

    int bid = blockIdx.x;
    int cpx = nwg >> 3;
    int swz = (bid & 7) * cpx + (bid >> 3);
    int n0 = (swz % nx) * 128;
    int m0 = (swz / nx) * 128;

    int tid = threadIdx.x;
    int w = tid >> 6, lane = tid & 63;
    int wm = (w >> 1) * 32, wn = (w & 1) * 64;   // 4m x 2n wave grid
    int col = lane & 15, kq = lane >> 4;

    int srow = lane >> 3;                    // 0..7
    int scol = ((lane & 7) ^ srow) << 3;     // pre-swizzled src ushort offset
    int xr = (col & 7) << 4;                 // read-side XOR (bytes)

    float4v acc[2][4];
    #pragma unroll
    for (int i = 0; i < 2; ++i)
        #pragma unroll
        for (int j = 0; j < 4; ++j) acc[i][j] = (float4v){0.f, 0.f, 0.f, 0.f};

    const int Kd = LL;
    const int kTiles = 32;

    #pragma unroll
    for (int it = 0; it < 2; ++it) {
        int rb = (w << 4) + (it << 3);
        async16(A + (size_t)(m0 + rb + srow) * Kd + scol, smem + (rb << 6));
        async16(W + (size_t)(n0 + rb + srow) * Kd + scol, smem + 8192 + (rb << 6));
    }
    __syncthreads();

    for (int kt = 0; kt < kTiles; ++kt) {
        int cur = kt & 1;
        const ushort* Ac = smem + (cur << 14);
        const ushort* Bc = Ac + 8192;
        if (kt + 1 < kTiles) {
            ushort* An = smem + ((cur ^ 1) << 14);
            ushort* Bn = An + 8192;
            int kb = (kt + 1) << 6;
            #pragma unroll
            for (int it = 0; it < 2; ++it) {
                int rb = (w << 4) + (it << 3);
                async16(A + (size_t)(m0 + rb + srow) * Kd + kb + scol, An + (rb << 6));
                async16(W + (size_t)(n0 + rb + srow) * Kd + kb + scol, Bn + (rb << 6));
            }
        }
        __builtin_amdgcn_s_setprio(1);
        #pragma unroll
        for (int ksub = 0; ksub < 2; ++ksub) {
            int cswz = (((ksub << 6) + (kq << 4)) ^ xr) >> 1;
            short8v af[2], bf[4];
            #pragma unroll
            for (int mf = 0; mf < 2; ++mf)
                af[mf] = *(const short8v*)(Ac + (wm + mf * 16 + col) * 64 + cswz);
            #pragma unroll
            for (int nf = 0; nf < 4; ++nf)
                bf[nf] = *(const short8v*)(Bc + (wn + nf * 16 + col) * 64 + cswz);
            #pragma unroll
            for (int mf = 0; mf < 2; ++mf)
                #pragma unroll
                for (int nf = 0; nf < 4; ++nf)
                    acc[mf][nf] = __builtin_amdgcn_mfma_f32_16x16x32_bf16(
                        af[mf], bf[nf], acc[mf][nf], 0, 0, 0);
        }
        __builtin_amdgcn_s_setprio(0);
        __syncthreads();
    }

    // Epilogue: 4 rounds of 32-n strips through Ol (512-thread variant)
    int b = m0 >> 7;
    float cs[8], cq[8];
    #pragma unroll
    for (int j = 0; j < 8; ++j) { cs[j] = 0.f; cq[j] = 0.f; }
    int nloc = tid >> 4, c0 = (tid & 15) * 8;
    #pragma unroll
    for (int q = 0; q < 4; ++q) {
        __syncthreads();
        #pragma unroll
        for (int nf = 0; nf < 4; ++nf) {
            int gnl = wn + nf * 16;
            if ((gnl >> 5) != q) continue;
            int gn = n0 + gnl + col;
            float bn = bias[gn];
            int nl = gnl - q * 32 + col;
            #pragma unroll
            for (int mf = 0; mf < 2; ++mf)
                #pragma unroll
                for (int r = 0; r < 4; ++r) {
                    float v = acc[mf][nf][r] + bn;
                    v = fast_gelu(v);
                    Ol[nl][wm + mf * 16 + kq * 4 + r] = v;
                }
        }
        __syncthreads();
        int gn = n0 + q * 32 + nloc;
        float* zr = Z + ((size_t)b * LL + gn) * CC + c0;
        #pragma unroll
        for (int i = 0; i < 2; ++i) {
            float4 v = *(float4*)&Ol[nloc][c0 + i * 4];
            float4 o = *(float4*)(zr + i * 4);
            v.x += o.x; v.y += o.y; v.z += o.z; v.w += o.w;
            *(float4*)(zr + i * 4) = v;
            cs[i * 4 + 0] += v.x; cs[i * 4 + 1] += v.y;
            cs[i * 4 + 2] += v.z; cs[i * 4 + 3] += v.w;
            cq[i * 4 + 0] += v.x * v.x; cq[i * 4 + 1] += v.y * v.y;
            cq[i * 4 + 2] += v.z * v.z; cq[i * 4 + 3] += v.w * v.w;
        }
    }
    // per-block feature-BN partials
    __syncthreads();
    float* sred = (float*)smem;         // [32][128]
    float* qred = sred + 4096;          // [32][128]
    #pragma unroll
    for (int j = 0; j < 8; ++j) {
        sred[nloc * 128 + c0 + j] = cs[j];
        qred[nloc * 128 + c0 + j] = cq[j];
    }
    __syncthreads();
    if (tid < 128) {
        float a = 0.f;
        for (int r = 0; r < 32; ++r) a += sred[r * 128 + tid];
        bnfP[(size_t)bid * 256 + tid] = a;
    } else if (tid < 256) {
        int c = tid - 128;
        float a = 0.f;
        for (int r = 0; r < 32; ++r) a += qred[r * 128 + c];
        bnfP[(size_t)bid * 256 + 128 + c] = a;
    }
}

// ---------------------------------------------------------------------------
// 8-wave bf16 MFMA GEMM (generic K) for scores (EPM=3) and head (EPM=2).
// ---------------------------------------------------------------------------
template <int EPM>
__global__ __launch_bounds__(512)
void mfma_g8_kernel(const ushort* __restrict__ A, const ushort* __restrict__ W,
                    const float* __restrict__ bias, float* Z,
                    int N, int Kd, int LDO, int nx, int nwg,
                    const float* __restrict__ epS, const float* __restrict__ epM) {
    __shared__ __align__(16) ushort smem[32768];
    float (*Ol)[132] = (float(*)[132])smem;

    int bid = blockIdx.x;
    int cpx = nwg >> 3;
    int swz = (bid & 7) * cpx + (bid >> 3);
    int n0 = (swz % nx) * 128;
    int m0 = (swz / nx) * 128;

    int tid = threadIdx.x;
    int w = tid >> 6, lane = tid & 63;
    int wm = (w >> 1) * 32, wn = (w & 1) * 64;
    int col = lane & 15, kq = lane >> 4;

    int srow = lane >> 3;
    int scol = ((lane & 7) ^ srow) << 3;
    int xr = (col & 7) << 4;

    float4v acc[2][4];
    #pragma unroll
    for (int i = 0; i < 2; ++i)
        #pragma unroll
        for (int j = 0; j < 4; ++j) acc[i][j] = (float4v){0.f, 0.f, 0.f, 0.f};

    int kTiles = Kd >> 6;

    #pragma unroll
    for (int it = 0; it < 2; ++it) {
        int rb = (w << 4) + (it << 3);
        async16(A + (size_t)(m0 + rb + srow) * Kd + scol, smem + (rb << 6));
        async16(W + (size_t)(n0 + rb + srow) * Kd + scol, smem + 8192 + (rb << 6));
    }
    __syncthreads();

    for (int kt = 0; kt < kTiles; ++kt) {
        int cur = kt & 1;
        const ushort* Ac = smem + (cur << 14);
        const ushort* Bc = Ac + 8192;
        if (kt + 1 < kTiles) {
            ushort* An = smem + ((cur ^ 1) << 14);
            ushort* Bn = An + 8192;
            int kb = (kt + 1) << 6;
            #pragma unroll
            for (int it = 0; it < 2; ++it) {
                int rb = (w << 4) + (it << 3);
                async16(A + (size_t)(m0 + rb + srow) * Kd + kb + scol, An + (rb << 6));
                async16(W + (size_t)(n0 + rb + srow) * Kd + kb + scol, Bn + (rb << 6));
            }
        }
        __builtin_amdgcn_s_setprio(1);
        #pragma unroll
        for (int ksub = 0; ksub < 2; ++ksub) {
            int cswz = (((ksub << 6) + (kq << 4)) ^ xr) >> 1;
            short8v af[2], bf[4];
            #pragma unroll
            for (int mf = 0; mf < 2; ++mf)
                af[mf] = *(const short8v*)(Ac + (wm + mf * 16 + col) * 64 + cswz);
            #pragma unroll
            for (int nf = 0; nf < 4; ++nf)
                bf[nf] = *(const short8v*)(Bc + (wn + nf * 16 + col) * 64 + cswz);
            #pragma unroll
            for (int mf = 0; mf < 2; ++mf)
                #pragma unroll
                for (int nf = 0; nf < 4; ++nf)
                    acc[mf][nf] = __builtin_amdgcn_mfma_f32_16x16x32_bf16(
                        af[mf], bf[nf], acc[mf][nf], 0, 0, 0);
        }
        __builtin_amdgcn_s_setprio(0);
        __syncthreads();
    }

    // Epilogue: 4 rounds of 32-n strips through Ol (512-thread indexing)
    int b = m0 >> 7;
    int nloc = tid >> 4, c0 = (tid & 15) * 8;
    #pragma unroll
    for (int q = 0; q < 4; ++q) {
        __syncthreads();
        #pragma unroll
        for (int nf = 0; nf < 4; ++nf) {
            int gnl = wn + nf * 16;
            if ((gnl >> 5) != q) continue;
            int gn = n0 + gnl + col;
            float bn = (EPM == 2 && gn >= N) ? 0.f : bias[gn];
            int nl = gnl - q * 32 + col;
            #pragma unroll
            for (int mf = 0; mf < 2; ++mf)
                #pragma unroll
                for (int r = 0; r < 4; ++r)
                    Ol[nl][wm + mf * 16 + kq * 4 + r] = acc[mf][nf][r] + bn;
        }
        __syncthreads();
        int gn = n0 + q * 32 + nloc;
        if (gn >= N) continue;
        float* zr;
        if (EPM == 3)
            zr = Z + (((size_t)(m0 >> 11) * 64 + gn) * 2048) + (m0 & 2047) + c0;
        else
            zr = Z + ((size_t)b * LDO + gn) * CC + c0;
        #pragma unroll
        for (int i = 0; i < 2; ++i) {
            float4 v = *(float4*)&Ol[nloc][c0 + i * 4];
            if (EPM == 2) {
                int mb = m0 + c0 + i * 4;
                float4 s4 = *(const float4*)(epS + mb);
                float4 m4 = *(const float4*)(epM + mb);
                v.x = v.x * s4.x + m4.x; v.y = v.y * s4.y + m4.y;
                v.z = v.z * s4.z + m4.z; v.w = v.w * s4.w + m4.w;
            }
            *(float4*)(zr + i * 4) = v;
        }
    }
}

// W [K][N] f32 -> WT [Npad][K] bf16 (zero-filled for n >= N).
__global__ void wtrans_kernel(const float* __restrict__ W, ushort* __restrict__ WT,
                              int Kd, int N) {
    __shared__ float t[32][33];
    int k0 = blockIdx.x * 32, n0 = blockIdx.y * 32;
    int tx = threadIdx.x, ty = threadIdx.y;
    for (int i = ty; i < 32; i += 8) {
        int n = n0 + tx;
        t[i][tx] = (n < N) ? W[(size_t)(k0 + i) * N + n] : 0.f;
    }
    __syncthreads();
    for (int i = ty; i < 32; i += 8)
        WT[(size_t)(n0 + i) * Kd + k0 + tx] = f2bf(t[tx][i]);
}

// ---------------------------------------------------------------------------
__global__ void cn_split_kernel(const float* __restrict__ ce, ushort* __restrict__ ch,
                                ushort* __restrict__ cl) {
    int k = blockIdx.x, h = threadIdx.x;
    if (k >= KK) {
        ch[(size_t)k * 128 + h] = 0;
        cl[(size_t)k * 128 + h] = 0;
        return;
    }
    __shared__ float sh[128];
    float v = ce[(size_t)k * HH + h];
    sh[h] = v * v;
    __syncthreads();
    for (int o = 64; o >= 1; o >>= 1) {
        if (h < o) sh[h] += sh[h + o];
        __syncthreads();
    }
    float nv = v / (sqrtf(sh[0]) + 1e-8f);
    ushort hh = f2bf(nv);
    ch[(size_t)k * 128 + h] = hh;
    cl[(size_t)k * 128 + h] = f2bf(nv - bf2f(hh));
}

// Qp bf16 [128][128] (rows >= 64 zero), qb f32 [128]
__global__ void qprime_kernel(const float* __restrict__ Q, const float* __restrict__ wk_w,
                              const float* __restrict__ wk_b, ushort* __restrict__ qpb,
                              float* __restrict__ qbp) {
    int k = blockIdx.x;
    int hp = threadIdx.x;
    if (k >= KK) {
        qpb[(size_t)k * HH + hp] = 0;
        if (hp == 0) qbp[k] = 0.f;
        return;
    }
    __shared__ float qrow[128];
    __shared__ float red[128];
    qrow[hp] = Q[(size_t)k * HH + hp];
    __syncthreads();
    float s = 0.f;
    for (int h = 0; h < HH; ++h) s = fmaf(qrow[h], wk_w[(size_t)hp * HH + h], s);
    const float rs = 0.088388347648318447f;
    qpb[(size_t)k * HH + hp] = f2bf(s * rs);
    red[hp] = qrow[hp] * wk_b[hp];
    __syncthreads();
    for (int o = 64; o >= 1; o >>= 1) {
        if (hp < o) red[hp] += red[hp + o];
        __syncthreads();
    }
    if (hp == 0) qbp[k] = red[0] * rs;
}

// ---------------------------------------------------------------------------
__global__ __launch_bounds__(256)
void pmask_kernel(const float* __restrict__ sp, const float* __restrict__ rn,
                  const float* __restrict__ bern, unsigned char* __restrict__ Mt,
                  float* __restrict__ ppart) {
    int b = blockIdx.y;
    int l0 = blockIdx.x * 32;
    int tid = threadIdx.x;
    int wv = tid >> 6, lane = tid & 63;
    __shared__ float Msh[64][33];
    __shared__ float psum[4][64];
    float pa = 0.f;
    for (int tt = 0; tt < 8; ++tt) {
        int l = l0 + wv * 8 + tt;
        size_t tok = (size_t)b * LL + l;
        float s = sp[tok * 64 + lane] * rn[tok];
        float mx = s;
        #pragma unroll
        for (int o = 32; o >= 1; o >>= 1) mx = fmaxf(mx, __shfl_xor(mx, o));
        float ev = expf(s - mx);
        float sm = ev;
        #pragma unroll
        for (int o = 32; o >= 1; o >>= 1) sm += __shfl_xor(sm, o);
        float p = ev / sm;
        pa += p;
        Msh[lane][wv * 8 + tt] = (bern[tok * KK + lane] < p) ? 1.f : 0.f;
    }
    psum[wv][lane] = pa;
    __syncthreads();
    for (int q = tid; q < 64 * 32; q += 256) {
        int k = q >> 5, j = q & 31;
        Mt[((size_t)b * KK + k) * LL + l0 + j] = (unsigned char)Msh[k][j];
    }
    if (tid < 64)
        ppart[((size_t)b * (LL / 32) + blockIdx.x) * KK + tid] =
            psum[0][tid] + psum[1][tid] + psum[2][tid] + psum[3][tid];
}

__global__ void pmean_final_kernel(const float* __restrict__ part, float* __restrict__ pm) {
    int b = blockIdx.x, k = threadIdx.x;
    float s = 0.f;
    for (int i = 0; i < LL / 32; ++i) s += part[((size_t)b * (LL / 32) + i) * KK + k];
    pm[b * KK + k] = s * (1.f / LL);
}

// ---------------------------------------------------------------------------
__global__ __launch_bounds__(256)
void aw_kernel(float* __restrict__ S, const unsigned char* __restrict__ Mt) {
    size_t base = (size_t)blockIdx.x * LL;
    int tid = threadIdx.x;
    float t[8];
    float mx = -1e30f;
    #pragma unroll
    for (int i = 0; i < 8; ++i) {
        int l = tid + i * 256;
        float v = expf(S[base + l]) * (float)Mt[base + l];
        t[i] = v;
        mx = fmaxf(mx, v);
    }
    __shared__ float shA[4];
    __shared__ float shB[4];
    #pragma unroll
    for (int o = 32; o >= 1; o >>= 1) mx = fmaxf(mx, __shfl_xor(mx, o));
    if ((tid & 63) == 0) shA[tid >> 6] = mx;
    __syncthreads();
    mx = fmaxf(fmaxf(shA[0], shA[1]), fmaxf(shA[2], shA[3]));
    float e[8];
    float sum = 0.f;
    #pragma unroll
    for (int i = 0; i < 8; ++i) { e[i] = expf(t[i] - mx); sum += e[i]; }
    #pragma unroll
    for (int o = 32; o >= 1; o >>= 1) sum += __shfl_xor(sum, o);
    if ((tid & 63) == 0) shB[tid >> 6] = sum;
    __syncthreads();
    sum = (shB[0] + shB[1]) + (shB[2] + shB[3]);
    float inv = 1.f / sum;
    #pragma unroll
    for (int i = 0; i < 8; ++i) S[base + tid + i * 256] = e[i] * inv;
}

// ---------------------------------------------------------------------------
__global__ __launch_bounds__(256)
void awh_part_kernel(const float* __restrict__ AWs, const float* __restrict__ hmat,
                     float* __restrict__ part) {
    __shared__ float AT[32][64];
    __shared__ float VT[32][128];
    int b = blockIdx.y, sp = blockIdx.x;
    int tid = threadIdx.x;
    int tx = tid & 15, ty = tid >> 4;
    float acc[4][8] = {};
    const float* Ab = AWs + (size_t)b * KK * LL + sp * 512;
    const float* Vb = hmat + ((size_t)b * LL + sp * 512) * HH;
    for (int lt = 0; lt < 512; lt += 32) {
        __syncthreads();
        #pragma unroll
        for (int it = 0; it < 2; ++it) {
            int q = tid + it * 256;
            int row = q >> 3;
            int lq = (q & 7) << 2;
            float4 v = *(const float4*)(Ab + (size_t)row * LL + lt + lq);
            AT[lq][row] = v.x; AT[lq + 1][row] = v.y;
            AT[lq + 2][row] = v.z; AT[lq + 3][row] = v.w;
        }
        #pragma unroll
        for (int it = 0; it < 4; ++it) {
            int q = tid + it * 256;
            int lr = q >> 5;
            int hc = (q & 31) << 2;
            *(float4*)&VT[lr][hc] = *(const float4*)(Vb + (size_t)(lt + lr) * HH + hc);
        }
        __syncthreads();
        #pragma unroll
        for (int l = 0; l < 32; ++l) {
            float av[4], vv[8];
            *(float4*)&av[0] = *(const float4*)&AT[l][ty * 4];
            *(float4*)&vv[0] = *(const float4*)&VT[l][tx * 4];
            *(float4*)&vv[4] = *(const float4*)&VT[l][64 + tx * 4];
            #pragma unroll
            for (int i = 0; i < 4; ++i)
                #pragma unroll
                for (int j = 0; j < 8; ++j)
                    acc[i][j] = fmaf(av[i], vv[j], acc[i][j]);
        }
    }
    #pragma unroll
    for (int i = 0; i < 4; ++i) {
        int k = ty * 4 + i;
        #pragma unroll
        for (int jj = 0; jj < 8; jj += 4) {
            int h = (jj ? 64 + tx * 4 : tx * 4);
            float o[4];
            #pragma unroll
            for (int j = 0; j < 4; ++j) o[j] = acc[i][jj + j];
            *(float4*)(part + (((size_t)b * 4 + sp) * KK + k) * HH + h) = *(float4*)o;
        }
    }
}

__global__ void awh_reduce_kernel(const float* __restrict__ part, float* __restrict__ awh) {
    int bk = blockIdx.x, h = threadIdx.x;
    int b = bk >> 6, k = bk & 63;
    float s = 0.f;
    #pragma unroll
    for (int sp = 0; sp < 4; ++sp)
        s += part[(((size_t)b * 4 + sp) * KK + k) * HH + h];
    awh[(size_t)bk * HH + h] = s;
}

__global__ void newce_kernel(const float* __restrict__ ao, const float* __restrict__ pm,
                             float* __restrict__ outTail) {
    int k = blockIdx.x, h = threadIdx.x;
    float s = 0.f;
    for (int b = 0; b < BB; ++b)
        s += ao[((size_t)b * KK + k) * HH + h] * pm[b * KK + k];
    outTail[(size_t)k * HH + h] = s * (1.f / BB);
}

// z_out = (in - mean2)*rstd2; also emits per-row sum/sumsq. grid (32, B), block 256
__global__ void revin_apply_kernel(const float* __restrict__ in, float* __restrict__ out,
                                   const float* __restrict__ mu, const float* __restrict__ rs,
                                   float* __restrict__ rsum, float* __restrict__ rsq) {
    int b = blockIdx.y;
    size_t base = (size_t)b * LL * CC + (size_t)blockIdx.x * 8192;
    int c0 = (threadIdx.x * 4) & 127;
    int lane = threadIdx.x & 63;
    float4 m4 = *(const float4*)(mu + b * CC + c0);
    float4 r4 = *(const float4*)(rs + b * CC + c0);
    #pragma unroll
    for (int j = 0; j < 8; ++j) {
        float4 v = *(const float4*)(in + base + threadIdx.x * 4 + j * 1024);
        v.x = (v.x - m4.x) * r4.x; v.y = (v.y - m4.y) * r4.y;
        v.z = (v.z - m4.z) * r4.z; v.w = (v.w - m4.w) * r4.w;
        *(float4*)(out + base + threadIdx.x * 4 + j * 1024) = v;
        float s = v.x + v.y + v.z + v.w;
        float q = v.x * v.x + v.y * v.y + v.z * v.z + v.w * v.w;
        #pragma unroll
        for (int o = 1; o <= 16; o <<= 1) {
            s += __shfl_xor(s, o);
            q += __shfl_xor(q, o);
        }
        if ((lane & 31) == 0) {
            size_t row = (base + (size_t)threadIdx.x * 4 + (size_t)j * 1024) >> 7;
            rsum[row] = s;
            rsq[row] = q;
        }
    }
}

// timestep-BN final: per l over 64 b's of row stats. grid 8, block 256
__global__ void bnt_final_kernel(const float* __restrict__ rsum, const float* __restrict__ rsq,
                                 float* __restrict__ mu, float* __restrict__ rv) {
    int l = blockIdx.x * 256 + threadIdx.x;
    float s = 0.f, q = 0.f;
    for (int b = 0; b < BB; ++b) {
        s += rsum[(size_t)b * LL + l];
        q += rsq[(size_t)b * LL + l];
    }
    float m = s * (1.f / (BB * CC));
    float var = q * (1.f / (BB * CC)) - m * m;
    var = fmaxf(var, 0.f);
    mu[l] = m;
    rv[l] = 1.f / sqrtf(var + EPSf);
}

// ---------------------------------------------------------------------------
// [B,L,C] f32 -> [B,C,L] bf16, optional timestep-BN. v2: 64(l)x32(c) tiles,
// uint4 (8 bf16) coalesced writes. grid (L/64, C/32, B), block 256.
// ---------------------------------------------------------------------------
template <bool DO_BN>
__global__ __launch_bounds__(256)
void transpose_bn_kernel(const float* __restrict__ in, ushort* __restrict__ out,
                         const float* __restrict__ mu, const float* __restrict__ rv,
                         const float* __restrict__ g, const float* __restrict__ be) {
    __shared__ ushort tile[32][72];   // [c][l] bf16, padded
    int l0 = blockIdx.x * 64, c0 = blockIdx.y * 32, b = blockIdx.z;
    int t = threadIdx.x;
    const float* ib = in + ((size_t)b * LL + l0) * CC + c0;
    #pragma unroll
    for (int it = 0; it < 2; ++it) {
        int idx = t + it * 256;
        int row = idx >> 3;           // 0..63 (l offset)
        int c = (idx & 7) * 4;        // 0..28
        float4 v = *(const float4*)(ib + (size_t)row * CC + c);
        if (DO_BN) {
            int l = l0 + row;
            float sc = rv[l] * g[l];
            float m = mu[l], bb = be[l];
            v.x = (v.x - m) * sc + bb; v.y = (v.y - m) * sc + bb;
            v.z = (v.z - m) * sc + bb; v.w = (v.w - m) * sc + bb;
        }
        tile[c    ][row] = f2bf(v.x);
        tile[c + 1][row] = f2bf(v.y);
        tile[c + 2][row] = f2bf(v.z);
        tile[c + 3][row] = f2bf(v.w);
    }
    __syncthreads();
    int cc = t >> 3, l8 = (t & 7) * 8;
    ushort* ob = out + (size_t)b * CC * LL + (size_t)(c0 + cc) * LL + l0 + l8;
    *(uint4*)ob = *(const uint4*)&tile[cc][l8];
}

// feature-BN two-stage reduce: mid over 16 blocks each; final over 64 mids
__global__ void bnf_mid_kernel(const float* __restrict__ part, float* __restrict__ mid) {
    int gblk = blockIdx.x, t = threadIdx.x;   // grid 64, block 256
    float s = 0.f;
    #pragma unroll
    for (int i = 0; i < 16; ++i)
        s += part[(size_t)(gblk * 16 + i) * 256 + t];
    mid[(size_t)gblk * 256 + t] = s;
}

__global__ void bnf_final_kernel(const float* __restrict__ mid, const float* __restrict__ g,
                                 const float* __restrict__ be, float* __restrict__ mu,
                                 float* __restrict__ sA, float* __restrict__ tA) {
    int c = threadIdx.x;   // block 128
    float s = 0.f, s2 = 0.f;
    #pragma unroll
    for (int i = 0; i < 64; ++i) {
        s += mid[(size_t)i * 256 + c];
        s2 += mid[(size_t)i * 256 + 128 + c];
    }
    float m = s / (float)(BB * LL);
    float var = s2 / (float)(BB * LL) - m * m;
    var = fmaxf(var, 0.f);
    float rvv = 1.f / sqrtf(var + EPSf);
    mu[c] = m;
    sA[c] = rvv * g[c];
    tA[c] = be[c];
}

// ---------------------------------------------------------------------------
extern "C" void kernel_launch(void* const* d_in, const int* in_sizes, int n_in,
                              void* d_out, int out_size, void* d_ws, size_t ws_size,
                              hipStream_t stream) {
    const float* x     = (const float*)d_in[0];
    const float* bern  = (const float*)d_in[1];
    const float* ce    = (const float*)d_in[2];
    const float* wq_w  = (const float*)d_in[3];
    const float* wq_b  = (const float*)d_in[4];
    const float* wk_w  = (const float*)d_in[5];
    const float* wk_b  = (const float*)d_in[6];
    const float* wv_w  = (const float*)d_in[7];
    const float* wv_b  = (const float*)d_in[8];
    const float* cm_w1 = (const float*)d_in[9];
    const float* cm_b1 = (const float*)d_in[10];
    const float* cm_w2 = (const float*)d_in[11];
    const float* cm_b2 = (const float*)d_in[12];
    const float* tm_w1 = (const float*)d_in[13];
    const float* tm_b1 = (const float*)d_in[14];
    const float* tm_w2 = (const float*)d_in[15];
    const float* tm_b2 = (const float*)d_in[16];
    const float* bn_t_g = (const float*)d_in[17];
    const float* bn_t_b = (const float*)d_in[18];
    const float* lin_t_w = (const float*)d_in[19];
    const float* lin_t_b = (const float*)d_in[20];
    const float* bn_f_g = (const float*)d_in[21];
    const float* bn_f_b = (const float*)d_in[22];
    const float* f1_w  = (const float*)d_in[23];
    const float* f1_b  = (const float*)d_in[24];
    const float* f2_w  = (const float*)d_in[25];
    const float* f2_b  = (const float*)d_in[26];
    const float* out_w = (const float*)d_in[27];
    const float* out_b = (const float*)d_in[28];
    (void)in_sizes; (void)n_in; (void)out_size;

    float* y = (float*)d_out;                         // [B,P,C]
    float* ceOut = y + (size_t)BB * PP * CC;          // [K,H]

    float* ws = (float*)d_ws;
    size_t off = 0;
    auto alloc = [&](size_t n) { float* p = ws + off; off += n; return p; };
    float* mean1  = alloc(BB * CC);
    float* rstd1  = alloc(BB * CC);
    float* std1   = alloc(BB * CC);
    float* mean2  = alloc(BB * CC);
    float* rstd2  = alloc(BB * CC);
    float* std2   = alloc(BB * CC);
    float* bnmu   = alloc(LL);
    float* bnrv   = alloc(LL);
    float* bfpart = alloc(1024 * 256);
    float* bfmid  = alloc(64 * 256);
    float* bfmu   = alloc(CC);
    float* bfs    = alloc(CC);
    float* bft    = alloc(CC);
    float* cxpart = alloc(BB * 8 * 256);                      // colstats-1 partials
    float* cpart2 = alloc(1024 * 256);                        // colstats-2 partials (tm pair)
    float* qbuf   = alloc(KK * HH);
    ushort* qpb   = (ushort*)alloc(128 * 128 / 2);            // Qp bf16 padded
    float* qbp    = alloc(128);
    ushort* cnbh  = (ushort*)alloc(8192);                     // codebook hi bf16 [128][128]
    ushort* cnbl  = (ushort*)alloc(8192);                     // codebook lo
    float* rn     = alloc((size_t)BB * LL);
    float* rsum   = alloc((size_t)BB * LL);                   // per-row z sums
    float* rsq    = alloc((size_t)BB * LL);
    float* ppart  = alloc((size_t)BB * (LL / 32) * KK);
    float* pmean  = alloc(BB * KK);
    float* awhprt = alloc((size_t)BB * 4 * KK * HH);
    float* awh    = alloc((size_t)BB * KK * HH);
    float* aobuf  = alloc((size_t)BB * KK * HH);
    ushort* wsp   = (ushort*)alloc(7 * 2 * 16384 / 2);        // 7 split 128x128 weights
    ushort* wtT   = (ushort*)alloc((size_t)LL * LL / 2);      // lin_t_w^T bf16 [2048][2048]
    ushort* owT   = (ushort*)alloc((size_t)384 * LL / 2);     // out_w^T bf16 [384][2048]
    float* S      = alloc((size_t)BB * KK * LL);
    float* buf0   = alloc((size_t)BB * LL * CC);
    float* buf2   = alloc((size_t)BB * LL * CC);
    unsigned char* Mt = (unsigned char*)(ws + off);           // [B,K,L] u8
    ushort* abf = (ushort*)S;       // bf16 [B,C,L] overlay on S (mixer phase)
    ushort* hb  = (ushort*)buf0;    // bf16 h [B,L,H] overlay on buf0 (attn phase)
    (void)ws_size;

    auto whi = [&](int i) { return wsp + (size_t)i * 2 * 16384; };
    auto wlo = [&](int i) { return wsp + (size_t)i * 2 * 16384 + 16384; };

    const int ML = BB * LL;      // 131072
    dim3 tb(32, 8);
    dim3 tgrid(LL / 64, CC / 32, BB);
    dim3 wsg(4, 4);

    // 0) weight prep
    wtrans_kernel<<<dim3(LL / 32, LL / 32), tb, 0, stream>>>(lin_t_w, wtT, LL, LL);
    wtrans_kernel<<<dim3(LL / 32, 12), tb, 0, stream>>>(out_w, owT, LL, PP);
    wsplit_kernel<<<wsg, tb, 0, stream>>>(cm_w1, whi(0), wlo(0));
    wsplit_kernel<<<wsg, tb, 0, stream>>>(cm_w2, whi(1), wlo(1));
    wsplit_kernel<<<wsg, tb, 0, stream>>>(tm_w1, whi(2), wlo(2));
    wsplit_kernel<<<wsg, tb, 0, stream>>>(tm_w2, whi(3), wlo(3));
    wsplit_kernel<<<wsg, tb, 0, stream>>>(f1_w, whi(4), wlo(4));
    wsplit_kernel<<<wsg, tb, 0, stream>>>(f2_w, whi(5), wlo(5));
    wsplit_kernel<<<wsg, tb, 0, stream>>>(wv_w, whi(6), wlo(6));

    // 1) RevIN-1 stats (two-stage)
    colstats_part_kernel<<<dim3(8, BB), 256, 0, stream>>>(x, cxpart);
    colstats_final_kernel<<<dim3(BB), dim3(128), 0, stream>>>(cxpart, mean1, rstd1, std1);
    // 2) h = buf2 (fused split pair) + per-row sumsq -> rsq (for rownorm)
    mfma_sq2_kernel<1, 1, 0, 3, 1><<<dim3(ML / 128), 512, 0, stream>>>(
        x, whi(0), wlo(0), cm_b1, whi(1), wlo(1), cm_b2, buf2, mean1, rstd1, nullptr, CC,
        nullptr, rsq);
    rn_final_kernel<<<dim3(ML / 256), 256, 0, stream>>>(rsq, rn);
    // 3) Q, Qp(bf16), qb ; split codebook
    gemm_kernel<<<dim3(1, 1), 256, 0, stream>>>(ce, wq_w, wq_b, qbuf,
        KK, HH, HH, HH, HH, HH);
    qprime_kernel<<<dim3(128), dim3(128), 0, stream>>>(qbuf, wk_w, wk_b, qpb, qbp);
    cn_split_kernel<<<dim3(128), dim3(128), 0, stream>>>(ce, cnbh, cnbl);
    // 4) routing scores via split-precision MFMA (also emits hb = bf16 h)
    mfma_sq_kernel<0, 0, 2><<<dim3(ML / 128), 512, 0, stream>>>(
        buf2, cnbh, cnbl, nullptr, S, nullptr, nullptr, nullptr, 0, hb);
    // 5) softmax/mask/p-mean
    pmask_kernel<<<dim3(LL / 32, BB), 256, 0, stream>>>(S, rn, bern, Mt, ppart);
    pmean_final_kernel<<<dim3(BB), dim3(64), 0, stream>>>(ppart, pmean);
    // 6) attn scores via 8-wave MFMA: S[b][k][l] = Qp.h + qb   (overwrites S, k-major)
    mfma_g8_kernel<3><<<dim3(1024), 512, 0, stream>>>(
        hb, qpb, qbp, S, KK, 128, 0, 1, 1024, nullptr, nullptr);
    // 7) masked double-exp softmax
    aw_kernel<<<dim3(BB * KK), 256, 0, stream>>>(S, Mt);
    // 8) awh -> ao -> cluster update
    awh_part_kernel<<<dim3(4, BB), 256, 0, stream>>>(S, buf2, awhprt);
    awh_reduce_kernel<<<dim3(BB * KK), dim3(128), 0, stream>>>(awhprt, awh);
    mfma_sq_kernel<0, 0, 0><<<dim3((BB * KK) / 128), 512, 0, stream>>>(
        awh, whi(6), wlo(6), wv_b, aobuf, nullptr, nullptr, nullptr, 0, nullptr);
    newce_kernel<<<dim3(KK), dim3(128), 0, stream>>>(aobuf, pmean, ceOut);
    // 9) temporal module (fused split pair): h2 = buf0, emits column-stat partials
    mfma_sq2_kernel<0, 1, 0, 2, 1><<<dim3(ML / 128), 512, 0, stream>>>(
        buf2, whi(2), wlo(2), tm_b1, whi(3), wlo(3), tm_b2, buf0,
        nullptr, nullptr, nullptr, 0, cpart2, nullptr);
    // 10) RevIN-2 stats (from fused partials) + apply: z = buf2
    colstats2_final_kernel<<<dim3(BB), dim3(128), 0, stream>>>(cpart2, mean2, rstd2, std2);
    revin_apply_kernel<<<dim3(32, BB), 256, 0, stream>>>(buf0, buf2, mean2, rstd2, rsum, rsq);
    // 11) 4 mixer blocks
    for (int blkI = 0; blkI < 4; ++blkI) {
        bnt_final_kernel<<<dim3(8), 256, 0, stream>>>(rsum, rsq, bnmu, bnrv);
        transpose_bn_kernel<true><<<tgrid, 256, 0, stream>>>(buf2, abf, bnmu, bnrv, bn_t_g, bn_t_b);
        mfma_ts5_kernel<<<dim3(1024), 512, 0, stream>>>(
            abf, wtT, lin_t_b, buf2, 16, 1024, bfpart);
        bnf_mid_kernel<<<dim3(64), 256, 0, stream>>>(bfpart, bfmid);
        bnf_final_kernel<<<dim3(1), dim3(128), 0, stream>>>(bfmid, bn_f_g, bn_f_b, bfmu, bfs, bft);
        mfma_sq2_kernel<2, 2, 0, 1, 0><<<dim3(ML / 128), 512, 0, stream>>>(
            buf2, whi(4), wlo(4), f1_b, whi(5), wlo(5), f2_b, buf2, bfmu, bfs, bft, 0,
            rsum, rsq);
    }
    // 12) head via 8-wave MFMA: y[b,p,c] = (z^T @ out_w + out_b) * std2 + mean2
    transpose_bn_kernel<false><<<tgrid, 256, 0, stream>>>(buf2, abf,
        nullptr, nullptr, nullptr, nullptr);
    mfma_g8_kernel<2><<<dim3(192), 512, 0, stream>>>(
        abf, owT, out_b, y, PP, LL, PP, 3, 192, std2, mean2);
}

// Round 22
// 1110.141 us; speedup vs baseline: 1.2343x; 1.0460x over previous
//
#include <hip/hip_runtime.h>
#include <math.h>

#define BB 64
#define LL 2048
#define CC 128
#define HH 128
#define KK 64
#define PP 336
#define EPSf 1e-5f

typedef __attribute__((ext_vector_type(8))) short short8v;
typedef __attribute__((ext_vector_type(4))) float float4v;

__device__ inline ushort f2bf(float f) {
    union { float f; unsigned u; } v; v.f = f;
    unsigned r = (v.u + 0x7FFFu + ((v.u >> 16) & 1u)) >> 16;
    return (ushort)r;
}
__device__ inline float bf2f(ushort h) {
    union { unsigned u; float f; } v; v.u = ((unsigned)h) << 16;
    return v.f;
}

// exact-GELU via Abramowitz-Stegun 7.1.26 erf (|err| <= 1.5e-7)
__device__ inline float fast_gelu(float v) {
    float x = 0.70710678118654752f * v;
    float ax = fabsf(x);
    float t = 1.f / fmaf(0.3275911f, ax, 1.f);
    float p = t * fmaf(t, fmaf(t, fmaf(t, fmaf(t, 1.061405429f, -1.453152027f),
                                       1.421413741f), -0.284496736f), 0.254829592f);
    float er = fmaf(-p, __expf(-ax * ax), 1.f);
    er = (x < 0.f) ? -er : er;
    return 0.5f * v * (1.f + er);
}

// async 16B global -> LDS (wave-uniform LDS base + lane*16, per-lane global src)
__device__ __forceinline__ void async16(const ushort* g, ushort* l) {
    __builtin_amdgcn_global_load_lds(
        (const __attribute__((address_space(1))) void*)g,
        (__attribute__((address_space(3))) void*)l, 16, 0, 0);
}

// ---------------------------------------------------------------------------
// RevIN column stats, two-stage. part: grid (8, B), block 256.
// ---------------------------------------------------------------------------
__global__ __launch_bounds__(256)
void colstats_part_kernel(const float* __restrict__ x, float* __restrict__ part) {
    int b = blockIdx.y, chunk = blockIdx.x;
    int t = threadIdx.x;
    int c4 = (t & 31) * 4, rg = t >> 5;
    const float* xb = x + ((size_t)b * LL + chunk * 256) * CC;
    float4 s = make_float4(0.f, 0.f, 0.f, 0.f);
    float4 q = make_float4(0.f, 0.f, 0.f, 0.f);
    for (int l = rg; l < 256; l += 8) {
        float4 v = *(const float4*)(xb + (size_t)l * CC + c4);
        s.x += v.x; s.y += v.y; s.z += v.z; s.w += v.w;
        q.x += v.x * v.x; q.y += v.y * v.y; q.z += v.z * v.z; q.w += v.w * v.w;
    }
    __shared__ float ls[8][128];
    __shared__ float lq[8][128];
    *(float4*)&ls[rg][c4] = s;
    *(float4*)&lq[rg][c4] = q;
    __syncthreads();
    if (t < 128) {
        float a = 0.f, d = 0.f;
        #pragma unroll
        for (int i = 0; i < 8; ++i) { a += ls[i][t]; d += lq[i][t]; }
        part[((size_t)b * 8 + chunk) * 256 + t] = a;
        part[((size_t)b * 8 + chunk) * 256 + 128 + t] = d;
    }
}

__global__ void colstats_final_kernel(const float* __restrict__ part, float* __restrict__ mean,
                                      float* __restrict__ rstd, float* __restrict__ stdv) {
    int b = blockIdx.x, c = threadIdx.x;
    float s = 0.f, q = 0.f;
    #pragma unroll
    for (int i = 0; i < 8; ++i) {
        s += part[((size_t)b * 8 + i) * 256 + c];
        q += part[((size_t)b * 8 + i) * 256 + 128 + c];
    }
    float mu = s * (1.f / LL);
    float var = q * (1.f / LL) - mu * mu;
    var = fmaxf(var, 0.f);
    float sd = sqrtf(var + EPSf);
    mean[b * CC + c] = mu;
    stdv[b * CC + c] = sd;
    rstd[b * CC + c] = 1.f / sd;
}

__global__ void colstats2_final_kernel(const float* __restrict__ cpart, float* __restrict__ mean,
                                       float* __restrict__ rstd, float* __restrict__ stdv) {
    int b = blockIdx.x, c = threadIdx.x;
    float s = 0.f, q = 0.f;
    #pragma unroll
    for (int i = 0; i < 16; ++i) {
        s += cpart[((size_t)b * 16 + i) * 256 + c];
        q += cpart[((size_t)b * 16 + i) * 256 + 128 + c];
    }
    float mu = s * (1.f / LL);
    float var = q * (1.f / LL) - mu * mu;
    var = fmaxf(var, 0.f);
    float sd = sqrtf(var + EPSf);
    mean[b * CC + c] = mu;
    stdv[b * CC + c] = sd;
    rstd[b * CC + c] = 1.f / sd;
}

// rn[i] = 1/(sqrt(rowsumsq)+1e-8); grid 512, block 256
__global__ void rn_final_kernel(const float* __restrict__ rsq, float* __restrict__ rn) {
    size_t i = (size_t)blockIdx.x * 256 + threadIdx.x;
    rn[i] = 1.f / (sqrtf(rsq[i]) + 1e-8f);
}

// ---------------------------------------------------------------------------
// plain f32 VALU GEMM (tiny Q-GEMM only)
// ---------------------------------------------------------------------------
__global__ __launch_bounds__(256)
void gemm_kernel(const float* __restrict__ A, const float* __restrict__ W,
                 const float* __restrict__ bias, float* __restrict__ Out,
                 int M, int N, int Kd, int lda, int ldw, int ldo) {
    __shared__ float As[32][128];
    __shared__ float Ws[32][128];
    int tid = threadIdx.x;
    int tx = tid & 15, ty = tid >> 4;
    int n0 = blockIdx.x * 128;
    int m0 = blockIdx.y * 128;
    float acc[8][8] = {};

    for (int kt = 0; kt < Kd; kt += 32) {
        __syncthreads();
        #pragma unroll
        for (int it = 0; it < 4; ++it) {
            int q = tid + it * 256;
            int row = q >> 3;
            int kq = (q & 7) << 2;
            float4 v = make_float4(0.f, 0.f, 0.f, 0.f);
            int m = m0 + row;
            if (m < M) v = *(const float4*)(A + (size_t)m * lda + kt + kq);
            As[kq    ][row] = v.x;
            As[kq + 1][row] = v.y;
            As[kq + 2][row] = v.z;
            As[kq + 3][row] = v.w;
        }
        #pragma unroll
        for (int it = 0; it < 4; ++it) {
            int q = tid + it * 256;
            int kr = q >> 5;
            int nc = (q & 31) << 2;
            int n = n0 + nc;
            float4 v = make_float4(0.f, 0.f, 0.f, 0.f);
            if (n < N) v = *(const float4*)(W + (size_t)(kt + kr) * ldw + n);
            *(float4*)&Ws[kr][nc] = v;
        }
        __syncthreads();
        #pragma unroll
        for (int k = 0; k < 32; ++k) {
            float a[8], w[8];
            *(float4*)&a[0] = *(const float4*)&As[k][ty * 8];
            *(float4*)&a[4] = *(const float4*)&As[k][ty * 8 + 4];
            *(float4*)&w[0] = *(const float4*)&Ws[k][tx * 4];
            *(float4*)&w[4] = *(const float4*)&Ws[k][64 + tx * 4];
            #pragma unroll
            for (int i = 0; i < 8; ++i)
                #pragma unroll
                for (int j = 0; j < 8; ++j)
                    acc[i][j] = fmaf(a[i], w[j], acc[i][j]);
        }
    }

    #pragma unroll
    for (int i = 0; i < 8; ++i) {
        int m = m0 + ty * 8 + i;
        if (m >= M) continue;
        #pragma unroll
        for (int jj = 0; jj < 8; jj += 4) {
            int n = n0 + (jj ? 64 + tx * 4 : tx * 4);
            if (n >= N) continue;
            float o[4];
            #pragma unroll
            for (int j = 0; j < 4; ++j)
                o[j] = acc[i][jj + j] + (bias ? bias[n + j] : 0.f);
            *(float4*)(Out + (size_t)m * ldo + n) = *(float4*)o;
        }
    }
}

// ---------------------------------------------------------------------------
// Split-precision MFMA GEMM for K=128, 8-wave (512 thr, 4m x 2n, acc 2x4).
// EP: 0 -> Out[m*128+n]; 2 -> Out[m*64+n] only n<64.
// ---------------------------------------------------------------------------
template <int NORM, int ACT, int EP>
__global__ __launch_bounds__(512)
void mfma_sq_kernel(const float* __restrict__ A, const ushort* __restrict__ Whi,
                    const ushort* __restrict__ Wlo, const float* __restrict__ bias,
                    float* Out,
                    const float* __restrict__ nmu, const float* __restrict__ ns,
                    const float* __restrict__ nt, int normStride,
                    ushort* __restrict__ hbOut) {
    __shared__ ushort Ahi[128][72];
    __shared__ ushort Alo[128][72];
    __shared__ ushort Bhi[128][72];
    __shared__ ushort Blo[128][72];
    int tid = threadIdx.x;
    int m0 = blockIdx.x * 128;
    int noff = (NORM == 1) ? (m0 / LL) * normStride : 0;

    int w = tid >> 6, lane = tid & 63;
    int wm = (w >> 1) * 32, wn = (w & 1) * 64;
    int col = lane & 15, kq = lane >> 4;

    float4v acc[2][4];
    #pragma unroll
    for (int i = 0; i < 2; ++i)
        #pragma unroll
        for (int j = 0; j < 4; ++j) acc[i][j] = (float4v){0.f, 0.f, 0.f, 0.f};

    for (int kt = 0; kt < 2; ++kt) {
        __syncthreads();
        #pragma unroll
        for (int it = 0; it < 2; ++it) {
            int q = tid + it * 512;
            int row = q >> 3, k0 = (q & 7) * 8;
            int kg = kt * 64 + k0;
            const float* ap = A + (size_t)(m0 + row) * 128 + kg;
            float vv[8];
            *(float4*)&vv[0] = *(const float4*)ap;
            *(float4*)&vv[4] = *(const float4*)(ap + 4);
            ushort hi[8], lo[8];
            #pragma unroll
            for (int j = 0; j < 8; ++j) {
                float v = vv[j];
                if (NORM == 1) v = (v - nmu[noff + kg + j]) * ns[noff + kg + j];
                if (NORM == 2) v = (v - nmu[kg + j]) * ns[kg + j] + nt[kg + j];
                ushort h = f2bf(v);
                hi[j] = h;
                lo[j] = f2bf(v - bf2f(h));
            }
            if (hbOut)
                *(short8v*)(hbOut + (size_t)(m0 + row) * 128 + kg) = *(short8v*)hi;
            *(short8v*)&Ahi[row][k0] = *(short8v*)hi;
            *(short8v*)&Alo[row][k0] = *(short8v*)lo;
        }
        #pragma unroll
        for (int it = 0; it < 2; ++it) {
            int q = tid + it * 512;
            int row = q >> 3, k0 = (q & 7) * 8;
            *(short8v*)&Bhi[row][k0] =
                *(const short8v*)(Whi + (size_t)row * 128 + kt * 64 + k0);
            *(short8v*)&Blo[row][k0] =
                *(const short8v*)(Wlo + (size_t)row * 128 + kt * 64 + k0);
        }
        __syncthreads();
        #pragma unroll
        for (int ksub = 0; ksub < 2; ++ksub) {
            short8v ah[2], al[2], bh[4], bl[4];
            #pragma unroll
            for (int mf = 0; mf < 2; ++mf) {
                ah[mf] = *(const short8v*)&Ahi[wm + mf * 16 + col][ksub * 32 + kq * 8];
                al[mf] = *(const short8v*)&Alo[wm + mf * 16 + col][ksub * 32 + kq * 8];
            }
            #pragma unroll
            for (int nf = 0; nf < 4; ++nf) {
                bh[nf] = *(const short8v*)&Bhi[wn + nf * 16 + col][ksub * 32 + kq * 8];
                bl[nf] = *(const short8v*)&Blo[wn + nf * 16 + col][ksub * 32 + kq * 8];
            }
            #pragma unroll
            for (int mf = 0; mf < 2; ++mf)
                #pragma unroll
                for (int nf = 0; nf < 4; ++nf)
                    acc[mf][nf] = __builtin_amdgcn_mfma_f32_16x16x32_bf16(
                        ah[mf], bh[nf], acc[mf][nf], 0, 0, 0);
            #pragma unroll
            for (int mf = 0; mf < 2; ++mf)
                #pragma unroll
                for (int nf = 0; nf < 4; ++nf)
                    acc[mf][nf] = __builtin_amdgcn_mfma_f32_16x16x32_bf16(
                        ah[mf], bl[nf], acc[mf][nf], 0, 0, 0);
            #pragma unroll
            for (int mf = 0; mf < 2; ++mf)
                #pragma unroll
                for (int nf = 0; nf < 4; ++nf)
                    acc[mf][nf] = __builtin_amdgcn_mfma_f32_16x16x32_bf16(
                        al[mf], bh[nf], acc[mf][nf], 0, 0, 0);
        }
    }

    int rbase = kq * 4;
    #pragma unroll
    for (int nf = 0; nf < 4; ++nf) {
        int n = wn + nf * 16 + col;
        if (EP == 2 && n >= 64) continue;
        float bn = bias ? bias[n] : 0.f;
        #pragma unroll
        for (int mf = 0; mf < 2; ++mf) {
            #pragma unroll
            for (int r = 0; r < 4; ++r) {
                int m = m0 + wm + mf * 16 + rbase + r;
                float v = acc[mf][nf][r] + bn;
                if (ACT == 1) v = fmaxf(v, 0.f);
                if (ACT == 2) v = fast_gelu(v);
                if (EP == 0) Out[(size_t)m * 128 + n] = v;
                else if (EP == 1) Out[(size_t)m * 128 + n] += v;
                else Out[(size_t)m * 64 + n] = v;
            }
        }
    }
}

// ---------------------------------------------------------------------------
// FUSED pair of K=128 GEMMs, 8-wave (512 thr, 4m x 2n, acc 2x4).
// EP2: 0 store; 1 residual+= with row sum/sumsq -> rsum/rsq;
//      2 store with per-block column partials -> rsum;
//      3 store with per-row sumsq -> rsq (for rownorm)
// EMITT=1 (with EP2==1): also emit transposed bf16 of fin -> abfT [B,C,L]
// ---------------------------------------------------------------------------
template <int NORM, int ACT1, int ACT2, int EP2, int PREC, int EMITT>
__global__ __launch_bounds__(512)
void mfma_sq2_kernel(const float* __restrict__ A,
                     const ushort* __restrict__ W1h, const ushort* __restrict__ W1l,
                     const float* __restrict__ b1v,
                     const ushort* __restrict__ W2h, const ushort* __restrict__ W2l,
                     const float* __restrict__ b2v, float* Out,
                     const float* __restrict__ nmu, const float* __restrict__ ns,
                     const float* __restrict__ nt, int normStride,
                     float* __restrict__ rsum, float* __restrict__ rsq,
                     ushort* __restrict__ abfT) {
    __shared__ ushort Xhi[128][72];
    __shared__ ushort Xlo[PREC ? 128 : 1][72];
    __shared__ ushort Bh[128][72];
    __shared__ ushort Bl[PREC ? 128 : 1][72];
    __shared__ ushort Tbuf[EMITT ? 128 : 1][136];
    int tid = threadIdx.x;
    int m0 = blockIdx.x * 128;
    int noff = (NORM == 1) ? (m0 / LL) * normStride : 0;
    int w = tid >> 6, lane = tid & 63;
    int wm = (w >> 1) * 32, wn = (w & 1) * 64;
    int col = lane & 15, kq = lane >> 4;

    float4v acc[2][4];
    #pragma unroll
    for (int i = 0; i < 2; ++i)
        #pragma unroll
        for (int j = 0; j < 4; ++j) acc[i][j] = (float4v){0.f, 0.f, 0.f, 0.f};

    // ---- GEMM1 over 2 K-tiles ----
    for (int kt = 0; kt < 2; ++kt) {
        __syncthreads();
        #pragma unroll
        for (int it = 0; it < 2; ++it) {
            int q = tid + it * 512;
            int row = q >> 3, k0 = (q & 7) * 8;
            int kg = kt * 64 + k0;
            const float* ap = A + (size_t)(m0 + row) * 128 + kg;
            float vv[8];
            *(float4*)&vv[0] = *(const float4*)ap;
            *(float4*)&vv[4] = *(const float4*)(ap + 4);
            ushort hi[8], lo[8];
            #pragma unroll
            for (int j = 0; j < 8; ++j) {
                float v = vv[j];
                if (NORM == 1) v = (v - nmu[noff + kg + j]) * ns[noff + kg + j];
                if (NORM == 2) v = (v - nmu[kg + j]) * ns[kg + j] + nt[kg + j];
                ushort h = f2bf(v);
                hi[j] = h;
                if (PREC) lo[j] = f2bf(v - bf2f(h));
            }
            *(short8v*)&Xhi[row][k0] = *(short8v*)hi;
            if (PREC) *(short8v*)&Xlo[row][k0] = *(short8v*)lo;
        }
        #pragma unroll
        for (int it = 0; it < 2; ++it) {
            int q = tid + it * 512;
            int row = q >> 3, k0 = (q & 7) * 8;
            *(short8v*)&Bh[row][k0] =
                *(const short8v*)(W1h + (size_t)row * 128 + kt * 64 + k0);
            if (PREC)
                *(short8v*)&Bl[row][k0] =
                    *(const short8v*)(W1l + (size_t)row * 128 + kt * 64 + k0);
        }
        __syncthreads();
        #pragma unroll
        for (int ksub = 0; ksub < 2; ++ksub) {
            short8v ah[2], al[2], bh[4], bl[4];
            #pragma unroll
            for (int mf = 0; mf < 2; ++mf) {
                ah[mf] = *(const short8v*)&Xhi[wm + mf * 16 + col][ksub * 32 + kq * 8];
                if (PREC) al[mf] = *(const short8v*)&Xlo[wm + mf * 16 + col][ksub * 32 + kq * 8];
            }
            #pragma unroll
            for (int nf = 0; nf < 4; ++nf) {
                bh[nf] = *(const short8v*)&Bh[wn + nf * 16 + col][ksub * 32 + kq * 8];
                if (PREC) bl[nf] = *(const short8v*)&Bl[wn + nf * 16 + col][ksub * 32 + kq * 8];
            }
            #pragma unroll
            for (int mf = 0; mf < 2; ++mf)
                #pragma unroll
                for (int nf = 0; nf < 4; ++nf)
                    acc[mf][nf] = __builtin_amdgcn_mfma_f32_16x16x32_bf16(
                        ah[mf], bh[nf], acc[mf][nf], 0, 0, 0);
            if (PREC) {
                #pragma unroll
                for (int mf = 0; mf < 2; ++mf)
                    #pragma unroll
                    for (int nf = 0; nf < 4; ++nf)
                        acc[mf][nf] = __builtin_amdgcn_mfma_f32_16x16x32_bf16(
                            ah[mf], bl[nf], acc[mf][nf], 0, 0, 0);
                #pragma unroll
                for (int mf = 0; mf < 2; ++mf)
                    #pragma unroll
                    for (int nf = 0; nf < 4; ++nf)
                        acc[mf][nf] = __builtin_amdgcn_mfma_f32_16x16x32_bf16(
                            al[mf], bh[nf], acc[mf][nf], 0, 0, 0);
            }
        }
    }

    // ---- GEMM2 ----
    float4v acc2[2][4];
    #pragma unroll
    for (int i = 0; i < 2; ++i)
        #pragma unroll
        for (int j = 0; j < 4; ++j) acc2[i][j] = (float4v){0.f, 0.f, 0.f, 0.f};

    for (int kt2 = 0; kt2 < 2; ++kt2) {
        __syncthreads();
        if ((wn >> 6) == kt2) {   // wave-uniform
            #pragma unroll
            for (int nf = 0; nf < 4; ++nf) {
                float bn = b1v[wn + nf * 16 + col];
                #pragma unroll
                for (int mf = 0; mf < 2; ++mf) {
                    #pragma unroll
                    for (int r = 0; r < 4; ++r) {
                        float v = acc[mf][nf][r] + bn;
                        if (ACT1 == 1) v = fmaxf(v, 0.f);
                        if (ACT1 == 2) v = fast_gelu(v);
                        int row = wm + mf * 16 + kq * 4 + r;
                        int c2 = nf * 16 + col;
                        ushort h = f2bf(v);
                        Xhi[row][c2] = h;
                        if (PREC) Xlo[row][c2] = f2bf(v - bf2f(h));
                    }
                }
            }
        }
        #pragma unroll
        for (int it = 0; it < 2; ++it) {
            int q = tid + it * 512;
            int row = q >> 3, k0 = (q & 7) * 8;
            *(short8v*)&Bh[row][k0] =
                *(const short8v*)(W2h + (size_t)row * 128 + kt2 * 64 + k0);
            if (PREC)
                *(short8v*)&Bl[row][k0] =
                    *(const short8v*)(W2l + (size_t)row * 128 + kt2 * 64 + k0);
        }
        __syncthreads();
        #pragma unroll
        for (int ksub = 0; ksub < 2; ++ksub) {
            short8v ah[2], al[2], bh[4], bl[4];
            #pragma unroll
            for (int mf = 0; mf < 2; ++mf) {
                ah[mf] = *(const short8v*)&Xhi[wm + mf * 16 + col][ksub * 32 + kq * 8];
                if (PREC) al[mf] = *(const short8v*)&Xlo[wm + mf * 16 + col][ksub * 32 + kq * 8];
            }
            #pragma unroll
            for (int nf = 0; nf < 4; ++nf) {
                bh[nf] = *(const short8v*)&Bh[wn + nf * 16 + col][ksub * 32 + kq * 8];
                if (PREC) bl[nf] = *(const short8v*)&Bl[wn + nf * 16 + col][ksub * 32 + kq * 8];
            }
            #pragma unroll
            for (int mf = 0; mf < 2; ++mf)
                #pragma unroll
                for (int nf = 0; nf < 4; ++nf)
                    acc2[mf][nf] = __builtin_amdgcn_mfma_f32_16x16x32_bf16(
                        ah[mf], bh[nf], acc2[mf][nf], 0, 0, 0);
            if (PREC) {
                #pragma unroll
                for (int mf = 0; mf < 2; ++mf)
                    #pragma unroll
                    for (int nf = 0; nf < 4; ++nf)
                        acc2[mf][nf] = __builtin_amdgcn_mfma_f32_16x16x32_bf16(
                            ah[mf], bl[nf], acc2[mf][nf], 0, 0, 0);
                #pragma unroll
                for (int mf = 0; mf < 2; ++mf)
                    #pragma unroll
                    for (int nf = 0; nf < 4; ++nf)
                        acc2[mf][nf] = __builtin_amdgcn_mfma_f32_16x16x32_bf16(
                            al[mf], bh[nf], acc2[mf][nf], 0, 0, 0);
            }
        }
    }

    int rbase = kq * 4;
    float rs_[2][4];
    float rq_[2][4];
    float cs_[4], cq_[4];
    if (EP2 == 1 || EP2 == 3) {
        #pragma unroll
        for (int a = 0; a < 2; ++a)
            #pragma unroll
            for (int b = 0; b < 4; ++b) { rs_[a][b] = 0.f; rq_[a][b] = 0.f; }
    }
    if (EP2 == 2) {
        #pragma unroll
        for (int a = 0; a < 4; ++a) { cs_[a] = 0.f; cq_[a] = 0.f; }
    }
    #pragma unroll
    for (int nf = 0; nf < 4; ++nf) {
        int n = wn + nf * 16 + col;
        float bn = b2v[n];
        #pragma unroll
        for (int mf = 0; mf < 2; ++mf) {
            #pragma unroll
            for (int r = 0; r < 4; ++r) {
                int m = m0 + wm + mf * 16 + rbase + r;
                float v = acc2[mf][nf][r] + bn;
                if (ACT2 == 1) v = fmaxf(v, 0.f);
                if (ACT2 == 2) v = fast_gelu(v);
                if (EP2 == 1) {
                    float fin = Out[(size_t)m * 128 + n] + v;
                    Out[(size_t)m * 128 + n] = fin;
                    if (EMITT) Tbuf[n][wm + mf * 16 + rbase + r] = f2bf(fin);
                    rs_[mf][r] += fin;
                    rq_[mf][r] += fin * fin;
                } else {
                    Out[(size_t)m * 128 + n] = v;
                    if (EP2 == 2) { cs_[nf] += v; cq_[nf] += v * v; }
                    if (EP2 == 3) rq_[mf][r] += v * v;
                }
            }
        }
    }
    if (EP2 == 1) {
        #pragma unroll
        for (int mf = 0; mf < 2; ++mf)
            #pragma unroll
            for (int r = 0; r < 4; ++r) {
                float s = rs_[mf][r], q = rq_[mf][r];
                #pragma unroll
                for (int o = 1; o <= 8; o <<= 1) {
                    s += __shfl_xor(s, o);
                    q += __shfl_xor(q, o);
                }
                rs_[mf][r] = s; rq_[mf][r] = q;
            }
        __syncthreads();
        float* sred = (float*)&Xhi[0][0];   // [128][2]
        float* qred = sred + 256;
        if (col == 0) {
            #pragma unroll
            for (int mf = 0; mf < 2; ++mf)
                #pragma unroll
                for (int r = 0; r < 4; ++r) {
                    int row = wm + mf * 16 + kq * 4 + r;
                    sred[row * 2 + (wn >> 6)] = rs_[mf][r];
                    qred[row * 2 + (wn >> 6)] = rq_[mf][r];
                }
        }
        __syncthreads();
        if (tid < 128) {
            rsum[(size_t)m0 + tid] = sred[tid * 2] + sred[tid * 2 + 1];
            rsq[(size_t)m0 + tid]  = qred[tid * 2] + qred[tid * 2 + 1];
        }
        if (EMITT) {
            // Tbuf[c][l_local] complete (synced above); coalesced write to abfT
            int bT = m0 >> 11, l0 = m0 & 2047;
            #pragma unroll
            for (int it = 0; it < 4; ++it) {
                int idx = tid + it * 512;
                int cr = idx >> 4, u = (idx & 15) * 8;
                *(uint4*)(abfT + ((size_t)bT * CC + cr) * LL + l0 + u) =
                    *(const uint4*)&Tbuf[cr][u];
            }
        }
    }
    if (EP2 == 3) {
        #pragma unroll
        for (int mf = 0; mf < 2; ++mf)
            #pragma unroll
            for (int r = 0; r < 4; ++r) {
                float q = rq_[mf][r];
                #pragma unroll
                for (int o = 1; o <= 8; o <<= 1) q += __shfl_xor(q, o);
                rq_[mf][r] = q;
            }
        __syncthreads();
        float* qred = (float*)&Xhi[0][0];   // [128][2]
        if (col == 0) {
            #pragma unroll
            for (int mf = 0; mf < 2; ++mf)
                #pragma unroll
                for (int r = 0; r < 4; ++r) {
                    int row = wm + mf * 16 + kq * 4 + r;
                    qred[row * 2 + (wn >> 6)] = rq_[mf][r];
                }
        }
        __syncthreads();
        if (tid < 128)
            rsq[(size_t)m0 + tid] = qred[tid * 2] + qred[tid * 2 + 1];
    }
    if (EP2 == 2) {
        #pragma unroll
        for (int nf = 0; nf < 4; ++nf) {
            #pragma unroll
            for (int o = 16; o <= 32; o <<= 1) {
                cs_[nf] += __shfl_xor(cs_[nf], o);
                cq_[nf] += __shfl_xor(cq_[nf], o);
            }
        }
        __syncthreads();
        float* colS = (float*)&Xhi[0][0];   // [4][128]
        float* colQ = colS + 512;
        if (kq == 0) {
            #pragma unroll
            for (int nf = 0; nf < 4; ++nf) {
                int n = wn + nf * 16 + col;
                colS[(wm >> 5) * 128 + n] = cs_[nf];
                colQ[(wm >> 5) * 128 + n] = cq_[nf];
            }
        }
        __syncthreads();
        if (tid < 128) {
            rsum[(size_t)blockIdx.x * 256 + tid] =
                (colS[tid] + colS[128 + tid]) + (colS[256 + tid] + colS[384 + tid]);
            rsum[(size_t)blockIdx.x * 256 + 128 + tid] =
                (colQ[tid] + colQ[128 + tid]) + (colQ[256 + tid] + colQ[384 + tid]);
        }
    }
}

// W [128][128] f32 -> Whi/Wlo [n][k] bf16 split (transposed). grid (4,4), block (32,8)
__global__ void wsplit_kernel(const float* __restrict__ W, ushort* __restrict__ Whi,
                              ushort* __restrict__ Wlo) {
    __shared__ float t[32][33];
    int k0 = blockIdx.x * 32, n0 = blockIdx.y * 32;
    int tx = threadIdx.x, ty = threadIdx.y;
    for (int i = ty; i < 32; i += 8)
        t[i][tx] = W[(size_t)(k0 + i) * 128 + n0 + tx];
    __syncthreads();
    for (int i = ty; i < 32; i += 8) {
        float v = t[tx][i];
        ushort h = f2bf(v);
        Whi[(size_t)(n0 + i) * 128 + k0 + tx] = h;
        Wlo[(size_t)(n0 + i) * 128 + k0 + tx] = f2bf(v - bf2f(h));
    }
}

// ---------------------------------------------------------------------------
// Timestep MFMA GEMM v5: 2-phase BK=64 128x128 64KB, 512 threads / 8 waves.
// Epilogue: v=gelu(acc+bias[n]); Z[(b*2048+n)*128+c] += v; emits bnf partials.
// ---------------------------------------------------------------------------
__global__ __launch_bounds__(512)
void mfma_ts5_kernel(const ushort* __restrict__ A, const ushort* __restrict__ W,
                     const float* __restrict__ bias, float* Z,
                     int nx, int nwg, float* __restrict__ bnfP) {
    __shared__ __align__(16) ushort smem[32768];   // 64 KB = 2 x (A 16KB + B 16KB)
    float (*Ol)[132] = (float(*)[132])smem;        // epilogue overlay

    int bid = blockIdx.x;
    int cpx = nwg >> 3;
    int swz = (bid & 7) * cpx + (bid >> 3);
    int n0 = (swz % nx) * 128;
    int m0 = (swz / nx) * 128;

    int tid = threadIdx.x;
    int w = tid >> 6, lane = tid & 63;
    int wm = (w >> 1) * 32, wn = (w & 1) * 64;   // 4m x 2n wave grid
    int col = lane & 15, kq = lane >> 4;

    int srow = lane >> 3;                    // 0..7
    int scol = ((lane & 7) ^ srow) << 3;     // pre-swizzled src ushort offset
    int xr = (col & 7) << 4;                 // read-side XOR (bytes)

    float4v acc[2][4];
    #pragma unroll
    for (int i = 0; i < 2; ++i)
        #pragma unroll
        for (int j = 0; j < 4; ++j) acc[i][j] = (float4v){0.f, 0.f, 0.f, 0.f};

    const int Kd = LL;
    const int kTiles = 32;

    #pragma unroll
    for (int it = 0; it < 2; ++it) {
        int rb = (w << 4) + (it << 3);
        async16(A + (size_t)(m0 + rb + srow) * Kd + scol, smem + (rb << 6));
        async16(W + (size_t)(n0 + rb + srow) * Kd + scol, smem + 8192 + (rb << 6));
    }
    __syncthreads();

    for (int kt = 0; kt < kTiles; ++kt) {
        int cur = kt & 1;
        const ushort* Ac = smem + (cur << 14);
        const ushort* Bc = Ac + 8192;
        if (kt + 1 < kTiles) {
            ushort* An = smem + ((cur ^ 1) << 14);
            ushort* Bn = An + 8192;
            int kb = (kt + 1) << 6;
            #pragma unroll
            for (int it = 0; it < 2; ++it) {
                int rb = (w << 4) + (it << 3);
                async16(A + (size_t)(m0 + rb + srow) * Kd + kb + scol, An + (rb << 6));
                async16(W + (size_t)(n0 + rb + srow) * Kd + kb + scol, Bn + (rb << 6));
            }
        }
        __builtin_amdgcn_s_setprio(1);
        #pragma unroll
        for (int ksub = 0; ksub < 2; ++ksub) {
            int cswz = (((ksub << 6) + (kq << 4)) ^ xr) >> 1;
            short8v af[2], bf[4];
            #pragma unroll
            for (int mf = 0; mf < 2; ++mf)
                af[mf] = *(const short8v*)(Ac + (wm + mf * 16 + col) * 64 + cswz);
            #pragma unroll
            for (int nf = 0; nf < 4; ++nf)
                bf[nf] = *(const short8v*)(Bc + (wn + nf * 16 + col) * 64 + cswz);
            #pragma unroll
            for (int mf = 0; mf < 2; ++mf)
                #pragma unroll
                for (int nf = 0; nf < 4; ++nf)
                    acc[mf][nf] = __builtin_amdgcn_mfma_f32_16x16x32_bf16(
                        af[mf], bf[nf], acc[mf][nf], 0, 0, 0);
        }
        __builtin_amdgcn_s_setprio(0);
        __syncthreads();
    }

    // Epilogue: 4 rounds of 32-n strips through Ol (512-thread variant)
    int b = m0 >> 7;
    float cs[8], cq[8];
    #pragma unroll
    for (int j = 0; j < 8; ++j) { cs[j] = 0.f; cq[j] = 0.f; }
    int nloc = tid >> 4, c0 = (tid & 15) * 8;
    #pragma unroll
    for (int q = 0; q < 4; ++q) {
        __syncthreads();
        #pragma unroll
        for (int nf = 0; nf < 4; ++nf) {
            int gnl = wn + nf * 16;
            if ((gnl >> 5) != q) continue;
            int gn = n0 + gnl + col;
            float bn = bias[gn];
            int nl = gnl - q * 32 + col;
            #pragma unroll
            for (int mf = 0; mf < 2; ++mf)
                #pragma unroll
                for (int r = 0; r < 4; ++r) {
                    float v = acc[mf][nf][r] + bn;
                    v = fast_gelu(v);
                    Ol[nl][wm + mf * 16 + kq * 4 + r] = v;
                }
        }
        __syncthreads();
        int gn = n0 + q * 32 + nloc;
        float* zr = Z + ((size_t)b * LL + gn) * CC + c0;
        #pragma unroll
        for (int i = 0; i < 2; ++i) {
            float4 v = *(float4*)&Ol[nloc][c0 + i * 4];
            float4 o = *(float4*)(zr + i * 4);
            v.x += o.x; v.y += o.y; v.z += o.z; v.w += o.w;
            *(float4*)(zr + i * 4) = v;
            cs[i * 4 + 0] += v.x; cs[i * 4 + 1] += v.y;
            cs[i * 4 + 2] += v.z; cs[i * 4 + 3] += v.w;
            cq[i * 4 + 0] += v.x * v.x; cq[i * 4 + 1] += v.y * v.y;
            cq[i * 4 + 2] += v.z * v.z; cq[i * 4 + 3] += v.w * v.w;
        }
    }
    // per-block feature-BN partials
    __syncthreads();
    float* sred = (float*)smem;         // [32][128]
    float* qred = sred + 4096;          // [32][128]
    #pragma unroll
    for (int j = 0; j < 8; ++j) {
        sred[nloc * 128 + c0 + j] = cs[j];
        qred[nloc * 128 + c0 + j] = cq[j];
    }
    __syncthreads();
    if (tid < 128) {
        float a = 0.f;
        for (int r = 0; r < 32; ++r) a += sred[r * 128 + tid];
        bnfP[(size_t)bid * 256 + tid] = a;
    } else if (tid < 256) {
        int c = tid - 128;
        float a = 0.f;
        for (int r = 0; r < 32; ++r) a += qred[r * 128 + c];
        bnfP[(size_t)bid * 256 + 128 + c] = a;
    }
}

// ---------------------------------------------------------------------------
// 8-wave bf16 MFMA GEMM (generic K) for scores (EPM=3) and head (EPM=2).
// ---------------------------------------------------------------------------
template <int EPM>
__global__ __launch_bounds__(512)
void mfma_g8_kernel(const ushort* __restrict__ A, const ushort* __restrict__ W,
                    const float* __restrict__ bias, float* Z,
                    int N, int Kd, int LDO, int nx, int nwg,
                    const float* __restrict__ epS, const float* __restrict__ epM) {
    __shared__ __align__(16) ushort smem[32768];
    float (*Ol)[132] = (float(*)[132])smem;

    int bid = blockIdx.x;
    int cpx = nwg >> 3;
    int swz = (bid & 7) * cpx + (bid >> 3);
    int n0 = (swz % nx) * 128;
    int m0 = (swz / nx) * 128;

    int tid = threadIdx.x;
    int w = tid >> 6, lane = tid & 63;
    int wm = (w >> 1) * 32, wn = (w & 1) * 64;
    int col = lane & 15, kq = lane >> 4;

    int srow = lane >> 3;
    int scol = ((lane & 7) ^ srow) << 3;
    int xr = (col & 7) << 4;

    float4v acc[2][4];
    #pragma unroll
    for (int i = 0; i < 2; ++i)
        #pragma unroll
        for (int j = 0; j < 4; ++j) acc[i][j] = (float4v){0.f, 0.f, 0.f, 0.f};

    int kTiles = Kd >> 6;

    #pragma unroll
    for (int it = 0; it < 2; ++it) {
        int rb = (w << 4) + (it << 3);
        async16(A + (size_t)(m0 + rb + srow) * Kd + scol, smem + (rb << 6));
        async16(W + (size_t)(n0 + rb + srow) * Kd + scol, smem + 8192 + (rb << 6));
    }
    __syncthreads();

    for (int kt = 0; kt < kTiles; ++kt) {
        int cur = kt & 1;
        const ushort* Ac = smem + (cur << 14);
        const ushort* Bc = Ac + 8192;
        if (kt + 1 < kTiles) {
            ushort* An = smem + ((cur ^ 1) << 14);
            ushort* Bn = An + 8192;
            int kb = (kt + 1) << 6;
            #pragma unroll
            for (int it = 0; it < 2; ++it) {
                int rb = (w << 4) + (it << 3);
                async16(A + (size_t)(m0 + rb + srow) * Kd + kb + scol, An + (rb << 6));
                async16(W + (size_t)(n0 + rb + srow) * Kd + kb + scol, Bn + (rb << 6));
            }
        }
        __builtin_amdgcn_s_setprio(1);
        #pragma unroll
        for (int ksub = 0; ksub < 2; ++ksub) {
            int cswz = (((ksub << 6) + (kq << 4)) ^ xr) >> 1;
            short8v af[2], bf[4];
            #pragma unroll
            for (int mf = 0; mf < 2; ++mf)
                af[mf] = *(const short8v*)(Ac + (wm + mf * 16 + col) * 64 + cswz);
            #pragma unroll
            for (int nf = 0; nf < 4; ++nf)
                bf[nf] = *(const short8v*)(Bc + (wn + nf * 16 + col) * 64 + cswz);
            #pragma unroll
            for (int mf = 0; mf < 2; ++mf)
                #pragma unroll
                for (int nf = 0; nf < 4; ++nf)
                    acc[mf][nf] = __builtin_amdgcn_mfma_f32_16x16x32_bf16(
                        af[mf], bf[nf], acc[mf][nf], 0, 0, 0);
        }
        __builtin_amdgcn_s_setprio(0);
        __syncthreads();
    }

    // Epilogue: 4 rounds of 32-n strips through Ol (512-thread indexing)
    int b = m0 >> 7;
    int nloc = tid >> 4, c0 = (tid & 15) * 8;
    #pragma unroll
    for (int q = 0; q < 4; ++q) {
        __syncthreads();
        #pragma unroll
        for (int nf = 0; nf < 4; ++nf) {
            int gnl = wn + nf * 16;
            if ((gnl >> 5) != q) continue;
            int gn = n0 + gnl + col;
            float bn = (EPM == 2 && gn >= N) ? 0.f : bias[gn];
            int nl = gnl - q * 32 + col;
            #pragma unroll
            for (int mf = 0; mf < 2; ++mf)
                #pragma unroll
                for (int r = 0; r < 4; ++r)
                    Ol[nl][wm + mf * 16 + kq * 4 + r] = acc[mf][nf][r] + bn;
        }
        __syncthreads();
        int gn = n0 + q * 32 + nloc;
        if (gn >= N) continue;
        float* zr;
        if (EPM == 3)
            zr = Z + (((size_t)(m0 >> 11) * 64 + gn) * 2048) + (m0 & 2047) + c0;
        else
            zr = Z + ((size_t)b * LDO + gn) * CC + c0;
        #pragma unroll
        for (int i = 0; i < 2; ++i) {
            float4 v = *(float4*)&Ol[nloc][c0 + i * 4];
            if (EPM == 2) {
                int mb = m0 + c0 + i * 4;
                float4 s4 = *(const float4*)(epS + mb);
                float4 m4 = *(const float4*)(epM + mb);
                v.x = v.x * s4.x + m4.x; v.y = v.y * s4.y + m4.y;
                v.z = v.z * s4.z + m4.z; v.w = v.w * s4.w + m4.w;
            }
            *(float4*)(zr + i * 4) = v;
        }
    }
}

// W [K][N] f32 -> WT [Npad][K] bf16 (zero-filled for n >= N).
__global__ void wtrans_kernel(const float* __restrict__ W, ushort* __restrict__ WT,
                              int Kd, int N) {
    __shared__ float t[32][33];
    int k0 = blockIdx.x * 32, n0 = blockIdx.y * 32;
    int tx = threadIdx.x, ty = threadIdx.y;
    for (int i = ty; i < 32; i += 8) {
        int n = n0 + tx;
        t[i][tx] = (n < N) ? W[(size_t)(k0 + i) * N + n] : 0.f;
    }
    __syncthreads();
    for (int i = ty; i < 32; i += 8)
        WT[(size_t)(n0 + i) * Kd + k0 + tx] = f2bf(t[tx][i]);
}

// wtTs[n][l] = f2bf(bf2f(wtT[n][l]) * sc[l]); grid 2048, block 256
__global__ void wtfold_kernel(const ushort* __restrict__ wtT, const float* __restrict__ sc,
                              ushort* __restrict__ wtTs) {
    int n = blockIdx.x;
    int l = threadIdx.x * 8;
    ushort u[8];
    *(uint4*)u = *(const uint4*)(wtT + (size_t)n * LL + l);
    float4 s0 = *(const float4*)(sc + l);
    float4 s1 = *(const float4*)(sc + l + 4);
    u[0] = f2bf(bf2f(u[0]) * s0.x); u[1] = f2bf(bf2f(u[1]) * s0.y);
    u[2] = f2bf(bf2f(u[2]) * s0.z); u[3] = f2bf(bf2f(u[3]) * s0.w);
    u[4] = f2bf(bf2f(u[4]) * s1.x); u[5] = f2bf(bf2f(u[5]) * s1.y);
    u[6] = f2bf(bf2f(u[6]) * s1.z); u[7] = f2bf(bf2f(u[7]) * s1.w);
    *(uint4*)(wtTs + (size_t)n * LL + l) = *(uint4*)u;
}

// bn2[n] = lin_t_b[n] + sum_l shift[l]*bf2f(wtT[n][l]); grid 2048, block 256
__global__ void tbias_kernel(const ushort* __restrict__ wtT, const float* __restrict__ shift,
                             const float* __restrict__ tb, float* __restrict__ bn2) {
    int n = blockIdx.x;
    int t = threadIdx.x;
    int l = t * 8;
    ushort u[8];
    *(uint4*)u = *(const uint4*)(wtT + (size_t)n * LL + l);
    float4 s0 = *(const float4*)(shift + l);
    float4 s1 = *(const float4*)(shift + l + 4);
    float p = bf2f(u[0]) * s0.x + bf2f(u[1]) * s0.y + bf2f(u[2]) * s0.z +
              bf2f(u[3]) * s0.w + bf2f(u[4]) * s1.x + bf2f(u[5]) * s1.y +
              bf2f(u[6]) * s1.z + bf2f(u[7]) * s1.w;
    #pragma unroll
    for (int o = 1; o <= 32; o <<= 1) p += __shfl_xor(p, o);
    __shared__ float red[4];
    if ((t & 63) == 0) red[t >> 6] = p;
    __syncthreads();
    if (t == 0) bn2[n] = tb[n] + red[0] + red[1] + red[2] + red[3];
}

// ---------------------------------------------------------------------------
__global__ void cn_split_kernel(const float* __restrict__ ce, ushort* __restrict__ ch,
                                ushort* __restrict__ cl) {
    int k = blockIdx.x, h = threadIdx.x;
    if (k >= KK) {
        ch[(size_t)k * 128 + h] = 0;
        cl[(size_t)k * 128 + h] = 0;
        return;
    }
    __shared__ float sh[128];
    float v = ce[(size_t)k * HH + h];
    sh[h] = v * v;
    __syncthreads();
    for (int o = 64; o >= 1; o >>= 1) {
        if (h < o) sh[h] += sh[h + o];
        __syncthreads();
    }
    float nv = v / (sqrtf(sh[0]) + 1e-8f);
    ushort hh = f2bf(nv);
    ch[(size_t)k * 128 + h] = hh;
    cl[(size_t)k * 128 + h] = f2bf(nv - bf2f(hh));
}

// Qp bf16 [128][128] (rows >= 64 zero), qb f32 [128]
__global__ void qprime_kernel(const float* __restrict__ Q, const float* __restrict__ wk_w,
                              const float* __restrict__ wk_b, ushort* __restrict__ qpb,
                              float* __restrict__ qbp) {
    int k = blockIdx.x;
    int hp = threadIdx.x;
    if (k >= KK) {
        qpb[(size_t)k * HH + hp] = 0;
        if (hp == 0) qbp[k] = 0.f;
        return;
    }
    __shared__ float qrow[128];
    __shared__ float red[128];
    qrow[hp] = Q[(size_t)k * HH + hp];
    __syncthreads();
    float s = 0.f;
    for (int h = 0; h < HH; ++h) s = fmaf(qrow[h], wk_w[(size_t)hp * HH + h], s);
    const float rs = 0.088388347648318447f;
    qpb[(size_t)k * HH + hp] = f2bf(s * rs);
    red[hp] = qrow[hp] * wk_b[hp];
    __syncthreads();
    for (int o = 64; o >= 1; o >>= 1) {
        if (hp < o) red[hp] += red[hp + o];
        __syncthreads();
    }
    if (hp == 0) qbp[k] = red[0] * rs;
}

// ---------------------------------------------------------------------------
__global__ __launch_bounds__(256)
void pmask_kernel(const float* __restrict__ sp, const float* __restrict__ rn,
                  const float* __restrict__ bern, unsigned char* __restrict__ Mt,
                  float* __restrict__ ppart) {
    int b = blockIdx.y;
    int l0 = blockIdx.x * 32;
    int tid = threadIdx.x;
    int wv = tid >> 6, lane = tid & 63;
    __shared__ float Msh[64][33];
    __shared__ float psum[4][64];
    float pa = 0.f;
    for (int tt = 0; tt < 8; ++tt) {
        int l = l0 + wv * 8 + tt;
        size_t tok = (size_t)b * LL + l;
        float s = sp[tok * 64 + lane] * rn[tok];
        float mx = s;
        #pragma unroll
        for (int o = 32; o >= 1; o >>= 1) mx = fmaxf(mx, __shfl_xor(mx, o));
        float ev = expf(s - mx);
        float sm = ev;
        #pragma unroll
        for (int o = 32; o >= 1; o >>= 1) sm += __shfl_xor(sm, o);
        float p = ev / sm;
        pa += p;
        Msh[lane][wv * 8 + tt] = (bern[tok * KK + lane] < p) ? 1.f : 0.f;
    }
    psum[wv][lane] = pa;
    __syncthreads();
    for (int q = tid; q < 64 * 32; q += 256) {
        int k = q >> 5, j = q & 31;
        Mt[((size_t)b * KK + k) * LL + l0 + j] = (unsigned char)Msh[k][j];
    }
    if (tid < 64)
        ppart[((size_t)b * (LL / 32) + blockIdx.x) * KK + tid] =
            psum[0][tid] + psum[1][tid] + psum[2][tid] + psum[3][tid];
}

__global__ void pmean_final_kernel(const float* __restrict__ part, float* __restrict__ pm) {
    int b = blockIdx.x, k = threadIdx.x;
    float s = 0.f;
    for (int i = 0; i < LL / 32; ++i) s += part[((size_t)b * (LL / 32) + i) * KK + k];
    pm[b * KK + k] = s * (1.f / LL);
}

// ---------------------------------------------------------------------------
__global__ __launch_bounds__(256)
void aw_kernel(float* __restrict__ S, const unsigned char* __restrict__ Mt) {
    size_t base = (size_t)blockIdx.x * LL;
    int tid = threadIdx.x;
    float t[8];
    float mx = -1e30f;
    #pragma unroll
    for (int i = 0; i < 8; ++i) {
        int l = tid + i * 256;
        float v = expf(S[base + l]) * (float)Mt[base + l];
        t[i] = v;
        mx = fmaxf(mx, v);
    }
    __shared__ float shA[4];
    __shared__ float shB[4];
    #pragma unroll
    for (int o = 32; o >= 1; o >>= 1) mx = fmaxf(mx, __shfl_xor(mx, o));
    if ((tid & 63) == 0) shA[tid >> 6] = mx;
    __syncthreads();
    mx = fmaxf(fmaxf(shA[0], shA[1]), fmaxf(shA[2], shA[3]));
    float e[8];
    float sum = 0.f;
    #pragma unroll
    for (int i = 0; i < 8; ++i) { e[i] = expf(t[i] - mx); sum += e[i]; }
    #pragma unroll
    for (int o = 32; o >= 1; o >>= 1) sum += __shfl_xor(sum, o);
    if ((tid & 63) == 0) shB[tid >> 6] = sum;
    __syncthreads();
    sum = (shB[0] + shB[1]) + (shB[2] + shB[3]);
    float inv = 1.f / sum;
    #pragma unroll
    for (int i = 0; i < 8; ++i) S[base + tid + i * 256] = e[i] * inv;
}

// ---------------------------------------------------------------------------
__global__ __launch_bounds__(256)
void awh_part_kernel(const float* __restrict__ AWs, const float* __restrict__ hmat,
                     float* __restrict__ part) {
    __shared__ float AT[32][64];
    __shared__ float VT[32][128];
    int b = blockIdx.y, sp = blockIdx.x;
    int tid = threadIdx.x;
    int tx = tid & 15, ty = tid >> 4;
    float acc[4][8] = {};
    const float* Ab = AWs + (size_t)b * KK * LL + sp * 512;
    const float* Vb = hmat + ((size_t)b * LL + sp * 512) * HH;
    for (int lt = 0; lt < 512; lt += 32) {
        __syncthreads();
        #pragma unroll
        for (int it = 0; it < 2; ++it) {
            int q = tid + it * 256;
            int row = q >> 3;
            int lq = (q & 7) << 2;
            float4 v = *(const float4*)(Ab + (size_t)row * LL + lt + lq);
            AT[lq][row] = v.x; AT[lq + 1][row] = v.y;
            AT[lq + 2][row] = v.z; AT[lq + 3][row] = v.w;
        }
        #pragma unroll
        for (int it = 0; it < 4; ++it) {
            int q = tid + it * 256;
            int lr = q >> 5;
            int hc = (q & 31) << 2;
            *(float4*)&VT[lr][hc] = *(const float4*)(Vb + (size_t)(lt + lr) * HH + hc);
        }
        __syncthreads();
        #pragma unroll
        for (int l = 0; l < 32; ++l) {
            float av[4], vv[8];
            *(float4*)&av[0] = *(const float4*)&AT[l][ty * 4];
            *(float4*)&vv[0] = *(const float4*)&VT[l][tx * 4];
            *(float4*)&vv[4] = *(const float4*)&VT[l][64 + tx * 4];
            #pragma unroll
            for (int i = 0; i < 4; ++i)
                #pragma unroll
                for (int j = 0; j < 8; ++j)
                    acc[i][j] = fmaf(av[i], vv[j], acc[i][j]);
        }
    }
    #pragma unroll
    for (int i = 0; i < 4; ++i) {
        int k = ty * 4 + i;
        #pragma unroll
        for (int jj = 0; jj < 8; jj += 4) {
            int h = (jj ? 64 + tx * 4 : tx * 4);
            float o[4];
            #pragma unroll
            for (int j = 0; j < 4; ++j) o[j] = acc[i][jj + j];
            *(float4*)(part + (((size_t)b * 4 + sp) * KK + k) * HH + h) = *(float4*)o;
        }
    }
}

__global__ void awh_reduce_kernel(const float* __restrict__ part, float* __restrict__ awh) {
    int bk = blockIdx.x, h = threadIdx.x;
    int b = bk >> 6, k = bk & 63;
    float s = 0.f;
    #pragma unroll
    for (int sp = 0; sp < 4; ++sp)
        s += part[(((size_t)b * 4 + sp) * KK + k) * HH + h];
    awh[(size_t)bk * HH + h] = s;
}

__global__ void newce_kernel(const float* __restrict__ ao, const float* __restrict__ pm,
                             float* __restrict__ outTail) {
    int k = blockIdx.x, h = threadIdx.x;
    float s = 0.f;
    for (int b = 0; b < BB; ++b)
        s += ao[((size_t)b * KK + k) * HH + h] * pm[b * KK + k];
    outTail[(size_t)k * HH + h] = s * (1.f / BB);
}

// z_out = (in - mean2)*rstd2; also emits per-row sum/sumsq. grid (32, B), block 256
__global__ void revin_apply_kernel(const float* __restrict__ in, float* __restrict__ out,
                                   const float* __restrict__ mu, const float* __restrict__ rs,
                                   float* __restrict__ rsum, float* __restrict__ rsq) {
    int b = blockIdx.y;
    size_t base = (size_t)b * LL * CC + (size_t)blockIdx.x * 8192;
    int c0 = (threadIdx.x * 4) & 127;
    int lane = threadIdx.x & 63;
    float4 m4 = *(const float4*)(mu + b * CC + c0);
    float4 r4 = *(const float4*)(rs + b * CC + c0);
    #pragma unroll
    for (int j = 0; j < 8; ++j) {
        float4 v = *(const float4*)(in + base + threadIdx.x * 4 + j * 1024);
        v.x = (v.x - m4.x) * r4.x; v.y = (v.y - m4.y) * r4.y;
        v.z = (v.z - m4.z) * r4.z; v.w = (v.w - m4.w) * r4.w;
        *(float4*)(out + base + threadIdx.x * 4 + j * 1024) = v;
        float s = v.x + v.y + v.z + v.w;
        float q = v.x * v.x + v.y * v.y + v.z * v.z + v.w * v.w;
        #pragma unroll
        for (int o = 1; o <= 16; o <<= 1) {
            s += __shfl_xor(s, o);
            q += __shfl_xor(q, o);
        }
        if ((lane & 31) == 0) {
            size_t row = (base + (size_t)threadIdx.x * 4 + (size_t)j * 1024) >> 7;
            rsum[row] = s;
            rsq[row] = q;
        }
    }
}

// timestep-BN fold: per l, sc = rv*g, shift = be - mu*sc. grid 8, block 256
__global__ void bnt_final_kernel(const float* __restrict__ rsum, const float* __restrict__ rsq,
                                 const float* __restrict__ g, const float* __restrict__ be,
                                 float* __restrict__ scv, float* __restrict__ shv) {
    int l = blockIdx.x * 256 + threadIdx.x;
    float s = 0.f, q = 0.f;
    for (int b = 0; b < BB; ++b) {
        s += rsum[(size_t)b * LL + l];
        q += rsq[(size_t)b * LL + l];
    }
    float m = s * (1.f / (BB * CC));
    float var = q * (1.f / (BB * CC)) - m * m;
    var = fmaxf(var, 0.f);
    float rv = 1.f / sqrtf(var + EPSf);
    float sc = rv * g[l];
    scv[l] = sc;
    shv[l] = be[l] - m * sc;
}

// ---------------------------------------------------------------------------
// [B,L,C] f32 -> [B,C,L] bf16. v2: 64(l)x32(c) tiles, uint4 coalesced writes.
// ---------------------------------------------------------------------------
template <bool DO_BN>
__global__ __launch_bounds__(256)
void transpose_bn_kernel(const float* __restrict__ in, ushort* __restrict__ out,
                         const float* __restrict__ mu, const float* __restrict__ rv,
                         const float* __restrict__ g, const float* __restrict__ be) {
    __shared__ ushort tile[32][72];   // [c][l] bf16, padded
    int l0 = blockIdx.x * 64, c0 = blockIdx.y * 32, b = blockIdx.z;
    int t = threadIdx.x;
    const float* ib = in + ((size_t)b * LL + l0) * CC + c0;
    #pragma unroll
    for (int it = 0; it < 2; ++it) {
        int idx = t + it * 256;
        int row = idx >> 3;           // 0..63 (l offset)
        int c = (idx & 7) * 4;        // 0..28
        float4 v = *(const float4*)(ib + (size_t)row * CC + c);
        if (DO_BN) {
            int l = l0 + row;
            float sc = rv[l] * g[l];
            float m = mu[l], bb = be[l];
            v.x = (v.x - m) * sc + bb; v.y = (v.y - m) * sc + bb;
            v.z = (v.z - m) * sc + bb; v.w = (v.w - m) * sc + bb;
        }
        tile[c    ][row] = f2bf(v.x);
        tile[c + 1][row] = f2bf(v.y);
        tile[c + 2][row] = f2bf(v.z);
        tile[c + 3][row] = f2bf(v.w);
    }
    __syncthreads();
    int cc = t >> 3, l8 = (t & 7) * 8;
    ushort* ob = out + (size_t)b * CC * LL + (size_t)(c0 + cc) * LL + l0 + l8;
    *(uint4*)ob = *(const uint4*)&tile[cc][l8];
}

// feature-BN two-stage reduce: mid over 16 blocks each; final over 64 mids
__global__ void bnf_mid_kernel(const float* __restrict__ part, float* __restrict__ mid) {
    int gblk = blockIdx.x, t = threadIdx.x;   // grid 64, block 256
    float s = 0.f;
    #pragma unroll
    for (int i = 0; i < 16; ++i)
        s += part[(size_t)(gblk * 16 + i) * 256 + t];
    mid[(size_t)gblk * 256 + t] = s;
}

__global__ void bnf_final_kernel(const float* __restrict__ mid, const float* __restrict__ g,
                                 const float* __restrict__ be, float* __restrict__ mu,
                                 float* __restrict__ sA, float* __restrict__ tA) {
    int c = threadIdx.x;   // block 128
    float s = 0.f, s2 = 0.f;
    #pragma unroll
    for (int i = 0; i < 64; ++i) {
        s += mid[(size_t)i * 256 + c];
        s2 += mid[(size_t)i * 256 + 128 + c];
    }
    float m = s / (float)(BB * LL);
    float var = s2 / (float)(BB * LL) - m * m;
    var = fmaxf(var, 0.f);
    float rvv = 1.f / sqrtf(var + EPSf);
    mu[c] = m;
    sA[c] = rvv * g[c];
    tA[c] = be[c];
}

// ---------------------------------------------------------------------------
extern "C" void kernel_launch(void* const* d_in, const int* in_sizes, int n_in,
                              void* d_out, int out_size, void* d_ws, size_t ws_size,
                              hipStream_t stream) {
    const float* x     = (const float*)d_in[0];
    const float* bern  = (const float*)d_in[1];
    const float* ce    = (const float*)d_in[2];
    const float* wq_w  = (const float*)d_in[3];
    const float* wq_b  = (const float*)d_in[4];
    const float* wk_w  = (const float*)d_in[5];
    const float* wk_b  = (const float*)d_in[6];
    const float* wv_w  = (const float*)d_in[7];
    const float* wv_b  = (const float*)d_in[8];
    const float* cm_w1 = (const float*)d_in[9];
    const float* cm_b1 = (const float*)d_in[10];
    const float* cm_w2 = (const float*)d_in[11];
    const float* cm_b2 = (const float*)d_in[12];
    const float* tm_w1 = (const float*)d_in[13];
    const float* tm_b1 = (const float*)d_in[14];
    const float* tm_w2 = (const float*)d_in[15];
    const float* tm_b2 = (const float*)d_in[16];
    const float* bn_t_g = (const float*)d_in[17];
    const float* bn_t_b = (const float*)d_in[18];
    const float* lin_t_w = (const float*)d_in[19];
    const float* lin_t_b = (const float*)d_in[20];
    const float* bn_f_g = (const float*)d_in[21];
    const float* bn_f_b = (const float*)d_in[22];
    const float* f1_w  = (const float*)d_in[23];
    const float* f1_b  = (const float*)d_in[24];
    const float* f2_w  = (const float*)d_in[25];
    const float* f2_b  = (const float*)d_in[26];
    const float* out_w = (const float*)d_in[27];
    const float* out_b = (const float*)d_in[28];
    (void)in_sizes; (void)n_in; (void)out_size;

    float* y = (float*)d_out;                         // [B,P,C]
    float* ceOut = y + (size_t)BB * PP * CC;          // [K,H]

    float* ws = (float*)d_ws;
    size_t off = 0;
    auto alloc = [&](size_t n) { float* p = ws + off; off += n; return p; };
    float* mean1  = alloc(BB * CC);
    float* rstd1  = alloc(BB * CC);
    float* std1   = alloc(BB * CC);
    float* mean2  = alloc(BB * CC);
    float* rstd2  = alloc(BB * CC);
    float* std2   = alloc(BB * CC);
    float* bnsc   = alloc(LL);
    float* bnsh   = alloc(LL);
    float* bn2    = alloc(LL);
    float* bfpart = alloc(1024 * 256);
    float* bfmid  = alloc(64 * 256);
    float* bfmu   = alloc(CC);
    float* bfs    = alloc(CC);
    float* bft    = alloc(CC);
    float* cxpart = alloc(BB * 8 * 256);                      // colstats-1 partials
    float* cpart2 = alloc(1024 * 256);                        // colstats-2 partials (tm pair)
    float* qbuf   = alloc(KK * HH);
    ushort* qpb   = (ushort*)alloc(128 * 128 / 2);            // Qp bf16 padded
    float* qbp    = alloc(128);
    ushort* cnbh  = (ushort*)alloc(8192);                     // codebook hi bf16 [128][128]
    ushort* cnbl  = (ushort*)alloc(8192);                     // codebook lo
    float* rn     = alloc((size_t)BB * LL);
    float* rsum   = alloc((size_t)BB * LL);                   // per-row z sums
    float* rsq    = alloc((size_t)BB * LL);
    float* ppart  = alloc((size_t)BB * (LL / 32) * KK);
    float* pmean  = alloc(BB * KK);
    float* awhprt = alloc((size_t)BB * 4 * KK * HH);
    float* awh    = alloc((size_t)BB * KK * HH);
    float* aobuf  = alloc((size_t)BB * KK * HH);
    ushort* wsp   = (ushort*)alloc(7 * 2 * 16384 / 2);        // 7 split 128x128 weights
    ushort* wtT   = (ushort*)alloc((size_t)LL * LL / 2);      // lin_t_w^T bf16 [2048][2048]
    ushort* wtTs  = (ushort*)alloc((size_t)LL * LL / 2);      // BN-folded lin_t_w^T bf16
    ushort* owT   = (ushort*)alloc((size_t)384 * LL / 2);     // out_w^T bf16 [384][2048]
    float* S      = alloc((size_t)BB * KK * LL);
    float* buf0   = alloc((size_t)BB * LL * CC);
    float* buf2   = alloc((size_t)BB * LL * CC);
    unsigned char* Mt = (unsigned char*)(ws + off);           // [B,K,L] u8
    ushort* abf = (ushort*)S;       // bf16 [B,C,L] overlay on S (mixer phase)
    ushort* hb  = (ushort*)buf0;    // bf16 h [B,L,H] overlay on buf0 (attn phase)
    (void)ws_size;

    auto whi = [&](int i) { return wsp + (size_t)i * 2 * 16384; };
    auto wlo = [&](int i) { return wsp + (size_t)i * 2 * 16384 + 16384; };

    const int ML = BB * LL;      // 131072
    dim3 tb(32, 8);
    dim3 tgrid(LL / 64, CC / 32, BB);
    dim3 wsg(4, 4);

    // 0) weight prep
    wtrans_kernel<<<dim3(LL / 32, LL / 32), tb, 0, stream>>>(lin_t_w, wtT, LL, LL);
    wtrans_kernel<<<dim3(LL / 32, 12), tb, 0, stream>>>(out_w, owT, LL, PP);
    wsplit_kernel<<<wsg, tb, 0, stream>>>(cm_w1, whi(0), wlo(0));
    wsplit_kernel<<<wsg, tb, 0, stream>>>(cm_w2, whi(1), wlo(1));
    wsplit_kernel<<<wsg, tb, 0, stream>>>(tm_w1, whi(2), wlo(2));
    wsplit_kernel<<<wsg, tb, 0, stream>>>(tm_w2, whi(3), wlo(3));
    wsplit_kernel<<<wsg, tb, 0, stream>>>(f1_w, whi(4), wlo(4));
    wsplit_kernel<<<wsg, tb, 0, stream>>>(f2_w, whi(5), wlo(5));
    wsplit_kernel<<<wsg, tb, 0, stream>>>(wv_w, whi(6), wlo(6));

    // 1) RevIN-1 stats (two-stage)
    colstats_part_kernel<<<dim3(8, BB), 256, 0, stream>>>(x, cxpart);
    colstats_final_kernel<<<dim3(BB), dim3(128), 0, stream>>>(cxpart, mean1, rstd1, std1);
    // 2) h = buf2 (fused split pair) + per-row sumsq -> rsq (for rownorm)
    mfma_sq2_kernel<1, 1, 0, 3, 1, 0><<<dim3(ML / 128), 512, 0, stream>>>(
        x, whi(0), wlo(0), cm_b1, whi(1), wlo(1), cm_b2, buf2, mean1, rstd1, nullptr, CC,
        nullptr, rsq, nullptr);
    rn_final_kernel<<<dim3(ML / 256), 256, 0, stream>>>(rsq, rn);
    // 3) Q, Qp(bf16), qb ; split codebook
    gemm_kernel<<<dim3(1, 1), 256, 0, stream>>>(ce, wq_w, wq_b, qbuf,
        KK, HH, HH, HH, HH, HH);
    qprime_kernel<<<dim3(128), dim3(128), 0, stream>>>(qbuf, wk_w, wk_b, qpb, qbp);
    cn_split_kernel<<<dim3(128), dim3(128), 0, stream>>>(ce, cnbh, cnbl);
    // 4) routing scores via split-precision MFMA (also emits hb = bf16 h)
    mfma_sq_kernel<0, 0, 2><<<dim3(ML / 128), 512, 0, stream>>>(
        buf2, cnbh, cnbl, nullptr, S, nullptr, nullptr, nullptr, 0, hb);
    // 5) softmax/mask/p-mean
    pmask_kernel<<<dim3(LL / 32, BB), 256, 0, stream>>>(S, rn, bern, Mt, ppart);
    pmean_final_kernel<<<dim3(BB), dim3(64), 0, stream>>>(ppart, pmean);
    // 6) attn scores via 8-wave MFMA: S[b][k][l] = Qp.h + qb   (overwrites S, k-major)
    mfma_g8_kernel<3><<<dim3(1024), 512, 0, stream>>>(
        hb, qpb, qbp, S, KK, 128, 0, 1, 1024, nullptr, nullptr);
    // 7) masked double-exp softmax
    aw_kernel<<<dim3(BB * KK), 256, 0, stream>>>(S, Mt);
    // 8) awh -> ao -> cluster update
    awh_part_kernel<<<dim3(4, BB), 256, 0, stream>>>(S, buf2, awhprt);
    awh_reduce_kernel<<<dim3(BB * KK), dim3(128), 0, stream>>>(awhprt, awh);
    mfma_sq_kernel<0, 0, 0><<<dim3((BB * KK) / 128), 512, 0, stream>>>(
        awh, whi(6), wlo(6), wv_b, aobuf, nullptr, nullptr, nullptr, 0, nullptr);
    newce_kernel<<<dim3(KK), dim3(128), 0, stream>>>(aobuf, pmean, ceOut);
    // 9) temporal module (fused split pair): h2 = buf0, emits column-stat partials
    mfma_sq2_kernel<0, 1, 0, 2, 1, 0><<<dim3(ML / 128), 512, 0, stream>>>(
        buf2, whi(2), wlo(2), tm_b1, whi(3), wlo(3), tm_b2, buf0,
        nullptr, nullptr, nullptr, 0, cpart2, nullptr, nullptr);
    // 10) RevIN-2 stats (from fused partials) + apply: z = buf2
    colstats2_final_kernel<<<dim3(BB), dim3(128), 0, stream>>>(cpart2, mean2, rstd2, std2);
    revin_apply_kernel<<<dim3(32, BB), 256, 0, stream>>>(buf0, buf2, mean2, rstd2, rsum, rsq);
    // pre-loop: raw-z transpose (BN-t folded into weights each iteration)
    transpose_bn_kernel<false><<<tgrid, 256, 0, stream>>>(buf2, abf,
        nullptr, nullptr, nullptr, nullptr);
    // 11) 4 mixer blocks
    for (int blkI = 0; blkI < 4; ++blkI) {
        bnt_final_kernel<<<dim3(8), 256, 0, stream>>>(rsum, rsq, bn_t_g, bn_t_b, bnsc, bnsh);
        wtfold_kernel<<<dim3(LL), 256, 0, stream>>>(wtT, bnsc, wtTs);
        tbias_kernel<<<dim3(LL), 256, 0, stream>>>(wtT, bnsh, lin_t_b, bn2);
        mfma_ts5_kernel<<<dim3(1024), 512, 0, stream>>>(
            abf, wtTs, bn2, buf2, 16, 1024, bfpart);
        bnf_mid_kernel<<<dim3(64), 256, 0, stream>>>(bfpart, bfmid);
        bnf_final_kernel<<<dim3(1), dim3(128), 0, stream>>>(bfmid, bn_f_g, bn_f_b, bfmu, bfs, bft);
        mfma_sq2_kernel<2, 2, 0, 1, 0, 1><<<dim3(ML / 128), 512, 0, stream>>>(
            buf2, whi(4), wlo(4), f1_b, whi(5), wlo(5), f2_b, buf2, bfmu, bfs, bft, 0,
            rsum, rsq, abf);
    }
    // 12) head via 8-wave MFMA on abf emitted by last mixer sq2
    mfma_g8_kernel<2><<<dim3(192), 512, 0, stream>>>(
        abf, owT, out_b, y, PP, LL, PP, 3, 192, std2, mean2);
}